// Round 1
// baseline (8506.676 us; speedup 1.0000x reference)
//
#include <hip/hip_runtime.h>
#include <math.h>

// ---- static config (matches reference) ----
#define F 128
#define KRBF 32
#define SHC 16
#define TINTER 3
#define RMAX 5.0f
#define INV_AVG (1.0f/16.0f)
#define GAMMA 40.96f               // (KRBF/RMAX)^2
#define RSQRT_DH 0.17677669529663689f  // 1/sqrt(32)
#define PI_F 3.14159265358979323846f
#define EPB 4                      // edges (waves) per 256-thread block

__device__ __forceinline__ float silu_f(float x) { return x / (1.0f + expf(-x)); }
__device__ __forceinline__ int deg_of(int c) { return (c == 0) ? 0 : (c < 4) ? 1 : (c < 9) ? 2 : 3; }

// ---------------------------------------------------------------------------
// Edge geometry: vec, r, C, Y[16]; scatter ev0 = seg(Y*C)*INV_AVG
// ---------------------------------------------------------------------------
__global__ void edge_geom_kernel(const float* __restrict__ pos,
                                 const int* __restrict__ snd,
                                 const int* __restrict__ rcv,
                                 float* __restrict__ r_out,
                                 float* __restrict__ C_out,
                                 float* __restrict__ Y_out,
                                 float* __restrict__ ev,
                                 int E)
{
    int e = blockIdx.x * blockDim.x + threadIdx.x;
    if (e >= E) return;
    int s = snd[e], rc = rcv[e];
    float vx = pos[rc * 3 + 0] - pos[s * 3 + 0];
    float vy = pos[rc * 3 + 1] - pos[s * 3 + 1];
    float vz = pos[rc * 3 + 2] - pos[s * 3 + 2];
    float r = sqrtf(vx * vx + vy * vy + vz * vz);
    float rinv = 1.0f / fmaxf(r, 1e-9f);
    float x = vx * rinv, y = vy * rinv, z = vz * rinv;
    float x2 = x * x, y2 = y * y, z2 = z * z;
    const float s3 = 1.7320508075688772f, s5 = 2.23606797749979f, s15 = 3.872983346207417f;
    const float s70 = 8.366600265340756f, s105 = 10.246950765959598f;
    const float s42 = 6.48074069840786f, s7 = 2.6457513110645907f;
    float Y[16];
    Y[0] = 1.0f;
    Y[1] = s3 * x; Y[2] = s3 * y; Y[3] = s3 * z;
    Y[4] = s15 * x * y; Y[5] = s15 * y * z; Y[6] = 0.5f * s5 * (3.0f * z2 - 1.0f);
    Y[7] = s15 * x * z; Y[8] = 0.5f * s15 * (x2 - y2);
    Y[9]  = 0.25f * s70 * y * (3.0f * x2 - y2);
    Y[10] = s105 * x * y * z;
    Y[11] = 0.25f * s42 * y * (5.0f * z2 - 1.0f);
    Y[12] = 0.5f * s7 * z * (5.0f * z2 - 3.0f);
    Y[13] = 0.25f * s42 * x * (5.0f * z2 - 1.0f);
    Y[14] = 0.5f * s105 * z * (x2 - y2);
    Y[15] = 0.25f * s70 * x * (x2 - 3.0f * y2);
    float C = (r < RMAX) ? 0.5f * (cosf(PI_F * r / RMAX) + 1.0f) : 0.0f;
    r_out[e] = r; C_out[e] = C;
    float sc = C * INV_AVG;
    #pragma unroll
    for (int c = 0; c < 16; c++) {
        Y_out[e * 16 + c] = Y[c];
        atomicAdd(&ev[rc * 16 + c], Y[c] * sc);
    }
}

// ---------------------------------------------------------------------------
// f = embed[species]
// ---------------------------------------------------------------------------
__global__ void embed_kernel(const int* __restrict__ species,
                             const float* __restrict__ embed,
                             float* __restrict__ f, int N)
{
    int n = blockIdx.x;
    if (n >= N) return;
    int j = threadIdx.x;
    f[n * F + j] = embed[species[n] * F + j];
}

// ---------------------------------------------------------------------------
// out = (accumulate ? out : 0) + A @ W ; A:[N,128], W:[128,128]
// 8 nodes per 128-thread block; A tile in LDS, W coalesced across threads.
// ---------------------------------------------------------------------------
__global__ __launch_bounds__(128) void node_gemm_kernel(const float* __restrict__ A,
                                                        const float* __restrict__ W,
                                                        float* __restrict__ out,
                                                        int N, int accumulate)
{
    __shared__ float sA[8][F];
    int n0 = blockIdx.x * 8;
    int j = threadIdx.x;
    #pragma unroll
    for (int i = 0; i < 8; i++) {
        int n = n0 + i;
        sA[i][j] = (n < N) ? A[(size_t)n * F + j] : 0.0f;
    }
    __syncthreads();
    float acc[8] = {0, 0, 0, 0, 0, 0, 0, 0};
    for (int i = 0; i < F; i++) {
        float wv = W[i * F + j];
        #pragma unroll
        for (int nn = 0; nn < 8; nn++) acc[nn] += sA[nn][i] * wv;
    }
    #pragma unroll
    for (int nn = 0; nn < 8; nn++) {
        int n = n0 + nn;
        if (n < N) {
            size_t idx = (size_t)n * F + j;
            out[idx] = accumulate ? (out[idx] + acc[nn]) : acc[nn];
        }
    }
}

// ---------------------------------------------------------------------------
// Fused per-edge pass. One wave (64 lanes) per edge; lane handles feature
// elements {lane, lane+64}. mode 0: invariant attention -> scatter agg[N,128].
// mode 1: geometric attention -> scatter dEv[N,16].
// Recomputes the edge filter w = silu(R@Wrbf1+b)@Wrbf2 + dd@Wdeg both times
// (round 0: avoids storing w [E,128] = 245 MB).
// ---------------------------------------------------------------------------
__global__ __launch_bounds__(256) void edge_pass_kernel(
    const int* __restrict__ snd, const int* __restrict__ rcv,
    const float* __restrict__ rbuf, const float* __restrict__ Cbuf,
    const float* __restrict__ Ybuf, const float* __restrict__ ev,
    const float* __restrict__ qbuf, const float* __restrict__ kbuf,
    const float* __restrict__ vbuf,
    const float* __restrict__ Wrbf1, const float* __restrict__ brbf1,
    const float* __restrict__ Wrbf2, const float* __restrict__ Wdeg,
    float* __restrict__ outbuf, int E, int mode)
{
    int wave = threadIdx.x >> 6;
    int lane = threadIdx.x & 63;
    int e = blockIdx.x * EPB + wave;
    bool active = (e < E);
    __shared__ float sR[EPB][KRBF];
    __shared__ float sH[EPB][F];
    __shared__ float sDD[EPB][4];
    __shared__ float sA2[EPB][4];

    int s = 0, rc = 0; float rr = 0.0f, cc = 0.0f;
    if (active) { s = snd[e]; rc = rcv[e]; rr = rbuf[e]; cc = Cbuf[e]; }

    if (active && lane < KRBF) {
        float mu = lane * (RMAX / (KRBF - 1));
        float d = rr - mu;
        sR[wave][lane] = expf(-GAMMA * d * d);
    }
    if (lane < 4) sDD[wave][lane] = 0.0f;
    __syncthreads();

    if (active && lane < 16) {
        float p = ev[s * 16 + lane] * ev[rc * 16 + lane];
        atomicAdd(&sDD[wave][deg_of(lane)], p);
    }
    if (active) {
        float h0 = brbf1[lane], h1 = brbf1[lane + 64];
        #pragma unroll
        for (int kk = 0; kk < KRBF; kk++) {
            float rv = sR[wave][kk];
            h0 += rv * Wrbf1[kk * F + lane];
            h1 += rv * Wrbf1[kk * F + lane + 64];
        }
        sH[wave][lane] = silu_f(h0);
        sH[wave][lane + 64] = silu_f(h1);
    }
    __syncthreads();

    if (active) {
        float w0 = 0.0f, w1 = 0.0f;
        for (int i = 0; i < F; i++) {
            float hv = sH[wave][i];
            w0 += hv * Wrbf2[i * F + lane];
            w1 += hv * Wrbf2[i * F + lane + 64];
        }
        #pragma unroll
        for (int l = 0; l < 4; l++) {
            float dv = sDD[wave][l];
            w0 += dv * Wdeg[l * F + lane];
            w1 += dv * Wdeg[l * F + lane + 64];
        }
        float q0 = qbuf[(size_t)rc * F + lane], q1 = qbuf[(size_t)rc * F + lane + 64];
        float k0 = kbuf[(size_t)s * F + lane],  k1 = kbuf[(size_t)s * F + lane + 64];
        float p0 = q0 * w0 * k0, p1 = q1 * w1 * k1;
        #pragma unroll
        for (int off = 1; off < 32; off <<= 1) {
            p0 += __shfl_xor(p0, off, 64);
            p1 += __shfl_xor(p1, off, 64);
        }
        float scale = cc * RSQRT_DH * INV_AVG;
        p0 *= scale; p1 *= scale;
        if (mode == 0) {
            float v0 = vbuf[(size_t)s * F + lane], v1 = vbuf[(size_t)s * F + lane + 64];
            atomicAdd(&outbuf[(size_t)rc * F + lane], p0 * v0);
            atomicAdd(&outbuf[(size_t)rc * F + lane + 64], p1 * v1);
        } else {
            if ((lane & 31) == 0) {
                int hh = lane >> 5;
                sA2[wave][hh] = p0;      // degrees 0,1
                sA2[wave][hh + 2] = p1;  // degrees 2,3
            }
        }
    }
    if (mode == 1) {
        __syncthreads();
        if (active && lane < 16) {
            atomicAdd(&outbuf[rc * 16 + lane], sA2[wave][deg_of(lane)] * Ybuf[e * 16 + lane]);
        }
    }
}

// ---------------------------------------------------------------------------
// Exchange block: ev += dEv; ev_inv = deg_reduce(ev*ev); h=[f,ev_inv];
// yb = silu(h@Wex1+b1)@Wex2+b2; f += yb[:128]; ev *= (1 + deg_expand(yb[128:]))
// ---------------------------------------------------------------------------
__global__ __launch_bounds__(128) void exchange_kernel(
    float* __restrict__ f, float* __restrict__ ev, const float* __restrict__ dEv,
    const float* __restrict__ Wex1, const float* __restrict__ bex1,
    const float* __restrict__ Wex2, const float* __restrict__ bex2, int N)
{
    int n = blockIdx.x;
    if (n >= N) return;
    int j = threadIdx.x;
    __shared__ float sh[F + 4];
    __shared__ float shid[F];
    __shared__ float sev[16];
    __shared__ float syb[4];
    if (j < 16) sev[j] = ev[n * 16 + j] + dEv[n * 16 + j];
    sh[j] = f[(size_t)n * F + j];
    __syncthreads();
    if (j < 4) {
        int c0 = (j == 0) ? 0 : (j == 1) ? 1 : (j == 2) ? 4 : 9;
        int c1 = (j == 0) ? 1 : (j == 1) ? 4 : (j == 2) ? 9 : 16;
        float acc = 0.0f;
        for (int c = c0; c < c1; c++) acc += sev[c] * sev[c];
        sh[F + j] = acc;
    }
    __syncthreads();
    float acc = bex1[j];
    for (int i = 0; i < F + 4; i++) acc += sh[i] * Wex1[i * F + j];
    shid[j] = silu_f(acc);
    __syncthreads();
    float yb = bex2[j];
    for (int i = 0; i < F; i++) yb += shid[i] * Wex2[i * (F + 4) + j];
    if (j < 4) {
        float yb2 = bex2[F + j];
        for (int i = 0; i < F; i++) yb2 += shid[i] * Wex2[i * (F + 4) + F + j];
        syb[j] = yb2;
    }
    f[(size_t)n * F + j] = sh[j] + yb;
    __syncthreads();
    if (j < 16) ev[n * 16 + j] = sev[j] * (1.0f + syb[deg_of(j)]);
}

// ---------------------------------------------------------------------------
// node_e = silu(f@Wo1+bo1)@Wo2+bo2; energy[batch[n]] += node_e
// ---------------------------------------------------------------------------
__global__ __launch_bounds__(128) void readout_kernel(
    const float* __restrict__ f, const int* __restrict__ batch,
    const float* __restrict__ Wo1, const float* __restrict__ bo1,
    const float* __restrict__ Wo2, const float* __restrict__ bo2,
    float* __restrict__ energy, int N)
{
    int n = blockIdx.x;
    if (n >= N) return;
    int j = threadIdx.x;
    __shared__ float sf[F];
    __shared__ float sred[F];
    sf[j] = f[(size_t)n * F + j];
    __syncthreads();
    float acc = bo1[j];
    for (int i = 0; i < F; i++) acc += sf[i] * Wo1[i * F + j];
    sred[j] = silu_f(acc) * Wo2[j];
    __syncthreads();
    for (int st = 64; st > 0; st >>= 1) {
        if (j < st) sred[j] += sred[j + st];
        __syncthreads();
    }
    if (j == 0) atomicAdd(&energy[batch[n]], sred[0] + bo2[0]);
}

// ---------------------------------------------------------------------------
extern "C" void kernel_launch(void* const* d_in, const int* in_sizes, int n_in,
                              void* d_out, int out_size, void* d_ws, size_t ws_size,
                              hipStream_t stream)
{
    const float* positions = (const float*)d_in[0];
    const int*   species   = (const int*)d_in[1];
    const int*   senders   = (const int*)d_in[2];
    const int*   receivers = (const int*)d_in[3];
    const int*   batch     = (const int*)d_in[4];
    const float* embed     = (const float*)d_in[5];
    const float* Wq    = (const float*)d_in[6];
    const float* Wk    = (const float*)d_in[7];
    const float* Wv    = (const float*)d_in[8];
    const float* Wo    = (const float*)d_in[9];
    const float* Wrbf1 = (const float*)d_in[10];
    const float* brbf1 = (const float*)d_in[11];
    const float* Wrbf2 = (const float*)d_in[12];
    const float* Wdeg  = (const float*)d_in[13];
    const float* Wq2   = (const float*)d_in[14];
    const float* Wk2   = (const float*)d_in[15];
    const float* Wex1  = (const float*)d_in[16];
    const float* bex1  = (const float*)d_in[17];
    const float* Wex2  = (const float*)d_in[18];
    const float* bex2  = (const float*)d_in[19];
    const float* Wo1   = (const float*)d_in[20];
    const float* bo1   = (const float*)d_in[21];
    const float* Wo2   = (const float*)d_in[22];
    const float* bo2   = (const float*)d_in[23];

    int N = in_sizes[0] / 3;
    int E = in_sizes[2];

    // workspace layout (fp32): ~115 MB total
    float* ws   = (float*)d_ws;
    float* Ybuf = ws;  ws += (size_t)E * 16;
    float* rbuf = ws;  ws += (size_t)E;
    float* Cbuf = ws;  ws += (size_t)E;
    float* f    = ws;  ws += (size_t)N * F;
    float* evb  = ws;  ws += (size_t)N * 16;
    float* dEv  = ws;  ws += (size_t)N * 16;
    float* q    = ws;  ws += (size_t)N * F;
    float* k    = ws;  ws += (size_t)N * F;
    float* v    = ws;  ws += (size_t)N * F;
    float* agg  = ws;  ws += (size_t)N * F;

    hipMemsetAsync(evb, 0, (size_t)N * 16 * sizeof(float), stream);
    edge_geom_kernel<<<(E + 255) / 256, 256, 0, stream>>>(positions, senders, receivers,
                                                          rbuf, Cbuf, Ybuf, evb, E);
    embed_kernel<<<N, F, 0, stream>>>(species, embed, f, N);

    int ngb = (N + 7) / 8;
    int egb = (E + EPB - 1) / EPB;
    for (int t = 0; t < TINTER; t++) {
        size_t tFF = (size_t)t * F * F;
        node_gemm_kernel<<<ngb, F, 0, stream>>>(f, Wq + tFF, q, N, 0);
        node_gemm_kernel<<<ngb, F, 0, stream>>>(f, Wk + tFF, k, N, 0);
        node_gemm_kernel<<<ngb, F, 0, stream>>>(f, Wv + tFF, v, N, 0);
        hipMemsetAsync(agg, 0, (size_t)N * F * sizeof(float), stream);
        edge_pass_kernel<<<egb, 256, 0, stream>>>(senders, receivers, rbuf, Cbuf, Ybuf, evb,
            q, k, v,
            Wrbf1 + (size_t)t * KRBF * F, brbf1 + (size_t)t * F,
            Wrbf2 + tFF, Wdeg + (size_t)t * 4 * F, agg, E, 0);
        node_gemm_kernel<<<ngb, F, 0, stream>>>(agg, Wo + tFF, f, N, 1);
        node_gemm_kernel<<<ngb, F, 0, stream>>>(f, Wq2 + tFF, q, N, 0);
        node_gemm_kernel<<<ngb, F, 0, stream>>>(f, Wk2 + tFF, k, N, 0);
        hipMemsetAsync(dEv, 0, (size_t)N * 16 * sizeof(float), stream);
        edge_pass_kernel<<<egb, 256, 0, stream>>>(senders, receivers, rbuf, Cbuf, Ybuf, evb,
            q, k, nullptr,
            Wrbf1 + (size_t)t * KRBF * F, brbf1 + (size_t)t * F,
            Wrbf2 + tFF, Wdeg + (size_t)t * 4 * F, dEv, E, 1);
        exchange_kernel<<<N, F, 0, stream>>>(f, evb, dEv,
            Wex1 + (size_t)t * (F + 4) * F, bex1 + (size_t)t * F,
            Wex2 + (size_t)t * F * (F + 4), bex2 + (size_t)t * (F + 4), N);
    }
    hipMemsetAsync(d_out, 0, (size_t)out_size * sizeof(float), stream);
    readout_kernel<<<N, F, 0, stream>>>(f, batch, Wo1, bo1, Wo2, bo2, (float*)d_out, N);
}

// Round 2
// 3091.261 us; speedup vs baseline: 2.7518x; 2.7518x over previous
//
#include <hip/hip_runtime.h>
#include <math.h>

// ---- static config (matches reference) ----
#define F 128
#define KRBF 32
#define SHC 16
#define TINTER 3
#define RMAX 5.0f
#define INV_AVG (1.0f/16.0f)
#define GAMMA 40.96f               // (KRBF/RMAX)^2
#define RSQRT_DH 0.17677669529663689f  // 1/sqrt(32)
#define PI_F 3.14159265358979323846f
#define EPB 4                      // edges (waves) per 256-thread block
#define TAB_N 2048                 // w(r) interpolation table entries over [0, RMAX]

__device__ __forceinline__ float silu_f(float x) { return x / (1.0f + expf(-x)); }
__device__ __forceinline__ int deg_of(int c) { return (c == 0) ? 0 : (c < 4) ? 1 : (c < 9) ? 2 : 3; }

// ---------------------------------------------------------------------------
// Edge geometry: vec, r, C, Y[16]; scatter ev0 = seg(Y*C)*INV_AVG
// ---------------------------------------------------------------------------
__global__ void edge_geom_kernel(const float* __restrict__ pos,
                                 const int* __restrict__ snd,
                                 const int* __restrict__ rcv,
                                 float* __restrict__ r_out,
                                 float* __restrict__ C_out,
                                 float* __restrict__ Y_out,
                                 float* __restrict__ ev,
                                 int E)
{
    int e = blockIdx.x * blockDim.x + threadIdx.x;
    if (e >= E) return;
    int s = snd[e], rc = rcv[e];
    float vx = pos[rc * 3 + 0] - pos[s * 3 + 0];
    float vy = pos[rc * 3 + 1] - pos[s * 3 + 1];
    float vz = pos[rc * 3 + 2] - pos[s * 3 + 2];
    float r = sqrtf(vx * vx + vy * vy + vz * vz);
    float rinv = 1.0f / fmaxf(r, 1e-9f);
    float x = vx * rinv, y = vy * rinv, z = vz * rinv;
    float x2 = x * x, y2 = y * y, z2 = z * z;
    const float s3 = 1.7320508075688772f, s5 = 2.23606797749979f, s15 = 3.872983346207417f;
    const float s70 = 8.366600265340756f, s105 = 10.246950765959598f;
    const float s42 = 6.48074069840786f, s7 = 2.6457513110645907f;
    float Y[16];
    Y[0] = 1.0f;
    Y[1] = s3 * x; Y[2] = s3 * y; Y[3] = s3 * z;
    Y[4] = s15 * x * y; Y[5] = s15 * y * z; Y[6] = 0.5f * s5 * (3.0f * z2 - 1.0f);
    Y[7] = s15 * x * z; Y[8] = 0.5f * s15 * (x2 - y2);
    Y[9]  = 0.25f * s70 * y * (3.0f * x2 - y2);
    Y[10] = s105 * x * y * z;
    Y[11] = 0.25f * s42 * y * (5.0f * z2 - 1.0f);
    Y[12] = 0.5f * s7 * z * (5.0f * z2 - 3.0f);
    Y[13] = 0.25f * s42 * x * (5.0f * z2 - 1.0f);
    Y[14] = 0.5f * s105 * z * (x2 - y2);
    Y[15] = 0.25f * s70 * x * (x2 - 3.0f * y2);
    float C = (r < RMAX) ? 0.5f * (cosf(PI_F * r / RMAX) + 1.0f) : 0.0f;
    r_out[e] = r; C_out[e] = C;
    float sc = C * INV_AVG;
    #pragma unroll
    for (int c = 0; c < 16; c++) {
        Y_out[e * 16 + c] = Y[c];
        atomicAdd(&ev[rc * 16 + c], Y[c] * sc);
    }
}

// ---------------------------------------------------------------------------
// f = embed[species]
// ---------------------------------------------------------------------------
__global__ void embed_kernel(const int* __restrict__ species,
                             const float* __restrict__ embed,
                             float* __restrict__ f, int N)
{
    int n = blockIdx.x;
    if (n >= N) return;
    int j = threadIdx.x;
    f[n * F + j] = embed[species[n] * F + j];
}

// ---------------------------------------------------------------------------
// Build w(r) table: tab[t][i][:] = silu(R(r_i)@Wrbf1[t]+brbf1[t]) @ Wrbf2[t]
// r_i = i * RMAX/(TAB_N-1). One wave per entry.
// ---------------------------------------------------------------------------
__global__ __launch_bounds__(256) void build_table_kernel(
    const float* __restrict__ Wrbf1_all, const float* __restrict__ brbf1_all,
    const float* __restrict__ Wrbf2_all, float* __restrict__ tab)
{
    int wave = threadIdx.x >> 6;
    int lane = threadIdx.x & 63;
    int idx = blockIdx.x * 4 + wave;
    int t = blockIdx.y;
    const float* W1 = Wrbf1_all + (size_t)t * KRBF * F;
    const float* b1 = brbf1_all + (size_t)t * F;
    const float* W2 = Wrbf2_all + (size_t)t * F * F;
    float r = idx * (RMAX / (TAB_N - 1));
    __shared__ float sR[4][KRBF];
    __shared__ float sH[4][F];
    if (lane < KRBF) {
        float mu = lane * (RMAX / (KRBF - 1));
        float d = r - mu;
        sR[wave][lane] = expf(-GAMMA * d * d);
    }
    __syncthreads();
    float h0 = b1[lane], h1 = b1[lane + 64];
    #pragma unroll
    for (int kk = 0; kk < KRBF; kk++) {
        float rv = sR[wave][kk];
        h0 += rv * W1[kk * F + lane];
        h1 += rv * W1[kk * F + lane + 64];
    }
    sH[wave][lane] = silu_f(h0);
    sH[wave][lane + 64] = silu_f(h1);
    __syncthreads();
    float w0 = 0.0f, w1 = 0.0f;
    for (int i = 0; i < F; i++) {
        float hv = sH[wave][i];
        w0 += hv * W2[i * F + lane];
        w1 += hv * W2[i * F + lane + 64];
    }
    size_t base = ((size_t)t * TAB_N + idx) * F;
    tab[base + lane] = w0;
    tab[base + lane + 64] = w1;
}

// ---------------------------------------------------------------------------
// out = (accumulate ? out : 0) + A @ W ; A:[N,128], W:[128,128]
// 8 nodes per 128-thread block; A tile in LDS (float4 broadcasts), W coalesced.
// ---------------------------------------------------------------------------
__global__ __launch_bounds__(128) void node_gemm_kernel(const float* __restrict__ A,
                                                        const float* __restrict__ W,
                                                        float* __restrict__ out,
                                                        int N, int accumulate)
{
    __shared__ float sA[8][F];
    int n0 = blockIdx.x * 8;
    int j = threadIdx.x;
    #pragma unroll
    for (int i = 0; i < 8; i++) {
        int n = n0 + i;
        sA[i][j] = (n < N) ? A[(size_t)n * F + j] : 0.0f;
    }
    __syncthreads();
    float acc[8] = {0, 0, 0, 0, 0, 0, 0, 0};
    for (int i = 0; i < F; i += 4) {
        float wv0 = W[(i + 0) * F + j];
        float wv1 = W[(i + 1) * F + j];
        float wv2 = W[(i + 2) * F + j];
        float wv3 = W[(i + 3) * F + j];
        #pragma unroll
        for (int nn = 0; nn < 8; nn++) {
            float4 a = *(const float4*)&sA[nn][i];   // ds_read_b128 broadcast
            acc[nn] += a.x * wv0 + a.y * wv1 + a.z * wv2 + a.w * wv3;
        }
    }
    #pragma unroll
    for (int nn = 0; nn < 8; nn++) {
        int n = n0 + nn;
        if (n < N) {
            size_t idx = (size_t)n * F + j;
            out[idx] = accumulate ? (out[idx] + acc[nn]) : acc[nn];
        }
    }
}

// ---------------------------------------------------------------------------
// Fused per-edge pass with table-interpolated filter.
// One wave per edge; lane handles features {lane, lane+64}.
// mode 0: invariant attention -> scatter agg[N,128].
// mode 1: geometric attention -> scatter dEv[N,16].
// w = lerp(tab, r) + dd @ Wdeg (Wdeg staged in LDS).
// ---------------------------------------------------------------------------
__global__ __launch_bounds__(256) void edge_pass_kernel(
    const int* __restrict__ snd, const int* __restrict__ rcv,
    const float* __restrict__ rbuf, const float* __restrict__ Cbuf,
    const float* __restrict__ Ybuf, const float* __restrict__ ev,
    const float* __restrict__ qbuf, const float* __restrict__ kbuf,
    const float* __restrict__ vbuf,
    const float* __restrict__ tab_t, const float* __restrict__ Wdeg_t,
    float* __restrict__ outbuf, int E, int mode)
{
    __shared__ float sWdeg[4 * F];
    __shared__ float sDD[EPB][4];
    __shared__ float sA2[EPB][4];
    for (int i = threadIdx.x; i < 4 * F; i += 256) sWdeg[i] = Wdeg_t[i];

    int wave = threadIdx.x >> 6;
    int lane = threadIdx.x & 63;
    int e = blockIdx.x * EPB + wave;
    bool active = (e < E);

    int s = 0, rc = 0; float rr = 0.0f, cc = 0.0f;
    if (active) { s = snd[e]; rc = rcv[e]; rr = rbuf[e]; cc = Cbuf[e]; }

    if (lane < 4) sDD[wave][lane] = 0.0f;
    __syncthreads();
    if (active && lane < 16) {
        float p = ev[s * 16 + lane] * ev[rc * 16 + lane];
        atomicAdd(&sDD[wave][deg_of(lane)], p);
    }
    __syncthreads();

    if (active) {
        // table lerp (r >= RMAX extrapolates; result is multiplied by C=0 there)
        float u = rr * ((float)(TAB_N - 1) / RMAX);
        int i0 = (int)u;
        i0 = (i0 > TAB_N - 2) ? (TAB_N - 2) : i0;
        float fr = u - (float)i0;
        const float* t0 = tab_t + (size_t)i0 * F;
        float a0 = t0[lane],     a1 = t0[lane + 64];
        float b0 = t0[F + lane], b1 = t0[F + lane + 64];
        float w0 = a0 + fr * (b0 - a0);
        float w1 = a1 + fr * (b1 - a1);
        #pragma unroll
        for (int l = 0; l < 4; l++) {
            float dv = sDD[wave][l];
            w0 += dv * sWdeg[l * F + lane];
            w1 += dv * sWdeg[l * F + lane + 64];
        }
        float q0 = qbuf[(size_t)rc * F + lane], q1 = qbuf[(size_t)rc * F + lane + 64];
        float k0 = kbuf[(size_t)s * F + lane],  k1 = kbuf[(size_t)s * F + lane + 64];
        float p0 = q0 * w0 * k0, p1 = q1 * w1 * k1;
        #pragma unroll
        for (int off = 1; off < 32; off <<= 1) {
            p0 += __shfl_xor(p0, off, 64);
            p1 += __shfl_xor(p1, off, 64);
        }
        float scale = cc * RSQRT_DH * INV_AVG;
        p0 *= scale; p1 *= scale;
        if (mode == 0) {
            float v0 = vbuf[(size_t)s * F + lane], v1 = vbuf[(size_t)s * F + lane + 64];
            atomicAdd(&outbuf[(size_t)rc * F + lane], p0 * v0);
            atomicAdd(&outbuf[(size_t)rc * F + lane + 64], p1 * v1);
        } else {
            if ((lane & 31) == 0) {
                int hh = lane >> 5;
                sA2[wave][hh] = p0;      // degrees 0,1
                sA2[wave][hh + 2] = p1;  // degrees 2,3
            }
        }
    }
    if (mode == 1) {
        __syncthreads();
        if (active && lane < 16) {
            atomicAdd(&outbuf[rc * 16 + lane], sA2[wave][deg_of(lane)] * Ybuf[e * 16 + lane]);
        }
    }
}

// ---------------------------------------------------------------------------
// Exchange block: ev += dEv; ev_inv = deg_reduce(ev*ev); h=[f,ev_inv];
// yb = silu(h@Wex1+b1)@Wex2+b2; f += yb[:128]; ev *= (1 + deg_expand(yb[128:]))
// ---------------------------------------------------------------------------
__global__ __launch_bounds__(128) void exchange_kernel(
    float* __restrict__ f, float* __restrict__ ev, const float* __restrict__ dEv,
    const float* __restrict__ Wex1, const float* __restrict__ bex1,
    const float* __restrict__ Wex2, const float* __restrict__ bex2, int N)
{
    int n = blockIdx.x;
    if (n >= N) return;
    int j = threadIdx.x;
    __shared__ float sh[F + 4];
    __shared__ float shid[F];
    __shared__ float sev[16];
    __shared__ float syb[4];
    if (j < 16) sev[j] = ev[n * 16 + j] + dEv[n * 16 + j];
    sh[j] = f[(size_t)n * F + j];
    __syncthreads();
    if (j < 4) {
        int c0 = (j == 0) ? 0 : (j == 1) ? 1 : (j == 2) ? 4 : 9;
        int c1 = (j == 0) ? 1 : (j == 1) ? 4 : (j == 2) ? 9 : 16;
        float acc = 0.0f;
        for (int c = c0; c < c1; c++) acc += sev[c] * sev[c];
        sh[F + j] = acc;
    }
    __syncthreads();
    float acc = bex1[j];
    for (int i = 0; i < F + 4; i++) acc += sh[i] * Wex1[i * F + j];
    shid[j] = silu_f(acc);
    __syncthreads();
    float yb = bex2[j];
    for (int i = 0; i < F; i++) yb += shid[i] * Wex2[i * (F + 4) + j];
    if (j < 4) {
        float yb2 = bex2[F + j];
        for (int i = 0; i < F; i++) yb2 += shid[i] * Wex2[i * (F + 4) + F + j];
        syb[j] = yb2;
    }
    f[(size_t)n * F + j] = sh[j] + yb;
    __syncthreads();
    if (j < 16) ev[n * 16 + j] = sev[j] * (1.0f + syb[deg_of(j)]);
}

// ---------------------------------------------------------------------------
// node_e = silu(f@Wo1+bo1)@Wo2+bo2; energy[batch[n]] += node_e
// ---------------------------------------------------------------------------
__global__ __launch_bounds__(128) void readout_kernel(
    const float* __restrict__ f, const int* __restrict__ batch,
    const float* __restrict__ Wo1, const float* __restrict__ bo1,
    const float* __restrict__ Wo2, const float* __restrict__ bo2,
    float* __restrict__ energy, int N)
{
    int n = blockIdx.x;
    if (n >= N) return;
    int j = threadIdx.x;
    __shared__ float sf[F];
    __shared__ float sred[F];
    sf[j] = f[(size_t)n * F + j];
    __syncthreads();
    float acc = bo1[j];
    for (int i = 0; i < F; i++) acc += sf[i] * Wo1[i * F + j];
    sred[j] = silu_f(acc) * Wo2[j];
    __syncthreads();
    for (int st = 64; st > 0; st >>= 1) {
        if (j < st) sred[j] += sred[j + st];
        __syncthreads();
    }
    if (j == 0) atomicAdd(&energy[batch[n]], sred[0] + bo2[0]);
}

// ---------------------------------------------------------------------------
extern "C" void kernel_launch(void* const* d_in, const int* in_sizes, int n_in,
                              void* d_out, int out_size, void* d_ws, size_t ws_size,
                              hipStream_t stream)
{
    const float* positions = (const float*)d_in[0];
    const int*   species   = (const int*)d_in[1];
    const int*   senders   = (const int*)d_in[2];
    const int*   receivers = (const int*)d_in[3];
    const int*   batch     = (const int*)d_in[4];
    const float* embed     = (const float*)d_in[5];
    const float* Wq    = (const float*)d_in[6];
    const float* Wk    = (const float*)d_in[7];
    const float* Wv    = (const float*)d_in[8];
    const float* Wo    = (const float*)d_in[9];
    const float* Wrbf1 = (const float*)d_in[10];
    const float* brbf1 = (const float*)d_in[11];
    const float* Wrbf2 = (const float*)d_in[12];
    const float* Wdeg  = (const float*)d_in[13];
    const float* Wq2   = (const float*)d_in[14];
    const float* Wk2   = (const float*)d_in[15];
    const float* Wex1  = (const float*)d_in[16];
    const float* bex1  = (const float*)d_in[17];
    const float* Wex2  = (const float*)d_in[18];
    const float* bex2  = (const float*)d_in[19];
    const float* Wo1   = (const float*)d_in[20];
    const float* bo1   = (const float*)d_in[21];
    const float* Wo2   = (const float*)d_in[22];
    const float* bo2   = (const float*)d_in[23];

    int N = in_sizes[0] / 3;
    int E = in_sizes[2];

    // workspace layout (fp32): ~118 MB total
    float* ws   = (float*)d_ws;
    float* Ybuf = ws;  ws += (size_t)E * 16;
    float* rbuf = ws;  ws += (size_t)E;
    float* Cbuf = ws;  ws += (size_t)E;
    float* f    = ws;  ws += (size_t)N * F;
    float* evb  = ws;  ws += (size_t)N * 16;
    float* dEv  = ws;  ws += (size_t)N * 16;
    float* q    = ws;  ws += (size_t)N * F;
    float* k    = ws;  ws += (size_t)N * F;
    float* v    = ws;  ws += (size_t)N * F;
    float* agg  = ws;  ws += (size_t)N * F;
    float* tab  = ws;  ws += (size_t)TINTER * TAB_N * F;   // 3 MB

    hipMemsetAsync(evb, 0, (size_t)N * 16 * sizeof(float), stream);
    build_table_kernel<<<dim3(TAB_N / 4, TINTER), 256, 0, stream>>>(Wrbf1, brbf1, Wrbf2, tab);
    edge_geom_kernel<<<(E + 255) / 256, 256, 0, stream>>>(positions, senders, receivers,
                                                          rbuf, Cbuf, Ybuf, evb, E);
    embed_kernel<<<N, F, 0, stream>>>(species, embed, f, N);

    int ngb = (N + 7) / 8;
    int egb = (E + EPB - 1) / EPB;
    for (int t = 0; t < TINTER; t++) {
        size_t tFF = (size_t)t * F * F;
        const float* tab_t  = tab + (size_t)t * TAB_N * F;
        const float* Wdeg_t = Wdeg + (size_t)t * 4 * F;
        node_gemm_kernel<<<ngb, F, 0, stream>>>(f, Wq + tFF, q, N, 0);
        node_gemm_kernel<<<ngb, F, 0, stream>>>(f, Wk + tFF, k, N, 0);
        node_gemm_kernel<<<ngb, F, 0, stream>>>(f, Wv + tFF, v, N, 0);
        hipMemsetAsync(agg, 0, (size_t)N * F * sizeof(float), stream);
        edge_pass_kernel<<<egb, 256, 0, stream>>>(senders, receivers, rbuf, Cbuf, Ybuf, evb,
            q, k, v, tab_t, Wdeg_t, agg, E, 0);
        node_gemm_kernel<<<ngb, F, 0, stream>>>(agg, Wo + tFF, f, N, 1);
        node_gemm_kernel<<<ngb, F, 0, stream>>>(f, Wq2 + tFF, q, N, 0);
        node_gemm_kernel<<<ngb, F, 0, stream>>>(f, Wk2 + tFF, k, N, 0);
        hipMemsetAsync(dEv, 0, (size_t)N * 16 * sizeof(float), stream);
        edge_pass_kernel<<<egb, 256, 0, stream>>>(senders, receivers, rbuf, Cbuf, Ybuf, evb,
            q, k, nullptr, tab_t, Wdeg_t, dEv, E, 1);
        exchange_kernel<<<N, F, 0, stream>>>(f, evb, dEv,
            Wex1 + (size_t)t * (F + 4) * F, bex1 + (size_t)t * F,
            Wex2 + (size_t)t * F * (F + 4), bex2 + (size_t)t * (F + 4), N);
    }
    hipMemsetAsync(d_out, 0, (size_t)out_size * sizeof(float), stream);
    readout_kernel<<<N, F, 0, stream>>>(f, batch, Wo1, bo1, Wo2, bo2, (float*)d_out, N);
}

// Round 3
// 2591.565 us; speedup vs baseline: 3.2824x; 1.1928x over previous
//
#include <hip/hip_runtime.h>
#include <math.h>

// ---- static config (matches reference) ----
#define F 128
#define KRBF 32
#define TINTER 3
#define RMAX 5.0f
#define INV_AVG (1.0f/16.0f)
#define GAMMA 40.96f               // (KRBF/RMAX)^2
#define RSQRT_DH 0.17677669529663689f  // 1/sqrt(32)
#define PI_F 3.14159265358979323846f
#define TAB_N 2048                 // w(r) interpolation table entries over [0, RMAX]

__device__ __forceinline__ float silu_f(float x) { return x / (1.0f + expf(-x)); }
__device__ __forceinline__ int deg_of(int c) { return (c == 0) ? 0 : (c < 4) ? 1 : (c < 9) ? 2 : 3; }

// ---------------------------------------------------------------------------
// CSR build: count -> scan -> scatter (receivers fixed for whole launch)
// ---------------------------------------------------------------------------
__global__ void count_kernel(const int* __restrict__ rcv, int* __restrict__ cnt, int E)
{
    int e = blockIdx.x * blockDim.x + threadIdx.x;
    if (e < E) atomicAdd(&cnt[rcv[e]], 1);
}

__global__ __launch_bounds__(1024) void scan_kernel(const int* __restrict__ cnt,
                                                    int* __restrict__ off,
                                                    int* __restrict__ cur, int N)
{
    __shared__ int part[1024];
    int t = threadIdx.x;
    int chunk = (N + 1023) / 1024;
    int lo = t * chunk, hi = min(lo + chunk, N);
    int sum = 0;
    for (int i = lo; i < hi; i++) sum += cnt[i];
    part[t] = sum;
    __syncthreads();
    for (int st = 1; st < 1024; st <<= 1) {
        int v = (t >= st) ? part[t - st] : 0;
        __syncthreads();
        part[t] += v;
        __syncthreads();
    }
    int run = (t == 0) ? 0 : part[t - 1];
    for (int i = lo; i < hi; i++) {
        off[i] = run; cur[i] = run;
        run += cnt[i];
    }
    if (t == 1023) off[N] = part[1023];
}

__global__ void scatter_kernel(const int* __restrict__ rcv, int* __restrict__ cur,
                               int* __restrict__ elist, int E)
{
    int e = blockIdx.x * blockDim.x + threadIdx.x;
    if (e < E) {
        int p = atomicAdd(&cur[rcv[e]], 1);
        elist[p] = e;
    }
}

// ---------------------------------------------------------------------------
// Edge geometry: r, C, Y[16] (pure streaming, no scatter)
// ---------------------------------------------------------------------------
__global__ void edge_geom_kernel(const float* __restrict__ pos,
                                 const int* __restrict__ snd,
                                 const int* __restrict__ rcv,
                                 float* __restrict__ r_out,
                                 float* __restrict__ C_out,
                                 float* __restrict__ Y_out,
                                 int E)
{
    int e = blockIdx.x * blockDim.x + threadIdx.x;
    if (e >= E) return;
    int s = snd[e], rc = rcv[e];
    float vx = pos[rc * 3 + 0] - pos[s * 3 + 0];
    float vy = pos[rc * 3 + 1] - pos[s * 3 + 1];
    float vz = pos[rc * 3 + 2] - pos[s * 3 + 2];
    float r = sqrtf(vx * vx + vy * vy + vz * vz);
    float rinv = 1.0f / fmaxf(r, 1e-9f);
    float x = vx * rinv, y = vy * rinv, z = vz * rinv;
    float x2 = x * x, y2 = y * y, z2 = z * z;
    const float s3 = 1.7320508075688772f, s5 = 2.23606797749979f, s15 = 3.872983346207417f;
    const float s70 = 8.366600265340756f, s105 = 10.246950765959598f;
    const float s42 = 6.48074069840786f, s7 = 2.6457513110645907f;
    float Y[16];
    Y[0] = 1.0f;
    Y[1] = s3 * x; Y[2] = s3 * y; Y[3] = s3 * z;
    Y[4] = s15 * x * y; Y[5] = s15 * y * z; Y[6] = 0.5f * s5 * (3.0f * z2 - 1.0f);
    Y[7] = s15 * x * z; Y[8] = 0.5f * s15 * (x2 - y2);
    Y[9]  = 0.25f * s70 * y * (3.0f * x2 - y2);
    Y[10] = s105 * x * y * z;
    Y[11] = 0.25f * s42 * y * (5.0f * z2 - 1.0f);
    Y[12] = 0.5f * s7 * z * (5.0f * z2 - 3.0f);
    Y[13] = 0.25f * s42 * x * (5.0f * z2 - 1.0f);
    Y[14] = 0.5f * s105 * z * (x2 - y2);
    Y[15] = 0.25f * s70 * x * (x2 - 3.0f * y2);
    float C = (r < RMAX) ? 0.5f * (cosf(PI_F * r / RMAX) + 1.0f) : 0.0f;
    r_out[e] = r; C_out[e] = C;
    #pragma unroll
    for (int c = 0; c < 16; c++) Y_out[e * 16 + c] = Y[c];
}

// ---------------------------------------------------------------------------
// ev0[n] = sum_{e in CSR(n)} Y[e]*C[e] * INV_AVG  (16 lanes per node)
// ---------------------------------------------------------------------------
__global__ void ev0_kernel(const int* __restrict__ elist, const int* __restrict__ off,
                           const float* __restrict__ Ybuf, const float* __restrict__ Cbuf,
                           float* __restrict__ ev, int N)
{
    int n = blockIdx.x * 16 + (threadIdx.x >> 4);
    int c = threadIdx.x & 15;
    if (n >= N) return;
    float acc = 0.0f;
    int e0 = off[n], e1 = off[n + 1];
    for (int ei = e0; ei < e1; ei++) {
        int e = elist[ei];
        acc += Ybuf[e * 16 + c] * Cbuf[e];
    }
    ev[n * 16 + c] = acc * INV_AVG;
}

// ---------------------------------------------------------------------------
// f = embed[species]
// ---------------------------------------------------------------------------
__global__ void embed_kernel(const int* __restrict__ species,
                             const float* __restrict__ embed,
                             float* __restrict__ f, int N)
{
    int n = blockIdx.x;
    if (n >= N) return;
    int j = threadIdx.x;
    f[n * F + j] = embed[species[n] * F + j];
}

// ---------------------------------------------------------------------------
// Build w(r) table: tab[t][i][:] = silu(R(r_i)@Wrbf1[t]+brbf1[t]) @ Wrbf2[t]
// ---------------------------------------------------------------------------
__global__ __launch_bounds__(256) void build_table_kernel(
    const float* __restrict__ Wrbf1_all, const float* __restrict__ brbf1_all,
    const float* __restrict__ Wrbf2_all, float* __restrict__ tab)
{
    int wave = threadIdx.x >> 6;
    int lane = threadIdx.x & 63;
    int idx = blockIdx.x * 4 + wave;
    int t = blockIdx.y;
    const float* W1 = Wrbf1_all + (size_t)t * KRBF * F;
    const float* b1 = brbf1_all + (size_t)t * F;
    const float* W2 = Wrbf2_all + (size_t)t * F * F;
    float r = idx * (RMAX / (TAB_N - 1));
    __shared__ float sR[4][KRBF];
    __shared__ float sH[4][F];
    if (lane < KRBF) {
        float mu = lane * (RMAX / (KRBF - 1));
        float d = r - mu;
        sR[wave][lane] = expf(-GAMMA * d * d);
    }
    __syncthreads();
    float h0 = b1[lane], h1 = b1[lane + 64];
    #pragma unroll
    for (int kk = 0; kk < KRBF; kk++) {
        float rv = sR[wave][kk];
        h0 += rv * W1[kk * F + lane];
        h1 += rv * W1[kk * F + lane + 64];
    }
    sH[wave][lane] = silu_f(h0);
    sH[wave][lane + 64] = silu_f(h1);
    __syncthreads();
    float w0 = 0.0f, w1 = 0.0f;
    for (int i = 0; i < F; i++) {
        float hv = sH[wave][i];
        w0 += hv * W2[i * F + lane];
        w1 += hv * W2[i * F + lane + 64];
    }
    size_t base = ((size_t)t * TAB_N + idx) * F;
    tab[base + lane] = w0;
    tab[base + lane + 64] = w1;
}

// ---------------------------------------------------------------------------
// Multi-output node GEMM: out[m] = A @ W[m], m < nw (nw<=3). A:[N,128] in LDS.
// 8 nodes per 128-thread block. accumulate applies to out[0] only.
// ---------------------------------------------------------------------------
__global__ __launch_bounds__(128) void node_gemm_kernel(
    const float* __restrict__ A,
    const float* __restrict__ W0, const float* __restrict__ W1f, const float* __restrict__ W2f,
    float* __restrict__ out0, float* __restrict__ out1, float* __restrict__ out2,
    int N, int nw, int accumulate)
{
    __shared__ float sA[8][F];
    int n0 = blockIdx.x * 8;
    int j = threadIdx.x;
    #pragma unroll
    for (int i = 0; i < 8; i++) {
        int n = n0 + i;
        sA[i][j] = (n < N) ? A[(size_t)n * F + j] : 0.0f;
    }
    __syncthreads();
    for (int m = 0; m < nw; m++) {
        const float* W = (m == 0) ? W0 : (m == 1) ? W1f : W2f;
        float* out = (m == 0) ? out0 : (m == 1) ? out1 : out2;
        float acc[8] = {0, 0, 0, 0, 0, 0, 0, 0};
        for (int i = 0; i < F; i += 4) {
            float wv0 = W[(i + 0) * F + j];
            float wv1 = W[(i + 1) * F + j];
            float wv2 = W[(i + 2) * F + j];
            float wv3 = W[(i + 3) * F + j];
            #pragma unroll
            for (int nn = 0; nn < 8; nn++) {
                float4 a = *(const float4*)&sA[nn][i];
                acc[nn] += a.x * wv0 + a.y * wv1 + a.z * wv2 + a.w * wv3;
            }
        }
        #pragma unroll
        for (int nn = 0; nn < 8; nn++) {
            int n = n0 + nn;
            if (n < N) {
                size_t idx = (size_t)n * F + j;
                out[idx] = (accumulate && m == 0) ? (out[idx] + acc[nn]) : acc[nn];
            }
        }
    }
}

// ---------------------------------------------------------------------------
// Node-centric fused edge pass. One wave per receiver node; loops its CSR
// edge list. Lane handles features {lane, lane+64}. No atomics.
// mode 0: invariant attention -> agg[n,128] (written once)
// mode 1: geometric attention -> dEv[n,16]  (written once)
// ---------------------------------------------------------------------------
__global__ __launch_bounds__(256) void edge_pass_node_kernel(
    const int* __restrict__ elist, const int* __restrict__ off,
    const int* __restrict__ snd,
    const float* __restrict__ rbuf, const float* __restrict__ Cbuf,
    const float* __restrict__ Ybuf, const float* __restrict__ ev,
    const float* __restrict__ qbuf, const float* __restrict__ kbuf,
    const float* __restrict__ vbuf,
    const float* __restrict__ tab_t, const float* __restrict__ Wdeg_t,
    float* __restrict__ outbuf, int N, int mode)
{
    __shared__ float sWdeg[4 * F];
    for (int i = threadIdx.x; i < 4 * F; i += 256) sWdeg[i] = Wdeg_t[i];
    __syncthreads();

    int wave = threadIdx.x >> 6;
    int lane = threadIdx.x & 63;
    int n = blockIdx.x * 4 + wave;
    if (n >= N) return;

    int e0 = off[n], e1 = off[n + 1];
    float q0 = qbuf[(size_t)n * F + lane], q1 = qbuf[(size_t)n * F + lane + 64];
    float evr = (lane < 16) ? ev[n * 16 + lane] : 0.0f;
    float acc0 = 0.0f, acc1 = 0.0f;   // mode 0 accumulators
    float devacc = 0.0f;              // mode 1 accumulator (lane<16)

    for (int ei = e0; ei < e1; ei++) {
        int e = elist[ei];
        int s = snd[e];
        float rr = rbuf[e], cc = Cbuf[e];
        // degree-wise EV contraction dd = deg_reduce(ev[s]*ev[n])
        float pc = (lane < 16) ? ev[s * 16 + lane] * evr : 0.0f;
        float dd0 = __shfl(pc, 0);
        float dd1 = __shfl(pc, 1) + __shfl(pc, 2) + __shfl(pc, 3);
        float dd2 = __shfl(pc, 4) + __shfl(pc, 5) + __shfl(pc, 6) + __shfl(pc, 7) + __shfl(pc, 8);
        float dd3 = __shfl(pc, 9) + __shfl(pc, 10) + __shfl(pc, 11) + __shfl(pc, 12)
                  + __shfl(pc, 13) + __shfl(pc, 14) + __shfl(pc, 15);
        // table lerp
        float u = rr * ((float)(TAB_N - 1) / RMAX);
        int i0 = (int)u;
        i0 = (i0 > TAB_N - 2) ? (TAB_N - 2) : i0;
        float fr = u - (float)i0;
        const float* t0 = tab_t + (size_t)i0 * F;
        float a0 = t0[lane],     a1 = t0[lane + 64];
        float b0 = t0[F + lane], b1 = t0[F + lane + 64];
        float w0 = a0 + fr * (b0 - a0)
                 + dd0 * sWdeg[lane] + dd1 * sWdeg[F + lane]
                 + dd2 * sWdeg[2 * F + lane] + dd3 * sWdeg[3 * F + lane];
        float w1 = a1 + fr * (b1 - a1)
                 + dd0 * sWdeg[lane + 64] + dd1 * sWdeg[F + lane + 64]
                 + dd2 * sWdeg[2 * F + lane + 64] + dd3 * sWdeg[3 * F + lane + 64];
        float k0 = kbuf[(size_t)s * F + lane], k1 = kbuf[(size_t)s * F + lane + 64];
        float p0 = q0 * w0 * k0, p1 = q1 * w1 * k1;
        #pragma unroll
        for (int o = 1; o < 32; o <<= 1) {
            p0 += __shfl_xor(p0, o, 64);
            p1 += __shfl_xor(p1, o, 64);
        }
        float scale = cc * RSQRT_DH * INV_AVG;
        p0 *= scale; p1 *= scale;
        if (mode == 0) {
            acc0 += p0 * vbuf[(size_t)s * F + lane];
            acc1 += p1 * vbuf[(size_t)s * F + lane + 64];
        } else {
            // heads<->degrees: a2[0]=p0@lane0, a2[1]=p0@lane32, a2[2]=p1@lane0, a2[3]=p1@lane32
            float a20 = __shfl(p0, 0), a21 = __shfl(p0, 32);
            float a22 = __shfl(p1, 0), a23 = __shfl(p1, 32);
            if (lane < 16) {
                float a2d = (lane == 0) ? a20 : (lane < 4) ? a21 : (lane < 9) ? a22 : a23;
                devacc += a2d * Ybuf[e * 16 + lane];
            }
        }
    }
    if (mode == 0) {
        outbuf[(size_t)n * F + lane] = acc0;
        outbuf[(size_t)n * F + lane + 64] = acc1;
    } else if (lane < 16) {
        outbuf[n * 16 + lane] = devacc;
    }
}

// ---------------------------------------------------------------------------
// Exchange block: ev += dEv; ev_inv = deg_reduce(ev*ev); h=[f,ev_inv];
// yb = silu(h@Wex1+b1)@Wex2+b2; f += yb[:128]; ev *= (1 + deg_expand(yb[128:]))
// ---------------------------------------------------------------------------
__global__ __launch_bounds__(128) void exchange_kernel(
    float* __restrict__ f, float* __restrict__ ev, const float* __restrict__ dEv,
    const float* __restrict__ Wex1, const float* __restrict__ bex1,
    const float* __restrict__ Wex2, const float* __restrict__ bex2, int N)
{
    int n = blockIdx.x;
    if (n >= N) return;
    int j = threadIdx.x;
    __shared__ float sh[F + 4];
    __shared__ float shid[F];
    __shared__ float sev[16];
    __shared__ float syb[4];
    if (j < 16) sev[j] = ev[n * 16 + j] + dEv[n * 16 + j];
    sh[j] = f[(size_t)n * F + j];
    __syncthreads();
    if (j < 4) {
        int c0 = (j == 0) ? 0 : (j == 1) ? 1 : (j == 2) ? 4 : 9;
        int c1 = (j == 0) ? 1 : (j == 1) ? 4 : (j == 2) ? 9 : 16;
        float acc = 0.0f;
        for (int c = c0; c < c1; c++) acc += sev[c] * sev[c];
        sh[F + j] = acc;
    }
    __syncthreads();
    float acc = bex1[j];
    for (int i = 0; i < F + 4; i++) acc += sh[i] * Wex1[i * F + j];
    shid[j] = silu_f(acc);
    __syncthreads();
    float yb = bex2[j];
    for (int i = 0; i < F; i++) yb += shid[i] * Wex2[i * (F + 4) + j];
    if (j < 4) {
        float yb2 = bex2[F + j];
        for (int i = 0; i < F; i++) yb2 += shid[i] * Wex2[i * (F + 4) + F + j];
        syb[j] = yb2;
    }
    f[(size_t)n * F + j] = sh[j] + yb;
    __syncthreads();
    if (j < 16) ev[n * 16 + j] = sev[j] * (1.0f + syb[deg_of(j)]);
}

// ---------------------------------------------------------------------------
// node_e = silu(f@Wo1+bo1)@Wo2+bo2; energy[batch[n]] += node_e
// ---------------------------------------------------------------------------
__global__ __launch_bounds__(128) void readout_kernel(
    const float* __restrict__ f, const int* __restrict__ batch,
    const float* __restrict__ Wo1, const float* __restrict__ bo1,
    const float* __restrict__ Wo2, const float* __restrict__ bo2,
    float* __restrict__ energy, int N)
{
    int n = blockIdx.x;
    if (n >= N) return;
    int j = threadIdx.x;
    __shared__ float sf[F];
    __shared__ float sred[F];
    sf[j] = f[(size_t)n * F + j];
    __syncthreads();
    float acc = bo1[j];
    for (int i = 0; i < F; i++) acc += sf[i] * Wo1[i * F + j];
    sred[j] = silu_f(acc) * Wo2[j];
    __syncthreads();
    for (int st = 64; st > 0; st >>= 1) {
        if (j < st) sred[j] += sred[j + st];
        __syncthreads();
    }
    if (j == 0) atomicAdd(&energy[batch[n]], sred[0] + bo2[0]);
}

// ---------------------------------------------------------------------------
extern "C" void kernel_launch(void* const* d_in, const int* in_sizes, int n_in,
                              void* d_out, int out_size, void* d_ws, size_t ws_size,
                              hipStream_t stream)
{
    const float* positions = (const float*)d_in[0];
    const int*   species   = (const int*)d_in[1];
    const int*   senders   = (const int*)d_in[2];
    const int*   receivers = (const int*)d_in[3];
    const int*   batch     = (const int*)d_in[4];
    const float* embed     = (const float*)d_in[5];
    const float* Wq    = (const float*)d_in[6];
    const float* Wk    = (const float*)d_in[7];
    const float* Wv    = (const float*)d_in[8];
    const float* Wo    = (const float*)d_in[9];
    const float* Wrbf1 = (const float*)d_in[10];
    const float* brbf1 = (const float*)d_in[11];
    const float* Wrbf2 = (const float*)d_in[12];
    const float* Wdeg  = (const float*)d_in[13];
    const float* Wq2   = (const float*)d_in[14];
    const float* Wk2   = (const float*)d_in[15];
    const float* Wex1  = (const float*)d_in[16];
    const float* bex1  = (const float*)d_in[17];
    const float* Wex2  = (const float*)d_in[18];
    const float* bex2  = (const float*)d_in[19];
    const float* Wo1   = (const float*)d_in[20];
    const float* bo1   = (const float*)d_in[21];
    const float* Wo2   = (const float*)d_in[22];
    const float* bo2   = (const float*)d_in[23];

    int N = in_sizes[0] / 3;
    int E = in_sizes[2];

    // workspace layout: floats then ints (~125 MB total)
    float* ws   = (float*)d_ws;
    float* Ybuf = ws;  ws += (size_t)E * 16;
    float* rbuf = ws;  ws += (size_t)E;
    float* Cbuf = ws;  ws += (size_t)E;
    float* f    = ws;  ws += (size_t)N * F;
    float* evb  = ws;  ws += (size_t)N * 16;
    float* dEv  = ws;  ws += (size_t)N * 16;
    float* q    = ws;  ws += (size_t)N * F;
    float* k    = ws;  ws += (size_t)N * F;
    float* v    = ws;  ws += (size_t)N * F;
    float* agg  = ws;  ws += (size_t)N * F;
    float* tab  = ws;  ws += (size_t)TINTER * TAB_N * F;   // 3 MB
    int* cnt   = (int*)ws;  ws += N;
    int* off   = (int*)ws;  ws += N + 1;
    int* cur   = (int*)ws;  ws += N;
    int* elist = (int*)ws;  ws += E;

    // ---- CSR build (receivers constant across iterations) ----
    hipMemsetAsync(cnt, 0, (size_t)N * sizeof(int), stream);
    count_kernel<<<(E + 255) / 256, 256, 0, stream>>>(receivers, cnt, E);
    scan_kernel<<<1, 1024, 0, stream>>>(cnt, off, cur, N);
    scatter_kernel<<<(E + 255) / 256, 256, 0, stream>>>(receivers, cur, elist, E);

    build_table_kernel<<<dim3(TAB_N / 4, TINTER), 256, 0, stream>>>(Wrbf1, brbf1, Wrbf2, tab);
    edge_geom_kernel<<<(E + 255) / 256, 256, 0, stream>>>(positions, senders, receivers,
                                                          rbuf, Cbuf, Ybuf, E);
    ev0_kernel<<<(N + 15) / 16, 256, 0, stream>>>(elist, off, Ybuf, Cbuf, evb, N);
    embed_kernel<<<N, F, 0, stream>>>(species, embed, f, N);

    int ngb = (N + 7) / 8;
    int npb = (N + 3) / 4;
    for (int t = 0; t < TINTER; t++) {
        size_t tFF = (size_t)t * F * F;
        const float* tab_t  = tab + (size_t)t * TAB_N * F;
        const float* Wdeg_t = Wdeg + (size_t)t * 4 * F;
        node_gemm_kernel<<<ngb, F, 0, stream>>>(f, Wq + tFF, Wk + tFF, Wv + tFF,
                                                q, k, v, N, 3, 0);
        edge_pass_node_kernel<<<npb, 256, 0, stream>>>(elist, off, senders,
            rbuf, Cbuf, Ybuf, evb, q, k, v, tab_t, Wdeg_t, agg, N, 0);
        node_gemm_kernel<<<ngb, F, 0, stream>>>(agg, Wo + tFF, nullptr, nullptr,
                                                f, nullptr, nullptr, N, 1, 1);
        node_gemm_kernel<<<ngb, F, 0, stream>>>(f, Wq2 + tFF, Wk2 + tFF, nullptr,
                                                q, k, nullptr, N, 2, 0);
        edge_pass_node_kernel<<<npb, 256, 0, stream>>>(elist, off, senders,
            rbuf, Cbuf, Ybuf, evb, q, k, nullptr, tab_t, Wdeg_t, dEv, N, 1);
        exchange_kernel<<<N, F, 0, stream>>>(f, evb, dEv,
            Wex1 + (size_t)t * (F + 4) * F, bex1 + (size_t)t * F,
            Wex2 + (size_t)t * F * (F + 4), bex2 + (size_t)t * (F + 4), N);
    }
    hipMemsetAsync(d_out, 0, (size_t)out_size * sizeof(float), stream);
    readout_kernel<<<N, F, 0, stream>>>(f, batch, Wo1, bo1, Wo2, bo2, (float*)d_out, N);
}

// Round 4
// 2149.675 us; speedup vs baseline: 3.9572x; 1.2056x over previous
//
#include <hip/hip_runtime.h>
#include <math.h>

// ---- static config (matches reference) ----
#define F 128
#define KRBF 32
#define TINTER 3
#define RMAX 5.0f
#define INV_AVG (1.0f/16.0f)
#define GAMMA 40.96f               // (KRBF/RMAX)^2
#define RSQRT_DH 0.17677669529663689f  // 1/sqrt(32)
#define PI_F 3.14159265358979323846f
#define TAB_N 2048                 // w(r) interpolation table entries over [0, RMAX]
#define GNB 16                     // nodes per block in node_gemm
#define XNB 8                      // nodes per block in exchange / readout

__device__ __forceinline__ float silu_f(float x) { return x / (1.0f + expf(-x)); }
__device__ __forceinline__ int deg_of(int c) { return (c == 0) ? 0 : (c < 4) ? 1 : (c < 9) ? 2 : 3; }

// ---------------------------------------------------------------------------
// CSR build: count -> scan -> scatter (receivers fixed for whole launch)
// ---------------------------------------------------------------------------
__global__ void count_kernel(const int* __restrict__ rcv, int* __restrict__ cnt, int E)
{
    int e = blockIdx.x * blockDim.x + threadIdx.x;
    if (e < E) atomicAdd(&cnt[rcv[e]], 1);
}

__global__ __launch_bounds__(1024) void scan_kernel(const int* __restrict__ cnt,
                                                    int* __restrict__ off,
                                                    int* __restrict__ cur, int N)
{
    __shared__ int part[1024];
    int t = threadIdx.x;
    int chunk = (N + 1023) / 1024;
    int lo = t * chunk, hi = min(lo + chunk, N);
    int sum = 0;
    for (int i = lo; i < hi; i++) sum += cnt[i];
    part[t] = sum;
    __syncthreads();
    for (int st = 1; st < 1024; st <<= 1) {
        int v = (t >= st) ? part[t - st] : 0;
        __syncthreads();
        part[t] += v;
        __syncthreads();
    }
    int run = (t == 0) ? 0 : part[t - 1];
    for (int i = lo; i < hi; i++) {
        off[i] = run; cur[i] = run;
        run += cnt[i];
    }
    if (t == 1023) off[N] = part[1023];
}

__global__ void scatter_kernel(const int* __restrict__ rcv, int* __restrict__ cur,
                               int* __restrict__ elist, int E)
{
    int e = blockIdx.x * blockDim.x + threadIdx.x;
    if (e < E) {
        int p = atomicAdd(&cur[rcv[e]], 1);
        elist[p] = e;
    }
}

// ---------------------------------------------------------------------------
// Edge geometry: r, C, Y[16] (pure streaming, no scatter)
// ---------------------------------------------------------------------------
__global__ void edge_geom_kernel(const float* __restrict__ pos,
                                 const int* __restrict__ snd,
                                 const int* __restrict__ rcv,
                                 float* __restrict__ r_out,
                                 float* __restrict__ C_out,
                                 float* __restrict__ Y_out,
                                 int E)
{
    int e = blockIdx.x * blockDim.x + threadIdx.x;
    if (e >= E) return;
    int s = snd[e], rc = rcv[e];
    float vx = pos[rc * 3 + 0] - pos[s * 3 + 0];
    float vy = pos[rc * 3 + 1] - pos[s * 3 + 1];
    float vz = pos[rc * 3 + 2] - pos[s * 3 + 2];
    float r = sqrtf(vx * vx + vy * vy + vz * vz);
    float rinv = 1.0f / fmaxf(r, 1e-9f);
    float x = vx * rinv, y = vy * rinv, z = vz * rinv;
    float x2 = x * x, y2 = y * y, z2 = z * z;
    const float s3 = 1.7320508075688772f, s5 = 2.23606797749979f, s15 = 3.872983346207417f;
    const float s70 = 8.366600265340756f, s105 = 10.246950765959598f;
    const float s42 = 6.48074069840786f, s7 = 2.6457513110645907f;
    float Y[16];
    Y[0] = 1.0f;
    Y[1] = s3 * x; Y[2] = s3 * y; Y[3] = s3 * z;
    Y[4] = s15 * x * y; Y[5] = s15 * y * z; Y[6] = 0.5f * s5 * (3.0f * z2 - 1.0f);
    Y[7] = s15 * x * z; Y[8] = 0.5f * s15 * (x2 - y2);
    Y[9]  = 0.25f * s70 * y * (3.0f * x2 - y2);
    Y[10] = s105 * x * y * z;
    Y[11] = 0.25f * s42 * y * (5.0f * z2 - 1.0f);
    Y[12] = 0.5f * s7 * z * (5.0f * z2 - 3.0f);
    Y[13] = 0.25f * s42 * x * (5.0f * z2 - 1.0f);
    Y[14] = 0.5f * s105 * z * (x2 - y2);
    Y[15] = 0.25f * s70 * x * (x2 - 3.0f * y2);
    float C = (r < RMAX) ? 0.5f * (cosf(PI_F * r / RMAX) + 1.0f) : 0.0f;
    r_out[e] = r; C_out[e] = C;
    #pragma unroll
    for (int c = 0; c < 16; c++) Y_out[e * 16 + c] = Y[c];
}

// ---------------------------------------------------------------------------
// ev0[n] = sum_{e in CSR(n)} Y[e]*C[e] * INV_AVG  (16 lanes per node)
// ---------------------------------------------------------------------------
__global__ void ev0_kernel(const int* __restrict__ elist, const int* __restrict__ off,
                           const float* __restrict__ Ybuf, const float* __restrict__ Cbuf,
                           float* __restrict__ ev, int N)
{
    int n = blockIdx.x * 16 + (threadIdx.x >> 4);
    int c = threadIdx.x & 15;
    if (n >= N) return;
    float acc = 0.0f;
    int e0 = off[n], e1 = off[n + 1];
    for (int ei = e0; ei < e1; ei++) {
        int e = elist[ei];
        acc += Ybuf[e * 16 + c] * Cbuf[e];
    }
    ev[n * 16 + c] = acc * INV_AVG;
}

// ---------------------------------------------------------------------------
// f = embed[species]
// ---------------------------------------------------------------------------
__global__ void embed_kernel(const int* __restrict__ species,
                             const float* __restrict__ embed,
                             float* __restrict__ f, int N)
{
    int n = blockIdx.x;
    if (n >= N) return;
    int j = threadIdx.x;
    f[n * F + j] = embed[species[n] * F + j];
}

// ---------------------------------------------------------------------------
// Build w(r) table: tab[t][i][:] = silu(R(r_i)@Wrbf1[t]+brbf1[t]) @ Wrbf2[t]
// ---------------------------------------------------------------------------
__global__ __launch_bounds__(256) void build_table_kernel(
    const float* __restrict__ Wrbf1_all, const float* __restrict__ brbf1_all,
    const float* __restrict__ Wrbf2_all, float* __restrict__ tab)
{
    int wave = threadIdx.x >> 6;
    int lane = threadIdx.x & 63;
    int idx = blockIdx.x * 4 + wave;
    int t = blockIdx.y;
    const float* W1 = Wrbf1_all + (size_t)t * KRBF * F;
    const float* b1 = brbf1_all + (size_t)t * F;
    const float* W2 = Wrbf2_all + (size_t)t * F * F;
    float r = idx * (RMAX / (TAB_N - 1));
    __shared__ float sR[4][KRBF];
    __shared__ float sH[4][F];
    if (lane < KRBF) {
        float mu = lane * (RMAX / (KRBF - 1));
        float d = r - mu;
        sR[wave][lane] = expf(-GAMMA * d * d);
    }
    __syncthreads();
    float h0 = b1[lane], h1 = b1[lane + 64];
    #pragma unroll
    for (int kk = 0; kk < KRBF; kk++) {
        float rv = sR[wave][kk];
        h0 += rv * W1[kk * F + lane];
        h1 += rv * W1[kk * F + lane + 64];
    }
    sH[wave][lane] = silu_f(h0);
    sH[wave][lane + 64] = silu_f(h1);
    __syncthreads();
    float w0 = 0.0f, w1 = 0.0f;
    for (int i = 0; i < F; i++) {
        float hv = sH[wave][i];
        w0 += hv * W2[i * F + lane];
        w1 += hv * W2[i * F + lane + 64];
    }
    size_t base = ((size_t)t * TAB_N + idx) * F;
    tab[base + lane] = w0;
    tab[base + lane + 64] = w1;
}

// ---------------------------------------------------------------------------
// Multi-output node GEMM: out[m] = A @ W[m], m < nw (nw<=3). A:[N,128] in LDS.
// GNB nodes per 128-thread block. accumulate applies to out[0] only.
// ---------------------------------------------------------------------------
__global__ __launch_bounds__(128) void node_gemm_kernel(
    const float* __restrict__ A,
    const float* __restrict__ W0, const float* __restrict__ W1f, const float* __restrict__ W2f,
    float* __restrict__ out0, float* __restrict__ out1, float* __restrict__ out2,
    int N, int nw, int accumulate)
{
    __shared__ float sA[GNB][F];
    int n0 = blockIdx.x * GNB;
    int j = threadIdx.x;
    #pragma unroll
    for (int i = 0; i < GNB; i++) {
        int n = n0 + i;
        sA[i][j] = (n < N) ? A[(size_t)n * F + j] : 0.0f;
    }
    __syncthreads();
    for (int m = 0; m < nw; m++) {
        const float* W = (m == 0) ? W0 : (m == 1) ? W1f : W2f;
        float* out = (m == 0) ? out0 : (m == 1) ? out1 : out2;
        float acc[GNB];
        #pragma unroll
        for (int nn = 0; nn < GNB; nn++) acc[nn] = 0.0f;
        for (int i = 0; i < F; i += 4) {
            float wv0 = W[(i + 0) * F + j];
            float wv1 = W[(i + 1) * F + j];
            float wv2 = W[(i + 2) * F + j];
            float wv3 = W[(i + 3) * F + j];
            #pragma unroll
            for (int nn = 0; nn < GNB; nn++) {
                float4 a = *(const float4*)&sA[nn][i];
                acc[nn] += a.x * wv0 + a.y * wv1 + a.z * wv2 + a.w * wv3;
            }
        }
        #pragma unroll
        for (int nn = 0; nn < GNB; nn++) {
            int n = n0 + nn;
            if (n < N) {
                size_t idx = (size_t)n * F + j;
                out[idx] = (accumulate && m == 0) ? (out[idx] + acc[nn]) : acc[nn];
            }
        }
    }
}

// ---------------------------------------------------------------------------
// Node-centric fused edge pass. One wave per receiver node; loops its CSR
// edge list. Lane handles features {lane, lane+64}. No atomics.
// mode 0: invariant attention -> agg[n,128] (written once)
// mode 1: geometric attention -> dEv[n,16]  (written once)
// ---------------------------------------------------------------------------
__global__ __launch_bounds__(256) void edge_pass_node_kernel(
    const int* __restrict__ elist, const int* __restrict__ off,
    const int* __restrict__ snd,
    const float* __restrict__ rbuf, const float* __restrict__ Cbuf,
    const float* __restrict__ Ybuf, const float* __restrict__ ev,
    const float* __restrict__ qbuf, const float* __restrict__ kbuf,
    const float* __restrict__ vbuf,
    const float* __restrict__ tab_t, const float* __restrict__ Wdeg_t,
    float* __restrict__ outbuf, int N, int mode)
{
    __shared__ float sWdeg[4 * F];
    for (int i = threadIdx.x; i < 4 * F; i += 256) sWdeg[i] = Wdeg_t[i];
    __syncthreads();

    int wave = threadIdx.x >> 6;
    int lane = threadIdx.x & 63;
    int n = blockIdx.x * 4 + wave;
    if (n >= N) return;

    int e0 = off[n], e1 = off[n + 1];
    float q0 = qbuf[(size_t)n * F + lane], q1 = qbuf[(size_t)n * F + lane + 64];
    float evr = (lane < 16) ? ev[n * 16 + lane] : 0.0f;
    float acc0 = 0.0f, acc1 = 0.0f;   // mode 0 accumulators
    float devacc = 0.0f;              // mode 1 accumulator (lane<16)

    for (int ei = e0; ei < e1; ei++) {
        int e = elist[ei];
        int s = snd[e];
        float rr = rbuf[e], cc = Cbuf[e];
        // degree-wise EV contraction dd = deg_reduce(ev[s]*ev[n])
        float pc = (lane < 16) ? ev[s * 16 + lane] * evr : 0.0f;
        float dd0 = __shfl(pc, 0);
        float dd1 = __shfl(pc, 1) + __shfl(pc, 2) + __shfl(pc, 3);
        float dd2 = __shfl(pc, 4) + __shfl(pc, 5) + __shfl(pc, 6) + __shfl(pc, 7) + __shfl(pc, 8);
        float dd3 = __shfl(pc, 9) + __shfl(pc, 10) + __shfl(pc, 11) + __shfl(pc, 12)
                  + __shfl(pc, 13) + __shfl(pc, 14) + __shfl(pc, 15);
        // table lerp
        float u = rr * ((float)(TAB_N - 1) / RMAX);
        int i0 = (int)u;
        i0 = (i0 > TAB_N - 2) ? (TAB_N - 2) : i0;
        float fr = u - (float)i0;
        const float* t0 = tab_t + (size_t)i0 * F;
        float a0 = t0[lane],     a1 = t0[lane + 64];
        float b0 = t0[F + lane], b1 = t0[F + lane + 64];
        float w0 = a0 + fr * (b0 - a0)
                 + dd0 * sWdeg[lane] + dd1 * sWdeg[F + lane]
                 + dd2 * sWdeg[2 * F + lane] + dd3 * sWdeg[3 * F + lane];
        float w1 = a1 + fr * (b1 - a1)
                 + dd0 * sWdeg[lane + 64] + dd1 * sWdeg[F + lane + 64]
                 + dd2 * sWdeg[2 * F + lane + 64] + dd3 * sWdeg[3 * F + lane + 64];
        float k0 = kbuf[(size_t)s * F + lane], k1 = kbuf[(size_t)s * F + lane + 64];
        float p0 = q0 * w0 * k0, p1 = q1 * w1 * k1;
        #pragma unroll
        for (int o = 1; o < 32; o <<= 1) {
            p0 += __shfl_xor(p0, o, 64);
            p1 += __shfl_xor(p1, o, 64);
        }
        float scale = cc * RSQRT_DH * INV_AVG;
        p0 *= scale; p1 *= scale;
        if (mode == 0) {
            acc0 += p0 * vbuf[(size_t)s * F + lane];
            acc1 += p1 * vbuf[(size_t)s * F + lane + 64];
        } else {
            // heads<->degrees: a2[0]=p0@lane0, a2[1]=p0@lane32, a2[2]=p1@lane0, a2[3]=p1@lane32
            float a20 = __shfl(p0, 0), a21 = __shfl(p0, 32);
            float a22 = __shfl(p1, 0), a23 = __shfl(p1, 32);
            if (lane < 16) {
                float a2d = (lane == 0) ? a20 : (lane < 4) ? a21 : (lane < 9) ? a22 : a23;
                devacc += a2d * Ybuf[e * 16 + lane];
            }
        }
    }
    if (mode == 0) {
        outbuf[(size_t)n * F + lane] = acc0;
        outbuf[(size_t)n * F + lane + 64] = acc1;
    } else if (lane < 16) {
        outbuf[n * 16 + lane] = devacc;
    }
}

// ---------------------------------------------------------------------------
// Exchange block, XNB nodes per 128-thread block:
// ev += dEv; ev_inv = deg_reduce(ev*ev); h=[f,ev_inv];
// yb = silu(h@Wex1+b1)@Wex2+b2; f += yb[:128]; ev *= (1 + deg_expand(yb[128:]))
// ---------------------------------------------------------------------------
__global__ __launch_bounds__(128) void exchange_kernel(
    float* __restrict__ f, float* __restrict__ ev, const float* __restrict__ dEv,
    const float* __restrict__ Wex1, const float* __restrict__ bex1,
    const float* __restrict__ Wex2, const float* __restrict__ bex2, int N)
{
    __shared__ float sIn[XNB][F + 4];
    __shared__ float sHid[XNB][F];
    __shared__ float sev[XNB][16];
    __shared__ float syb[XNB][4];
    int n0 = blockIdx.x * XNB;
    int j = threadIdx.x;
    #pragma unroll
    for (int nn = 0; nn < XNB; nn++) {
        int n = n0 + nn;
        sIn[nn][j] = (n < N) ? f[(size_t)n * F + j] : 0.0f;
    }
    {
        int nn = j >> 4, c = j & 15;
        int n = n0 + nn;
        sev[nn][c] = (n < N) ? (ev[n * 16 + c] + dEv[n * 16 + c]) : 0.0f;
    }
    __syncthreads();
    if (j < XNB * 4) {
        int nn = j >> 2, d = j & 3;
        int c0 = (d == 0) ? 0 : (d == 1) ? 1 : (d == 2) ? 4 : 9;
        int c1 = (d == 0) ? 1 : (d == 1) ? 4 : (d == 2) ? 9 : 16;
        float a = 0.0f;
        for (int c = c0; c < c1; c++) a += sev[nn][c] * sev[nn][c];
        sIn[nn][F + d] = a;
    }
    __syncthreads();
    float acc[XNB];
    #pragma unroll
    for (int nn = 0; nn < XNB; nn++) acc[nn] = bex1[j];
    for (int i = 0; i < F + 4; i++) {
        float w = Wex1[i * F + j];
        #pragma unroll
        for (int nn = 0; nn < XNB; nn++) acc[nn] += sIn[nn][i] * w;
    }
    #pragma unroll
    for (int nn = 0; nn < XNB; nn++) sHid[nn][j] = silu_f(acc[nn]);
    __syncthreads();
    float yb[XNB];
    #pragma unroll
    for (int nn = 0; nn < XNB; nn++) yb[nn] = bex2[j];
    for (int i = 0; i < F; i++) {
        float w = Wex2[i * (F + 4) + j];
        #pragma unroll
        for (int nn = 0; nn < XNB; nn++) yb[nn] += sHid[nn][i] * w;
    }
    if (j < XNB * 4) {
        int nn = j >> 2, d = j & 3;
        float a = bex2[F + d];
        for (int i = 0; i < F; i++) a += sHid[nn][i] * Wex2[i * (F + 4) + F + d];
        syb[nn][d] = a;
    }
    __syncthreads();
    #pragma unroll
    for (int nn = 0; nn < XNB; nn++) {
        int n = n0 + nn;
        if (n < N) f[(size_t)n * F + j] = sIn[nn][j] + yb[nn];
    }
    {
        int nn = j >> 4, c = j & 15;
        int n = n0 + nn;
        if (n < N) ev[n * 16 + c] = sev[nn][c] * (1.0f + syb[nn][deg_of(c)]);
    }
}

// ---------------------------------------------------------------------------
// Readout stage 1: node_e[n] = silu(f@Wo1+bo1)@Wo2 + bo2, XNB nodes/block,
// wave-shuffle reduction (no atomics, no LDS tree).
// ---------------------------------------------------------------------------
__global__ __launch_bounds__(128) void readout_node_kernel(
    const float* __restrict__ f,
    const float* __restrict__ Wo1, const float* __restrict__ bo1,
    const float* __restrict__ Wo2, const float* __restrict__ bo2,
    float* __restrict__ node_e, int N)
{
    __shared__ float sA[XNB][F];
    __shared__ float swave[2][XNB];
    int n0 = blockIdx.x * XNB;
    int j = threadIdx.x;
    #pragma unroll
    for (int nn = 0; nn < XNB; nn++) {
        int n = n0 + nn;
        sA[nn][j] = (n < N) ? f[(size_t)n * F + j] : 0.0f;
    }
    __syncthreads();
    float acc[XNB];
    #pragma unroll
    for (int nn = 0; nn < XNB; nn++) acc[nn] = bo1[j];
    for (int i = 0; i < F; i += 4) {
        float w0 = Wo1[(i + 0) * F + j];
        float w1 = Wo1[(i + 1) * F + j];
        float w2 = Wo1[(i + 2) * F + j];
        float w3 = Wo1[(i + 3) * F + j];
        #pragma unroll
        for (int nn = 0; nn < XNB; nn++) {
            float4 a = *(const float4*)&sA[nn][i];
            acc[nn] += a.x * w0 + a.y * w1 + a.z * w2 + a.w * w3;
        }
    }
    float wo2 = Wo2[j];
    #pragma unroll
    for (int nn = 0; nn < XNB; nn++) {
        float z = silu_f(acc[nn]) * wo2;
        #pragma unroll
        for (int o = 1; o < 64; o <<= 1) z += __shfl_xor(z, o, 64);
        if ((j & 63) == 0) swave[j >> 6][nn] = z;
    }
    __syncthreads();
    if (j < XNB) {
        int n = n0 + j;
        if (n < N) node_e[n] = swave[0][j] + swave[1][j] + bo2[0];
    }
}

// ---------------------------------------------------------------------------
// Readout stage 2: energy[g] = sum_{batch[n]==g} node_e[n]
// Few blocks, per-block LDS accumulators, 64 global atomics per block.
// ---------------------------------------------------------------------------
__global__ __launch_bounds__(256) void energy_reduce_kernel(
    const float* __restrict__ node_e, const int* __restrict__ batch,
    float* __restrict__ energy, int N)
{
    __shared__ float eacc[64];
    if (threadIdx.x < 64) eacc[threadIdx.x] = 0.0f;
    __syncthreads();
    for (int n = blockIdx.x * blockDim.x + threadIdx.x; n < N; n += gridDim.x * blockDim.x)
        atomicAdd(&eacc[batch[n]], node_e[n]);
    __syncthreads();
    if (threadIdx.x < 64) atomicAdd(&energy[threadIdx.x], eacc[threadIdx.x]);
}

// ---------------------------------------------------------------------------
extern "C" void kernel_launch(void* const* d_in, const int* in_sizes, int n_in,
                              void* d_out, int out_size, void* d_ws, size_t ws_size,
                              hipStream_t stream)
{
    const float* positions = (const float*)d_in[0];
    const int*   species   = (const int*)d_in[1];
    const int*   senders   = (const int*)d_in[2];
    const int*   receivers = (const int*)d_in[3];
    const int*   batch     = (const int*)d_in[4];
    const float* embed     = (const float*)d_in[5];
    const float* Wq    = (const float*)d_in[6];
    const float* Wk    = (const float*)d_in[7];
    const float* Wv    = (const float*)d_in[8];
    const float* Wo    = (const float*)d_in[9];
    const float* Wrbf1 = (const float*)d_in[10];
    const float* brbf1 = (const float*)d_in[11];
    const float* Wrbf2 = (const float*)d_in[12];
    const float* Wdeg  = (const float*)d_in[13];
    const float* Wq2   = (const float*)d_in[14];
    const float* Wk2   = (const float*)d_in[15];
    const float* Wex1  = (const float*)d_in[16];
    const float* bex1  = (const float*)d_in[17];
    const float* Wex2  = (const float*)d_in[18];
    const float* bex2  = (const float*)d_in[19];
    const float* Wo1   = (const float*)d_in[20];
    const float* bo1   = (const float*)d_in[21];
    const float* Wo2   = (const float*)d_in[22];
    const float* bo2   = (const float*)d_in[23];

    int N = in_sizes[0] / 3;
    int E = in_sizes[2];

    // workspace layout: floats then ints (~125 MB total)
    float* ws   = (float*)d_ws;
    float* Ybuf = ws;  ws += (size_t)E * 16;
    float* rbuf = ws;  ws += (size_t)E;
    float* Cbuf = ws;  ws += (size_t)E;
    float* f    = ws;  ws += (size_t)N * F;
    float* evb  = ws;  ws += (size_t)N * 16;
    float* dEv  = ws;  ws += (size_t)N * 16;
    float* q    = ws;  ws += (size_t)N * F;
    float* k    = ws;  ws += (size_t)N * F;
    float* v    = ws;  ws += (size_t)N * F;
    float* agg  = ws;  ws += (size_t)N * F;
    float* tab  = ws;  ws += (size_t)TINTER * TAB_N * F;   // 3 MB
    float* node_e = ws; ws += (size_t)N;
    int* cnt   = (int*)ws;  ws += N;
    int* off   = (int*)ws;  ws += N + 1;
    int* cur   = (int*)ws;  ws += N;
    int* elist = (int*)ws;  ws += E;

    // ---- CSR build (receivers constant across iterations) ----
    hipMemsetAsync(cnt, 0, (size_t)N * sizeof(int), stream);
    count_kernel<<<(E + 255) / 256, 256, 0, stream>>>(receivers, cnt, E);
    scan_kernel<<<1, 1024, 0, stream>>>(cnt, off, cur, N);
    scatter_kernel<<<(E + 255) / 256, 256, 0, stream>>>(receivers, cur, elist, E);

    build_table_kernel<<<dim3(TAB_N / 4, TINTER), 256, 0, stream>>>(Wrbf1, brbf1, Wrbf2, tab);
    edge_geom_kernel<<<(E + 255) / 256, 256, 0, stream>>>(positions, senders, receivers,
                                                          rbuf, Cbuf, Ybuf, E);
    ev0_kernel<<<(N + 15) / 16, 256, 0, stream>>>(elist, off, Ybuf, Cbuf, evb, N);
    embed_kernel<<<N, F, 0, stream>>>(species, embed, f, N);

    int ngb = (N + GNB - 1) / GNB;
    int npb = (N + 3) / 4;
    int nxb = (N + XNB - 1) / XNB;
    for (int t = 0; t < TINTER; t++) {
        size_t tFF = (size_t)t * F * F;
        const float* tab_t  = tab + (size_t)t * TAB_N * F;
        const float* Wdeg_t = Wdeg + (size_t)t * 4 * F;
        node_gemm_kernel<<<ngb, F, 0, stream>>>(f, Wq + tFF, Wk + tFF, Wv + tFF,
                                                q, k, v, N, 3, 0);
        edge_pass_node_kernel<<<npb, 256, 0, stream>>>(elist, off, senders,
            rbuf, Cbuf, Ybuf, evb, q, k, v, tab_t, Wdeg_t, agg, N, 0);
        node_gemm_kernel<<<ngb, F, 0, stream>>>(agg, Wo + tFF, nullptr, nullptr,
                                                f, nullptr, nullptr, N, 1, 1);
        node_gemm_kernel<<<ngb, F, 0, stream>>>(f, Wq2 + tFF, Wk2 + tFF, nullptr,
                                                q, k, nullptr, N, 2, 0);
        edge_pass_node_kernel<<<npb, 256, 0, stream>>>(elist, off, senders,
            rbuf, Cbuf, Ybuf, evb, q, k, nullptr, tab_t, Wdeg_t, dEv, N, 1);
        exchange_kernel<<<nxb, F, 0, stream>>>(f, evb, dEv,
            Wex1 + (size_t)t * (F + 4) * F, bex1 + (size_t)t * F,
            Wex2 + (size_t)t * F * (F + 4), bex2 + (size_t)t * (F + 4), N);
    }
    readout_node_kernel<<<nxb, F, 0, stream>>>(f, Wo1, bo1, Wo2, bo2, node_e, N);
    hipMemsetAsync(d_out, 0, (size_t)out_size * sizeof(float), stream);
    energy_reduce_kernel<<<16, 256, 0, stream>>>(node_e, batch, (float*)d_out, N);
}

// Round 5
// 1790.865 us; speedup vs baseline: 4.7500x; 1.2004x over previous
//
#include <hip/hip_runtime.h>
#include <math.h>

// ---- static config (matches reference) ----
#define F 128
#define KRBF 32
#define TINTER 3
#define RMAX 5.0f
#define INV_AVG (1.0f/16.0f)
#define GAMMA 40.96f               // (KRBF/RMAX)^2
#define RSQRT_DH 0.17677669529663689f  // 1/sqrt(32)
#define PI_F 3.14159265358979323846f
#define TAB_N 2048                 // w(r) interpolation table entries over [0, RMAX]
#define GNB 16                     // nodes per block in node_gemm
#define XNB 8                      // nodes per block in exchange / readout

__device__ __forceinline__ float silu_f(float x) { return x / (1.0f + expf(-x)); }
__device__ __forceinline__ int deg_of(int c) { return (c == 0) ? 0 : (c < 4) ? 1 : (c < 9) ? 2 : 3; }

// bf16x2 pack/unpack: packed word = (elem_lo) | (elem_hi << 16), RNE rounding
__device__ __forceinline__ unsigned int pk_bf2(float lo, float hi) {
    unsigned int a = __float_as_uint(lo), b = __float_as_uint(hi);
    unsigned int ar = (a + 0x7fffu + ((a >> 16) & 1u)) >> 16;
    unsigned int br = (b + 0x7fffu + ((b >> 16) & 1u)) >> 16;
    return ar | (br << 16);
}
__device__ __forceinline__ float up_lo(unsigned int u) { return __uint_as_float(u << 16); }
__device__ __forceinline__ float up_hi(unsigned int u) { return __uint_as_float(u & 0xffff0000u); }

// ---------------------------------------------------------------------------
// CSR build: count -> scan -> scatter (receivers fixed for whole launch)
// ---------------------------------------------------------------------------
__global__ void count_kernel(const int* __restrict__ rcv, int* __restrict__ cnt, int E)
{
    int e = blockIdx.x * blockDim.x + threadIdx.x;
    if (e < E) atomicAdd(&cnt[rcv[e]], 1);
}

__global__ __launch_bounds__(1024) void scan_kernel(const int* __restrict__ cnt,
                                                    int* __restrict__ off,
                                                    int* __restrict__ cur, int N)
{
    __shared__ int part[1024];
    int t = threadIdx.x;
    int chunk = (N + 1023) / 1024;
    int lo = t * chunk, hi = min(lo + chunk, N);
    int sum = 0;
    for (int i = lo; i < hi; i++) sum += cnt[i];
    part[t] = sum;
    __syncthreads();
    for (int st = 1; st < 1024; st <<= 1) {
        int v = (t >= st) ? part[t - st] : 0;
        __syncthreads();
        part[t] += v;
        __syncthreads();
    }
    int run = (t == 0) ? 0 : part[t - 1];
    for (int i = lo; i < hi; i++) {
        off[i] = run; cur[i] = run;
        run += cnt[i];
    }
    if (t == 1023) off[N] = part[1023];
}

__global__ void scatter_kernel(const int* __restrict__ rcv, int* __restrict__ cur,
                               int* __restrict__ elist, int E)
{
    int e = blockIdx.x * blockDim.x + threadIdx.x;
    if (e < E) {
        int p = atomicAdd(&cur[rcv[e]], 1);
        elist[p] = e;
    }
}

// ---------------------------------------------------------------------------
// Edge geometry: r, C, Y[16] in edge order (staging; permuted to CSR after)
// ---------------------------------------------------------------------------
__global__ void edge_geom_kernel(const float* __restrict__ pos,
                                 const int* __restrict__ snd,
                                 const int* __restrict__ rcv,
                                 float* __restrict__ r_out,
                                 float* __restrict__ C_out,
                                 float* __restrict__ Y_out,
                                 int E)
{
    int e = blockIdx.x * blockDim.x + threadIdx.x;
    if (e >= E) return;
    int s = snd[e], rc = rcv[e];
    float vx = pos[rc * 3 + 0] - pos[s * 3 + 0];
    float vy = pos[rc * 3 + 1] - pos[s * 3 + 1];
    float vz = pos[rc * 3 + 2] - pos[s * 3 + 2];
    float r = sqrtf(vx * vx + vy * vy + vz * vz);
    float rinv = 1.0f / fmaxf(r, 1e-9f);
    float x = vx * rinv, y = vy * rinv, z = vz * rinv;
    float x2 = x * x, y2 = y * y, z2 = z * z;
    const float s3 = 1.7320508075688772f, s5 = 2.23606797749979f, s15 = 3.872983346207417f;
    const float s70 = 8.366600265340756f, s105 = 10.246950765959598f;
    const float s42 = 6.48074069840786f, s7 = 2.6457513110645907f;
    float Y[16];
    Y[0] = 1.0f;
    Y[1] = s3 * x; Y[2] = s3 * y; Y[3] = s3 * z;
    Y[4] = s15 * x * y; Y[5] = s15 * y * z; Y[6] = 0.5f * s5 * (3.0f * z2 - 1.0f);
    Y[7] = s15 * x * z; Y[8] = 0.5f * s15 * (x2 - y2);
    Y[9]  = 0.25f * s70 * y * (3.0f * x2 - y2);
    Y[10] = s105 * x * y * z;
    Y[11] = 0.25f * s42 * y * (5.0f * z2 - 1.0f);
    Y[12] = 0.5f * s7 * z * (5.0f * z2 - 3.0f);
    Y[13] = 0.25f * s42 * x * (5.0f * z2 - 1.0f);
    Y[14] = 0.5f * s105 * z * (x2 - y2);
    Y[15] = 0.25f * s70 * x * (x2 - 3.0f * y2);
    float C = (r < RMAX) ? 0.5f * (cosf(PI_F * r / RMAX) + 1.0f) : 0.0f;
    r_out[e] = r; C_out[e] = C;
    #pragma unroll
    for (int c = 0; c < 16; c++) Y_out[e * 16 + c] = Y[c];
}

// ---------------------------------------------------------------------------
// Permute edge data into CSR order (gather-style: random reads, coalesced writes)
// ---------------------------------------------------------------------------
__global__ void perm_edge_kernel(const int* __restrict__ elist,
                                 const int* __restrict__ snd, const int* __restrict__ rcv,
                                 const float* __restrict__ rbuf, const float* __restrict__ Cbuf,
                                 int* __restrict__ sp, int* __restrict__ rcvp,
                                 float2* __restrict__ rcC, int E)
{
    int ei = blockIdx.x * blockDim.x + threadIdx.x;
    if (ei >= E) return;
    int e = elist[ei];
    sp[ei] = snd[e];
    rcvp[ei] = rcv[e];
    rcC[ei] = make_float2(rbuf[e], Cbuf[e]);
}

__global__ void perm_Y_kernel(const int* __restrict__ elist,
                              const float* __restrict__ Ybuf,
                              float* __restrict__ Yp, int E)
{
    long long tid = (long long)blockIdx.x * blockDim.x + threadIdx.x;
    if (tid >= (long long)E * 16) return;
    int ei = (int)(tid >> 4), c = (int)(tid & 15);
    Yp[tid] = Ybuf[(size_t)elist[ei] * 16 + c];
}

// ---------------------------------------------------------------------------
// ev0[n] = sum_{ei in CSR(n)} Yp[ei]*C[ei] * INV_AVG  (16 lanes/node, streamed)
// ---------------------------------------------------------------------------
__global__ void ev0_kernel(const int* __restrict__ off,
                           const float* __restrict__ Yp, const float2* __restrict__ rcC,
                           float* __restrict__ ev, int N)
{
    int n = blockIdx.x * 16 + (threadIdx.x >> 4);
    int c = threadIdx.x & 15;
    if (n >= N) return;
    float acc = 0.0f;
    int e0 = off[n], e1 = off[n + 1];
    for (int ei = e0; ei < e1; ei++)
        acc += Yp[(size_t)ei * 16 + c] * rcC[ei].y;
    ev[n * 16 + c] = acc * INV_AVG;
}

// ---------------------------------------------------------------------------
// f = embed[species]
// ---------------------------------------------------------------------------
__global__ void embed_kernel(const int* __restrict__ species,
                             const float* __restrict__ embed,
                             float* __restrict__ f, int N)
{
    int n = blockIdx.x;
    if (n >= N) return;
    int j = threadIdx.x;
    f[n * F + j] = embed[species[n] * F + j];
}

// ---------------------------------------------------------------------------
// Build packed-bf16 w(r) table: tab16[t][i][j] = bf16x2(w[j], w[j+64])
// ---------------------------------------------------------------------------
__global__ __launch_bounds__(256) void build_table_kernel(
    const float* __restrict__ Wrbf1_all, const float* __restrict__ brbf1_all,
    const float* __restrict__ Wrbf2_all, unsigned int* __restrict__ tab16)
{
    int wave = threadIdx.x >> 6;
    int lane = threadIdx.x & 63;
    int idx = blockIdx.x * 4 + wave;
    int t = blockIdx.y;
    const float* W1 = Wrbf1_all + (size_t)t * KRBF * F;
    const float* b1 = brbf1_all + (size_t)t * F;
    const float* W2 = Wrbf2_all + (size_t)t * F * F;
    float r = idx * (RMAX / (TAB_N - 1));
    __shared__ float sR[4][KRBF];
    __shared__ float sH[4][F];
    if (lane < KRBF) {
        float mu = lane * (RMAX / (KRBF - 1));
        float d = r - mu;
        sR[wave][lane] = expf(-GAMMA * d * d);
    }
    __syncthreads();
    float h0 = b1[lane], h1 = b1[lane + 64];
    #pragma unroll
    for (int kk = 0; kk < KRBF; kk++) {
        float rv = sR[wave][kk];
        h0 += rv * W1[kk * F + lane];
        h1 += rv * W1[kk * F + lane + 64];
    }
    sH[wave][lane] = silu_f(h0);
    sH[wave][lane + 64] = silu_f(h1);
    __syncthreads();
    float w0 = 0.0f, w1 = 0.0f;
    for (int i = 0; i < F; i++) {
        float hv = sH[wave][i];
        w0 += hv * W2[i * F + lane];
        w1 += hv * W2[i * F + lane + 64];
    }
    tab16[((size_t)t * TAB_N + idx) * 64 + lane] = pk_bf2(w0, w1);
}

// ---------------------------------------------------------------------------
// dd_list[ei] = deg_reduce(ev[sp[ei]] * ev[rcvp[ei]])  (CSR order, float4)
// ev is L2-resident (1.9 MB); pure gather->coalesced-write.
// ---------------------------------------------------------------------------
__global__ void dd_kernel(const int* __restrict__ sp, const int* __restrict__ rcvp,
                          const float* __restrict__ ev, float4* __restrict__ ddl, int E)
{
    int ei = blockIdx.x * blockDim.x + threadIdx.x;
    if (ei >= E) return;
    int s = sp[ei], rc = rcvp[ei];
    const float4* a = (const float4*)(ev + (size_t)s * 16);
    const float4* b = (const float4*)(ev + (size_t)rc * 16);
    float4 a0 = a[0], a1 = a[1], a2 = a[2], a3 = a[3];
    float4 b0 = b[0], b1 = b[1], b2 = b[2], b3 = b[3];
    float d0 = a0.x * b0.x;
    float d1 = a0.y * b0.y + a0.z * b0.z + a0.w * b0.w;
    float d2 = a1.x * b1.x + a1.y * b1.y + a1.z * b1.z + a1.w * b1.w + a2.x * b2.x;
    float d3 = a2.y * b2.y + a2.z * b2.z + a2.w * b2.w
             + a3.x * b3.x + a3.y * b3.y + a3.z * b3.z + a3.w * b3.w;
    ddl[ei] = make_float4(d0, d1, d2, d3);
}

// ---------------------------------------------------------------------------
// Multi-output node GEMM. m==0 -> fp32 out0 (optional accumulate);
// m>=1 -> packed bf16x2 output (elem j | elem j+64 <<16), via LDS transpose.
// ---------------------------------------------------------------------------
__global__ __launch_bounds__(128) void node_gemm_kernel(
    const float* __restrict__ A,
    const float* __restrict__ W0, const float* __restrict__ W1f, const float* __restrict__ W2f,
    float* __restrict__ out0, unsigned int* __restrict__ out1, unsigned int* __restrict__ out2,
    int N, int nw, int accumulate)
{
    __shared__ float sA[GNB][F];
    __shared__ float sP[GNB][F];
    int n0 = blockIdx.x * GNB;
    int j = threadIdx.x;
    #pragma unroll
    for (int i = 0; i < GNB; i++) {
        int n = n0 + i;
        sA[i][j] = (n < N) ? A[(size_t)n * F + j] : 0.0f;
    }
    __syncthreads();
    for (int m = 0; m < nw; m++) {
        const float* W = (m == 0) ? W0 : (m == 1) ? W1f : W2f;
        float acc[GNB];
        #pragma unroll
        for (int nn = 0; nn < GNB; nn++) acc[nn] = 0.0f;
        for (int i = 0; i < F; i += 4) {
            float wv0 = W[(i + 0) * F + j];
            float wv1 = W[(i + 1) * F + j];
            float wv2 = W[(i + 2) * F + j];
            float wv3 = W[(i + 3) * F + j];
            #pragma unroll
            for (int nn = 0; nn < GNB; nn++) {
                float4 a = *(const float4*)&sA[nn][i];
                acc[nn] += a.x * wv0 + a.y * wv1 + a.z * wv2 + a.w * wv3;
            }
        }
        if (m == 0) {
            #pragma unroll
            for (int nn = 0; nn < GNB; nn++) {
                int n = n0 + nn;
                if (n < N) {
                    size_t idx = (size_t)n * F + j;
                    out0[idx] = accumulate ? (out0[idx] + acc[nn]) : acc[nn];
                }
            }
        } else {
            unsigned int* out16 = (m == 1) ? out1 : out2;
            __syncthreads();
            #pragma unroll
            for (int nn = 0; nn < GNB; nn++) sP[nn][j] = acc[nn];
            __syncthreads();
            if (j < 64) {
                #pragma unroll
                for (int nn = 0; nn < GNB; nn++) {
                    int n = n0 + nn;
                    if (n < N) out16[(size_t)n * 64 + j] = pk_bf2(sP[nn][j], sP[nn][j + 64]);
                }
            }
        }
    }
}

// ---------------------------------------------------------------------------
// Node-centric fused edge pass. One wave per receiver node; all per-edge
// streams (sp, rcC, ddl, Yp) are CSR-ordered; gathers are packed bf16
// (k16/v16: one uint32 per lane). dd precomputed -> no shuffle chain.
// mode 0 -> agg[n,128]; mode 1 -> dEv[n,16].
// ---------------------------------------------------------------------------
__global__ __launch_bounds__(256) void edge_pass_node_kernel(
    const int* __restrict__ off, const int* __restrict__ sp,
    const float2* __restrict__ rcC, const float4* __restrict__ ddl,
    const float* __restrict__ Yp,
    const float* __restrict__ qbuf,
    const unsigned int* __restrict__ k16, const unsigned int* __restrict__ v16,
    const unsigned int* __restrict__ tab16, const float* __restrict__ Wdeg_t,
    float* __restrict__ outbuf, int N, int mode)
{
    __shared__ float sWdeg[4 * F];
    for (int i = threadIdx.x; i < 4 * F; i += 256) sWdeg[i] = Wdeg_t[i];
    __syncthreads();

    int wave = threadIdx.x >> 6;
    int lane = threadIdx.x & 63;
    int n = blockIdx.x * 4 + wave;
    if (n >= N) return;

    int e0 = off[n], e1 = off[n + 1];
    float q0 = qbuf[(size_t)n * F + lane], q1 = qbuf[(size_t)n * F + lane + 64];
    float acc0 = 0.0f, acc1 = 0.0f;   // mode 0 accumulators
    float devacc = 0.0f;              // mode 1 accumulator (lane<16)

    for (int ei = e0; ei < e1; ei++) {
        int s = sp[ei];
        float2 rc2 = rcC[ei];
        float4 dd = ddl[ei];
        // table lerp (packed bf16 endpoints)
        float u = rc2.x * ((float)(TAB_N - 1) / RMAX);
        int i0 = (int)u;
        i0 = (i0 > TAB_N - 2) ? (TAB_N - 2) : i0;
        float fr = u - (float)i0;
        unsigned int ta = tab16[(size_t)i0 * 64 + lane];
        unsigned int tb = tab16[(size_t)(i0 + 1) * 64 + lane];
        float a0 = up_lo(ta), a1 = up_hi(ta);
        float b0 = up_lo(tb), b1 = up_hi(tb);
        float w0 = a0 + fr * (b0 - a0)
                 + dd.x * sWdeg[lane] + dd.y * sWdeg[F + lane]
                 + dd.z * sWdeg[2 * F + lane] + dd.w * sWdeg[3 * F + lane];
        float w1 = a1 + fr * (b1 - a1)
                 + dd.x * sWdeg[lane + 64] + dd.y * sWdeg[F + lane + 64]
                 + dd.z * sWdeg[2 * F + lane + 64] + dd.w * sWdeg[3 * F + lane + 64];
        unsigned int ku = k16[(size_t)s * 64 + lane];
        float p0 = q0 * w0 * up_lo(ku), p1 = q1 * w1 * up_hi(ku);
        #pragma unroll
        for (int o = 1; o < 32; o <<= 1) {
            p0 += __shfl_xor(p0, o, 64);
            p1 += __shfl_xor(p1, o, 64);
        }
        float scale = rc2.y * RSQRT_DH * INV_AVG;
        p0 *= scale; p1 *= scale;
        if (mode == 0) {
            unsigned int vu = v16[(size_t)s * 64 + lane];
            acc0 += p0 * up_lo(vu);
            acc1 += p1 * up_hi(vu);
        } else {
            // heads<->degrees: a2[0]=p0@lane0, a2[1]=p0@lane32, a2[2]=p1@lane0, a2[3]=p1@lane32
            float a20 = __shfl(p0, 0), a21 = __shfl(p0, 32);
            float a22 = __shfl(p1, 0), a23 = __shfl(p1, 32);
            if (lane < 16) {
                float a2d = (lane == 0) ? a20 : (lane < 4) ? a21 : (lane < 9) ? a22 : a23;
                devacc += a2d * Yp[(size_t)ei * 16 + lane];
            }
        }
    }
    if (mode == 0) {
        outbuf[(size_t)n * F + lane] = acc0;
        outbuf[(size_t)n * F + lane + 64] = acc1;
    } else if (lane < 16) {
        outbuf[n * 16 + lane] = devacc;
    }
}

// ---------------------------------------------------------------------------
// Exchange block, XNB nodes per 128-thread block.
// ---------------------------------------------------------------------------
__global__ __launch_bounds__(128) void exchange_kernel(
    float* __restrict__ f, float* __restrict__ ev, const float* __restrict__ dEv,
    const float* __restrict__ Wex1, const float* __restrict__ bex1,
    const float* __restrict__ Wex2, const float* __restrict__ bex2, int N)
{
    __shared__ float sIn[XNB][F + 4];
    __shared__ float sHid[XNB][F];
    __shared__ float sev[XNB][16];
    __shared__ float syb[XNB][4];
    int n0 = blockIdx.x * XNB;
    int j = threadIdx.x;
    #pragma unroll
    for (int nn = 0; nn < XNB; nn++) {
        int n = n0 + nn;
        sIn[nn][j] = (n < N) ? f[(size_t)n * F + j] : 0.0f;
    }
    {
        int nn = j >> 4, c = j & 15;
        int n = n0 + nn;
        sev[nn][c] = (n < N) ? (ev[n * 16 + c] + dEv[n * 16 + c]) : 0.0f;
    }
    __syncthreads();
    if (j < XNB * 4) {
        int nn = j >> 2, d = j & 3;
        int c0 = (d == 0) ? 0 : (d == 1) ? 1 : (d == 2) ? 4 : 9;
        int c1 = (d == 0) ? 1 : (d == 1) ? 4 : (d == 2) ? 9 : 16;
        float a = 0.0f;
        for (int c = c0; c < c1; c++) a += sev[nn][c] * sev[nn][c];
        sIn[nn][F + d] = a;
    }
    __syncthreads();
    float acc[XNB];
    #pragma unroll
    for (int nn = 0; nn < XNB; nn++) acc[nn] = bex1[j];
    for (int i = 0; i < F + 4; i++) {
        float w = Wex1[i * F + j];
        #pragma unroll
        for (int nn = 0; nn < XNB; nn++) acc[nn] += sIn[nn][i] * w;
    }
    #pragma unroll
    for (int nn = 0; nn < XNB; nn++) sHid[nn][j] = silu_f(acc[nn]);
    __syncthreads();
    float yb[XNB];
    #pragma unroll
    for (int nn = 0; nn < XNB; nn++) yb[nn] = bex2[j];
    for (int i = 0; i < F; i++) {
        float w = Wex2[i * (F + 4) + j];
        #pragma unroll
        for (int nn = 0; nn < XNB; nn++) yb[nn] += sHid[nn][i] * w;
    }
    if (j < XNB * 4) {
        int nn = j >> 2, d = j & 3;
        float a = bex2[F + d];
        for (int i = 0; i < F; i++) a += sHid[nn][i] * Wex2[i * (F + 4) + F + d];
        syb[nn][d] = a;
    }
    __syncthreads();
    #pragma unroll
    for (int nn = 0; nn < XNB; nn++) {
        int n = n0 + nn;
        if (n < N) f[(size_t)n * F + j] = sIn[nn][j] + yb[nn];
    }
    {
        int nn = j >> 4, c = j & 15;
        int n = n0 + nn;
        if (n < N) ev[n * 16 + c] = sev[nn][c] * (1.0f + syb[nn][deg_of(c)]);
    }
}

// ---------------------------------------------------------------------------
// Readout stage 1: node_e[n] = silu(f@Wo1+bo1)@Wo2 + bo2
// ---------------------------------------------------------------------------
__global__ __launch_bounds__(128) void readout_node_kernel(
    const float* __restrict__ f,
    const float* __restrict__ Wo1, const float* __restrict__ bo1,
    const float* __restrict__ Wo2, const float* __restrict__ bo2,
    float* __restrict__ node_e, int N)
{
    __shared__ float sA[XNB][F];
    __shared__ float swave[2][XNB];
    int n0 = blockIdx.x * XNB;
    int j = threadIdx.x;
    #pragma unroll
    for (int nn = 0; nn < XNB; nn++) {
        int n = n0 + nn;
        sA[nn][j] = (n < N) ? f[(size_t)n * F + j] : 0.0f;
    }
    __syncthreads();
    float acc[XNB];
    #pragma unroll
    for (int nn = 0; nn < XNB; nn++) acc[nn] = bo1[j];
    for (int i = 0; i < F; i += 4) {
        float w0 = Wo1[(i + 0) * F + j];
        float w1 = Wo1[(i + 1) * F + j];
        float w2 = Wo1[(i + 2) * F + j];
        float w3 = Wo1[(i + 3) * F + j];
        #pragma unroll
        for (int nn = 0; nn < XNB; nn++) {
            float4 a = *(const float4*)&sA[nn][i];
            acc[nn] += a.x * w0 + a.y * w1 + a.z * w2 + a.w * w3;
        }
    }
    float wo2 = Wo2[j];
    #pragma unroll
    for (int nn = 0; nn < XNB; nn++) {
        float z = silu_f(acc[nn]) * wo2;
        #pragma unroll
        for (int o = 1; o < 64; o <<= 1) z += __shfl_xor(z, o, 64);
        if ((j & 63) == 0) swave[j >> 6][nn] = z;
    }
    __syncthreads();
    if (j < XNB) {
        int n = n0 + j;
        if (n < N) node_e[n] = swave[0][j] + swave[1][j] + bo2[0];
    }
}

// ---------------------------------------------------------------------------
// Readout stage 2: energy[g] = sum_{batch[n]==g} node_e[n]
// ---------------------------------------------------------------------------
__global__ __launch_bounds__(256) void energy_reduce_kernel(
    const float* __restrict__ node_e, const int* __restrict__ batch,
    float* __restrict__ energy, int N)
{
    __shared__ float eacc[64];
    if (threadIdx.x < 64) eacc[threadIdx.x] = 0.0f;
    __syncthreads();
    for (int n = blockIdx.x * blockDim.x + threadIdx.x; n < N; n += gridDim.x * blockDim.x)
        atomicAdd(&eacc[batch[n]], node_e[n]);
    __syncthreads();
    if (threadIdx.x < 64) atomicAdd(&energy[threadIdx.x], eacc[threadIdx.x]);
}

// ---------------------------------------------------------------------------
extern "C" void kernel_launch(void* const* d_in, const int* in_sizes, int n_in,
                              void* d_out, int out_size, void* d_ws, size_t ws_size,
                              hipStream_t stream)
{
    const float* positions = (const float*)d_in[0];
    const int*   species   = (const int*)d_in[1];
    const int*   senders   = (const int*)d_in[2];
    const int*   receivers = (const int*)d_in[3];
    const int*   batch     = (const int*)d_in[4];
    const float* embed     = (const float*)d_in[5];
    const float* Wq    = (const float*)d_in[6];
    const float* Wk    = (const float*)d_in[7];
    const float* Wv    = (const float*)d_in[8];
    const float* Wo    = (const float*)d_in[9];
    const float* Wrbf1 = (const float*)d_in[10];
    const float* brbf1 = (const float*)d_in[11];
    const float* Wrbf2 = (const float*)d_in[12];
    const float* Wdeg  = (const float*)d_in[13];
    const float* Wq2   = (const float*)d_in[14];
    const float* Wk2   = (const float*)d_in[15];
    const float* Wex1  = (const float*)d_in[16];
    const float* bex1  = (const float*)d_in[17];
    const float* Wex2  = (const float*)d_in[18];
    const float* bex2  = (const float*)d_in[19];
    const float* Wo1   = (const float*)d_in[20];
    const float* bo1   = (const float*)d_in[21];
    const float* Wo2   = (const float*)d_in[22];
    const float* bo2   = (const float*)d_in[23];

    int N = in_sizes[0] / 3;
    int E = in_sizes[2];

    // ---- workspace layout (~125 MB), staging region aliased ----
    float* ws     = (float*)d_ws;
    float* Yp     = ws;  ws += (size_t)E * 16;      // CSR-ordered Y
    float2* rcC   = (float2*)ws; ws += (size_t)E * 2; // CSR-ordered (r, C)
    float* f      = ws;  ws += (size_t)N * F;
    float* evb    = ws;  ws += (size_t)N * 16;
    float* dEv    = ws;  ws += (size_t)N * 16;
    float* q      = ws;  ws += (size_t)N * F;
    float* agg    = ws;  ws += (size_t)N * F;
    float* node_e = ws;  ws += (size_t)N;
    // union region: staging (rbuf/Cbuf/Ybuf, E*18 floats) then tab16/k16/v16/ddl
    float* un     = ws;  ws += (size_t)E * 18;
    float* rbuf   = un;
    float* Cbuf   = un + E;
    float* Ybuf   = un + (size_t)2 * E;
    unsigned int* tab16 = (unsigned int*)un;                       // 3*TAB_N*64
    unsigned int* k16   = tab16 + (size_t)TINTER * TAB_N * 64;     // N*64
    unsigned int* v16   = k16 + (size_t)N * 64;                    // N*64
    float4* ddl   = (float4*)(v16 + (size_t)N * 64);               // E
    int* sp    = (int*)ws;  ws += E;
    int* rcvp  = (int*)ws;  ws += E;
    int* cnt   = (int*)ws;  ws += N;
    int* off   = (int*)ws;  ws += N + 1;
    int* cur   = (int*)ws;  ws += N;
    int* elist = (int*)ws;  ws += E;

    // ---- CSR build (receivers constant across iterations) ----
    hipMemsetAsync(cnt, 0, (size_t)N * sizeof(int), stream);
    count_kernel<<<(E + 255) / 256, 256, 0, stream>>>(receivers, cnt, E);
    scan_kernel<<<1, 1024, 0, stream>>>(cnt, off, cur, N);
    scatter_kernel<<<(E + 255) / 256, 256, 0, stream>>>(receivers, cur, elist, E);

    // ---- geometry + CSR-order permute (staging region live) ----
    edge_geom_kernel<<<(E + 255) / 256, 256, 0, stream>>>(positions, senders, receivers,
                                                          rbuf, Cbuf, Ybuf, E);
    perm_edge_kernel<<<(E + 255) / 256, 256, 0, stream>>>(elist, senders, receivers,
                                                          rbuf, Cbuf, sp, rcvp, rcC, E);
    perm_Y_kernel<<<(int)(((size_t)E * 16 + 255) / 256), 256, 0, stream>>>(elist, Ybuf, Yp, E);
    // staging dead from here; tab16/k16/v16/ddl may overwrite it
    build_table_kernel<<<dim3(TAB_N / 4, TINTER), 256, 0, stream>>>(Wrbf1, brbf1, Wrbf2, tab16);
    ev0_kernel<<<(N + 15) / 16, 256, 0, stream>>>(off, Yp, rcC, evb, N);
    embed_kernel<<<N, F, 0, stream>>>(species, embed, f, N);

    int ngb = (N + GNB - 1) / GNB;
    int npb = (N + 3) / 4;
    int nxb = (N + XNB - 1) / XNB;
    int edb = (E + 255) / 256;
    for (int t = 0; t < TINTER; t++) {
        size_t tFF = (size_t)t * F * F;
        const unsigned int* tab_t = tab16 + (size_t)t * TAB_N * 64;
        const float* Wdeg_t = Wdeg + (size_t)t * 4 * F;
        node_gemm_kernel<<<ngb, F, 0, stream>>>(f, Wq + tFF, Wk + tFF, Wv + tFF,
                                                q, k16, v16, N, 3, 0);
        dd_kernel<<<edb, 256, 0, stream>>>(sp, rcvp, evb, ddl, E);
        edge_pass_node_kernel<<<npb, 256, 0, stream>>>(off, sp, rcC, ddl, Yp,
            q, k16, v16, tab_t, Wdeg_t, agg, N, 0);
        node_gemm_kernel<<<ngb, F, 0, stream>>>(agg, Wo + tFF, nullptr, nullptr,
                                                f, nullptr, nullptr, N, 1, 1);
        node_gemm_kernel<<<ngb, F, 0, stream>>>(f, Wq2 + tFF, Wk2 + tFF, nullptr,
                                                q, k16, nullptr, N, 2, 0);
        edge_pass_node_kernel<<<npb, 256, 0, stream>>>(off, sp, rcC, ddl, Yp,
            q, k16, nullptr, tab_t, Wdeg_t, dEv, N, 1);
        exchange_kernel<<<nxb, F, 0, stream>>>(f, evb, dEv,
            Wex1 + (size_t)t * (F + 4) * F, bex1 + (size_t)t * F,
            Wex2 + (size_t)t * F * (F + 4), bex2 + (size_t)t * (F + 4), N);
    }
    readout_node_kernel<<<nxb, F, 0, stream>>>(f, Wo1, bo1, Wo2, bo2, node_e, N);
    hipMemsetAsync(d_out, 0, (size_t)out_size * sizeof(float), stream);
    energy_reduce_kernel<<<16, 256, 0, stream>>>(node_e, batch, (float*)d_out, N);
}

// Round 6
// 1360.443 us; speedup vs baseline: 6.2529x; 1.3164x over previous
//
#include <hip/hip_runtime.h>
#include <math.h>

// ---- static config (matches reference) ----
#define F 128
#define KRBF 32
#define TINTER 3
#define RMAX 5.0f
#define INV_AVG (1.0f/16.0f)
#define GAMMA 40.96f               // (KRBF/RMAX)^2
#define RSQRT_DH 0.17677669529663689f  // 1/sqrt(32)
#define PI_F 3.14159265358979323846f
#define TAB_N 2048                 // w(r) interpolation table entries over [0, RMAX]
#define XNB 8                      // nodes per block in exchange / readout
#define APITCH 68                  // LDS A-tile pitch in dwords (136 bf16, 16B-aligned rows)

__device__ __forceinline__ float silu_f(float x) { return x / (1.0f + expf(-x)); }
__device__ __forceinline__ int deg_of(int c) { return (c == 0) ? 0 : (c < 4) ? 1 : (c < 9) ? 2 : 3; }

// bf16x2 pack/unpack: packed word = (elem0) | (elem1 << 16), RNE rounding
__device__ __forceinline__ unsigned int pk_bf2(float lo, float hi) {
    unsigned int a = __float_as_uint(lo), b = __float_as_uint(hi);
    unsigned int ar = (a + 0x7fffu + ((a >> 16) & 1u)) >> 16;
    unsigned int br = (b + 0x7fffu + ((b >> 16) & 1u)) >> 16;
    return ar | (br << 16);
}
__device__ __forceinline__ float up_lo(unsigned int u) { return __uint_as_float(u << 16); }
__device__ __forceinline__ float up_hi(unsigned int u) { return __uint_as_float(u & 0xffff0000u); }

typedef short s16x8 __attribute__((ext_vector_type(8)));
typedef float f32x4 __attribute__((ext_vector_type(4)));
union FragU { uint4 u; s16x8 s; };

// ---------------------------------------------------------------------------
// CSR build: count -> scan -> scatter (receivers fixed for whole launch)
// ---------------------------------------------------------------------------
__global__ void count_kernel(const int* __restrict__ rcv, int* __restrict__ cnt, int E)
{
    int e = blockIdx.x * blockDim.x + threadIdx.x;
    if (e < E) atomicAdd(&cnt[rcv[e]], 1);
}

__global__ __launch_bounds__(1024) void scan_kernel(const int* __restrict__ cnt,
                                                    int* __restrict__ off,
                                                    int* __restrict__ cur, int N)
{
    __shared__ int part[1024];
    int t = threadIdx.x;
    int chunk = (N + 1023) / 1024;
    int lo = t * chunk, hi = min(lo + chunk, N);
    int sum = 0;
    for (int i = lo; i < hi; i++) sum += cnt[i];
    part[t] = sum;
    __syncthreads();
    for (int st = 1; st < 1024; st <<= 1) {
        int v = (t >= st) ? part[t - st] : 0;
        __syncthreads();
        part[t] += v;
        __syncthreads();
    }
    int run = (t == 0) ? 0 : part[t - 1];
    for (int i = lo; i < hi; i++) {
        off[i] = run; cur[i] = run;
        run += cnt[i];
    }
    if (t == 1023) off[N] = part[1023];
}

__global__ void scatter_kernel(const int* __restrict__ rcv, int* __restrict__ cur,
                               int* __restrict__ elist, int E)
{
    int e = blockIdx.x * blockDim.x + threadIdx.x;
    if (e < E) {
        int p = atomicAdd(&cur[rcv[e]], 1);
        elist[p] = e;
    }
}

// ---------------------------------------------------------------------------
// Edge geometry: r, C, Y[16] in edge order (staging; permuted to CSR after)
// ---------------------------------------------------------------------------
__global__ void edge_geom_kernel(const float* __restrict__ pos,
                                 const int* __restrict__ snd,
                                 const int* __restrict__ rcv,
                                 float* __restrict__ r_out,
                                 float* __restrict__ C_out,
                                 float* __restrict__ Y_out,
                                 int E)
{
    int e = blockIdx.x * blockDim.x + threadIdx.x;
    if (e >= E) return;
    int s = snd[e], rc = rcv[e];
    float vx = pos[rc * 3 + 0] - pos[s * 3 + 0];
    float vy = pos[rc * 3 + 1] - pos[s * 3 + 1];
    float vz = pos[rc * 3 + 2] - pos[s * 3 + 2];
    float r = sqrtf(vx * vx + vy * vy + vz * vz);
    float rinv = 1.0f / fmaxf(r, 1e-9f);
    float x = vx * rinv, y = vy * rinv, z = vz * rinv;
    float x2 = x * x, y2 = y * y, z2 = z * z;
    const float s3 = 1.7320508075688772f, s5 = 2.23606797749979f, s15 = 3.872983346207417f;
    const float s70 = 8.366600265340756f, s105 = 10.246950765959598f;
    const float s42 = 6.48074069840786f, s7 = 2.6457513110645907f;
    float Y[16];
    Y[0] = 1.0f;
    Y[1] = s3 * x; Y[2] = s3 * y; Y[3] = s3 * z;
    Y[4] = s15 * x * y; Y[5] = s15 * y * z; Y[6] = 0.5f * s5 * (3.0f * z2 - 1.0f);
    Y[7] = s15 * x * z; Y[8] = 0.5f * s15 * (x2 - y2);
    Y[9]  = 0.25f * s70 * y * (3.0f * x2 - y2);
    Y[10] = s105 * x * y * z;
    Y[11] = 0.25f * s42 * y * (5.0f * z2 - 1.0f);
    Y[12] = 0.5f * s7 * z * (5.0f * z2 - 3.0f);
    Y[13] = 0.25f * s42 * x * (5.0f * z2 - 1.0f);
    Y[14] = 0.5f * s105 * z * (x2 - y2);
    Y[15] = 0.25f * s70 * x * (x2 - 3.0f * y2);
    float C = (r < RMAX) ? 0.5f * (cosf(PI_F * r / RMAX) + 1.0f) : 0.0f;
    r_out[e] = r; C_out[e] = C;
    #pragma unroll
    for (int c = 0; c < 16; c++) Y_out[e * 16 + c] = Y[c];
}

// ---------------------------------------------------------------------------
// Permute edge data into CSR order
// ---------------------------------------------------------------------------
__global__ void perm_edge_kernel(const int* __restrict__ elist,
                                 const int* __restrict__ snd, const int* __restrict__ rcv,
                                 const float* __restrict__ rbuf, const float* __restrict__ Cbuf,
                                 int* __restrict__ sp, int* __restrict__ rcvp,
                                 float2* __restrict__ rcC, int E)
{
    int ei = blockIdx.x * blockDim.x + threadIdx.x;
    if (ei >= E) return;
    int e = elist[ei];
    sp[ei] = snd[e];
    rcvp[ei] = rcv[e];
    rcC[ei] = make_float2(rbuf[e], Cbuf[e]);
}

__global__ void perm_Y_kernel(const int* __restrict__ elist,
                              const float* __restrict__ Ybuf,
                              float* __restrict__ Yp, int E)
{
    long long tid = (long long)blockIdx.x * blockDim.x + threadIdx.x;
    if (tid >= (long long)E * 16) return;
    int ei = (int)(tid >> 4), c = (int)(tid & 15);
    Yp[tid] = Ybuf[(size_t)elist[ei] * 16 + c];
}

// ---------------------------------------------------------------------------
// ev0[n] = sum_{ei in CSR(n)} Yp[ei]*C[ei] * INV_AVG  (16 lanes/node, streamed)
// ---------------------------------------------------------------------------
__global__ void ev0_kernel(const int* __restrict__ off,
                           const float* __restrict__ Yp, const float2* __restrict__ rcC,
                           float* __restrict__ ev, int N)
{
    int n = blockIdx.x * 16 + (threadIdx.x >> 4);
    int c = threadIdx.x & 15;
    if (n >= N) return;
    float acc = 0.0f;
    int e0 = off[n], e1 = off[n + 1];
    for (int ei = e0; ei < e1; ei++)
        acc += Yp[(size_t)ei * 16 + c] * rcC[ei].y;
    ev[n * 16 + c] = acc * INV_AVG;
}

// ---------------------------------------------------------------------------
// f = embed[species]
// ---------------------------------------------------------------------------
__global__ void embed_kernel(const int* __restrict__ species,
                             const float* __restrict__ embed,
                             float* __restrict__ f, int N)
{
    int n = blockIdx.x;
    if (n >= N) return;
    int j = threadIdx.x;
    f[n * F + j] = embed[species[n] * F + j];
}

// ---------------------------------------------------------------------------
// Pack 18 128x128 fp32 weight matrices into MFMA B-operand bf16 layout.
// Wpk[mat][((ct*16 + kb*4 + quad)*16 + n)*4 + iw] = bf16x2(W[k][ct*16+n], W[k+1][..])
// with k = kb*32 + quad*8 + iw*2. One dword per thread; one-time, ~2.4 MB read.
// mat order: Wq[0..2], Wk[0..2], Wv[0..2], Wo[0..2], Wq2[0..2], Wk2[0..2]
// ---------------------------------------------------------------------------
__global__ void pack_w_kernel(const float* __restrict__ Wq, const float* __restrict__ Wk,
                              const float* __restrict__ Wv, const float* __restrict__ Wo,
                              const float* __restrict__ Wq2, const float* __restrict__ Wk2,
                              unsigned int* __restrict__ Wpk)
{
    int tid = blockIdx.x * blockDim.x + threadIdx.x;
    if (tid >= 18 * 8192) return;
    int mat = tid >> 13;
    int rem = tid & 8191;
    int iw = rem & 3;
    int n = (rem >> 2) & 15;
    int quad = (rem >> 6) & 3;
    int kb = (rem >> 8) & 3;
    int ct = rem >> 10;
    const float* fam = (mat < 3) ? Wq : (mat < 6) ? Wk : (mat < 9) ? Wv
                     : (mat < 12) ? Wo : (mat < 15) ? Wq2 : Wk2;
    const float* src = fam + (size_t)(mat % 3) * F * F;
    int k = kb * 32 + quad * 8 + iw * 2;
    int col = ct * 16 + n;
    Wpk[tid] = pk_bf2(src[k * F + col], src[(k + 1) * F + col]);
}

// ---------------------------------------------------------------------------
// Build packed-bf16 w(r) table: tab16[t][i][l] = bf16x2(w[2l], w[2l+1])
// ---------------------------------------------------------------------------
__global__ __launch_bounds__(256) void build_table_kernel(
    const float* __restrict__ Wrbf1_all, const float* __restrict__ brbf1_all,
    const float* __restrict__ Wrbf2_all, unsigned int* __restrict__ tab16)
{
    int wave = threadIdx.x >> 6;
    int lane = threadIdx.x & 63;
    int idx = blockIdx.x * 4 + wave;
    int t = blockIdx.y;
    const float* W1 = Wrbf1_all + (size_t)t * KRBF * F;
    const float* b1 = brbf1_all + (size_t)t * F;
    const float* W2 = Wrbf2_all + (size_t)t * F * F;
    float r = idx * (RMAX / (TAB_N - 1));
    __shared__ float sR[4][KRBF];
    __shared__ float sH[4][F];
    if (lane < KRBF) {
        float mu = lane * (RMAX / (KRBF - 1));
        float d = r - mu;
        sR[wave][lane] = expf(-GAMMA * d * d);
    }
    __syncthreads();
    float h0 = b1[lane], h1 = b1[lane + 64];
    #pragma unroll
    for (int kk = 0; kk < KRBF; kk++) {
        float rv = sR[wave][kk];
        h0 += rv * W1[kk * F + lane];
        h1 += rv * W1[kk * F + lane + 64];
    }
    sH[wave][lane] = silu_f(h0);
    sH[wave][lane + 64] = silu_f(h1);
    __syncthreads();
    float w0 = 0.0f, w1 = 0.0f;
    for (int i = 0; i < F; i++) {
        float hv = sH[wave][i];
        w0 += hv * W2[i * F + 2 * lane];
        w1 += hv * W2[i * F + 2 * lane + 1];
    }
    tab16[((size_t)t * TAB_N + idx) * 64 + lane] = pk_bf2(w0, w1);
}

// ---------------------------------------------------------------------------
// dd_list[ei] = deg_reduce(ev[sp[ei]] * ev[rcvp[ei]])  (CSR order, float4)
// ---------------------------------------------------------------------------
__global__ void dd_kernel(const int* __restrict__ sp, const int* __restrict__ rcvp,
                          const float* __restrict__ ev, float4* __restrict__ ddl, int E)
{
    int ei = blockIdx.x * blockDim.x + threadIdx.x;
    if (ei >= E) return;
    int s = sp[ei], rc = rcvp[ei];
    const float4* a = (const float4*)(ev + (size_t)s * 16);
    const float4* b = (const float4*)(ev + (size_t)rc * 16);
    float4 a0 = a[0], a1 = a[1], a2 = a[2], a3 = a[3];
    float4 b0 = b[0], b1 = b[1], b2 = b[2], b3 = b[3];
    float d0 = a0.x * b0.x;
    float d1 = a0.y * b0.y + a0.z * b0.z + a0.w * b0.w;
    float d2 = a1.x * b1.x + a1.y * b1.y + a1.z * b1.z + a1.w * b1.w + a2.x * b2.x;
    float d3 = a2.y * b2.y + a2.z * b2.z + a2.w * b2.w
             + a3.x * b3.x + a3.y * b3.y + a3.z * b3.z + a3.w * b3.w;
    ddl[ei] = make_float4(d0, d1, d2, d3);
}

// ---------------------------------------------------------------------------
// MFMA node GEMM: out[m] = A @ W[m]. 64 nodes/block, 4 waves, 16x16x32 bf16.
// A (fp32) staged to LDS as bf16 pairs; B pre-packed (pack_w_kernel layout).
// m==0 -> fp32 out0 (optional accumulate); m>=1 -> packed bf16x2 (2j,2j+1).
// ---------------------------------------------------------------------------
__global__ __launch_bounds__(256) void node_gemm_mfma_kernel(
    const float* __restrict__ A,
    const unsigned int* __restrict__ B0, const unsigned int* __restrict__ B1,
    const unsigned int* __restrict__ B2,
    float* __restrict__ out0, unsigned int* __restrict__ out1, unsigned int* __restrict__ out2,
    int N, int nw, int accumulate)
{
    __shared__ unsigned int sA[64 * APITCH];
    int tid = threadIdx.x;
    int n0 = blockIdx.x * 64;
    #pragma unroll
    for (int rep = 0; rep < 16; rep++) {
        int idx = rep * 256 + tid;            // 0..4095
        int node = idx >> 6, jj = idx & 63;
        int n = n0 + node;
        float2 v = (n < N) ? ((const float2*)A)[(size_t)n * 64 + jj] : make_float2(0.f, 0.f);
        sA[node * APITCH + jj] = pk_bf2(v.x, v.y);
    }
    __syncthreads();
    int wave = tid >> 6, lane = tid & 63;
    int quad = lane >> 4, col = lane & 15;
    int mrow = wave * 16 + col;               // A-tile row this lane supplies
    s16x8 af[4];
    #pragma unroll
    for (int kb = 0; kb < 4; kb++) {
        FragU fu;
        fu.u = *(const uint4*)&sA[mrow * APITCH + kb * 16 + quad * 4];
        af[kb] = fu.s;
    }
    for (int m = 0; m < nw; m++) {
        const unsigned int* B = (m == 0) ? B0 : (m == 1) ? B1 : B2;
        unsigned int* o16 = (m == 1) ? out1 : out2;
        for (int ct = 0; ct < 8; ct++) {
            f32x4 acc = {0.f, 0.f, 0.f, 0.f};
            #pragma unroll
            for (int kb = 0; kb < 4; kb++) {
                FragU bu;
                bu.u = *(const uint4*)&B[(size_t)((ct * 16 + kb * 4 + quad) * 16 + col) * 4];
                acc = __builtin_amdgcn_mfma_f32_16x16x32_bf16(af[kb], bu.s, acc, 0, 0, 0);
            }
            if (m == 0) {
                #pragma unroll
                for (int r = 0; r < 4; r++) {
                    int n = n0 + wave * 16 + quad * 4 + r;
                    if (n < N) {
                        size_t ix = (size_t)n * F + ct * 16 + col;
                        out0[ix] = accumulate ? out0[ix] + acc[r] : acc[r];
                    }
                }
            } else {
                #pragma unroll
                for (int r = 0; r < 4; r++) {
                    float other = __shfl_xor(acc[r], 1, 64);
                    if (!(lane & 1)) {
                        int n = n0 + wave * 16 + quad * 4 + r;
                        if (n < N)
                            o16[(size_t)n * 64 + ct * 8 + (col >> 1)] = pk_bf2(acc[r], other);
                    }
                }
            }
        }
    }
}

// ---------------------------------------------------------------------------
// Node-centric fused edge pass. One wave per receiver node. bf16 pairs are
// (2l, 2l+1): lane l handles features {2l, 2l+1}; head h = lane>>4.
// mode 0 -> agg[n,128]; mode 1 -> dEv[n,16].
// ---------------------------------------------------------------------------
__global__ __launch_bounds__(256) void edge_pass_node_kernel(
    const int* __restrict__ off, const int* __restrict__ sp,
    const float2* __restrict__ rcC, const float4* __restrict__ ddl,
    const float* __restrict__ Yp,
    const float* __restrict__ qbuf,
    const unsigned int* __restrict__ k16, const unsigned int* __restrict__ v16,
    const unsigned int* __restrict__ tab16, const float* __restrict__ Wdeg_t,
    float* __restrict__ outbuf, int N, int mode)
{
    __shared__ float sWdeg[4 * F];
    for (int i = threadIdx.x; i < 4 * F; i += 256) sWdeg[i] = Wdeg_t[i];
    __syncthreads();

    int wave = threadIdx.x >> 6;
    int lane = threadIdx.x & 63;
    int n = blockIdx.x * 4 + wave;
    if (n >= N) return;

    int e0 = off[n], e1 = off[n + 1];
    float2 qq = ((const float2*)qbuf)[(size_t)n * 64 + lane];
    float acc0 = 0.0f, acc1 = 0.0f;   // mode 0 accumulators
    float devacc = 0.0f;              // mode 1 accumulator (lane<16)

    for (int ei = e0; ei < e1; ei++) {
        int s = sp[ei];
        float2 rc2 = rcC[ei];
        float4 dd = ddl[ei];
        // table lerp (packed bf16 endpoints)
        float u = rc2.x * ((float)(TAB_N - 1) / RMAX);
        int i0 = (int)u;
        i0 = (i0 > TAB_N - 2) ? (TAB_N - 2) : i0;
        float fr = u - (float)i0;
        unsigned int ta = tab16[(size_t)i0 * 64 + lane];
        unsigned int tb = tab16[(size_t)(i0 + 1) * 64 + lane];
        float a0 = up_lo(ta), a1 = up_hi(ta);
        float b0 = up_lo(tb), b1 = up_hi(tb);
        int j0 = 2 * lane, j1 = 2 * lane + 1;
        float w0 = a0 + fr * (b0 - a0)
                 + dd.x * sWdeg[j0] + dd.y * sWdeg[F + j0]
                 + dd.z * sWdeg[2 * F + j0] + dd.w * sWdeg[3 * F + j0];
        float w1 = a1 + fr * (b1 - a1)
                 + dd.x * sWdeg[j1] + dd.y * sWdeg[F + j1]
                 + dd.z * sWdeg[2 * F + j1] + dd.w * sWdeg[3 * F + j1];
        unsigned int ku = k16[(size_t)s * 64 + lane];
        float p = qq.x * w0 * up_lo(ku) + qq.y * w1 * up_hi(ku);
        // per-head (16-lane) reduction
        #pragma unroll
        for (int o = 1; o < 16; o <<= 1) p += __shfl_xor(p, o, 64);
        float alpha = p * (rc2.y * RSQRT_DH * INV_AVG);
        if (mode == 0) {
            unsigned int vu = v16[(size_t)s * 64 + lane];
            acc0 += alpha * up_lo(vu);
            acc1 += alpha * up_hi(vu);
        } else {
            float a20 = __shfl(alpha, 0), a21 = __shfl(alpha, 16);
            float a22 = __shfl(alpha, 32), a23 = __shfl(alpha, 48);
            if (lane < 16) {
                float a2d = (lane == 0) ? a20 : (lane < 4) ? a21 : (lane < 9) ? a22 : a23;
                devacc += a2d * Yp[(size_t)ei * 16 + lane];
            }
        }
    }
    if (mode == 0) {
        ((float2*)outbuf)[(size_t)n * 64 + lane] = make_float2(acc0, acc1);
    } else if (lane < 16) {
        outbuf[n * 16 + lane] = devacc;
    }
}

// ---------------------------------------------------------------------------
// Exchange block, XNB nodes per 128-thread block.
// ---------------------------------------------------------------------------
__global__ __launch_bounds__(128) void exchange_kernel(
    float* __restrict__ f, float* __restrict__ ev, const float* __restrict__ dEv,
    const float* __restrict__ Wex1, const float* __restrict__ bex1,
    const float* __restrict__ Wex2, const float* __restrict__ bex2, int N)
{
    __shared__ float sIn[XNB][F + 4];
    __shared__ float sHid[XNB][F];
    __shared__ float sev[XNB][16];
    __shared__ float syb[XNB][4];
    int n0 = blockIdx.x * XNB;
    int j = threadIdx.x;
    #pragma unroll
    for (int nn = 0; nn < XNB; nn++) {
        int n = n0 + nn;
        sIn[nn][j] = (n < N) ? f[(size_t)n * F + j] : 0.0f;
    }
    {
        int nn = j >> 4, c = j & 15;
        int n = n0 + nn;
        sev[nn][c] = (n < N) ? (ev[n * 16 + c] + dEv[n * 16 + c]) : 0.0f;
    }
    __syncthreads();
    if (j < XNB * 4) {
        int nn = j >> 2, d = j & 3;
        int c0 = (d == 0) ? 0 : (d == 1) ? 1 : (d == 2) ? 4 : 9;
        int c1 = (d == 0) ? 1 : (d == 1) ? 4 : (d == 2) ? 9 : 16;
        float a = 0.0f;
        for (int c = c0; c < c1; c++) a += sev[nn][c] * sev[nn][c];
        sIn[nn][F + d] = a;
    }
    __syncthreads();
    float acc[XNB];
    #pragma unroll
    for (int nn = 0; nn < XNB; nn++) acc[nn] = bex1[j];
    for (int i = 0; i < F + 4; i++) {
        float w = Wex1[i * F + j];
        #pragma unroll
        for (int nn = 0; nn < XNB; nn++) acc[nn] += sIn[nn][i] * w;
    }
    #pragma unroll
    for (int nn = 0; nn < XNB; nn++) sHid[nn][j] = silu_f(acc[nn]);
    __syncthreads();
    float yb[XNB];
    #pragma unroll
    for (int nn = 0; nn < XNB; nn++) yb[nn] = bex2[j];
    for (int i = 0; i < F; i++) {
        float w = Wex2[i * (F + 4) + j];
        #pragma unroll
        for (int nn = 0; nn < XNB; nn++) yb[nn] += sHid[nn][i] * w;
    }
    if (j < XNB * 4) {
        int nn = j >> 2, d = j & 3;
        float a = bex2[F + d];
        for (int i = 0; i < F; i++) a += sHid[nn][i] * Wex2[i * (F + 4) + F + d];
        syb[nn][d] = a;
    }
    __syncthreads();
    #pragma unroll
    for (int nn = 0; nn < XNB; nn++) {
        int n = n0 + nn;
        if (n < N) f[(size_t)n * F + j] = sIn[nn][j] + yb[nn];
    }
    {
        int nn = j >> 4, c = j & 15;
        int n = n0 + nn;
        if (n < N) ev[n * 16 + c] = sev[nn][c] * (1.0f + syb[nn][deg_of(c)]);
    }
}

// ---------------------------------------------------------------------------
// Readout stage 1: node_e[n] = silu(f@Wo1+bo1)@Wo2 + bo2
// ---------------------------------------------------------------------------
__global__ __launch_bounds__(128) void readout_node_kernel(
    const float* __restrict__ f,
    const float* __restrict__ Wo1, const float* __restrict__ bo1,
    const float* __restrict__ Wo2, const float* __restrict__ bo2,
    float* __restrict__ node_e, int N)
{
    __shared__ float sA[XNB][F];
    __shared__ float swave[2][XNB];
    int n0 = blockIdx.x * XNB;
    int j = threadIdx.x;
    #pragma unroll
    for (int nn = 0; nn < XNB; nn++) {
        int n = n0 + nn;
        sA[nn][j] = (n < N) ? f[(size_t)n * F + j] : 0.0f;
    }
    __syncthreads();
    float acc[XNB];
    #pragma unroll
    for (int nn = 0; nn < XNB; nn++) acc[nn] = bo1[j];
    for (int i = 0; i < F; i += 4) {
        float w0 = Wo1[(i + 0) * F + j];
        float w1 = Wo1[(i + 1) * F + j];
        float w2 = Wo1[(i + 2) * F + j];
        float w3 = Wo1[(i + 3) * F + j];
        #pragma unroll
        for (int nn = 0; nn < XNB; nn++) {
            float4 a = *(const float4*)&sA[nn][i];
            acc[nn] += a.x * w0 + a.y * w1 + a.z * w2 + a.w * w3;
        }
    }
    float wo2 = Wo2[j];
    #pragma unroll
    for (int nn = 0; nn < XNB; nn++) {
        float z = silu_f(acc[nn]) * wo2;
        #pragma unroll
        for (int o = 1; o < 64; o <<= 1) z += __shfl_xor(z, o, 64);
        if ((j & 63) == 0) swave[j >> 6][nn] = z;
    }
    __syncthreads();
    if (j < XNB) {
        int n = n0 + j;
        if (n < N) node_e[n] = swave[0][j] + swave[1][j] + bo2[0];
    }
}

// ---------------------------------------------------------------------------
// Readout stage 2: energy[g] = sum_{batch[n]==g} node_e[n]
// ---------------------------------------------------------------------------
__global__ __launch_bounds__(256) void energy_reduce_kernel(
    const float* __restrict__ node_e, const int* __restrict__ batch,
    float* __restrict__ energy, int N)
{
    __shared__ float eacc[64];
    if (threadIdx.x < 64) eacc[threadIdx.x] = 0.0f;
    __syncthreads();
    for (int n = blockIdx.x * blockDim.x + threadIdx.x; n < N; n += gridDim.x * blockDim.x)
        atomicAdd(&eacc[batch[n]], node_e[n]);
    __syncthreads();
    if (threadIdx.x < 64) atomicAdd(&energy[threadIdx.x], eacc[threadIdx.x]);
}

// ---------------------------------------------------------------------------
extern "C" void kernel_launch(void* const* d_in, const int* in_sizes, int n_in,
                              void* d_out, int out_size, void* d_ws, size_t ws_size,
                              hipStream_t stream)
{
    const float* positions = (const float*)d_in[0];
    const int*   species   = (const int*)d_in[1];
    const int*   senders   = (const int*)d_in[2];
    const int*   receivers = (const int*)d_in[3];
    const int*   batch     = (const int*)d_in[4];
    const float* embed     = (const float*)d_in[5];
    const float* Wq    = (const float*)d_in[6];
    const float* Wk    = (const float*)d_in[7];
    const float* Wv    = (const float*)d_in[8];
    const float* Wo    = (const float*)d_in[9];
    const float* Wrbf1 = (const float*)d_in[10];
    const float* brbf1 = (const float*)d_in[11];
    const float* Wrbf2 = (const float*)d_in[12];
    const float* Wdeg  = (const float*)d_in[13];
    const float* Wq2   = (const float*)d_in[14];
    const float* Wk2   = (const float*)d_in[15];
    const float* Wex1  = (const float*)d_in[16];
    const float* bex1  = (const float*)d_in[17];
    const float* Wex2  = (const float*)d_in[18];
    const float* bex2  = (const float*)d_in[19];
    const float* Wo1   = (const float*)d_in[20];
    const float* bo1   = (const float*)d_in[21];
    const float* Wo2   = (const float*)d_in[22];
    const float* bo2   = (const float*)d_in[23];

    int N = in_sizes[0] / 3;
    int E = in_sizes[2];

    // ---- workspace layout (~126 MB), staging region aliased ----
    float* ws     = (float*)d_ws;
    float* Yp     = ws;  ws += (size_t)E * 16;        // CSR-ordered Y
    float2* rcC   = (float2*)ws; ws += (size_t)E * 2; // CSR-ordered (r, C)
    float* f      = ws;  ws += (size_t)N * F;
    float* evb    = ws;  ws += (size_t)N * 16;
    float* dEv    = ws;  ws += (size_t)N * 16;
    float* q      = ws;  ws += (size_t)N * F;
    float* agg    = ws;  ws += (size_t)N * F;
    float* node_e = ws;  ws += (size_t)N;
    // union region: staging (rbuf/Cbuf/Ybuf, E*18 floats) then tab16/k16/v16/ddl
    float* un     = ws;  ws += (size_t)E * 18;
    float* rbuf   = un;
    float* Cbuf   = un + E;
    float* Ybuf   = un + (size_t)2 * E;
    unsigned int* tab16 = (unsigned int*)un;                       // 3*TAB_N*64
    unsigned int* k16   = tab16 + (size_t)TINTER * TAB_N * 64;     // N*64
    unsigned int* v16   = k16 + (size_t)N * 64;                    // N*64
    float4* ddl   = (float4*)(v16 + (size_t)N * 64);               // E
    int* sp    = (int*)ws;  ws += E;
    int* rcvp  = (int*)ws;  ws += E;
    int* cnt   = (int*)ws;  ws += N;
    int* off   = (int*)ws;  ws += N + 1;
    int* cur   = (int*)ws;  ws += N;
    int* elist = (int*)ws;  ws += E;
    unsigned int* Wpk = (unsigned int*)ws;  ws += 18 * 8192;       // packed MFMA weights

    // ---- CSR build (receivers constant across iterations) ----
    hipMemsetAsync(cnt, 0, (size_t)N * sizeof(int), stream);
    count_kernel<<<(E + 255) / 256, 256, 0, stream>>>(receivers, cnt, E);
    scan_kernel<<<1, 1024, 0, stream>>>(cnt, off, cur, N);
    scatter_kernel<<<(E + 255) / 256, 256, 0, stream>>>(receivers, cur, elist, E);

    // ---- geometry + CSR-order permute (staging region live) ----
    edge_geom_kernel<<<(E + 255) / 256, 256, 0, stream>>>(positions, senders, receivers,
                                                          rbuf, Cbuf, Ybuf, E);
    perm_edge_kernel<<<(E + 255) / 256, 256, 0, stream>>>(elist, senders, receivers,
                                                          rbuf, Cbuf, sp, rcvp, rcC, E);
    perm_Y_kernel<<<(int)(((size_t)E * 16 + 255) / 256), 256, 0, stream>>>(elist, Ybuf, Yp, E);
    // staging dead from here; tab16/k16/v16/ddl may overwrite it
    pack_w_kernel<<<(18 * 8192 + 255) / 256, 256, 0, stream>>>(Wq, Wk, Wv, Wo, Wq2, Wk2, Wpk);
    build_table_kernel<<<dim3(TAB_N / 4, TINTER), 256, 0, stream>>>(Wrbf1, brbf1, Wrbf2, tab16);
    ev0_kernel<<<(N + 15) / 16, 256, 0, stream>>>(off, Yp, rcC, evb, N);
    embed_kernel<<<N, F, 0, stream>>>(species, embed, f, N);

    int nmb = (N + 63) / 64;
    int npb = (N + 3) / 4;
    int nxb = (N + XNB - 1) / XNB;
    int edb = (E + 255) / 256;
    for (int t = 0; t < TINTER; t++) {
        const unsigned int* Wpk_q  = Wpk + (size_t)(0 * 3 + t) * 8192;
        const unsigned int* Wpk_k  = Wpk + (size_t)(1 * 3 + t) * 8192;
        const unsigned int* Wpk_v  = Wpk + (size_t)(2 * 3 + t) * 8192;
        const unsigned int* Wpk_o  = Wpk + (size_t)(3 * 3 + t) * 8192;
        const unsigned int* Wpk_q2 = Wpk + (size_t)(4 * 3 + t) * 8192;
        const unsigned int* Wpk_k2 = Wpk + (size_t)(5 * 3 + t) * 8192;
        const unsigned int* tab_t = tab16 + (size_t)t * TAB_N * 64;
        const float* Wdeg_t = Wdeg + (size_t)t * 4 * F;
        node_gemm_mfma_kernel<<<nmb, 256, 0, stream>>>(f, Wpk_q, Wpk_k, Wpk_v,
                                                       q, k16, v16, N, 3, 0);
        dd_kernel<<<edb, 256, 0, stream>>>(sp, rcvp, evb, ddl, E);
        edge_pass_node_kernel<<<npb, 256, 0, stream>>>(off, sp, rcC, ddl, Yp,
            q, k16, v16, tab_t, Wdeg_t, agg, N, 0);
        node_gemm_mfma_kernel<<<nmb, 256, 0, stream>>>(agg, Wpk_o, nullptr, nullptr,
                                                       f, nullptr, nullptr, N, 1, 1);
        node_gemm_mfma_kernel<<<nmb, 256, 0, stream>>>(f, Wpk_q2, Wpk_k2, nullptr,
                                                       q, k16, nullptr, N, 2, 0);
        edge_pass_node_kernel<<<npb, 256, 0, stream>>>(off, sp, rcC, ddl, Yp,
            q, k16, nullptr, tab_t, Wdeg_t, dEv, N, 1);
        exchange_kernel<<<nxb, F, 0, stream>>>(f, evb, dEv,
            Wex1 + (size_t)t * (F + 4) * F, bex1 + (size_t)t * F,
            Wex2 + (size_t)t * F * (F + 4), bex2 + (size_t)t * (F + 4), N);
    }
    readout_node_kernel<<<nxb, F, 0, stream>>>(f, Wo1, bo1, Wo2, bo2, node_e, N);
    hipMemsetAsync(d_out, 0, (size_t)out_size * sizeof(float), stream);
    energy_reduce_kernel<<<16, 256, 0, stream>>>(node_e, batch, (float*)d_out, N);
}

// Round 7
// 1261.207 us; speedup vs baseline: 6.7449x; 1.0787x over previous
//
#include <hip/hip_runtime.h>
#include <math.h>

// ---- static config (matches reference) ----
#define F 128
#define KRBF 32
#define TINTER 3
#define RMAX 5.0f
#define INV_AVG (1.0f/16.0f)
#define GAMMA 40.96f               // (KRBF/RMAX)^2
#define RSQRT_DH 0.17677669529663689f  // 1/sqrt(32)
#define PI_F 3.14159265358979323846f
#define TAB_N 2048                 // w(r) interpolation table entries over [0, RMAX]
#define XNB 16                     // nodes per block in exchange / readout
#define APITCH 68                  // LDS A-tile pitch in dwords (136 bf16, 16B-aligned rows)

__device__ __forceinline__ float silu_f(float x) { return x / (1.0f + expf(-x)); }
__device__ __forceinline__ int deg_of(int c) { return (c == 0) ? 0 : (c < 4) ? 1 : (c < 9) ? 2 : 3; }

// bf16x2 pack/unpack: packed word = (elem0) | (elem1 << 16), RNE rounding
__device__ __forceinline__ unsigned int pk_bf2(float lo, float hi) {
    unsigned int a = __float_as_uint(lo), b = __float_as_uint(hi);
    unsigned int ar = (a + 0x7fffu + ((a >> 16) & 1u)) >> 16;
    unsigned int br = (b + 0x7fffu + ((b >> 16) & 1u)) >> 16;
    return ar | (br << 16);
}
__device__ __forceinline__ float up_lo(unsigned int u) { return __uint_as_float(u << 16); }
__device__ __forceinline__ float up_hi(unsigned int u) { return __uint_as_float(u & 0xffff0000u); }

typedef short s16x8 __attribute__((ext_vector_type(8)));
typedef float f32x4 __attribute__((ext_vector_type(4)));
union FragU { uint4 u; s16x8 s; };

// ---------------------------------------------------------------------------
// CSR build: count -> scan -> scatter (receivers fixed for whole launch)
// ---------------------------------------------------------------------------
__global__ void count_kernel(const int* __restrict__ rcv, int* __restrict__ cnt, int E)
{
    int e = blockIdx.x * blockDim.x + threadIdx.x;
    if (e < E) atomicAdd(&cnt[rcv[e]], 1);
}

__global__ __launch_bounds__(1024) void scan_kernel(const int* __restrict__ cnt,
                                                    int* __restrict__ off,
                                                    int* __restrict__ cur, int N)
{
    __shared__ int part[1024];
    int t = threadIdx.x;
    int chunk = (N + 1023) / 1024;
    int lo = t * chunk, hi = min(lo + chunk, N);
    int sum = 0;
    for (int i = lo; i < hi; i++) sum += cnt[i];
    part[t] = sum;
    __syncthreads();
    for (int st = 1; st < 1024; st <<= 1) {
        int v = (t >= st) ? part[t - st] : 0;
        __syncthreads();
        part[t] += v;
        __syncthreads();
    }
    int run = (t == 0) ? 0 : part[t - 1];
    for (int i = lo; i < hi; i++) {
        off[i] = run; cur[i] = run;
        run += cnt[i];
    }
    if (t == 1023) off[N] = part[1023];
}

__global__ void scatter_kernel(const int* __restrict__ rcv, int* __restrict__ cur,
                               int* __restrict__ elist, int E)
{
    int e = blockIdx.x * blockDim.x + threadIdx.x;
    if (e < E) {
        int p = atomicAdd(&cur[rcv[e]], 1);
        elist[p] = e;
    }
}

// ---------------------------------------------------------------------------
// Edge geometry: r, C, Y[16] in edge order (staging; permuted to CSR after)
// ---------------------------------------------------------------------------
__global__ void edge_geom_kernel(const float* __restrict__ pos,
                                 const int* __restrict__ snd,
                                 const int* __restrict__ rcv,
                                 float* __restrict__ r_out,
                                 float* __restrict__ C_out,
                                 float* __restrict__ Y_out,
                                 int E)
{
    int e = blockIdx.x * blockDim.x + threadIdx.x;
    if (e >= E) return;
    int s = snd[e], rc = rcv[e];
    float vx = pos[rc * 3 + 0] - pos[s * 3 + 0];
    float vy = pos[rc * 3 + 1] - pos[s * 3 + 1];
    float vz = pos[rc * 3 + 2] - pos[s * 3 + 2];
    float r = sqrtf(vx * vx + vy * vy + vz * vz);
    float rinv = 1.0f / fmaxf(r, 1e-9f);
    float x = vx * rinv, y = vy * rinv, z = vz * rinv;
    float x2 = x * x, y2 = y * y, z2 = z * z;
    const float s3 = 1.7320508075688772f, s5 = 2.23606797749979f, s15 = 3.872983346207417f;
    const float s70 = 8.366600265340756f, s105 = 10.246950765959598f;
    const float s42 = 6.48074069840786f, s7 = 2.6457513110645907f;
    float Y[16];
    Y[0] = 1.0f;
    Y[1] = s3 * x; Y[2] = s3 * y; Y[3] = s3 * z;
    Y[4] = s15 * x * y; Y[5] = s15 * y * z; Y[6] = 0.5f * s5 * (3.0f * z2 - 1.0f);
    Y[7] = s15 * x * z; Y[8] = 0.5f * s15 * (x2 - y2);
    Y[9]  = 0.25f * s70 * y * (3.0f * x2 - y2);
    Y[10] = s105 * x * y * z;
    Y[11] = 0.25f * s42 * y * (5.0f * z2 - 1.0f);
    Y[12] = 0.5f * s7 * z * (5.0f * z2 - 3.0f);
    Y[13] = 0.25f * s42 * x * (5.0f * z2 - 1.0f);
    Y[14] = 0.5f * s105 * z * (x2 - y2);
    Y[15] = 0.25f * s70 * x * (x2 - 3.0f * y2);
    float C = (r < RMAX) ? 0.5f * (cosf(PI_F * r / RMAX) + 1.0f) : 0.0f;
    r_out[e] = r; C_out[e] = C;
    #pragma unroll
    for (int c = 0; c < 16; c++) Y_out[e * 16 + c] = Y[c];
}

// ---------------------------------------------------------------------------
// Permute edge data into CSR order
// ---------------------------------------------------------------------------
__global__ void perm_edge_kernel(const int* __restrict__ elist,
                                 const int* __restrict__ snd, const int* __restrict__ rcv,
                                 const float* __restrict__ rbuf, const float* __restrict__ Cbuf,
                                 int* __restrict__ sp, int* __restrict__ rcvp,
                                 float2* __restrict__ rcC, int E)
{
    int ei = blockIdx.x * blockDim.x + threadIdx.x;
    if (ei >= E) return;
    int e = elist[ei];
    sp[ei] = snd[e];
    rcvp[ei] = rcv[e];
    rcC[ei] = make_float2(rbuf[e], Cbuf[e]);
}

__global__ void perm_Y_kernel(const int* __restrict__ elist,
                              const float* __restrict__ Ybuf,
                              float* __restrict__ Yp, int E)
{
    long long tid = (long long)blockIdx.x * blockDim.x + threadIdx.x;
    if (tid >= (long long)E * 16) return;
    int ei = (int)(tid >> 4), c = (int)(tid & 15);
    Yp[tid] = Ybuf[(size_t)elist[ei] * 16 + c];
}

// ---------------------------------------------------------------------------
// ev0[n] = sum_{ei in CSR(n)} Yp[ei]*C[ei] * INV_AVG  (16 lanes/node, streamed)
// ---------------------------------------------------------------------------
__global__ void ev0_kernel(const int* __restrict__ off,
                           const float* __restrict__ Yp, const float2* __restrict__ rcC,
                           float* __restrict__ ev, int N)
{
    int n = blockIdx.x * 16 + (threadIdx.x >> 4);
    int c = threadIdx.x & 15;
    if (n >= N) return;
    float acc = 0.0f;
    int e0 = off[n], e1 = off[n + 1];
    for (int ei = e0; ei < e1; ei++)
        acc += Yp[(size_t)ei * 16 + c] * rcC[ei].y;
    ev[n * 16 + c] = acc * INV_AVG;
}

// ---------------------------------------------------------------------------
// f = embed[species]
// ---------------------------------------------------------------------------
__global__ void embed_kernel(const int* __restrict__ species,
                             const float* __restrict__ embed,
                             float* __restrict__ f, int N)
{
    int n = blockIdx.x;
    if (n >= N) return;
    int j = threadIdx.x;
    f[n * F + j] = embed[species[n] * F + j];
}

// ---------------------------------------------------------------------------
// Pack 18 128x128 fp32 weight matrices into MFMA B-operand bf16 layout.
// ---------------------------------------------------------------------------
__global__ void pack_w_kernel(const float* __restrict__ Wq, const float* __restrict__ Wk,
                              const float* __restrict__ Wv, const float* __restrict__ Wo,
                              const float* __restrict__ Wq2, const float* __restrict__ Wk2,
                              unsigned int* __restrict__ Wpk)
{
    int tid = blockIdx.x * blockDim.x + threadIdx.x;
    if (tid >= 18 * 8192) return;
    int mat = tid >> 13;
    int rem = tid & 8191;
    int iw = rem & 3;
    int n = (rem >> 2) & 15;
    int quad = (rem >> 6) & 3;
    int kb = (rem >> 8) & 3;
    int ct = rem >> 10;
    const float* fam = (mat < 3) ? Wq : (mat < 6) ? Wk : (mat < 9) ? Wv
                     : (mat < 12) ? Wo : (mat < 15) ? Wq2 : Wk2;
    const float* src = fam + (size_t)(mat % 3) * F * F;
    int k = kb * 32 + quad * 8 + iw * 2;
    int col = ct * 16 + n;
    Wpk[tid] = pk_bf2(src[k * F + col], src[(k + 1) * F + col]);
}

// ---------------------------------------------------------------------------
// Build packed-bf16 w(r) table: tab16[t][i][l] = bf16x2(w[2l], w[2l+1])
// ---------------------------------------------------------------------------
__global__ __launch_bounds__(256) void build_table_kernel(
    const float* __restrict__ Wrbf1_all, const float* __restrict__ brbf1_all,
    const float* __restrict__ Wrbf2_all, unsigned int* __restrict__ tab16)
{
    int wave = threadIdx.x >> 6;
    int lane = threadIdx.x & 63;
    int idx = blockIdx.x * 4 + wave;
    int t = blockIdx.y;
    const float* W1 = Wrbf1_all + (size_t)t * KRBF * F;
    const float* b1 = brbf1_all + (size_t)t * F;
    const float* W2 = Wrbf2_all + (size_t)t * F * F;
    float r = idx * (RMAX / (TAB_N - 1));
    __shared__ float sR[4][KRBF];
    __shared__ float sH[4][F];
    if (lane < KRBF) {
        float mu = lane * (RMAX / (KRBF - 1));
        float d = r - mu;
        sR[wave][lane] = expf(-GAMMA * d * d);
    }
    __syncthreads();
    float h0 = b1[lane], h1 = b1[lane + 64];
    #pragma unroll
    for (int kk = 0; kk < KRBF; kk++) {
        float rv = sR[wave][kk];
        h0 += rv * W1[kk * F + lane];
        h1 += rv * W1[kk * F + lane + 64];
    }
    sH[wave][lane] = silu_f(h0);
    sH[wave][lane + 64] = silu_f(h1);
    __syncthreads();
    float w0 = 0.0f, w1 = 0.0f;
    for (int i = 0; i < F; i++) {
        float hv = sH[wave][i];
        w0 += hv * W2[i * F + 2 * lane];
        w1 += hv * W2[i * F + 2 * lane + 1];
    }
    tab16[((size_t)t * TAB_N + idx) * 64 + lane] = pk_bf2(w0, w1);
}

// ---------------------------------------------------------------------------
// dd_list[ei] = deg_reduce(ev[sp[ei]] * ev[rcvp[ei]])  (CSR order, float4)
// ---------------------------------------------------------------------------
__global__ void dd_kernel(const int* __restrict__ sp, const int* __restrict__ rcvp,
                          const float* __restrict__ ev, float4* __restrict__ ddl, int E)
{
    int ei = blockIdx.x * blockDim.x + threadIdx.x;
    if (ei >= E) return;
    int s = sp[ei], rc = rcvp[ei];
    const float4* a = (const float4*)(ev + (size_t)s * 16);
    const float4* b = (const float4*)(ev + (size_t)rc * 16);
    float4 a0 = a[0], a1 = a[1], a2 = a[2], a3 = a[3];
    float4 b0 = b[0], b1 = b[1], b2 = b[2], b3 = b[3];
    float d0 = a0.x * b0.x;
    float d1 = a0.y * b0.y + a0.z * b0.z + a0.w * b0.w;
    float d2 = a1.x * b1.x + a1.y * b1.y + a1.z * b1.z + a1.w * b1.w + a2.x * b2.x;
    float d3 = a2.y * b2.y + a2.z * b2.z + a2.w * b2.w
             + a3.x * b3.x + a3.y * b3.y + a3.z * b3.z + a3.w * b3.w;
    ddl[ei] = make_float4(d0, d1, d2, d3);
}

// ---------------------------------------------------------------------------
// MFMA node GEMM: out[m] = A @ W[m]. 64 nodes/block, 4 waves, 16x16x32 bf16.
// m==0 -> fp32 out0 (optional accumulate).
// m>=1 -> packed bf16x2 (2j,2j+1); ileave=1 writes m=1/m=2 interleaved as
// uint2 (k,v) into out1; ileave=0 writes plain into out1/out2.
// ---------------------------------------------------------------------------
__global__ __launch_bounds__(256) void node_gemm_mfma_kernel(
    const float* __restrict__ A,
    const unsigned int* __restrict__ B0, const unsigned int* __restrict__ B1,
    const unsigned int* __restrict__ B2,
    float* __restrict__ out0, unsigned int* __restrict__ out1, unsigned int* __restrict__ out2,
    int N, int nw, int accumulate, int ileave)
{
    __shared__ unsigned int sA[64 * APITCH];
    int tid = threadIdx.x;
    int n0 = blockIdx.x * 64;
    #pragma unroll
    for (int rep = 0; rep < 16; rep++) {
        int idx = rep * 256 + tid;            // 0..4095
        int node = idx >> 6, jj = idx & 63;
        int n = n0 + node;
        float2 v = (n < N) ? ((const float2*)A)[(size_t)n * 64 + jj] : make_float2(0.f, 0.f);
        sA[node * APITCH + jj] = pk_bf2(v.x, v.y);
    }
    __syncthreads();
    int wave = tid >> 6, lane = tid & 63;
    int quad = lane >> 4, col = lane & 15;
    int mrow = wave * 16 + col;               // A-tile row this lane supplies
    s16x8 af[4];
    #pragma unroll
    for (int kb = 0; kb < 4; kb++) {
        FragU fu;
        fu.u = *(const uint4*)&sA[mrow * APITCH + kb * 16 + quad * 4];
        af[kb] = fu.s;
    }
    for (int m = 0; m < nw; m++) {
        const unsigned int* B = (m == 0) ? B0 : (m == 1) ? B1 : B2;
        for (int ct = 0; ct < 8; ct++) {
            f32x4 acc = {0.f, 0.f, 0.f, 0.f};
            #pragma unroll
            for (int kb = 0; kb < 4; kb++) {
                FragU bu;
                bu.u = *(const uint4*)&B[(size_t)((ct * 16 + kb * 4 + quad) * 16 + col) * 4];
                acc = __builtin_amdgcn_mfma_f32_16x16x32_bf16(af[kb], bu.s, acc, 0, 0, 0);
            }
            if (m == 0) {
                #pragma unroll
                for (int r = 0; r < 4; r++) {
                    int n = n0 + wave * 16 + quad * 4 + r;
                    if (n < N) {
                        size_t ix = (size_t)n * F + ct * 16 + col;
                        out0[ix] = accumulate ? out0[ix] + acc[r] : acc[r];
                    }
                }
            } else {
                unsigned int* o16 = (m == 1) ? out1 : out2;
                #pragma unroll
                for (int r = 0; r < 4; r++) {
                    float other = __shfl_xor(acc[r], 1, 64);
                    if (!(lane & 1)) {
                        int n = n0 + wave * 16 + quad * 4 + r;
                        if (n < N) {
                            size_t base = (size_t)n * 64 + ct * 8 + (col >> 1);
                            if (ileave)
                                out1[base * 2 + (m - 1)] = pk_bf2(acc[r], other);
                            else
                                o16[base] = pk_bf2(acc[r], other);
                        }
                    }
                }
            }
        }
    }
}

// ---------------------------------------------------------------------------
// Per-edge alpha: table lerp + Wdeg correction + qk dot + per-head reduce.
// ---------------------------------------------------------------------------
__device__ __forceinline__ float edge_alpha(
    int lane, float2 qq, const float* sWdeg,
    const unsigned int* __restrict__ tab16,
    float2 rc2, float4 dd, unsigned int ku)
{
    float u = rc2.x * ((float)(TAB_N - 1) / RMAX);
    int i0 = (int)u;
    i0 = (i0 > TAB_N - 2) ? (TAB_N - 2) : i0;
    float fr = u - (float)i0;
    unsigned int ta = tab16[(size_t)i0 * 64 + lane];
    unsigned int tb = tab16[(size_t)(i0 + 1) * 64 + lane];
    float a0 = up_lo(ta), a1 = up_hi(ta);
    float b0 = up_lo(tb), b1 = up_hi(tb);
    int j0 = 2 * lane, j1 = 2 * lane + 1;
    float w0 = a0 + fr * (b0 - a0)
             + dd.x * sWdeg[j0] + dd.y * sWdeg[F + j0]
             + dd.z * sWdeg[2 * F + j0] + dd.w * sWdeg[3 * F + j0];
    float w1 = a1 + fr * (b1 - a1)
             + dd.x * sWdeg[j1] + dd.y * sWdeg[F + j1]
             + dd.z * sWdeg[2 * F + j1] + dd.w * sWdeg[3 * F + j1];
    float p = qq.x * w0 * up_lo(ku) + qq.y * w1 * up_hi(ku);
    #pragma unroll
    for (int o = 1; o < 16; o <<= 1) p += __shfl_xor(p, o, 64);
    return p * (rc2.y * RSQRT_DH * INV_AVG);
}

// ---------------------------------------------------------------------------
// Node-centric fused edge pass, 2-way unrolled edge loop for ILP.
// mode 0 -> agg[n,128] (kv16 interleaved gather); mode 1 -> dEv[n,16] (k16p).
// ---------------------------------------------------------------------------
__global__ __launch_bounds__(256) void edge_pass_node_kernel(
    const int* __restrict__ off, const int* __restrict__ sp,
    const float2* __restrict__ rcC, const float4* __restrict__ ddl,
    const float* __restrict__ Yp,
    const float* __restrict__ qbuf,
    const uint2* __restrict__ kv16, const unsigned int* __restrict__ k16p,
    const unsigned int* __restrict__ tab16, const float* __restrict__ Wdeg_t,
    float* __restrict__ outbuf, int N, int mode)
{
    __shared__ float sWdeg[4 * F];
    for (int i = threadIdx.x; i < 4 * F; i += 256) sWdeg[i] = Wdeg_t[i];
    __syncthreads();

    int wave = threadIdx.x >> 6;
    int lane = threadIdx.x & 63;
    int n = blockIdx.x * 4 + wave;
    if (n >= N) return;

    int e0 = off[n], e1 = off[n + 1];
    float2 qq = ((const float2*)qbuf)[(size_t)n * 64 + lane];
    float acc0 = 0.0f, acc1 = 0.0f;   // mode 0 accumulators
    float devacc = 0.0f;              // mode 1 accumulator (lane<16)

    int ei = e0;
    if (mode == 0) {
        for (; ei + 1 < e1; ei += 2) {
            int sA = sp[ei], sB = sp[ei + 1];
            float2 rcA = rcC[ei], rcB = rcC[ei + 1];
            float4 ddA = ddl[ei], ddB = ddl[ei + 1];
            uint2 kvA = kv16[(size_t)sA * 64 + lane];
            uint2 kvB = kv16[(size_t)sB * 64 + lane];
            float alA = edge_alpha(lane, qq, sWdeg, tab16, rcA, ddA, kvA.x);
            float alB = edge_alpha(lane, qq, sWdeg, tab16, rcB, ddB, kvB.x);
            acc0 += alA * up_lo(kvA.y) + alB * up_lo(kvB.y);
            acc1 += alA * up_hi(kvA.y) + alB * up_hi(kvB.y);
        }
        if (ei < e1) {
            int sA = sp[ei];
            uint2 kvA = kv16[(size_t)sA * 64 + lane];
            float alA = edge_alpha(lane, qq, sWdeg, tab16, rcC[ei], ddl[ei], kvA.x);
            acc0 += alA * up_lo(kvA.y);
            acc1 += alA * up_hi(kvA.y);
        }
        ((float2*)outbuf)[(size_t)n * 64 + lane] = make_float2(acc0, acc1);
    } else {
        for (; ei + 1 < e1; ei += 2) {
            int sA = sp[ei], sB = sp[ei + 1];
            float2 rcA = rcC[ei], rcB = rcC[ei + 1];
            float4 ddA = ddl[ei], ddB = ddl[ei + 1];
            unsigned int kA = k16p[(size_t)sA * 64 + lane];
            unsigned int kB = k16p[(size_t)sB * 64 + lane];
            float alA = edge_alpha(lane, qq, sWdeg, tab16, rcA, ddA, kA);
            float alB = edge_alpha(lane, qq, sWdeg, tab16, rcB, ddB, kB);
            float aA0 = __shfl(alA, 0), aA1 = __shfl(alA, 16);
            float aA2 = __shfl(alA, 32), aA3 = __shfl(alA, 48);
            float aB0 = __shfl(alB, 0), aB1 = __shfl(alB, 16);
            float aB2 = __shfl(alB, 32), aB3 = __shfl(alB, 48);
            if (lane < 16) {
                float adA = (lane == 0) ? aA0 : (lane < 4) ? aA1 : (lane < 9) ? aA2 : aA3;
                float adB = (lane == 0) ? aB0 : (lane < 4) ? aB1 : (lane < 9) ? aB2 : aB3;
                devacc += adA * Yp[(size_t)ei * 16 + lane]
                        + adB * Yp[(size_t)(ei + 1) * 16 + lane];
            }
        }
        if (ei < e1) {
            int sA = sp[ei];
            unsigned int kA = k16p[(size_t)sA * 64 + lane];
            float alA = edge_alpha(lane, qq, sWdeg, tab16, rcC[ei], ddl[ei], kA);
            float aA0 = __shfl(alA, 0), aA1 = __shfl(alA, 16);
            float aA2 = __shfl(alA, 32), aA3 = __shfl(alA, 48);
            if (lane < 16) {
                float adA = (lane == 0) ? aA0 : (lane < 4) ? aA1 : (lane < 9) ? aA2 : aA3;
                devacc += adA * Yp[(size_t)ei * 16 + lane];
            }
        }
        if (lane < 16) outbuf[n * 16 + lane] = devacc;
    }
}

// ---------------------------------------------------------------------------
// Exchange block, XNB nodes per 128-thread block.
// ---------------------------------------------------------------------------
__global__ __launch_bounds__(128) void exchange_kernel(
    float* __restrict__ f, float* __restrict__ ev, const float* __restrict__ dEv,
    const float* __restrict__ Wex1, const float* __restrict__ bex1,
    const float* __restrict__ Wex2, const float* __restrict__ bex2, int N)
{
    __shared__ float sIn[XNB][F + 4];
    __shared__ float sHid[XNB][F];
    __shared__ float sev[XNB][16];
    __shared__ float syb[XNB][4];
    int n0 = blockIdx.x * XNB;
    int j = threadIdx.x;
    #pragma unroll
    for (int nn = 0; nn < XNB; nn++) {
        int n = n0 + nn;
        sIn[nn][j] = (n < N) ? f[(size_t)n * F + j] : 0.0f;
    }
    for (int idx = j; idx < XNB * 16; idx += 128) {
        int nn = idx >> 4, c = idx & 15;
        int n = n0 + nn;
        sev[nn][c] = (n < N) ? (ev[n * 16 + c] + dEv[n * 16 + c]) : 0.0f;
    }
    __syncthreads();
    if (j < XNB * 4) {
        int nn = j >> 2, d = j & 3;
        int c0 = (d == 0) ? 0 : (d == 1) ? 1 : (d == 2) ? 4 : 9;
        int c1 = (d == 0) ? 1 : (d == 1) ? 4 : (d == 2) ? 9 : 16;
        float a = 0.0f;
        for (int c = c0; c < c1; c++) a += sev[nn][c] * sev[nn][c];
        sIn[nn][F + d] = a;
    }
    __syncthreads();
    float acc[XNB];
    #pragma unroll
    for (int nn = 0; nn < XNB; nn++) acc[nn] = bex1[j];
    for (int i = 0; i < F + 4; i++) {
        float w = Wex1[i * F + j];
        #pragma unroll
        for (int nn = 0; nn < XNB; nn++) acc[nn] += sIn[nn][i] * w;
    }
    #pragma unroll
    for (int nn = 0; nn < XNB; nn++) sHid[nn][j] = silu_f(acc[nn]);
    __syncthreads();
    float yb[XNB];
    #pragma unroll
    for (int nn = 0; nn < XNB; nn++) yb[nn] = bex2[j];
    for (int i = 0; i < F; i++) {
        float w = Wex2[i * (F + 4) + j];
        #pragma unroll
        for (int nn = 0; nn < XNB; nn++) yb[nn] += sHid[nn][i] * w;
    }
    if (j < XNB * 4) {
        int nn = j >> 2, d = j & 3;
        float a = bex2[F + d];
        for (int i = 0; i < F; i++) a += sHid[nn][i] * Wex2[i * (F + 4) + F + d];
        syb[nn][d] = a;
    }
    __syncthreads();
    #pragma unroll
    for (int nn = 0; nn < XNB; nn++) {
        int n = n0 + nn;
        if (n < N) f[(size_t)n * F + j] = sIn[nn][j] + yb[nn];
    }
    for (int idx = j; idx < XNB * 16; idx += 128) {
        int nn = idx >> 4, c = idx & 15;
        int n = n0 + nn;
        if (n < N) ev[n * 16 + c] = sev[nn][c] * (1.0f + syb[nn][deg_of(c)]);
    }
}

// ---------------------------------------------------------------------------
// Readout stage 1: node_e[n] = silu(f@Wo1+bo1)@Wo2 + bo2
// ---------------------------------------------------------------------------
__global__ __launch_bounds__(128) void readout_node_kernel(
    const float* __restrict__ f,
    const float* __restrict__ Wo1, const float* __restrict__ bo1,
    const float* __restrict__ Wo2, const float* __restrict__ bo2,
    float* __restrict__ node_e, int N)
{
    __shared__ float sA[XNB][F];
    __shared__ float swave[2][XNB];
    int n0 = blockIdx.x * XNB;
    int j = threadIdx.x;
    #pragma unroll
    for (int nn = 0; nn < XNB; nn++) {
        int n = n0 + nn;
        sA[nn][j] = (n < N) ? f[(size_t)n * F + j] : 0.0f;
    }
    __syncthreads();
    float acc[XNB];
    #pragma unroll
    for (int nn = 0; nn < XNB; nn++) acc[nn] = bo1[j];
    for (int i = 0; i < F; i += 4) {
        float w0 = Wo1[(i + 0) * F + j];
        float w1 = Wo1[(i + 1) * F + j];
        float w2 = Wo1[(i + 2) * F + j];
        float w3 = Wo1[(i + 3) * F + j];
        #pragma unroll
        for (int nn = 0; nn < XNB; nn++) {
            float4 a = *(const float4*)&sA[nn][i];
            acc[nn] += a.x * w0 + a.y * w1 + a.z * w2 + a.w * w3;
        }
    }
    float wo2 = Wo2[j];
    #pragma unroll
    for (int nn = 0; nn < XNB; nn++) {
        float z = silu_f(acc[nn]) * wo2;
        #pragma unroll
        for (int o = 1; o < 64; o <<= 1) z += __shfl_xor(z, o, 64);
        if ((j & 63) == 0) swave[j >> 6][nn] = z;
    }
    __syncthreads();
    if (j < XNB) {
        int n = n0 + j;
        if (n < N) node_e[n] = swave[0][j] + swave[1][j] + bo2[0];
    }
}

// ---------------------------------------------------------------------------
// Readout stage 2: energy[g] = sum_{batch[n]==g} node_e[n]
// ---------------------------------------------------------------------------
__global__ __launch_bounds__(256) void energy_reduce_kernel(
    const float* __restrict__ node_e, const int* __restrict__ batch,
    float* __restrict__ energy, int N)
{
    __shared__ float eacc[64];
    if (threadIdx.x < 64) eacc[threadIdx.x] = 0.0f;
    __syncthreads();
    for (int n = blockIdx.x * blockDim.x + threadIdx.x; n < N; n += gridDim.x * blockDim.x)
        atomicAdd(&eacc[batch[n]], node_e[n]);
    __syncthreads();
    if (threadIdx.x < 64) atomicAdd(&energy[threadIdx.x], eacc[threadIdx.x]);
}

// ---------------------------------------------------------------------------
extern "C" void kernel_launch(void* const* d_in, const int* in_sizes, int n_in,
                              void* d_out, int out_size, void* d_ws, size_t ws_size,
                              hipStream_t stream)
{
    const float* positions = (const float*)d_in[0];
    const int*   species   = (const int*)d_in[1];
    const int*   senders   = (const int*)d_in[2];
    const int*   receivers = (const int*)d_in[3];
    const int*   batch     = (const int*)d_in[4];
    const float* embed     = (const float*)d_in[5];
    const float* Wq    = (const float*)d_in[6];
    const float* Wk    = (const float*)d_in[7];
    const float* Wv    = (const float*)d_in[8];
    const float* Wo    = (const float*)d_in[9];
    const float* Wrbf1 = (const float*)d_in[10];
    const float* brbf1 = (const float*)d_in[11];
    const float* Wrbf2 = (const float*)d_in[12];
    const float* Wdeg  = (const float*)d_in[13];
    const float* Wq2   = (const float*)d_in[14];
    const float* Wk2   = (const float*)d_in[15];
    const float* Wex1  = (const float*)d_in[16];
    const float* bex1  = (const float*)d_in[17];
    const float* Wex2  = (const float*)d_in[18];
    const float* bex2  = (const float*)d_in[19];
    const float* Wo1   = (const float*)d_in[20];
    const float* bo1   = (const float*)d_in[21];
    const float* Wo2   = (const float*)d_in[22];
    const float* bo2   = (const float*)d_in[23];

    int N = in_sizes[0] / 3;
    int E = in_sizes[2];

    // ---- workspace layout (~126 MB), staging region aliased ----
    float* ws     = (float*)d_ws;
    float* Yp     = ws;  ws += (size_t)E * 16;        // CSR-ordered Y
    float2* rcC   = (float2*)ws; ws += (size_t)E * 2; // CSR-ordered (r, C)
    float* f      = ws;  ws += (size_t)N * F;
    float* evb    = ws;  ws += (size_t)N * 16;
    float* dEv    = ws;  ws += (size_t)N * 16;
    float* q      = ws;  ws += (size_t)N * F;
    float* agg    = ws;  ws += (size_t)N * F;
    float* node_e = ws;  ws += (size_t)N;
    // union region: staging (rbuf/Cbuf/Ybuf, E*18 floats) then tab16/kv16/k16p/ddl
    float* un     = ws;  ws += (size_t)E * 18;
    float* rbuf   = un;
    float* Cbuf   = un + E;
    float* Ybuf   = un + (size_t)2 * E;
    unsigned int* tab16 = (unsigned int*)un;                       // 3*TAB_N*64
    uint2* kv16 = (uint2*)(tab16 + (size_t)TINTER * TAB_N * 64);   // N*64 uint2 (k,v)
    unsigned int* k16p = (unsigned int*)(kv16 + (size_t)N * 64);   // N*64 (k2)
    float4* ddl   = (float4*)(k16p + (size_t)N * 64);              // E
    int* sp    = (int*)ws;  ws += E;
    int* rcvp  = (int*)ws;  ws += E;
    int* cnt   = (int*)ws;  ws += N;
    int* off   = (int*)ws;  ws += N + 1;
    int* cur   = (int*)ws;  ws += N;
    int* elist = (int*)ws;  ws += E;
    unsigned int* Wpk = (unsigned int*)ws;  ws += 18 * 8192;       // packed MFMA weights

    // ---- CSR build (receivers constant across iterations) ----
    hipMemsetAsync(cnt, 0, (size_t)N * sizeof(int), stream);
    count_kernel<<<(E + 255) / 256, 256, 0, stream>>>(receivers, cnt, E);
    scan_kernel<<<1, 1024, 0, stream>>>(cnt, off, cur, N);
    scatter_kernel<<<(E + 255) / 256, 256, 0, stream>>>(receivers, cur, elist, E);

    // ---- geometry + CSR-order permute (staging region live) ----
    edge_geom_kernel<<<(E + 255) / 256, 256, 0, stream>>>(positions, senders, receivers,
                                                          rbuf, Cbuf, Ybuf, E);
    perm_edge_kernel<<<(E + 255) / 256, 256, 0, stream>>>(elist, senders, receivers,
                                                          rbuf, Cbuf, sp, rcvp, rcC, E);
    perm_Y_kernel<<<(int)(((size_t)E * 16 + 255) / 256), 256, 0, stream>>>(elist, Ybuf, Yp, E);
    // staging dead from here; tab16/kv16/k16p/ddl may overwrite it
    pack_w_kernel<<<(18 * 8192 + 255) / 256, 256, 0, stream>>>(Wq, Wk, Wv, Wo, Wq2, Wk2, Wpk);
    build_table_kernel<<<dim3(TAB_N / 4, TINTER), 256, 0, stream>>>(Wrbf1, brbf1, Wrbf2, tab16);
    ev0_kernel<<<(N + 15) / 16, 256, 0, stream>>>(off, Yp, rcC, evb, N);
    embed_kernel<<<N, F, 0, stream>>>(species, embed, f, N);

    int nmb = (N + 63) / 64;
    int npb = (N + 3) / 4;
    int nxb = (N + XNB - 1) / XNB;
    int edb = (E + 255) / 256;
    for (int t = 0; t < TINTER; t++) {
        const unsigned int* Wpk_q  = Wpk + (size_t)(0 * 3 + t) * 8192;
        const unsigned int* Wpk_k  = Wpk + (size_t)(1 * 3 + t) * 8192;
        const unsigned int* Wpk_v  = Wpk + (size_t)(2 * 3 + t) * 8192;
        const unsigned int* Wpk_o  = Wpk + (size_t)(3 * 3 + t) * 8192;
        const unsigned int* Wpk_q2 = Wpk + (size_t)(4 * 3 + t) * 8192;
        const unsigned int* Wpk_k2 = Wpk + (size_t)(5 * 3 + t) * 8192;
        const unsigned int* tab_t = tab16 + (size_t)t * TAB_N * 64;
        const float* Wdeg_t = Wdeg + (size_t)t * 4 * F;
        node_gemm_mfma_kernel<<<nmb, 256, 0, stream>>>(f, Wpk_q, Wpk_k, Wpk_v,
                                                       q, (unsigned int*)kv16, nullptr,
                                                       N, 3, 0, 1);
        dd_kernel<<<edb, 256, 0, stream>>>(sp, rcvp, evb, ddl, E);
        edge_pass_node_kernel<<<npb, 256, 0, stream>>>(off, sp, rcC, ddl, Yp,
            q, kv16, nullptr, tab_t, Wdeg_t, agg, N, 0);
        node_gemm_mfma_kernel<<<nmb, 256, 0, stream>>>(agg, Wpk_o, nullptr, nullptr,
                                                       f, nullptr, nullptr, N, 1, 1, 0);
        node_gemm_mfma_kernel<<<nmb, 256, 0, stream>>>(f, Wpk_q2, Wpk_k2, nullptr,
                                                       q, k16p, nullptr, N, 2, 0, 0);
        edge_pass_node_kernel<<<npb, 256, 0, stream>>>(off, sp, rcC, ddl, Yp,
            q, nullptr, k16p, tab_t, Wdeg_t, dEv, N, 1);
        exchange_kernel<<<nxb, F, 0, stream>>>(f, evb, dEv,
            Wex1 + (size_t)t * (F + 4) * F, bex1 + (size_t)t * F,
            Wex2 + (size_t)t * F * (F + 4), bex2 + (size_t)t * (F + 4), N);
    }
    readout_node_kernel<<<nxb, F, 0, stream>>>(f, Wo1, bo1, Wo2, bo2, node_e, N);
    hipMemsetAsync(d_out, 0, (size_t)out_size * sizeof(float), stream);
    energy_reduce_kernel<<<16, 256, 0, stream>>>(node_e, batch, (float*)d_out, N);
}

// Round 8
// 1197.782 us; speedup vs baseline: 7.1020x; 1.0530x over previous
//
#include <hip/hip_runtime.h>
#include <math.h>

// ---- static config (matches reference) ----
#define F 128
#define KRBF 32
#define TINTER 3
#define RMAX 5.0f
#define INV_AVG (1.0f/16.0f)
#define GAMMA 40.96f               // (KRBF/RMAX)^2
#define RSQRT_DH 0.17677669529663689f  // 1/sqrt(32)
#define PI_F 3.14159265358979323846f
#define TAB_N 2048                 // w(r) interpolation table entries over [0, RMAX]
#define APITCH 68                  // LDS A-tile pitch in dwords (16B-aligned rows)

__device__ __forceinline__ float silu_f(float x) { return x / (1.0f + expf(-x)); }
__device__ __forceinline__ int deg_of(int c) { return (c == 0) ? 0 : (c < 4) ? 1 : (c < 9) ? 2 : 3; }

// bf16x2 pack/unpack: packed word = (elem0) | (elem1 << 16), RNE rounding
__device__ __forceinline__ unsigned int pk_bf2(float lo, float hi) {
    unsigned int a = __float_as_uint(lo), b = __float_as_uint(hi);
    unsigned int ar = (a + 0x7fffu + ((a >> 16) & 1u)) >> 16;
    unsigned int br = (b + 0x7fffu + ((b >> 16) & 1u)) >> 16;
    return ar | (br << 16);
}
__device__ __forceinline__ float up_lo(unsigned int u) { return __uint_as_float(u << 16); }
__device__ __forceinline__ float up_hi(unsigned int u) { return __uint_as_float(u & 0xffff0000u); }

typedef short s16x8 __attribute__((ext_vector_type(8)));
typedef float f32x4 __attribute__((ext_vector_type(4)));
union FragU { uint4 u; s16x8 s; };

// ---------------------------------------------------------------------------
// CSR build: count -> scan -> scatter
// ---------------------------------------------------------------------------
__global__ void count_kernel(const int* __restrict__ rcv, int* __restrict__ cnt, int E)
{
    int e = blockIdx.x * blockDim.x + threadIdx.x;
    if (e < E) atomicAdd(&cnt[rcv[e]], 1);
}

__global__ __launch_bounds__(1024) void scan_kernel(const int* __restrict__ cnt,
                                                    int* __restrict__ off,
                                                    int* __restrict__ cur, int N)
{
    __shared__ int part[1024];
    int t = threadIdx.x;
    int chunk = (N + 1023) / 1024;
    int lo = t * chunk, hi = min(lo + chunk, N);
    int sum = 0;
    for (int i = lo; i < hi; i++) sum += cnt[i];
    part[t] = sum;
    __syncthreads();
    for (int st = 1; st < 1024; st <<= 1) {
        int v = (t >= st) ? part[t - st] : 0;
        __syncthreads();
        part[t] += v;
        __syncthreads();
    }
    int run = (t == 0) ? 0 : part[t - 1];
    for (int i = lo; i < hi; i++) {
        off[i] = run; cur[i] = run;
        run += cnt[i];
    }
    if (t == 1023) off[N] = part[1023];
}

__global__ void scatter_kernel(const int* __restrict__ rcv, int* __restrict__ cur,
                               int* __restrict__ elist, int E)
{
    int e = blockIdx.x * blockDim.x + threadIdx.x;
    if (e < E) {
        int p = atomicAdd(&cur[rcv[e]], 1);
        elist[p] = e;
    }
}

// ---------------------------------------------------------------------------
// Edge geometry: r, C, Y[16] in edge order (staging; permuted to CSR after)
// ---------------------------------------------------------------------------
__global__ void edge_geom_kernel(const float* __restrict__ pos,
                                 const int* __restrict__ snd,
                                 const int* __restrict__ rcv,
                                 float* __restrict__ r_out,
                                 float* __restrict__ C_out,
                                 float* __restrict__ Y_out,
                                 int E)
{
    int e = blockIdx.x * blockDim.x + threadIdx.x;
    if (e >= E) return;
    int s = snd[e], rc = rcv[e];
    float vx = pos[rc * 3 + 0] - pos[s * 3 + 0];
    float vy = pos[rc * 3 + 1] - pos[s * 3 + 1];
    float vz = pos[rc * 3 + 2] - pos[s * 3 + 2];
    float r = sqrtf(vx * vx + vy * vy + vz * vz);
    float rinv = 1.0f / fmaxf(r, 1e-9f);
    float x = vx * rinv, y = vy * rinv, z = vz * rinv;
    float x2 = x * x, y2 = y * y, z2 = z * z;
    const float s3 = 1.7320508075688772f, s5 = 2.23606797749979f, s15 = 3.872983346207417f;
    const float s70 = 8.366600265340756f, s105 = 10.246950765959598f;
    const float s42 = 6.48074069840786f, s7 = 2.6457513110645907f;
    float Y[16];
    Y[0] = 1.0f;
    Y[1] = s3 * x; Y[2] = s3 * y; Y[3] = s3 * z;
    Y[4] = s15 * x * y; Y[5] = s15 * y * z; Y[6] = 0.5f * s5 * (3.0f * z2 - 1.0f);
    Y[7] = s15 * x * z; Y[8] = 0.5f * s15 * (x2 - y2);
    Y[9]  = 0.25f * s70 * y * (3.0f * x2 - y2);
    Y[10] = s105 * x * y * z;
    Y[11] = 0.25f * s42 * y * (5.0f * z2 - 1.0f);
    Y[12] = 0.5f * s7 * z * (5.0f * z2 - 3.0f);
    Y[13] = 0.25f * s42 * x * (5.0f * z2 - 1.0f);
    Y[14] = 0.5f * s105 * z * (x2 - y2);
    Y[15] = 0.25f * s70 * x * (x2 - 3.0f * y2);
    float C = (r < RMAX) ? 0.5f * (cosf(PI_F * r / RMAX) + 1.0f) : 0.0f;
    r_out[e] = r; C_out[e] = C;
    #pragma unroll
    for (int c = 0; c < 16; c++) Y_out[e * 16 + c] = Y[c];
}

// ---------------------------------------------------------------------------
// Permute edge data into CSR order
// ---------------------------------------------------------------------------
__global__ void perm_edge_kernel(const int* __restrict__ elist,
                                 const int* __restrict__ snd, const int* __restrict__ rcv,
                                 const float* __restrict__ rbuf, const float* __restrict__ Cbuf,
                                 int* __restrict__ sp, int* __restrict__ rcvp,
                                 float2* __restrict__ rcC, int E)
{
    int ei = blockIdx.x * blockDim.x + threadIdx.x;
    if (ei >= E) return;
    int e = elist[ei];
    sp[ei] = snd[e];
    rcvp[ei] = rcv[e];
    rcC[ei] = make_float2(rbuf[e], Cbuf[e]);
}

__global__ void perm_Y_kernel(const int* __restrict__ elist,
                              const float* __restrict__ Ybuf,
                              float* __restrict__ Yp, int E)
{
    long long tid = (long long)blockIdx.x * blockDim.x + threadIdx.x;
    if (tid >= (long long)E * 16) return;
    int ei = (int)(tid >> 4), c = (int)(tid & 15);
    Yp[tid] = Ybuf[(size_t)elist[ei] * 16 + c];
}

// ---------------------------------------------------------------------------
// ev0[n] = sum_{ei in CSR(n)} Yp[ei]*C[ei] * INV_AVG
// ---------------------------------------------------------------------------
__global__ void ev0_kernel(const int* __restrict__ off,
                           const float* __restrict__ Yp, const float2* __restrict__ rcC,
                           float* __restrict__ ev, int N)
{
    int n = blockIdx.x * 16 + (threadIdx.x >> 4);
    int c = threadIdx.x & 15;
    if (n >= N) return;
    float acc = 0.0f;
    int e0 = off[n], e1 = off[n + 1];
    for (int ei = e0; ei < e1; ei++)
        acc += Yp[(size_t)ei * 16 + c] * rcC[ei].y;
    ev[n * 16 + c] = acc * INV_AVG;
}

// ---------------------------------------------------------------------------
// f = embed[species]
// ---------------------------------------------------------------------------
__global__ void embed_kernel(const int* __restrict__ species,
                             const float* __restrict__ embed,
                             float* __restrict__ f, int N)
{
    int n = blockIdx.x;
    if (n >= N) return;
    int j = threadIdx.x;
    f[n * F + j] = embed[species[n] * F + j];
}

// ---------------------------------------------------------------------------
// Pack 18 128x128 fp32 weight matrices into MFMA B-operand bf16 layout.
// ---------------------------------------------------------------------------
__global__ void pack_w_kernel(const float* __restrict__ Wq, const float* __restrict__ Wk,
                              const float* __restrict__ Wv, const float* __restrict__ Wo,
                              const float* __restrict__ Wq2, const float* __restrict__ Wk2,
                              unsigned int* __restrict__ Wpk)
{
    int tid = blockIdx.x * blockDim.x + threadIdx.x;
    if (tid >= 18 * 8192) return;
    int mat = tid >> 13;
    int rem = tid & 8191;
    int iw = rem & 3;
    int n = (rem >> 2) & 15;
    int quad = (rem >> 6) & 3;
    int kb = (rem >> 8) & 3;
    int ct = rem >> 10;
    const float* fam = (mat < 3) ? Wq : (mat < 6) ? Wk : (mat < 9) ? Wv
                     : (mat < 12) ? Wo : (mat < 15) ? Wq2 : Wk2;
    const float* src = fam + (size_t)(mat % 3) * F * F;
    int k = kb * 32 + quad * 8 + iw * 2;
    int col = ct * 16 + n;
    Wpk[tid] = pk_bf2(src[k * F + col], src[(k + 1) * F + col]);
}

// Generic 128x128 submatrix pack with arbitrary row stride (for Wex1/Wex2/Wo1)
__global__ void pack_one_kernel(const float* __restrict__ src, int rowStride,
                                unsigned int* __restrict__ dst)
{
    int tid = blockIdx.x * blockDim.x + threadIdx.x;
    if (tid >= 8192) return;
    int iw = tid & 3;
    int n = (tid >> 2) & 15;
    int quad = (tid >> 6) & 3;
    int kb = (tid >> 8) & 3;
    int ct = tid >> 10;
    int k = kb * 32 + quad * 8 + iw * 2;
    int col = ct * 16 + n;
    dst[tid] = pk_bf2(src[(size_t)k * rowStride + col], src[(size_t)(k + 1) * rowStride + col]);
}

// ---------------------------------------------------------------------------
// Build packed-bf16 w(r) table: tab16[t][i][l] = bf16x2(w[2l], w[2l+1])
// ---------------------------------------------------------------------------
__global__ __launch_bounds__(256) void build_table_kernel(
    const float* __restrict__ Wrbf1_all, const float* __restrict__ brbf1_all,
    const float* __restrict__ Wrbf2_all, unsigned int* __restrict__ tab16)
{
    int wave = threadIdx.x >> 6;
    int lane = threadIdx.x & 63;
    int idx = blockIdx.x * 4 + wave;
    int t = blockIdx.y;
    const float* W1 = Wrbf1_all + (size_t)t * KRBF * F;
    const float* b1 = brbf1_all + (size_t)t * F;
    const float* W2 = Wrbf2_all + (size_t)t * F * F;
    float r = idx * (RMAX / (TAB_N - 1));
    __shared__ float sR[4][KRBF];
    __shared__ float sH[4][F];
    if (lane < KRBF) {
        float mu = lane * (RMAX / (KRBF - 1));
        float d = r - mu;
        sR[wave][lane] = expf(-GAMMA * d * d);
    }
    __syncthreads();
    float h0 = b1[lane], h1 = b1[lane + 64];
    #pragma unroll
    for (int kk = 0; kk < KRBF; kk++) {
        float rv = sR[wave][kk];
        h0 += rv * W1[kk * F + lane];
        h1 += rv * W1[kk * F + lane + 64];
    }
    sH[wave][lane] = silu_f(h0);
    sH[wave][lane + 64] = silu_f(h1);
    __syncthreads();
    float w0 = 0.0f, w1 = 0.0f;
    for (int i = 0; i < F; i++) {
        float hv = sH[wave][i];
        w0 += hv * W2[i * F + 2 * lane];
        w1 += hv * W2[i * F + 2 * lane + 1];
    }
    tab16[((size_t)t * TAB_N + idx) * 64 + lane] = pk_bf2(w0, w1);
}

// ---------------------------------------------------------------------------
// dd_list[ei] = deg_reduce(ev[sp[ei]] * ev[rcvp[ei]])  (CSR order, float4)
// ---------------------------------------------------------------------------
__global__ void dd_kernel(const int* __restrict__ sp, const int* __restrict__ rcvp,
                          const float* __restrict__ ev, float4* __restrict__ ddl, int E)
{
    int ei = blockIdx.x * blockDim.x + threadIdx.x;
    if (ei >= E) return;
    int s = sp[ei], rc = rcvp[ei];
    const float4* a = (const float4*)(ev + (size_t)s * 16);
    const float4* b = (const float4*)(ev + (size_t)rc * 16);
    float4 a0 = a[0], a1 = a[1], a2 = a[2], a3 = a[3];
    float4 b0 = b[0], b1 = b[1], b2 = b[2], b3 = b[3];
    float d0 = a0.x * b0.x;
    float d1 = a0.y * b0.y + a0.z * b0.z + a0.w * b0.w;
    float d2 = a1.x * b1.x + a1.y * b1.y + a1.z * b1.z + a1.w * b1.w + a2.x * b2.x;
    float d3 = a2.y * b2.y + a2.z * b2.z + a2.w * b2.w
             + a3.x * b3.x + a3.y * b3.y + a3.z * b3.z + a3.w * b3.w;
    ddl[ei] = make_float4(d0, d1, d2, d3);
}

// ---------------------------------------------------------------------------
// MFMA node GEMM: out[m] = A @ W[m]. 64 nodes/block, 4 waves, 16x16x32 bf16.
// ---------------------------------------------------------------------------
__global__ __launch_bounds__(256) void node_gemm_mfma_kernel(
    const float* __restrict__ A,
    const unsigned int* __restrict__ B0, const unsigned int* __restrict__ B1,
    const unsigned int* __restrict__ B2,
    float* __restrict__ out0, unsigned int* __restrict__ out1, unsigned int* __restrict__ out2,
    int N, int nw, int accumulate, int ileave)
{
    __shared__ unsigned int sA[64 * APITCH];
    int tid = threadIdx.x;
    int n0 = blockIdx.x * 64;
    #pragma unroll
    for (int rep = 0; rep < 16; rep++) {
        int idx = rep * 256 + tid;
        int node = idx >> 6, jj = idx & 63;
        int n = n0 + node;
        float2 v = (n < N) ? ((const float2*)A)[(size_t)n * 64 + jj] : make_float2(0.f, 0.f);
        sA[node * APITCH + jj] = pk_bf2(v.x, v.y);
    }
    __syncthreads();
    int wave = tid >> 6, lane = tid & 63;
    int quad = lane >> 4, col = lane & 15;
    int mrow = wave * 16 + col;
    s16x8 af[4];
    #pragma unroll
    for (int kb = 0; kb < 4; kb++) {
        FragU fu;
        fu.u = *(const uint4*)&sA[mrow * APITCH + kb * 16 + quad * 4];
        af[kb] = fu.s;
    }
    for (int m = 0; m < nw; m++) {
        const unsigned int* B = (m == 0) ? B0 : (m == 1) ? B1 : B2;
        for (int ct = 0; ct < 8; ct++) {
            f32x4 acc = {0.f, 0.f, 0.f, 0.f};
            #pragma unroll
            for (int kb = 0; kb < 4; kb++) {
                FragU bu;
                bu.u = *(const uint4*)&B[(size_t)((ct * 16 + kb * 4 + quad) * 16 + col) * 4];
                acc = __builtin_amdgcn_mfma_f32_16x16x32_bf16(af[kb], bu.s, acc, 0, 0, 0);
            }
            if (m == 0) {
                #pragma unroll
                for (int r = 0; r < 4; r++) {
                    int n = n0 + wave * 16 + quad * 4 + r;
                    if (n < N) {
                        size_t ix = (size_t)n * F + ct * 16 + col;
                        out0[ix] = accumulate ? out0[ix] + acc[r] : acc[r];
                    }
                }
            } else {
                unsigned int* o16 = (m == 1) ? out1 : out2;
                #pragma unroll
                for (int r = 0; r < 4; r++) {
                    float other = __shfl_xor(acc[r], 1, 64);
                    if (!(lane & 1)) {
                        int n = n0 + wave * 16 + quad * 4 + r;
                        if (n < N) {
                            size_t base = (size_t)n * 64 + ct * 8 + (col >> 1);
                            if (ileave)
                                out1[base * 2 + (m - 1)] = pk_bf2(acc[r], other);
                            else
                                o16[base] = pk_bf2(acc[r], other);
                        }
                    }
                }
            }
        }
    }
}

// ---------------------------------------------------------------------------
// Per-edge alpha: table lerp + Wdeg correction + qk dot + per-head reduce.
// ---------------------------------------------------------------------------
__device__ __forceinline__ float edge_alpha(
    int lane, float2 qq, const float* sWdeg,
    const unsigned int* __restrict__ tab16,
    float2 rc2, float4 dd, unsigned int ku)
{
    float u = rc2.x * ((float)(TAB_N - 1) / RMAX);
    int i0 = (int)u;
    i0 = (i0 > TAB_N - 2) ? (TAB_N - 2) : i0;
    float fr = u - (float)i0;
    unsigned int ta = tab16[(size_t)i0 * 64 + lane];
    unsigned int tb = tab16[(size_t)(i0 + 1) * 64 + lane];
    float a0 = up_lo(ta), a1 = up_hi(ta);
    float b0 = up_lo(tb), b1 = up_hi(tb);
    int j0 = 2 * lane, j1 = 2 * lane + 1;
    float w0 = a0 + fr * (b0 - a0)
             + dd.x * sWdeg[j0] + dd.y * sWdeg[F + j0]
             + dd.z * sWdeg[2 * F + j0] + dd.w * sWdeg[3 * F + j0];
    float w1 = a1 + fr * (b1 - a1)
             + dd.x * sWdeg[j1] + dd.y * sWdeg[F + j1]
             + dd.z * sWdeg[2 * F + j1] + dd.w * sWdeg[3 * F + j1];
    float p = qq.x * w0 * up_lo(ku) + qq.y * w1 * up_hi(ku);
    #pragma unroll
    for (int o = 1; o < 16; o <<= 1) p += __shfl_xor(p, o, 64);
    return p * (rc2.y * RSQRT_DH * INV_AVG);
}

// ---------------------------------------------------------------------------
// Node-centric fused edge pass. mode 0: 4-way unrolled; mode 1: 2-way.
// ---------------------------------------------------------------------------
__global__ __launch_bounds__(256) void edge_pass_node_kernel(
    const int* __restrict__ off, const int* __restrict__ sp,
    const float2* __restrict__ rcC, const float4* __restrict__ ddl,
    const float* __restrict__ Yp,
    const float* __restrict__ qbuf,
    const uint2* __restrict__ kv16, const unsigned int* __restrict__ k16p,
    const unsigned int* __restrict__ tab16, const float* __restrict__ Wdeg_t,
    float* __restrict__ outbuf, int N, int mode)
{
    __shared__ float sWdeg[4 * F];
    for (int i = threadIdx.x; i < 4 * F; i += 256) sWdeg[i] = Wdeg_t[i];
    __syncthreads();

    int wave = threadIdx.x >> 6;
    int lane = threadIdx.x & 63;
    int n = blockIdx.x * 4 + wave;
    if (n >= N) return;

    int e0 = off[n], e1 = off[n + 1];
    float2 qq = ((const float2*)qbuf)[(size_t)n * 64 + lane];
    float acc0 = 0.0f, acc1 = 0.0f;
    float devacc = 0.0f;

    int ei = e0;
    if (mode == 0) {
        for (; ei + 3 < e1; ei += 4) {
            int sA = sp[ei], sB = sp[ei + 1], sC = sp[ei + 2], sD = sp[ei + 3];
            float2 rcA = rcC[ei], rcB = rcC[ei + 1], rcCc = rcC[ei + 2], rcD = rcC[ei + 3];
            float4 ddA = ddl[ei], ddB = ddl[ei + 1], ddC = ddl[ei + 2], ddD = ddl[ei + 3];
            uint2 kvA = kv16[(size_t)sA * 64 + lane];
            uint2 kvB = kv16[(size_t)sB * 64 + lane];
            uint2 kvC = kv16[(size_t)sC * 64 + lane];
            uint2 kvD = kv16[(size_t)sD * 64 + lane];
            float alA = edge_alpha(lane, qq, sWdeg, tab16, rcA, ddA, kvA.x);
            float alB = edge_alpha(lane, qq, sWdeg, tab16, rcB, ddB, kvB.x);
            float alC = edge_alpha(lane, qq, sWdeg, tab16, rcCc, ddC, kvC.x);
            float alD = edge_alpha(lane, qq, sWdeg, tab16, rcD, ddD, kvD.x);
            acc0 += alA * up_lo(kvA.y) + alB * up_lo(kvB.y)
                  + alC * up_lo(kvC.y) + alD * up_lo(kvD.y);
            acc1 += alA * up_hi(kvA.y) + alB * up_hi(kvB.y)
                  + alC * up_hi(kvC.y) + alD * up_hi(kvD.y);
        }
        for (; ei < e1; ei++) {
            int sA = sp[ei];
            uint2 kvA = kv16[(size_t)sA * 64 + lane];
            float alA = edge_alpha(lane, qq, sWdeg, tab16, rcC[ei], ddl[ei], kvA.x);
            acc0 += alA * up_lo(kvA.y);
            acc1 += alA * up_hi(kvA.y);
        }
        ((float2*)outbuf)[(size_t)n * 64 + lane] = make_float2(acc0, acc1);
    } else {
        for (; ei + 1 < e1; ei += 2) {
            int sA = sp[ei], sB = sp[ei + 1];
            float2 rcA = rcC[ei], rcB = rcC[ei + 1];
            float4 ddA = ddl[ei], ddB = ddl[ei + 1];
            unsigned int kA = k16p[(size_t)sA * 64 + lane];
            unsigned int kB = k16p[(size_t)sB * 64 + lane];
            float alA = edge_alpha(lane, qq, sWdeg, tab16, rcA, ddA, kA);
            float alB = edge_alpha(lane, qq, sWdeg, tab16, rcB, ddB, kB);
            float aA0 = __shfl(alA, 0), aA1 = __shfl(alA, 16);
            float aA2 = __shfl(alA, 32), aA3 = __shfl(alA, 48);
            float aB0 = __shfl(alB, 0), aB1 = __shfl(alB, 16);
            float aB2 = __shfl(alB, 32), aB3 = __shfl(alB, 48);
            if (lane < 16) {
                float adA = (lane == 0) ? aA0 : (lane < 4) ? aA1 : (lane < 9) ? aA2 : aA3;
                float adB = (lane == 0) ? aB0 : (lane < 4) ? aB1 : (lane < 9) ? aB2 : aB3;
                devacc += adA * Yp[(size_t)ei * 16 + lane]
                        + adB * Yp[(size_t)(ei + 1) * 16 + lane];
            }
        }
        if (ei < e1) {
            int sA = sp[ei];
            unsigned int kA = k16p[(size_t)sA * 64 + lane];
            float alA = edge_alpha(lane, qq, sWdeg, tab16, rcC[ei], ddl[ei], kA);
            float aA0 = __shfl(alA, 0), aA1 = __shfl(alA, 16);
            float aA2 = __shfl(alA, 32), aA3 = __shfl(alA, 48);
            if (lane < 16) {
                float adA = (lane == 0) ? aA0 : (lane < 4) ? aA1 : (lane < 9) ? aA2 : aA3;
                devacc += adA * Yp[(size_t)ei * 16 + lane];
            }
        }
        if (lane < 16) outbuf[n * 16 + lane] = devacc;
    }
}

// ---------------------------------------------------------------------------
// MFMA exchange block: 64 nodes/block, 4 waves.
// sev = ev + dEv; ev_inv = deg_reduce(sev^2); h = [f, ev_inv]
// hid = silu(h @ Wex1 + b1)  (MFMA for f-part, VALU rank-4 for ev_inv rows)
// yb  = hid @ Wex2 + b2      (MFMA cols 0..127, VALU for cols 128..131)
// f += yb[:128]; ev = sev * (1 + deg_expand(yb[128:]))
// ---------------------------------------------------------------------------
__global__ __launch_bounds__(256) void exchange_mfma_kernel(
    float* __restrict__ f, float* __restrict__ ev, const float* __restrict__ dEv,
    const unsigned int* __restrict__ B1, const float* __restrict__ Wex1,
    const float* __restrict__ bex1,
    const unsigned int* __restrict__ B2, const float* __restrict__ Wex2,
    const float* __restrict__ bex2, int N)
{
    __shared__ unsigned int sA[64 * APITCH];  // f bf16, later hid bf16
    __shared__ float sev[64][17];
    __shared__ float sEvInv[64][4];
    __shared__ float sW1x[4][F];              // Wex1 rows 128..131
    __shared__ float sW2x[F][4];              // Wex2 cols 128..131
    __shared__ float sB1[F];
    __shared__ float sB2[F];
    __shared__ float sb2x[4];
    __shared__ float syb[64][4];

    int tid = threadIdx.x;
    int n0 = blockIdx.x * 64;
    #pragma unroll
    for (int rep = 0; rep < 16; rep++) {
        int idx = rep * 256 + tid;
        int node = idx >> 6, jj = idx & 63;
        int n = n0 + node;
        float2 v = (n < N) ? ((const float2*)f)[(size_t)n * 64 + jj] : make_float2(0.f, 0.f);
        sA[node * APITCH + jj] = pk_bf2(v.x, v.y);
    }
    for (int idx = tid; idx < 64 * 16; idx += 256) {
        int node = idx >> 4, c = idx & 15;
        int n = n0 + node;
        sev[node][c] = (n < N) ? (ev[(size_t)n * 16 + c] + dEv[(size_t)n * 16 + c]) : 0.0f;
    }
    for (int idx = tid; idx < 4 * F; idx += 256)
        sW1x[idx >> 7][idx & 127] = Wex1[(size_t)(128 + (idx >> 7)) * F + (idx & 127)];
    for (int idx = tid; idx < F * 4; idx += 256)
        sW2x[idx >> 2][idx & 3] = Wex2[(size_t)(idx >> 2) * (F + 4) + 128 + (idx & 3)];
    if (tid < F) sB1[tid] = bex1[tid];
    else sB2[tid - F] = bex2[tid - F];
    if (tid < 4) sb2x[tid] = bex2[F + tid];
    __syncthreads();
    {
        int node = tid >> 2, d = tid & 3;
        int c0 = (d == 0) ? 0 : (d == 1) ? 1 : (d == 2) ? 4 : 9;
        int c1 = (d == 0) ? 1 : (d == 1) ? 4 : (d == 2) ? 9 : 16;
        float a = 0.0f;
        for (int c = c0; c < c1; c++) { float v = sev[node][c]; a += v * v; }
        sEvInv[node][d] = a;
    }
    int wave = tid >> 6, lane = tid & 63;
    int quad = lane >> 4, col = lane & 15;
    int mrow = wave * 16 + col;
    s16x8 af[4];
    #pragma unroll
    for (int kb = 0; kb < 4; kb++) {
        FragU fu;
        fu.u = *(const uint4*)&sA[mrow * APITCH + kb * 16 + quad * 4];
        af[kb] = fu.s;
    }
    __syncthreads();
    float evq[4][4];
    #pragma unroll
    for (int r = 0; r < 4; r++) {
        int node = wave * 16 + quad * 4 + r;
        #pragma unroll
        for (int d = 0; d < 4; d++) evq[r][d] = sEvInv[node][d];
    }
    // GEMM1: hid = silu(f@Wex1[:128] + ev_inv@Wex1[128:] + b1) -> sA (bf16)
    for (int ct = 0; ct < 8; ct++) {
        f32x4 acc = {0.f, 0.f, 0.f, 0.f};
        #pragma unroll
        for (int kb = 0; kb < 4; kb++) {
            FragU bu;
            bu.u = *(const uint4*)&B1[(size_t)((ct * 16 + kb * 4 + quad) * 16 + col) * 4];
            acc = __builtin_amdgcn_mfma_f32_16x16x32_bf16(af[kb], bu.s, acc, 0, 0, 0);
        }
        int j = ct * 16 + col;
        float w0 = sW1x[0][j], w1 = sW1x[1][j], w2 = sW1x[2][j], w3 = sW1x[3][j];
        float bj = sB1[j];
        #pragma unroll
        for (int r = 0; r < 4; r++) {
            float x = acc[r] + bj + evq[r][0] * w0 + evq[r][1] * w1
                    + evq[r][2] * w2 + evq[r][3] * w3;
            float h = silu_f(x);
            float other = __shfl_xor(h, 1, 64);
            if (!(lane & 1)) {
                int node = wave * 16 + quad * 4 + r;
                sA[node * APITCH + ct * 8 + (col >> 1)] = pk_bf2(h, other);
            }
        }
    }
    __syncthreads();
    s16x8 a2[4];
    #pragma unroll
    for (int kb = 0; kb < 4; kb++) {
        FragU fu;
        fu.u = *(const uint4*)&sA[mrow * APITCH + kb * 16 + quad * 4];
        a2[kb] = fu.s;
    }
    // yb2 (cols 128..131) per (node, d) thread
    {
        int node = tid >> 2, d = tid & 3;
        float a = sb2x[d];
        for (int dw = 0; dw < 64; dw++) {
            unsigned int u = sA[node * APITCH + dw];
            a += up_lo(u) * sW2x[2 * dw][d] + up_hi(u) * sW2x[2 * dw + 1][d];
        }
        syb[node][d] = a;
    }
    // GEMM2 cols 0..127: f += hid@Wex2[:, :128] + b2
    for (int ct = 0; ct < 8; ct++) {
        f32x4 acc = {0.f, 0.f, 0.f, 0.f};
        #pragma unroll
        for (int kb = 0; kb < 4; kb++) {
            FragU bu;
            bu.u = *(const uint4*)&B2[(size_t)((ct * 16 + kb * 4 + quad) * 16 + col) * 4];
            acc = __builtin_amdgcn_mfma_f32_16x16x32_bf16(a2[kb], bu.s, acc, 0, 0, 0);
        }
        int j = ct * 16 + col;
        float bj = sB2[j];
        #pragma unroll
        for (int r = 0; r < 4; r++) {
            int n = n0 + wave * 16 + quad * 4 + r;
            if (n < N) {
                size_t ix = (size_t)n * F + j;
                f[ix] = f[ix] + acc[r] + bj;
            }
        }
    }
    __syncthreads();
    for (int idx = tid; idx < 64 * 16; idx += 256) {
        int node = idx >> 4, c = idx & 15;
        int n = n0 + node;
        if (n < N) ev[(size_t)n * 16 + c] = sev[node][c] * (1.0f + syb[node][deg_of(c)]);
    }
}

// ---------------------------------------------------------------------------
// MFMA readout: node_e[n] = silu(f@Wo1+bo1) . Wo2 + bo2  (64 nodes/block)
// ---------------------------------------------------------------------------
__global__ __launch_bounds__(256) void readout_mfma_kernel(
    const float* __restrict__ f, const unsigned int* __restrict__ B,
    const float* __restrict__ bo1, const float* __restrict__ Wo2,
    const float* __restrict__ bo2, float* __restrict__ node_e, int N)
{
    __shared__ unsigned int sA[64 * APITCH];
    __shared__ float sB1[F];
    __shared__ float sW2[F];
    int tid = threadIdx.x;
    int n0 = blockIdx.x * 64;
    #pragma unroll
    for (int rep = 0; rep < 16; rep++) {
        int idx = rep * 256 + tid;
        int node = idx >> 6, jj = idx & 63;
        int n = n0 + node;
        float2 v = (n < N) ? ((const float2*)f)[(size_t)n * 64 + jj] : make_float2(0.f, 0.f);
        sA[node * APITCH + jj] = pk_bf2(v.x, v.y);
    }
    if (tid < F) sB1[tid] = bo1[tid];
    else sW2[tid - F] = Wo2[tid - F];
    __syncthreads();
    int wave = tid >> 6, lane = tid & 63;
    int quad = lane >> 4, col = lane & 15;
    int mrow = wave * 16 + col;
    s16x8 af[4];
    #pragma unroll
    for (int kb = 0; kb < 4; kb++) {
        FragU fu;
        fu.u = *(const uint4*)&sA[mrow * APITCH + kb * 16 + quad * 4];
        af[kb] = fu.s;
    }
    float part[4] = {0.f, 0.f, 0.f, 0.f};
    for (int ct = 0; ct < 8; ct++) {
        f32x4 acc = {0.f, 0.f, 0.f, 0.f};
        #pragma unroll
        for (int kb = 0; kb < 4; kb++) {
            FragU bu;
            bu.u = *(const uint4*)&B[(size_t)((ct * 16 + kb * 4 + quad) * 16 + col) * 4];
            acc = __builtin_amdgcn_mfma_f32_16x16x32_bf16(af[kb], bu.s, acc, 0, 0, 0);
        }
        int j = ct * 16 + col;
        float bj = sB1[j], wj = sW2[j];
        #pragma unroll
        for (int r = 0; r < 4; r++) part[r] += silu_f(acc[r] + bj) * wj;
    }
    #pragma unroll
    for (int r = 0; r < 4; r++) {
        #pragma unroll
        for (int o = 1; o < 16; o <<= 1) part[r] += __shfl_xor(part[r], o, 64);
    }
    if (col == 0) {
        #pragma unroll
        for (int r = 0; r < 4; r++) {
            int n = n0 + wave * 16 + quad * 4 + r;
            if (n < N) node_e[n] = part[r] + bo2[0];
        }
    }
}

// ---------------------------------------------------------------------------
// energy[g] = sum_{batch[n]==g} node_e[n]
// ---------------------------------------------------------------------------
__global__ __launch_bounds__(256) void energy_reduce_kernel(
    const float* __restrict__ node_e, const int* __restrict__ batch,
    float* __restrict__ energy, int N)
{
    __shared__ float eacc[64];
    if (threadIdx.x < 64) eacc[threadIdx.x] = 0.0f;
    __syncthreads();
    for (int n = blockIdx.x * blockDim.x + threadIdx.x; n < N; n += gridDim.x * blockDim.x)
        atomicAdd(&eacc[batch[n]], node_e[n]);
    __syncthreads();
    if (threadIdx.x < 64) atomicAdd(&energy[threadIdx.x], eacc[threadIdx.x]);
}

// ---------------------------------------------------------------------------
extern "C" void kernel_launch(void* const* d_in, const int* in_sizes, int n_in,
                              void* d_out, int out_size, void* d_ws, size_t ws_size,
                              hipStream_t stream)
{
    const float* positions = (const float*)d_in[0];
    const int*   species   = (const int*)d_in[1];
    const int*   senders   = (const int*)d_in[2];
    const int*   receivers = (const int*)d_in[3];
    const int*   batch     = (const int*)d_in[4];
    const float* embed     = (const float*)d_in[5];
    const float* Wq    = (const float*)d_in[6];
    const float* Wk    = (const float*)d_in[7];
    const float* Wv    = (const float*)d_in[8];
    const float* Wo    = (const float*)d_in[9];
    const float* Wrbf1 = (const float*)d_in[10];
    const float* brbf1 = (const float*)d_in[11];
    const float* Wrbf2 = (const float*)d_in[12];
    const float* Wdeg  = (const float*)d_in[13];
    const float* Wq2   = (const float*)d_in[14];
    const float* Wk2   = (const float*)d_in[15];
    const float* Wex1  = (const float*)d_in[16];
    const float* bex1  = (const float*)d_in[17];
    const float* Wex2  = (const float*)d_in[18];
    const float* bex2  = (const float*)d_in[19];
    const float* Wo1   = (const float*)d_in[20];
    const float* bo1   = (const float*)d_in[21];
    const float* Wo2   = (const float*)d_in[22];
    const float* bo2   = (const float*)d_in[23];

    int N = in_sizes[0] / 3;
    int E = in_sizes[2];

    // ---- workspace layout (~127 MB), staging region aliased ----
    float* ws     = (float*)d_ws;
    float* Yp     = ws;  ws += (size_t)E * 16;        // CSR-ordered Y
    float2* rcC   = (float2*)ws; ws += (size_t)E * 2; // CSR-ordered (r, C)
    float* f      = ws;  ws += (size_t)N * F;
    float* evb    = ws;  ws += (size_t)N * 16;
    float* dEv    = ws;  ws += (size_t)N * 16;
    float* q      = ws;  ws += (size_t)N * F;
    float* agg    = ws;  ws += (size_t)N * F;
    float* node_e = ws;  ws += (size_t)N;
    // union region: staging (rbuf/Cbuf/Ybuf, E*18 floats) then tab16/kv16/k16p/ddl
    float* un     = ws;  ws += (size_t)E * 18;
    float* rbuf   = un;
    float* Cbuf   = un + E;
    float* Ybuf   = un + (size_t)2 * E;
    unsigned int* tab16 = (unsigned int*)un;                       // 3*TAB_N*64
    uint2* kv16 = (uint2*)(tab16 + (size_t)TINTER * TAB_N * 64);   // N*64 uint2 (k,v)
    unsigned int* k16p = (unsigned int*)(kv16 + (size_t)N * 64);   // N*64 (k2)
    float4* ddl   = (float4*)(k16p + (size_t)N * 64);              // E
    int* sp    = (int*)ws;  ws += E;
    int* rcvp  = (int*)ws;  ws += E;
    int* cnt   = (int*)ws;  ws += N;
    int* off   = (int*)ws;  ws += N + 1;
    int* cur   = (int*)ws;  ws += N;
    int* elist = (int*)ws;  ws += E;
    unsigned int* Wpk  = (unsigned int*)ws;  ws += 18 * 8192;      // qkv/o/q2/k2 packed
    unsigned int* Wpk2 = (unsigned int*)ws;  ws += 7 * 8192;       // ex1[3], ex2[3], wo1

    // ---- CSR build ----
    hipMemsetAsync(cnt, 0, (size_t)N * sizeof(int), stream);
    count_kernel<<<(E + 255) / 256, 256, 0, stream>>>(receivers, cnt, E);
    scan_kernel<<<1, 1024, 0, stream>>>(cnt, off, cur, N);
    scatter_kernel<<<(E + 255) / 256, 256, 0, stream>>>(receivers, cur, elist, E);

    // ---- geometry + CSR-order permute (staging region live) ----
    edge_geom_kernel<<<(E + 255) / 256, 256, 0, stream>>>(positions, senders, receivers,
                                                          rbuf, Cbuf, Ybuf, E);
    perm_edge_kernel<<<(E + 255) / 256, 256, 0, stream>>>(elist, senders, receivers,
                                                          rbuf, Cbuf, sp, rcvp, rcC, E);
    perm_Y_kernel<<<(int)(((size_t)E * 16 + 255) / 256), 256, 0, stream>>>(elist, Ybuf, Yp, E);
    // staging dead from here
    pack_w_kernel<<<(18 * 8192 + 255) / 256, 256, 0, stream>>>(Wq, Wk, Wv, Wo, Wq2, Wk2, Wpk);
    for (int t = 0; t < TINTER; t++) {
        pack_one_kernel<<<32, 256, 0, stream>>>(Wex1 + (size_t)t * (F + 4) * F, F,
                                                Wpk2 + (size_t)t * 8192);
        pack_one_kernel<<<32, 256, 0, stream>>>(Wex2 + (size_t)t * F * (F + 4), F + 4,
                                                Wpk2 + (size_t)(3 + t) * 8192);
    }
    pack_one_kernel<<<32, 256, 0, stream>>>(Wo1, F, Wpk2 + (size_t)6 * 8192);
    build_table_kernel<<<dim3(TAB_N / 4, TINTER), 256, 0, stream>>>(Wrbf1, brbf1, Wrbf2, tab16);
    ev0_kernel<<<(N + 15) / 16, 256, 0, stream>>>(off, Yp, rcC, evb, N);
    embed_kernel<<<N, F, 0, stream>>>(species, embed, f, N);

    int nmb = (N + 63) / 64;
    int npb = (N + 3) / 4;
    int edb = (E + 255) / 256;
    for (int t = 0; t < TINTER; t++) {
        const unsigned int* Wpk_q  = Wpk + (size_t)(0 * 3 + t) * 8192;
        const unsigned int* Wpk_k  = Wpk + (size_t)(1 * 3 + t) * 8192;
        const unsigned int* Wpk_v  = Wpk + (size_t)(2 * 3 + t) * 8192;
        const unsigned int* Wpk_o  = Wpk + (size_t)(3 * 3 + t) * 8192;
        const unsigned int* Wpk_q2 = Wpk + (size_t)(4 * 3 + t) * 8192;
        const unsigned int* Wpk_k2 = Wpk + (size_t)(5 * 3 + t) * 8192;
        const unsigned int* tab_t = tab16 + (size_t)t * TAB_N * 64;
        const float* Wdeg_t = Wdeg + (size_t)t * 4 * F;
        node_gemm_mfma_kernel<<<nmb, 256, 0, stream>>>(f, Wpk_q, Wpk_k, Wpk_v,
                                                       q, (unsigned int*)kv16, nullptr,
                                                       N, 3, 0, 1);
        dd_kernel<<<edb, 256, 0, stream>>>(sp, rcvp, evb, ddl, E);
        edge_pass_node_kernel<<<npb, 256, 0, stream>>>(off, sp, rcC, ddl, Yp,
            q, kv16, nullptr, tab_t, Wdeg_t, agg, N, 0);
        node_gemm_mfma_kernel<<<nmb, 256, 0, stream>>>(agg, Wpk_o, nullptr, nullptr,
                                                       f, nullptr, nullptr, N, 1, 1, 0);
        node_gemm_mfma_kernel<<<nmb, 256, 0, stream>>>(f, Wpk_q2, Wpk_k2, nullptr,
                                                       q, k16p, nullptr, N, 2, 0, 0);
        edge_pass_node_kernel<<<npb, 256, 0, stream>>>(off, sp, rcC, ddl, Yp,
            q, nullptr, k16p, tab_t, Wdeg_t, dEv, N, 1);
        exchange_mfma_kernel<<<nmb, 256, 0, stream>>>(f, evb, dEv,
            Wpk2 + (size_t)t * 8192, Wex1 + (size_t)t * (F + 4) * F, bex1 + (size_t)t * F,
            Wpk2 + (size_t)(3 + t) * 8192, Wex2 + (size_t)t * F * (F + 4),
            bex2 + (size_t)t * (F + 4), N);
    }
    readout_mfma_kernel<<<nmb, 256, 0, stream>>>(f, Wpk2 + (size_t)6 * 8192,
                                                 bo1, Wo2, bo2, node_e, N);
    hipMemsetAsync(d_out, 0, (size_t)out_size * sizeof(float), stream);
    energy_reduce_kernel<<<16, 256, 0, stream>>>(node_e, batch, (float*)d_out, N);
}

// Round 9
// 1102.923 us; speedup vs baseline: 7.7128x; 1.0860x over previous
//
#include <hip/hip_runtime.h>
#include <math.h>

// ---- static config (matches reference) ----
#define F 128
#define KRBF 32
#define TINTER 3
#define RMAX 5.0f
#define INV_AVG (1.0f/16.0f)
#define GAMMA 40.96f               // (KRBF/RMAX)^2
#define RSQRT_DH 0.17677669529663689f  // 1/sqrt(32)
#define PI_F 3.14159265358979323846f
#define TAB_N 2048                 // w(r) interpolation table entries over [0, RMAX]
#define APITCH 68                  // LDS A-tile pitch in dwords (16B-aligned rows)

__device__ __forceinline__ float silu_f(float x) { return x / (1.0f + expf(-x)); }
__device__ __forceinline__ int deg_of(int c) { return (c == 0) ? 0 : (c < 4) ? 1 : (c < 9) ? 2 : 3; }

// bf16x2 pack/unpack: packed word = (elem0) | (elem1 << 16), RNE rounding
__device__ __forceinline__ unsigned int pk_bf2(float lo, float hi) {
    unsigned int a = __float_as_uint(lo), b = __float_as_uint(hi);
    unsigned int ar = (a + 0x7fffu + ((a >> 16) & 1u)) >> 16;
    unsigned int br = (b + 0x7fffu + ((b >> 16) & 1u)) >> 16;
    return ar | (br << 16);
}
__device__ __forceinline__ float up_lo(unsigned int u) { return __uint_as_float(u << 16); }
__device__ __forceinline__ float up_hi(unsigned int u) { return __uint_as_float(u & 0xffff0000u); }

typedef short s16x8 __attribute__((ext_vector_type(8)));
typedef float f32x4 __attribute__((ext_vector_type(4)));
typedef float f32x2 __attribute__((ext_vector_type(2)));
union FragU { uint4 u; s16x8 s; };

__device__ __forceinline__ f32x2 up2(unsigned int u) {
    f32x2 r; r.x = up_lo(u); r.y = up_hi(u); return r;
}

// ---------------------------------------------------------------------------
// CSR build: count -> scan -> scatter
// ---------------------------------------------------------------------------
__global__ void count_kernel(const int* __restrict__ rcv, int* __restrict__ cnt, int E)
{
    int e = blockIdx.x * blockDim.x + threadIdx.x;
    if (e < E) atomicAdd(&cnt[rcv[e]], 1);
}

__global__ __launch_bounds__(1024) void scan_kernel(const int* __restrict__ cnt,
                                                    int* __restrict__ off,
                                                    int* __restrict__ cur, int N)
{
    __shared__ int part[1024];
    int t = threadIdx.x;
    int chunk = (N + 1023) / 1024;
    int lo = t * chunk, hi = min(lo + chunk, N);
    int sum = 0;
    for (int i = lo; i < hi; i++) sum += cnt[i];
    part[t] = sum;
    __syncthreads();
    for (int st = 1; st < 1024; st <<= 1) {
        int v = (t >= st) ? part[t - st] : 0;
        __syncthreads();
        part[t] += v;
        __syncthreads();
    }
    int run = (t == 0) ? 0 : part[t - 1];
    for (int i = lo; i < hi; i++) {
        off[i] = run; cur[i] = run;
        run += cnt[i];
    }
    if (t == 1023) off[N] = part[1023];
}

__global__ void scatter_kernel(const int* __restrict__ rcv, int* __restrict__ cur,
                               int* __restrict__ elist, int E)
{
    int e = blockIdx.x * blockDim.x + threadIdx.x;
    if (e < E) {
        int p = atomicAdd(&cur[rcv[e]], 1);
        elist[p] = e;
    }
}

// ---------------------------------------------------------------------------
// Edge geometry: r, C, Y[16] in edge order (staging; permuted to CSR after)
// ---------------------------------------------------------------------------
__global__ void edge_geom_kernel(const float* __restrict__ pos,
                                 const int* __restrict__ snd,
                                 const int* __restrict__ rcv,
                                 float* __restrict__ r_out,
                                 float* __restrict__ C_out,
                                 float* __restrict__ Y_out,
                                 int E)
{
    int e = blockIdx.x * blockDim.x + threadIdx.x;
    if (e >= E) return;
    int s = snd[e], rc = rcv[e];
    float vx = pos[rc * 3 + 0] - pos[s * 3 + 0];
    float vy = pos[rc * 3 + 1] - pos[s * 3 + 1];
    float vz = pos[rc * 3 + 2] - pos[s * 3 + 2];
    float r = sqrtf(vx * vx + vy * vy + vz * vz);
    float rinv = 1.0f / fmaxf(r, 1e-9f);
    float x = vx * rinv, y = vy * rinv, z = vz * rinv;
    float x2 = x * x, y2 = y * y, z2 = z * z;
    const float s3 = 1.7320508075688772f, s5 = 2.23606797749979f, s15 = 3.872983346207417f;
    const float s70 = 8.366600265340756f, s105 = 10.246950765959598f;
    const float s42 = 6.48074069840786f, s7 = 2.6457513110645907f;
    float Y[16];
    Y[0] = 1.0f;
    Y[1] = s3 * x; Y[2] = s3 * y; Y[3] = s3 * z;
    Y[4] = s15 * x * y; Y[5] = s15 * y * z; Y[6] = 0.5f * s5 * (3.0f * z2 - 1.0f);
    Y[7] = s15 * x * z; Y[8] = 0.5f * s15 * (x2 - y2);
    Y[9]  = 0.25f * s70 * y * (3.0f * x2 - y2);
    Y[10] = s105 * x * y * z;
    Y[11] = 0.25f * s42 * y * (5.0f * z2 - 1.0f);
    Y[12] = 0.5f * s7 * z * (5.0f * z2 - 3.0f);
    Y[13] = 0.25f * s42 * x * (5.0f * z2 - 1.0f);
    Y[14] = 0.5f * s105 * z * (x2 - y2);
    Y[15] = 0.25f * s70 * x * (x2 - 3.0f * y2);
    float C = (r < RMAX) ? 0.5f * (cosf(PI_F * r / RMAX) + 1.0f) : 0.0f;
    r_out[e] = r; C_out[e] = C;
    #pragma unroll
    for (int c = 0; c < 16; c++) Y_out[e * 16 + c] = Y[c];
}

// ---------------------------------------------------------------------------
// Permute edge data into CSR order
// ---------------------------------------------------------------------------
__global__ void perm_edge_kernel(const int* __restrict__ elist,
                                 const int* __restrict__ snd, const int* __restrict__ rcv,
                                 const float* __restrict__ rbuf, const float* __restrict__ Cbuf,
                                 int* __restrict__ sp, int* __restrict__ rcvp,
                                 float2* __restrict__ rcC, int E)
{
    int ei = blockIdx.x * blockDim.x + threadIdx.x;
    if (ei >= E) return;
    int e = elist[ei];
    sp[ei] = snd[e];
    rcvp[ei] = rcv[e];
    rcC[ei] = make_float2(rbuf[e], Cbuf[e]);
}

__global__ void perm_Y_kernel(const int* __restrict__ elist,
                              const float* __restrict__ Ybuf,
                              float* __restrict__ Yp, int E)
{
    long long tid = (long long)blockIdx.x * blockDim.x + threadIdx.x;
    if (tid >= (long long)E * 16) return;
    int ei = (int)(tid >> 4), c = (int)(tid & 15);
    Yp[tid] = Ybuf[(size_t)elist[ei] * 16 + c];
}

// ---------------------------------------------------------------------------
// ev0[n] = sum_{ei in CSR(n)} Yp[ei]*C[ei] * INV_AVG
// ---------------------------------------------------------------------------
__global__ void ev0_kernel(const int* __restrict__ off,
                           const float* __restrict__ Yp, const float2* __restrict__ rcC,
                           float* __restrict__ ev, int N)
{
    int n = blockIdx.x * 16 + (threadIdx.x >> 4);
    int c = threadIdx.x & 15;
    if (n >= N) return;
    float acc = 0.0f;
    int e0 = off[n], e1 = off[n + 1];
    for (int ei = e0; ei < e1; ei++)
        acc += Yp[(size_t)ei * 16 + c] * rcC[ei].y;
    ev[n * 16 + c] = acc * INV_AVG;
}

// ---------------------------------------------------------------------------
// f = embed[species]
// ---------------------------------------------------------------------------
__global__ void embed_kernel(const int* __restrict__ species,
                             const float* __restrict__ embed,
                             float* __restrict__ f, int N)
{
    int n = blockIdx.x;
    if (n >= N) return;
    int j = threadIdx.x;
    f[n * F + j] = embed[species[n] * F + j];
}

// ---------------------------------------------------------------------------
// Pack 18 128x128 fp32 weight matrices into MFMA B-operand bf16 layout.
// ---------------------------------------------------------------------------
__global__ void pack_w_kernel(const float* __restrict__ Wq, const float* __restrict__ Wk,
                              const float* __restrict__ Wv, const float* __restrict__ Wo,
                              const float* __restrict__ Wq2, const float* __restrict__ Wk2,
                              unsigned int* __restrict__ Wpk)
{
    int tid = blockIdx.x * blockDim.x + threadIdx.x;
    if (tid >= 18 * 8192) return;
    int mat = tid >> 13;
    int rem = tid & 8191;
    int iw = rem & 3;
    int n = (rem >> 2) & 15;
    int quad = (rem >> 6) & 3;
    int kb = (rem >> 8) & 3;
    int ct = rem >> 10;
    const float* fam = (mat < 3) ? Wq : (mat < 6) ? Wk : (mat < 9) ? Wv
                     : (mat < 12) ? Wo : (mat < 15) ? Wq2 : Wk2;
    const float* src = fam + (size_t)(mat % 3) * F * F;
    int k = kb * 32 + quad * 8 + iw * 2;
    int col = ct * 16 + n;
    Wpk[tid] = pk_bf2(src[k * F + col], src[(k + 1) * F + col]);
}

// Generic 128x128 submatrix pack with arbitrary row stride (for Wex1/Wex2/Wo1)
__global__ void pack_one_kernel(const float* __restrict__ src, int rowStride,
                                unsigned int* __restrict__ dst)
{
    int tid = blockIdx.x * blockDim.x + threadIdx.x;
    if (tid >= 8192) return;
    int iw = tid & 3;
    int n = (tid >> 2) & 15;
    int quad = (tid >> 6) & 3;
    int kb = (tid >> 8) & 3;
    int ct = tid >> 10;
    int k = kb * 32 + quad * 8 + iw * 2;
    int col = ct * 16 + n;
    dst[tid] = pk_bf2(src[(size_t)k * rowStride + col], src[(size_t)(k + 1) * rowStride + col]);
}

// ---------------------------------------------------------------------------
// Build packed-bf16 w(r) table (plain): tabp[t][i][l] = bf16x2(w[2l], w[2l+1])
// ---------------------------------------------------------------------------
__global__ __launch_bounds__(256) void build_table_kernel(
    const float* __restrict__ Wrbf1_all, const float* __restrict__ brbf1_all,
    const float* __restrict__ Wrbf2_all, unsigned int* __restrict__ tabp)
{
    int wave = threadIdx.x >> 6;
    int lane = threadIdx.x & 63;
    int idx = blockIdx.x * 4 + wave;
    int t = blockIdx.y;
    const float* W1 = Wrbf1_all + (size_t)t * KRBF * F;
    const float* b1 = brbf1_all + (size_t)t * F;
    const float* W2 = Wrbf2_all + (size_t)t * F * F;
    float r = idx * (RMAX / (TAB_N - 1));
    __shared__ float sR[4][KRBF];
    __shared__ float sH[4][F];
    if (lane < KRBF) {
        float mu = lane * (RMAX / (KRBF - 1));
        float d = r - mu;
        sR[wave][lane] = expf(-GAMMA * d * d);
    }
    __syncthreads();
    float h0 = b1[lane], h1 = b1[lane + 64];
    #pragma unroll
    for (int kk = 0; kk < KRBF; kk++) {
        float rv = sR[wave][kk];
        h0 += rv * W1[kk * F + lane];
        h1 += rv * W1[kk * F + lane + 64];
    }
    sH[wave][lane] = silu_f(h0);
    sH[wave][lane + 64] = silu_f(h1);
    __syncthreads();
    float w0 = 0.0f, w1 = 0.0f;
    for (int i = 0; i < F; i++) {
        float hv = sH[wave][i];
        w0 += hv * W2[i * F + 2 * lane];
        w1 += hv * W2[i * F + 2 * lane + 1];
    }
    tabp[((size_t)t * TAB_N + idx) * 64 + lane] = pk_bf2(w0, w1);
}

// Pair the table: tab2[t][i][l] = (tabp[t][i][l], tabp[t][i+1][l])
__global__ void pair_table_kernel(const unsigned int* __restrict__ tabp,
                                  uint2* __restrict__ tab2)
{
    int tid = blockIdx.x * blockDim.x + threadIdx.x;
    if (tid >= TINTER * TAB_N * 64) return;
    int lane = tid & 63;
    int i = (tid >> 6) & (TAB_N - 1);
    int t = tid / (TAB_N * 64);
    int i1 = (i < TAB_N - 1) ? i + 1 : i;
    tab2[tid] = make_uint2(tabp[tid],
                           tabp[((size_t)t * TAB_N + i1) * 64 + lane]);
}

// ---------------------------------------------------------------------------
// dd_list[ei] = deg_reduce(ev[sp[ei]] * ev[rcvp[ei]])  (CSR order, float4)
// ---------------------------------------------------------------------------
__global__ void dd_kernel(const int* __restrict__ sp, const int* __restrict__ rcvp,
                          const float* __restrict__ ev, float4* __restrict__ ddl, int E)
{
    int ei = blockIdx.x * blockDim.x + threadIdx.x;
    if (ei >= E) return;
    int s = sp[ei], rc = rcvp[ei];
    const float4* a = (const float4*)(ev + (size_t)s * 16);
    const float4* b = (const float4*)(ev + (size_t)rc * 16);
    float4 a0 = a[0], a1 = a[1], a2 = a[2], a3 = a[3];
    float4 b0 = b[0], b1 = b[1], b2 = b[2], b3 = b[3];
    float d0 = a0.x * b0.x;
    float d1 = a0.y * b0.y + a0.z * b0.z + a0.w * b0.w;
    float d2 = a1.x * b1.x + a1.y * b1.y + a1.z * b1.z + a1.w * b1.w + a2.x * b2.x;
    float d3 = a2.y * b2.y + a2.z * b2.z + a2.w * b2.w
             + a3.x * b3.x + a3.y * b3.y + a3.z * b3.z + a3.w * b3.w;
    ddl[ei] = make_float4(d0, d1, d2, d3);
}

// ---------------------------------------------------------------------------
// MFMA node GEMM: out[m] = A @ W[m]. 64 nodes/block, 4 waves, 16x16x32 bf16.
// ---------------------------------------------------------------------------
__global__ __launch_bounds__(256) void node_gemm_mfma_kernel(
    const float* __restrict__ A,
    const unsigned int* __restrict__ B0, const unsigned int* __restrict__ B1,
    const unsigned int* __restrict__ B2,
    float* __restrict__ out0, unsigned int* __restrict__ out1, unsigned int* __restrict__ out2,
    int N, int nw, int accumulate, int ileave)
{
    __shared__ unsigned int sA[64 * APITCH];
    int tid = threadIdx.x;
    int n0 = blockIdx.x * 64;
    #pragma unroll
    for (int rep = 0; rep < 16; rep++) {
        int idx = rep * 256 + tid;
        int node = idx >> 6, jj = idx & 63;
        int n = n0 + node;
        float2 v = (n < N) ? ((const float2*)A)[(size_t)n * 64 + jj] : make_float2(0.f, 0.f);
        sA[node * APITCH + jj] = pk_bf2(v.x, v.y);
    }
    __syncthreads();
    int wave = tid >> 6, lane = tid & 63;
    int quad = lane >> 4, col = lane & 15;
    int mrow = wave * 16 + col;
    s16x8 af[4];
    #pragma unroll
    for (int kb = 0; kb < 4; kb++) {
        FragU fu;
        fu.u = *(const uint4*)&sA[mrow * APITCH + kb * 16 + quad * 4];
        af[kb] = fu.s;
    }
    for (int m = 0; m < nw; m++) {
        const unsigned int* B = (m == 0) ? B0 : (m == 1) ? B1 : B2;
        for (int ct = 0; ct < 8; ct++) {
            f32x4 acc = {0.f, 0.f, 0.f, 0.f};
            #pragma unroll
            for (int kb = 0; kb < 4; kb++) {
                FragU bu;
                bu.u = *(const uint4*)&B[(size_t)((ct * 16 + kb * 4 + quad) * 16 + col) * 4];
                acc = __builtin_amdgcn_mfma_f32_16x16x32_bf16(af[kb], bu.s, acc, 0, 0, 0);
            }
            if (m == 0) {
                #pragma unroll
                for (int r = 0; r < 4; r++) {
                    int n = n0 + wave * 16 + quad * 4 + r;
                    if (n < N) {
                        size_t ix = (size_t)n * F + ct * 16 + col;
                        out0[ix] = accumulate ? out0[ix] + acc[r] : acc[r];
                    }
                }
            } else {
                unsigned int* o16 = (m == 1) ? out1 : out2;
                #pragma unroll
                for (int r = 0; r < 4; r++) {
                    float other = __shfl_xor(acc[r], 1, 64);
                    if (!(lane & 1)) {
                        int n = n0 + wave * 16 + quad * 4 + r;
                        if (n < N) {
                            size_t base = (size_t)n * 64 + ct * 8 + (col >> 1);
                            if (ileave)
                                out1[base * 2 + (m - 1)] = pk_bf2(acc[r], other);
                            else
                                o16[base] = pk_bf2(acc[r], other);
                        }
                    }
                }
            }
        }
    }
}

// ---------------------------------------------------------------------------
// Per-edge alpha, packed-fp32 form (lane owns features 2l, 2l+1).
// ---------------------------------------------------------------------------
__device__ __forceinline__ float edge_alpha(
    int lane, f32x2 qq, const f32x2* __restrict__ sW,
    const uint2* __restrict__ tab2, float2 rc2, float4 dd, unsigned int ku)
{
    float u = rc2.x * ((float)(TAB_N - 1) / RMAX);
    int i0 = (int)u;
    i0 = (i0 > TAB_N - 2) ? (TAB_N - 2) : i0;
    float fr = u - (float)i0;
    uint2 tp = tab2[(size_t)i0 * 64 + lane];
    f32x2 a = up2(tp.x), b = up2(tp.y);
    f32x2 fr2 = {fr, fr};
    f32x2 w = a + fr2 * (b - a);
    f32x2 d0 = {dd.x, dd.x}, d1 = {dd.y, dd.y}, d2 = {dd.z, dd.z}, d3 = {dd.w, dd.w};
    w = w + d0 * sW[lane] + d1 * sW[64 + lane] + d2 * sW[128 + lane] + d3 * sW[192 + lane];
    f32x2 p2 = qq * w * up2(ku);
    float p = p2.x + p2.y;
    #pragma unroll
    for (int o = 1; o < 16; o <<= 1) p += __shfl_xor(p, o, 64);
    return p * (rc2.y * RSQRT_DH * INV_AVG);
}

// ---------------------------------------------------------------------------
// Node-centric fused edge pass. mode 0: 4-way unrolled; mode 1: 2-way.
// ---------------------------------------------------------------------------
__global__ __launch_bounds__(256) void edge_pass_node_kernel(
    const int* __restrict__ off, const int* __restrict__ sp,
    const float2* __restrict__ rcC, const float4* __restrict__ ddl,
    const float* __restrict__ Yp,
    const float* __restrict__ qbuf,
    const uint2* __restrict__ kv16, const unsigned int* __restrict__ k16p,
    const uint2* __restrict__ tab2, const float* __restrict__ Wdeg_t,
    float* __restrict__ outbuf, int N, int mode)
{
    __shared__ f32x2 sW[4 * 64];   // Wdeg rows as packed pairs: sW[l*64+lane]
    if (threadIdx.x < 256) {
        int l = threadIdx.x >> 6, ln = threadIdx.x & 63;
        f32x2 v = {Wdeg_t[l * F + 2 * ln], Wdeg_t[l * F + 2 * ln + 1]};
        sW[l * 64 + ln] = v;
    }
    __syncthreads();

    int wave = threadIdx.x >> 6;
    int lane = threadIdx.x & 63;
    int n = blockIdx.x * 4 + wave;
    if (n >= N) return;

    int e0 = off[n], e1 = off[n + 1];
    float2 qf = ((const float2*)qbuf)[(size_t)n * 64 + lane];
    f32x2 qq = {qf.x, qf.y};
    f32x2 acc2 = {0.f, 0.f};
    float devacc = 0.0f;

    int ei = e0;
    if (mode == 0) {
        for (; ei + 3 < e1; ei += 4) {
            int sA = sp[ei], sB = sp[ei + 1], sC = sp[ei + 2], sD = sp[ei + 3];
            float2 rcA = rcC[ei], rcB = rcC[ei + 1], rcCc = rcC[ei + 2], rcD = rcC[ei + 3];
            float4 ddA = ddl[ei], ddB = ddl[ei + 1], ddC = ddl[ei + 2], ddD = ddl[ei + 3];
            uint2 kvA = kv16[(size_t)sA * 64 + lane];
            uint2 kvB = kv16[(size_t)sB * 64 + lane];
            uint2 kvC = kv16[(size_t)sC * 64 + lane];
            uint2 kvD = kv16[(size_t)sD * 64 + lane];
            float alA = edge_alpha(lane, qq, sW, tab2, rcA, ddA, kvA.x);
            float alB = edge_alpha(lane, qq, sW, tab2, rcB, ddB, kvB.x);
            float alC = edge_alpha(lane, qq, sW, tab2, rcCc, ddC, kvC.x);
            float alD = edge_alpha(lane, qq, sW, tab2, rcD, ddD, kvD.x);
            f32x2 vA = {alA, alA}, vB = {alB, alB}, vC = {alC, alC}, vD = {alD, alD};
            acc2 = acc2 + vA * up2(kvA.y) + vB * up2(kvB.y)
                        + vC * up2(kvC.y) + vD * up2(kvD.y);
        }
        for (; ei < e1; ei++) {
            int sA = sp[ei];
            uint2 kvA = kv16[(size_t)sA * 64 + lane];
            float alA = edge_alpha(lane, qq, sW, tab2, rcC[ei], ddl[ei], kvA.x);
            f32x2 vA = {alA, alA};
            acc2 = acc2 + vA * up2(kvA.y);
        }
        ((float2*)outbuf)[(size_t)n * 64 + lane] = make_float2(acc2.x, acc2.y);
    } else {
        for (; ei + 1 < e1; ei += 2) {
            int sA = sp[ei], sB = sp[ei + 1];
            float2 rcA = rcC[ei], rcB = rcC[ei + 1];
            float4 ddA = ddl[ei], ddB = ddl[ei + 1];
            unsigned int kA = k16p[(size_t)sA * 64 + lane];
            unsigned int kB = k16p[(size_t)sB * 64 + lane];
            float alA = edge_alpha(lane, qq, sW, tab2, rcA, ddA, kA);
            float alB = edge_alpha(lane, qq, sW, tab2, rcB, ddB, kB);
            float aA0 = __shfl(alA, 0), aA1 = __shfl(alA, 16);
            float aA2 = __shfl(alA, 32), aA3 = __shfl(alA, 48);
            float aB0 = __shfl(alB, 0), aB1 = __shfl(alB, 16);
            float aB2 = __shfl(alB, 32), aB3 = __shfl(alB, 48);
            if (lane < 16) {
                float adA = (lane == 0) ? aA0 : (lane < 4) ? aA1 : (lane < 9) ? aA2 : aA3;
                float adB = (lane == 0) ? aB0 : (lane < 4) ? aB1 : (lane < 9) ? aB2 : aB3;
                devacc += adA * Yp[(size_t)ei * 16 + lane]
                        + adB * Yp[(size_t)(ei + 1) * 16 + lane];
            }
        }
        if (ei < e1) {
            int sA = sp[ei];
            unsigned int kA = k16p[(size_t)sA * 64 + lane];
            float alA = edge_alpha(lane, qq, sW, tab2, rcC[ei], ddl[ei], kA);
            float aA0 = __shfl(alA, 0), aA1 = __shfl(alA, 16);
            float aA2 = __shfl(alA, 32), aA3 = __shfl(alA, 48);
            if (lane < 16) {
                float adA = (lane == 0) ? aA0 : (lane < 4) ? aA1 : (lane < 9) ? aA2 : aA3;
                devacc += adA * Yp[(size_t)ei * 16 + lane];
            }
        }
        if (lane < 16) outbuf[n * 16 + lane] = devacc;
    }
}

// ---------------------------------------------------------------------------
// MFMA exchange block: 64 nodes/block, 4 waves.
// ---------------------------------------------------------------------------
__global__ __launch_bounds__(256) void exchange_mfma_kernel(
    float* __restrict__ f, float* __restrict__ ev, const float* __restrict__ dEv,
    const unsigned int* __restrict__ B1, const float* __restrict__ Wex1,
    const float* __restrict__ bex1,
    const unsigned int* __restrict__ B2, const float* __restrict__ Wex2,
    const float* __restrict__ bex2, int N)
{
    __shared__ unsigned int sA[64 * APITCH];  // f bf16, later hid bf16
    __shared__ float sev[64][17];
    __shared__ float sEvInv[64][4];
    __shared__ float sW1x[4][F];              // Wex1 rows 128..131
    __shared__ float sW2x[F][4];              // Wex2 cols 128..131
    __shared__ float sB1[F];
    __shared__ float sB2[F];
    __shared__ float sb2x[4];
    __shared__ float syb[64][4];

    int tid = threadIdx.x;
    int n0 = blockIdx.x * 64;
    #pragma unroll
    for (int rep = 0; rep < 16; rep++) {
        int idx = rep * 256 + tid;
        int node = idx >> 6, jj = idx & 63;
        int n = n0 + node;
        float2 v = (n < N) ? ((const float2*)f)[(size_t)n * 64 + jj] : make_float2(0.f, 0.f);
        sA[node * APITCH + jj] = pk_bf2(v.x, v.y);
    }
    for (int idx = tid; idx < 64 * 16; idx += 256) {
        int node = idx >> 4, c = idx & 15;
        int n = n0 + node;
        sev[node][c] = (n < N) ? (ev[(size_t)n * 16 + c] + dEv[(size_t)n * 16 + c]) : 0.0f;
    }
    for (int idx = tid; idx < 4 * F; idx += 256)
        sW1x[idx >> 7][idx & 127] = Wex1[(size_t)(128 + (idx >> 7)) * F + (idx & 127)];
    for (int idx = tid; idx < F * 4; idx += 256)
        sW2x[idx >> 2][idx & 3] = Wex2[(size_t)(idx >> 2) * (F + 4) + 128 + (idx & 3)];
    if (tid < F) sB1[tid] = bex1[tid];
    else sB2[tid - F] = bex2[tid - F];
    if (tid < 4) sb2x[tid] = bex2[F + tid];
    __syncthreads();
    {
        int node = tid >> 2, d = tid & 3;
        int c0 = (d == 0) ? 0 : (d == 1) ? 1 : (d == 2) ? 4 : 9;
        int c1 = (d == 0) ? 1 : (d == 1) ? 4 : (d == 2) ? 9 : 16;
        float a = 0.0f;
        for (int c = c0; c < c1; c++) { float v = sev[node][c]; a += v * v; }
        sEvInv[node][d] = a;
    }
    int wave = tid >> 6, lane = tid & 63;
    int quad = lane >> 4, col = lane & 15;
    int mrow = wave * 16 + col;
    s16x8 af[4];
    #pragma unroll
    for (int kb = 0; kb < 4; kb++) {
        FragU fu;
        fu.u = *(const uint4*)&sA[mrow * APITCH + kb * 16 + quad * 4];
        af[kb] = fu.s;
    }
    __syncthreads();
    float evq[4][4];
    #pragma unroll
    for (int r = 0; r < 4; r++) {
        int node = wave * 16 + quad * 4 + r;
        #pragma unroll
        for (int d = 0; d < 4; d++) evq[r][d] = sEvInv[node][d];
    }
    // GEMM1: hid = silu(f@Wex1[:128] + ev_inv@Wex1[128:] + b1) -> sA (bf16)
    for (int ct = 0; ct < 8; ct++) {
        f32x4 acc = {0.f, 0.f, 0.f, 0.f};
        #pragma unroll
        for (int kb = 0; kb < 4; kb++) {
            FragU bu;
            bu.u = *(const uint4*)&B1[(size_t)((ct * 16 + kb * 4 + quad) * 16 + col) * 4];
            acc = __builtin_amdgcn_mfma_f32_16x16x32_bf16(af[kb], bu.s, acc, 0, 0, 0);
        }
        int j = ct * 16 + col;
        float w0 = sW1x[0][j], w1 = sW1x[1][j], w2 = sW1x[2][j], w3 = sW1x[3][j];
        float bj = sB1[j];
        #pragma unroll
        for (int r = 0; r < 4; r++) {
            float x = acc[r] + bj + evq[r][0] * w0 + evq[r][1] * w1
                    + evq[r][2] * w2 + evq[r][3] * w3;
            float h = silu_f(x);
            float other = __shfl_xor(h, 1, 64);
            if (!(lane & 1)) {
                int node = wave * 16 + quad * 4 + r;
                sA[node * APITCH + ct * 8 + (col >> 1)] = pk_bf2(h, other);
            }
        }
    }
    __syncthreads();
    s16x8 a2[4];
    #pragma unroll
    for (int kb = 0; kb < 4; kb++) {
        FragU fu;
        fu.u = *(const uint4*)&sA[mrow * APITCH + kb * 16 + quad * 4];
        a2[kb] = fu.s;
    }
    // yb2 (cols 128..131) per (node, d) thread
    {
        int node = tid >> 2, d = tid & 3;
        float a = sb2x[d];
        for (int dw = 0; dw < 64; dw++) {
            unsigned int u = sA[node * APITCH + dw];
            a += up_lo(u) * sW2x[2 * dw][d] + up_hi(u) * sW2x[2 * dw + 1][d];
        }
        syb[node][d] = a;
    }
    // GEMM2 cols 0..127: f += hid@Wex2[:, :128] + b2
    for (int ct = 0; ct < 8; ct++) {
        f32x4 acc = {0.f, 0.f, 0.f, 0.f};
        #pragma unroll
        for (int kb = 0; kb < 4; kb++) {
            FragU bu;
            bu.u = *(const uint4*)&B2[(size_t)((ct * 16 + kb * 4 + quad) * 16 + col) * 4];
            acc = __builtin_amdgcn_mfma_f32_16x16x32_bf16(a2[kb], bu.s, acc, 0, 0, 0);
        }
        int j = ct * 16 + col;
        float bj = sB2[j];
        #pragma unroll
        for (int r = 0; r < 4; r++) {
            int n = n0 + wave * 16 + quad * 4 + r;
            if (n < N) {
                size_t ix = (size_t)n * F + j;
                f[ix] = f[ix] + acc[r] + bj;
            }
        }
    }
    __syncthreads();
    for (int idx = tid; idx < 64 * 16; idx += 256) {
        int node = idx >> 4, c = idx & 15;
        int n = n0 + node;
        if (n < N) ev[(size_t)n * 16 + c] = sev[node][c] * (1.0f + syb[node][deg_of(c)]);
    }
}

// ---------------------------------------------------------------------------
// MFMA readout: node_e[n] = silu(f@Wo1+bo1) . Wo2 + bo2  (64 nodes/block)
// ---------------------------------------------------------------------------
__global__ __launch_bounds__(256) void readout_mfma_kernel(
    const float* __restrict__ f, const unsigned int* __restrict__ B,
    const float* __restrict__ bo1, const float* __restrict__ Wo2,
    const float* __restrict__ bo2, float* __restrict__ node_e, int N)
{
    __shared__ unsigned int sA[64 * APITCH];
    __shared__ float sB1[F];
    __shared__ float sW2[F];
    int tid = threadIdx.x;
    int n0 = blockIdx.x * 64;
    #pragma unroll
    for (int rep = 0; rep < 16; rep++) {
        int idx = rep * 256 + tid;
        int node = idx >> 6, jj = idx & 63;
        int n = n0 + node;
        float2 v = (n < N) ? ((const float2*)f)[(size_t)n * 64 + jj] : make_float2(0.f, 0.f);
        sA[node * APITCH + jj] = pk_bf2(v.x, v.y);
    }
    if (tid < F) sB1[tid] = bo1[tid];
    else sW2[tid - F] = Wo2[tid - F];
    __syncthreads();
    int wave = tid >> 6, lane = tid & 63;
    int quad = lane >> 4, col = lane & 15;
    int mrow = wave * 16 + col;
    s16x8 af[4];
    #pragma unroll
    for (int kb = 0; kb < 4; kb++) {
        FragU fu;
        fu.u = *(const uint4*)&sA[mrow * APITCH + kb * 16 + quad * 4];
        af[kb] = fu.s;
    }
    float part[4] = {0.f, 0.f, 0.f, 0.f};
    for (int ct = 0; ct < 8; ct++) {
        f32x4 acc = {0.f, 0.f, 0.f, 0.f};
        #pragma unroll
        for (int kb = 0; kb < 4; kb++) {
            FragU bu;
            bu.u = *(const uint4*)&B[(size_t)((ct * 16 + kb * 4 + quad) * 16 + col) * 4];
            acc = __builtin_amdgcn_mfma_f32_16x16x32_bf16(af[kb], bu.s, acc, 0, 0, 0);
        }
        int j = ct * 16 + col;
        float bj = sB1[j], wj = sW2[j];
        #pragma unroll
        for (int r = 0; r < 4; r++) part[r] += silu_f(acc[r] + bj) * wj;
    }
    #pragma unroll
    for (int r = 0; r < 4; r++) {
        #pragma unroll
        for (int o = 1; o < 16; o <<= 1) part[r] += __shfl_xor(part[r], o, 64);
    }
    if (col == 0) {
        #pragma unroll
        for (int r = 0; r < 4; r++) {
            int n = n0 + wave * 16 + quad * 4 + r;
            if (n < N) node_e[n] = part[r] + bo2[0];
        }
    }
}

// ---------------------------------------------------------------------------
// energy[g] = sum_{batch[n]==g} node_e[n]
// ---------------------------------------------------------------------------
__global__ __launch_bounds__(256) void energy_reduce_kernel(
    const float* __restrict__ node_e, const int* __restrict__ batch,
    float* __restrict__ energy, int N)
{
    __shared__ float eacc[64];
    if (threadIdx.x < 64) eacc[threadIdx.x] = 0.0f;
    __syncthreads();
    for (int n = blockIdx.x * blockDim.x + threadIdx.x; n < N; n += gridDim.x * blockDim.x)
        atomicAdd(&eacc[batch[n]], node_e[n]);
    __syncthreads();
    if (threadIdx.x < 64) atomicAdd(&energy[threadIdx.x], eacc[threadIdx.x]);
}

// ---------------------------------------------------------------------------
extern "C" void kernel_launch(void* const* d_in, const int* in_sizes, int n_in,
                              void* d_out, int out_size, void* d_ws, size_t ws_size,
                              hipStream_t stream)
{
    const float* positions = (const float*)d_in[0];
    const int*   species   = (const int*)d_in[1];
    const int*   senders   = (const int*)d_in[2];
    const int*   receivers = (const int*)d_in[3];
    const int*   batch     = (const int*)d_in[4];
    const float* embed     = (const float*)d_in[5];
    const float* Wq    = (const float*)d_in[6];
    const float* Wk    = (const float*)d_in[7];
    const float* Wv    = (const float*)d_in[8];
    const float* Wo    = (const float*)d_in[9];
    const float* Wrbf1 = (const float*)d_in[10];
    const float* brbf1 = (const float*)d_in[11];
    const float* Wrbf2 = (const float*)d_in[12];
    const float* Wdeg  = (const float*)d_in[13];
    const float* Wq2   = (const float*)d_in[14];
    const float* Wk2   = (const float*)d_in[15];
    const float* Wex1  = (const float*)d_in[16];
    const float* bex1  = (const float*)d_in[17];
    const float* Wex2  = (const float*)d_in[18];
    const float* bex2  = (const float*)d_in[19];
    const float* Wo1   = (const float*)d_in[20];
    const float* bo1   = (const float*)d_in[21];
    const float* Wo2   = (const float*)d_in[22];
    const float* bo2   = (const float*)d_in[23];

    int N = in_sizes[0] / 3;
    int E = in_sizes[2];

    // ---- workspace layout (~127 MB), staging region aliased ----
    float* ws     = (float*)d_ws;
    float* Yp     = ws;  ws += (size_t)E * 16;        // CSR-ordered Y
    float2* rcC   = (float2*)ws; ws += (size_t)E * 2; // CSR-ordered (r, C)
    float* f      = ws;  ws += (size_t)N * F;
    float* evb    = ws;  ws += (size_t)N * 16;
    float* dEv    = ws;  ws += (size_t)N * 16;
    float* q      = ws;  ws += (size_t)N * F;
    float* agg    = ws;  ws += (size_t)N * F;
    float* node_e = ws;  ws += (size_t)N;
    // union region: staging (rbuf/Cbuf/Ybuf, E*18 floats) then tab2/kv16/k16p/ddl
    float* un     = ws;  ws += (size_t)E * 18;
    float* rbuf   = un;
    float* Cbuf   = un + E;
    float* Ybuf   = un + (size_t)2 * E;
    uint2* tab2 = (uint2*)un;                                      // 3*TAB_N*64 uint2 (3 MB)
    uint2* kv16 = tab2 + (size_t)TINTER * TAB_N * 64;              // N*64 uint2 (k,v)
    unsigned int* k16p = (unsigned int*)(kv16 + (size_t)N * 64);   // N*64 (k2)
    float4* ddl   = (float4*)(k16p + (size_t)N * 64);              // E
    int* sp    = (int*)ws;  ws += E;
    int* rcvp  = (int*)ws;  ws += E;
    int* cnt   = (int*)ws;  ws += N;
    int* off   = (int*)ws;  ws += N + 1;
    int* cur   = (int*)ws;  ws += N;
    int* elist = (int*)ws;  ws += E;
    unsigned int* Wpk  = (unsigned int*)ws;  ws += 18 * 8192;      // qkv/o/q2/k2 packed
    unsigned int* Wpk2 = (unsigned int*)ws;  ws += 7 * 8192;       // ex1[3], ex2[3], wo1
    unsigned int* tabp = (unsigned int*)agg;                       // plain table scratch (1.5 MB, agg dead here)

    // ---- CSR build ----
    hipMemsetAsync(cnt, 0, (size_t)N * sizeof(int), stream);
    count_kernel<<<(E + 255) / 256, 256, 0, stream>>>(receivers, cnt, E);
    scan_kernel<<<1, 1024, 0, stream>>>(cnt, off, cur, N);
    scatter_kernel<<<(E + 255) / 256, 256, 0, stream>>>(receivers, cur, elist, E);

    // ---- geometry + CSR-order permute (staging region live) ----
    edge_geom_kernel<<<(E + 255) / 256, 256, 0, stream>>>(positions, senders, receivers,
                                                          rbuf, Cbuf, Ybuf, E);
    perm_edge_kernel<<<(E + 255) / 256, 256, 0, stream>>>(elist, senders, receivers,
                                                          rbuf, Cbuf, sp, rcvp, rcC, E);
    perm_Y_kernel<<<(int)(((size_t)E * 16 + 255) / 256), 256, 0, stream>>>(elist, Ybuf, Yp, E);
    // staging dead from here
    pack_w_kernel<<<(18 * 8192 + 255) / 256, 256, 0, stream>>>(Wq, Wk, Wv, Wo, Wq2, Wk2, Wpk);
    for (int t = 0; t < TINTER; t++) {
        pack_one_kernel<<<32, 256, 0, stream>>>(Wex1 + (size_t)t * (F + 4) * F, F,
                                                Wpk2 + (size_t)t * 8192);
        pack_one_kernel<<<32, 256, 0, stream>>>(Wex2 + (size_t)t * F * (F + 4), F + 4,
                                                Wpk2 + (size_t)(3 + t) * 8192);
    }
    pack_one_kernel<<<32, 256, 0, stream>>>(Wo1, F, Wpk2 + (size_t)6 * 8192);
    build_table_kernel<<<dim3(TAB_N / 4, TINTER), 256, 0, stream>>>(Wrbf1, brbf1, Wrbf2, tabp);
    pair_table_kernel<<<(TINTER * TAB_N * 64 + 255) / 256, 256, 0, stream>>>(tabp, tab2);
    ev0_kernel<<<(N + 15) / 16, 256, 0, stream>>>(off, Yp, rcC, evb, N);
    embed_kernel<<<N, F, 0, stream>>>(species, embed, f, N);

    int nmb = (N + 63) / 64;
    int npb = (N + 3) / 4;
    int edb = (E + 255) / 256;
    for (int t = 0; t < TINTER; t++) {
        const unsigned int* Wpk_q  = Wpk + (size_t)(0 * 3 + t) * 8192;
        const unsigned int* Wpk_k  = Wpk + (size_t)(1 * 3 + t) * 8192;
        const unsigned int* Wpk_v  = Wpk + (size_t)(2 * 3 + t) * 8192;
        const unsigned int* Wpk_o  = Wpk + (size_t)(3 * 3 + t) * 8192;
        const unsigned int* Wpk_q2 = Wpk + (size_t)(4 * 3 + t) * 8192;
        const unsigned int* Wpk_k2 = Wpk + (size_t)(5 * 3 + t) * 8192;
        const uint2* tab_t = tab2 + (size_t)t * TAB_N * 64;
        const float* Wdeg_t = Wdeg + (size_t)t * 4 * F;
        node_gemm_mfma_kernel<<<nmb, 256, 0, stream>>>(f, Wpk_q, Wpk_k, Wpk_v,
                                                       q, (unsigned int*)kv16, nullptr,
                                                       N, 3, 0, 1);
        dd_kernel<<<edb, 256, 0, stream>>>(sp, rcvp, evb, ddl, E);
        edge_pass_node_kernel<<<npb, 256, 0, stream>>>(off, sp, rcC, ddl, Yp,
            q, kv16, nullptr, tab_t, Wdeg_t, agg, N, 0);
        node_gemm_mfma_kernel<<<nmb, 256, 0, stream>>>(agg, Wpk_o, nullptr, nullptr,
                                                       f, nullptr, nullptr, N, 1, 1, 0);
        node_gemm_mfma_kernel<<<nmb, 256, 0, stream>>>(f, Wpk_q2, Wpk_k2, nullptr,
                                                       q, k16p, nullptr, N, 2, 0, 0);
        edge_pass_node_kernel<<<npb, 256, 0, stream>>>(off, sp, rcC, ddl, Yp,
            q, nullptr, k16p, tab_t, Wdeg_t, dEv, N, 1);
        exchange_mfma_kernel<<<nmb, 256, 0, stream>>>(f, evb, dEv,
            Wpk2 + (size_t)t * 8192, Wex1 + (size_t)t * (F + 4) * F, bex1 + (size_t)t * F,
            Wpk2 + (size_t)(3 + t) * 8192, Wex2 + (size_t)t * F * (F + 4),
            bex2 + (size_t)t * (F + 4), N);
    }
    readout_mfma_kernel<<<nmb, 256, 0, stream>>>(f, Wpk2 + (size_t)6 * 8192,
                                                 bo1, Wo2, bo2, node_e, N);
    hipMemsetAsync(d_out, 0, (size_t)out_size * sizeof(float), stream);
    energy_reduce_kernel<<<16, 256, 0, stream>>>(node_e, batch, (float*)d_out, N);
}

// Round 10
// 935.262 us; speedup vs baseline: 9.0955x; 1.1793x over previous
//
#include <hip/hip_runtime.h>
#include <math.h>

// ---- static config (matches reference) ----
#define F 128
#define KRBF 32
#define TINTER 3
#define RMAX 5.0f
#define INV_AVG (1.0f/16.0f)
#define GAMMA 40.96f               // (KRBF/RMAX)^2
#define RSQRT_DH 0.17677669529663689f  // 1/sqrt(32)
#define PI_F 3.14159265358979323846f
#define TAB_N 2048                 // w(r) interpolation table entries over [0, RMAX]
#define APITCH 68                  // LDS A-tile pitch in dwords (16B-aligned rows)

__device__ __forceinline__ float silu_f(float x) { return x / (1.0f + expf(-x)); }
__device__ __forceinline__ int deg_of(int c) { return (c == 0) ? 0 : (c < 4) ? 1 : (c < 9) ? 2 : 3; }

// bf16x2 pack/unpack: packed word = (elem0) | (elem1 << 16), RNE rounding
__device__ __forceinline__ unsigned int pk_bf2(float lo, float hi) {
    unsigned int a = __float_as_uint(lo), b = __float_as_uint(hi);
    unsigned int ar = (a + 0x7fffu + ((a >> 16) & 1u)) >> 16;
    unsigned int br = (b + 0x7fffu + ((b >> 16) & 1u)) >> 16;
    return ar | (br << 16);
}
__device__ __forceinline__ float up_lo(unsigned int u) { return __uint_as_float(u << 16); }
__device__ __forceinline__ float up_hi(unsigned int u) { return __uint_as_float(u & 0xffff0000u); }

typedef short s16x8 __attribute__((ext_vector_type(8)));
typedef float f32x4 __attribute__((ext_vector_type(4)));
typedef float f32x2 __attribute__((ext_vector_type(2)));
union FragU { uint4 u; s16x8 s; };

__device__ __forceinline__ f32x2 up2(unsigned int u) {
    f32x2 r; r.x = up_lo(u); r.y = up_hi(u); return r;
}

// ---------------------------------------------------------------------------
// CSR build: count -> scan -> scatter
// ---------------------------------------------------------------------------
__global__ void count_kernel(const int* __restrict__ rcv, int* __restrict__ cnt, int E)
{
    int e = blockIdx.x * blockDim.x + threadIdx.x;
    if (e < E) atomicAdd(&cnt[rcv[e]], 1);
}

__global__ __launch_bounds__(1024) void scan_kernel(const int* __restrict__ cnt,
                                                    int* __restrict__ off,
                                                    int* __restrict__ cur, int N)
{
    __shared__ int part[1024];
    int t = threadIdx.x;
    int chunk = (N + 1023) / 1024;
    int lo = t * chunk, hi = min(lo + chunk, N);
    int sum = 0;
    for (int i = lo; i < hi; i++) sum += cnt[i];
    part[t] = sum;
    __syncthreads();
    for (int st = 1; st < 1024; st <<= 1) {
        int v = (t >= st) ? part[t - st] : 0;
        __syncthreads();
        part[t] += v;
        __syncthreads();
    }
    int run = (t == 0) ? 0 : part[t - 1];
    for (int i = lo; i < hi; i++) {
        off[i] = run; cur[i] = run;
        run += cnt[i];
    }
    if (t == 1023) off[N] = part[1023];
}

__global__ void scatter_kernel(const int* __restrict__ rcv, int* __restrict__ cur,
                               int* __restrict__ elist, int E)
{
    int e = blockIdx.x * blockDim.x + threadIdx.x;
    if (e < E) {
        int p = atomicAdd(&cur[rcv[e]], 1);
        elist[p] = e;
    }
}

// ---------------------------------------------------------------------------
// Fused edge geometry in CSR order: sp, rcvp, (r,C), Y written directly
// permuted (no staging buffers).
// ---------------------------------------------------------------------------
__global__ void edge_geom_csr_kernel(const int* __restrict__ elist,
                                     const float* __restrict__ pos,
                                     const int* __restrict__ snd,
                                     const int* __restrict__ rcv,
                                     int* __restrict__ sp, int* __restrict__ rcvp,
                                     float2* __restrict__ rcC,
                                     float* __restrict__ Yp, int E)
{
    int ei = blockIdx.x * blockDim.x + threadIdx.x;
    if (ei >= E) return;
    int e = elist[ei];
    int s = snd[e], rc = rcv[e];
    sp[ei] = s; rcvp[ei] = rc;
    float vx = pos[rc * 3 + 0] - pos[s * 3 + 0];
    float vy = pos[rc * 3 + 1] - pos[s * 3 + 1];
    float vz = pos[rc * 3 + 2] - pos[s * 3 + 2];
    float r = sqrtf(vx * vx + vy * vy + vz * vz);
    float rinv = 1.0f / fmaxf(r, 1e-9f);
    float x = vx * rinv, y = vy * rinv, z = vz * rinv;
    float x2 = x * x, y2 = y * y, z2 = z * z;
    const float s3 = 1.7320508075688772f, s5 = 2.23606797749979f, s15 = 3.872983346207417f;
    const float s70 = 8.366600265340756f, s105 = 10.246950765959598f;
    const float s42 = 6.48074069840786f, s7 = 2.6457513110645907f;
    float Y[16];
    Y[0] = 1.0f;
    Y[1] = s3 * x; Y[2] = s3 * y; Y[3] = s3 * z;
    Y[4] = s15 * x * y; Y[5] = s15 * y * z; Y[6] = 0.5f * s5 * (3.0f * z2 - 1.0f);
    Y[7] = s15 * x * z; Y[8] = 0.5f * s15 * (x2 - y2);
    Y[9]  = 0.25f * s70 * y * (3.0f * x2 - y2);
    Y[10] = s105 * x * y * z;
    Y[11] = 0.25f * s42 * y * (5.0f * z2 - 1.0f);
    Y[12] = 0.5f * s7 * z * (5.0f * z2 - 3.0f);
    Y[13] = 0.25f * s42 * x * (5.0f * z2 - 1.0f);
    Y[14] = 0.5f * s105 * z * (x2 - y2);
    Y[15] = 0.25f * s70 * x * (x2 - 3.0f * y2);
    float C = (r < RMAX) ? 0.5f * (cosf(PI_F * r / RMAX) + 1.0f) : 0.0f;
    rcC[ei] = make_float2(r, C);
    #pragma unroll
    for (int c = 0; c < 16; c++) Yp[(size_t)ei * 16 + c] = Y[c];
}

// ---------------------------------------------------------------------------
// ev0[n] = sum_{ei in CSR(n)} Yp[ei]*C[ei] * INV_AVG
// ---------------------------------------------------------------------------
__global__ void ev0_kernel(const int* __restrict__ off,
                           const float* __restrict__ Yp, const float2* __restrict__ rcC,
                           float* __restrict__ ev, int N)
{
    int n = blockIdx.x * 16 + (threadIdx.x >> 4);
    int c = threadIdx.x & 15;
    if (n >= N) return;
    float acc = 0.0f;
    int e0 = off[n], e1 = off[n + 1];
    for (int ei = e0; ei < e1; ei++)
        acc += Yp[(size_t)ei * 16 + c] * rcC[ei].y;
    ev[n * 16 + c] = acc * INV_AVG;
}

// ---------------------------------------------------------------------------
// f = embed[species]
// ---------------------------------------------------------------------------
__global__ void embed_kernel(const int* __restrict__ species,
                             const float* __restrict__ embed,
                             float* __restrict__ f, int N)
{
    int n = blockIdx.x;
    if (n >= N) return;
    int j = threadIdx.x;
    f[n * F + j] = embed[species[n] * F + j];
}

// ---------------------------------------------------------------------------
// Pack 18 128x128 fp32 weight matrices into MFMA B-operand bf16 layout.
// ---------------------------------------------------------------------------
__global__ void pack_w_kernel(const float* __restrict__ Wq, const float* __restrict__ Wk,
                              const float* __restrict__ Wv, const float* __restrict__ Wo,
                              const float* __restrict__ Wq2, const float* __restrict__ Wk2,
                              unsigned int* __restrict__ Wpk)
{
    int tid = blockIdx.x * blockDim.x + threadIdx.x;
    if (tid >= 18 * 8192) return;
    int mat = tid >> 13;
    int rem = tid & 8191;
    int iw = rem & 3;
    int n = (rem >> 2) & 15;
    int quad = (rem >> 6) & 3;
    int kb = (rem >> 8) & 3;
    int ct = rem >> 10;
    const float* fam = (mat < 3) ? Wq : (mat < 6) ? Wk : (mat < 9) ? Wv
                     : (mat < 12) ? Wo : (mat < 15) ? Wq2 : Wk2;
    const float* src = fam + (size_t)(mat % 3) * F * F;
    int k = kb * 32 + quad * 8 + iw * 2;
    int col = ct * 16 + n;
    Wpk[tid] = pk_bf2(src[k * F + col], src[(k + 1) * F + col]);
}

// Generic 128x128 submatrix pack with arbitrary row stride (for Wex1/Wex2/Wo1)
__global__ void pack_one_kernel(const float* __restrict__ src, int rowStride,
                                unsigned int* __restrict__ dst)
{
    int tid = blockIdx.x * blockDim.x + threadIdx.x;
    if (tid >= 8192) return;
    int iw = tid & 3;
    int n = (tid >> 2) & 15;
    int quad = (tid >> 6) & 3;
    int kb = (tid >> 8) & 3;
    int ct = tid >> 10;
    int k = kb * 32 + quad * 8 + iw * 2;
    int col = ct * 16 + n;
    dst[tid] = pk_bf2(src[(size_t)k * rowStride + col], src[(size_t)(k + 1) * rowStride + col]);
}

// ---------------------------------------------------------------------------
// Build packed-bf16 w(r) table (plain): tabp[t][i][l] = bf16x2(w[2l], w[2l+1])
// ---------------------------------------------------------------------------
__global__ __launch_bounds__(256) void build_table_kernel(
    const float* __restrict__ Wrbf1_all, const float* __restrict__ brbf1_all,
    const float* __restrict__ Wrbf2_all, unsigned int* __restrict__ tabp)
{
    int wave = threadIdx.x >> 6;
    int lane = threadIdx.x & 63;
    int idx = blockIdx.x * 4 + wave;
    int t = blockIdx.y;
    const float* W1 = Wrbf1_all + (size_t)t * KRBF * F;
    const float* b1 = brbf1_all + (size_t)t * F;
    const float* W2 = Wrbf2_all + (size_t)t * F * F;
    float r = idx * (RMAX / (TAB_N - 1));
    __shared__ float sR[4][KRBF];
    __shared__ float sH[4][F];
    if (lane < KRBF) {
        float mu = lane * (RMAX / (KRBF - 1));
        float d = r - mu;
        sR[wave][lane] = expf(-GAMMA * d * d);
    }
    __syncthreads();
    float h0 = b1[lane], h1 = b1[lane + 64];
    #pragma unroll
    for (int kk = 0; kk < KRBF; kk++) {
        float rv = sR[wave][kk];
        h0 += rv * W1[kk * F + lane];
        h1 += rv * W1[kk * F + lane + 64];
    }
    sH[wave][lane] = silu_f(h0);
    sH[wave][lane + 64] = silu_f(h1);
    __syncthreads();
    float w0 = 0.0f, w1 = 0.0f;
    for (int i = 0; i < F; i++) {
        float hv = sH[wave][i];
        w0 += hv * W2[i * F + 2 * lane];
        w1 += hv * W2[i * F + 2 * lane + 1];
    }
    tabp[((size_t)t * TAB_N + idx) * 64 + lane] = pk_bf2(w0, w1);
}

// Pair the table: tab2[t][i][l] = (tabp[t][i][l], tabp[t][i+1][l])
__global__ void pair_table_kernel(const unsigned int* __restrict__ tabp,
                                  uint2* __restrict__ tab2)
{
    int tid = blockIdx.x * blockDim.x + threadIdx.x;
    if (tid >= TINTER * TAB_N * 64) return;
    int lane = tid & 63;
    int i = (tid >> 6) & (TAB_N - 1);
    int t = tid / (TAB_N * 64);
    int i1 = (i < TAB_N - 1) ? i + 1 : i;
    tab2[tid] = make_uint2(tabp[tid],
                           tabp[((size_t)t * TAB_N + i1) * 64 + lane]);
}

// ---------------------------------------------------------------------------
// dd_list[ei] = deg_reduce(ev[sp[ei]] * ev[rcvp[ei]])  (CSR order, float4)
// ---------------------------------------------------------------------------
__global__ void dd_kernel(const int* __restrict__ sp, const int* __restrict__ rcvp,
                          const float* __restrict__ ev, float4* __restrict__ ddl, int E)
{
    int ei = blockIdx.x * blockDim.x + threadIdx.x;
    if (ei >= E) return;
    int s = sp[ei], rc = rcvp[ei];
    const float4* a = (const float4*)(ev + (size_t)s * 16);
    const float4* b = (const float4*)(ev + (size_t)rc * 16);
    float4 a0 = a[0], a1 = a[1], a2 = a[2], a3 = a[3];
    float4 b0 = b[0], b1 = b[1], b2 = b[2], b3 = b[3];
    float d0 = a0.x * b0.x;
    float d1 = a0.y * b0.y + a0.z * b0.z + a0.w * b0.w;
    float d2 = a1.x * b1.x + a1.y * b1.y + a1.z * b1.z + a1.w * b1.w + a2.x * b2.x;
    float d3 = a2.y * b2.y + a2.z * b2.z + a2.w * b2.w
             + a3.x * b3.x + a3.y * b3.y + a3.z * b3.z + a3.w * b3.w;
    ddl[ei] = make_float4(d0, d1, d2, d3);
}

// ---------------------------------------------------------------------------
// MFMA node GEMM: out[m] = A @ W[m]. 64 nodes/block, 4 waves, 16x16x32 bf16.
// ---------------------------------------------------------------------------
__global__ __launch_bounds__(256) void node_gemm_mfma_kernel(
    const float* __restrict__ A,
    const unsigned int* __restrict__ B0, const unsigned int* __restrict__ B1,
    const unsigned int* __restrict__ B2,
    float* __restrict__ out0, unsigned int* __restrict__ out1, unsigned int* __restrict__ out2,
    int N, int nw, int accumulate, int ileave)
{
    __shared__ unsigned int sA[64 * APITCH];
    int tid = threadIdx.x;
    int n0 = blockIdx.x * 64;
    #pragma unroll
    for (int rep = 0; rep < 16; rep++) {
        int idx = rep * 256 + tid;
        int node = idx >> 6, jj = idx & 63;
        int n = n0 + node;
        float2 v = (n < N) ? ((const float2*)A)[(size_t)n * 64 + jj] : make_float2(0.f, 0.f);
        sA[node * APITCH + jj] = pk_bf2(v.x, v.y);
    }
    __syncthreads();
    int wave = tid >> 6, lane = tid & 63;
    int quad = lane >> 4, col = lane & 15;
    int mrow = wave * 16 + col;
    s16x8 af[4];
    #pragma unroll
    for (int kb = 0; kb < 4; kb++) {
        FragU fu;
        fu.u = *(const uint4*)&sA[mrow * APITCH + kb * 16 + quad * 4];
        af[kb] = fu.s;
    }
    for (int m = 0; m < nw; m++) {
        const unsigned int* B = (m == 0) ? B0 : (m == 1) ? B1 : B2;
        for (int ct = 0; ct < 8; ct++) {
            f32x4 acc = {0.f, 0.f, 0.f, 0.f};
            #pragma unroll
            for (int kb = 0; kb < 4; kb++) {
                FragU bu;
                bu.u = *(const uint4*)&B[(size_t)((ct * 16 + kb * 4 + quad) * 16 + col) * 4];
                acc = __builtin_amdgcn_mfma_f32_16x16x32_bf16(af[kb], bu.s, acc, 0, 0, 0);
            }
            if (m == 0) {
                #pragma unroll
                for (int r = 0; r < 4; r++) {
                    int n = n0 + wave * 16 + quad * 4 + r;
                    if (n < N) {
                        size_t ix = (size_t)n * F + ct * 16 + col;
                        out0[ix] = accumulate ? out0[ix] + acc[r] : acc[r];
                    }
                }
            } else {
                unsigned int* o16 = (m == 1) ? out1 : out2;
                #pragma unroll
                for (int r = 0; r < 4; r++) {
                    float other = __shfl_xor(acc[r], 1, 64);
                    if (!(lane & 1)) {
                        int n = n0 + wave * 16 + quad * 4 + r;
                        if (n < N) {
                            size_t base = (size_t)n * 64 + ct * 8 + (col >> 1);
                            if (ileave)
                                out1[base * 2 + (m - 1)] = pk_bf2(acc[r], other);
                            else
                                o16[base] = pk_bf2(acc[r], other);
                        }
                    }
                }
            }
        }
    }
}

// ---------------------------------------------------------------------------
// Per-edge alpha, packed-fp32 form; Wdeg held in VGPRs (wd0..wd3).
// ---------------------------------------------------------------------------
__device__ __forceinline__ float edge_alpha(
    int lane, f32x2 qq, f32x2 wd0, f32x2 wd1, f32x2 wd2, f32x2 wd3,
    const uint2* __restrict__ tab2, float2 rc2, float4 dd, unsigned int ku)
{
    float u = rc2.x * ((float)(TAB_N - 1) / RMAX);
    int i0 = (int)u;
    i0 = (i0 > TAB_N - 2) ? (TAB_N - 2) : i0;
    float fr = u - (float)i0;
    uint2 tp = tab2[(size_t)i0 * 64 + lane];
    f32x2 a = up2(tp.x), b = up2(tp.y);
    f32x2 fr2 = {fr, fr};
    f32x2 w = a + fr2 * (b - a);
    f32x2 d0 = {dd.x, dd.x}, d1 = {dd.y, dd.y}, d2 = {dd.z, dd.z}, d3 = {dd.w, dd.w};
    w = w + d0 * wd0 + d1 * wd1 + d2 * wd2 + d3 * wd3;
    f32x2 p2 = qq * w * up2(ku);
    float p = p2.x + p2.y;
    #pragma unroll
    for (int o = 1; o < 16; o <<= 1) p += __shfl_xor(p, o, 64);
    return p * (rc2.y * RSQRT_DH * INV_AVG);
}

// ---------------------------------------------------------------------------
// Node-centric fused edge pass. One wave per node; uniform edge stream
// scalarized (readfirstlane); Wdeg in registers; no LDS.
// mode 0: 4-way unrolled -> agg[n,128]; mode 1: 2-way -> dEv[n,16].
// ---------------------------------------------------------------------------
__global__ __launch_bounds__(256) void edge_pass_node_kernel(
    const int* __restrict__ off, const int* __restrict__ sp,
    const float2* __restrict__ rcC, const float4* __restrict__ ddl,
    const float* __restrict__ Yp,
    const float* __restrict__ qbuf,
    const uint2* __restrict__ kv16, const unsigned int* __restrict__ k16p,
    const uint2* __restrict__ tab2, const float* __restrict__ Wdeg_t,
    float* __restrict__ outbuf, int N, int mode)
{
    int wave = threadIdx.x >> 6;
    int lane = threadIdx.x & 63;
    int n = blockIdx.x * 4 + wave;
    if (n >= N) return;

    const float2* wdp = (const float2*)Wdeg_t;
    float2 w0f = wdp[lane], w1f = wdp[64 + lane], w2f = wdp[128 + lane], w3f = wdp[192 + lane];
    f32x2 wd0 = {w0f.x, w0f.y}, wd1 = {w1f.x, w1f.y};
    f32x2 wd2 = {w2f.x, w2f.y}, wd3 = {w3f.x, w3f.y};

    int e0 = __builtin_amdgcn_readfirstlane(off[n]);
    int e1 = __builtin_amdgcn_readfirstlane(off[n + 1]);
    float2 qf = ((const float2*)qbuf)[(size_t)n * 64 + lane];
    f32x2 qq = {qf.x, qf.y};
    f32x2 acc2 = {0.f, 0.f};
    float devacc = 0.0f;

    int ei = e0;
    if (mode == 0) {
        for (; ei + 3 < e1; ei += 4) {
            int sA = sp[ei], sB = sp[ei + 1], sC = sp[ei + 2], sD = sp[ei + 3];
            float2 rcA = rcC[ei], rcB = rcC[ei + 1], rcCc = rcC[ei + 2], rcD = rcC[ei + 3];
            float4 ddA = ddl[ei], ddB = ddl[ei + 1], ddC = ddl[ei + 2], ddD = ddl[ei + 3];
            uint2 kvA = kv16[(size_t)sA * 64 + lane];
            uint2 kvB = kv16[(size_t)sB * 64 + lane];
            uint2 kvC = kv16[(size_t)sC * 64 + lane];
            uint2 kvD = kv16[(size_t)sD * 64 + lane];
            float alA = edge_alpha(lane, qq, wd0, wd1, wd2, wd3, tab2, rcA, ddA, kvA.x);
            float alB = edge_alpha(lane, qq, wd0, wd1, wd2, wd3, tab2, rcB, ddB, kvB.x);
            float alC = edge_alpha(lane, qq, wd0, wd1, wd2, wd3, tab2, rcCc, ddC, kvC.x);
            float alD = edge_alpha(lane, qq, wd0, wd1, wd2, wd3, tab2, rcD, ddD, kvD.x);
            f32x2 vA = {alA, alA}, vB = {alB, alB}, vC = {alC, alC}, vD = {alD, alD};
            acc2 = acc2 + vA * up2(kvA.y) + vB * up2(kvB.y)
                        + vC * up2(kvC.y) + vD * up2(kvD.y);
        }
        for (; ei < e1; ei++) {
            int sA = sp[ei];
            uint2 kvA = kv16[(size_t)sA * 64 + lane];
            float alA = edge_alpha(lane, qq, wd0, wd1, wd2, wd3, tab2, rcC[ei], ddl[ei], kvA.x);
            f32x2 vA = {alA, alA};
            acc2 = acc2 + vA * up2(kvA.y);
        }
        ((float2*)outbuf)[(size_t)n * 64 + lane] = make_float2(acc2.x, acc2.y);
    } else {
        // per-lane source lane for the head->degree broadcast (lanes<16 used)
        int ssel = (lane == 0) ? 0 : (lane < 4) ? 16 : (lane < 9) ? 32 : 48;
        for (; ei + 1 < e1; ei += 2) {
            int sA = sp[ei], sB = sp[ei + 1];
            float2 rcA = rcC[ei], rcB = rcC[ei + 1];
            float4 ddA = ddl[ei], ddB = ddl[ei + 1];
            unsigned int kA = k16p[(size_t)sA * 64 + lane];
            unsigned int kB = k16p[(size_t)sB * 64 + lane];
            float alA = edge_alpha(lane, qq, wd0, wd1, wd2, wd3, tab2, rcA, ddA, kA);
            float alB = edge_alpha(lane, qq, wd0, wd1, wd2, wd3, tab2, rcB, ddB, kB);
            float adA = __shfl(alA, ssel);
            float adB = __shfl(alB, ssel);
            if (lane < 16) {
                devacc += adA * Yp[(size_t)ei * 16 + lane]
                        + adB * Yp[(size_t)(ei + 1) * 16 + lane];
            }
        }
        if (ei < e1) {
            int sA = sp[ei];
            unsigned int kA = k16p[(size_t)sA * 64 + lane];
            float alA = edge_alpha(lane, qq, wd0, wd1, wd2, wd3, tab2, rcC[ei], ddl[ei], kA);
            float adA = __shfl(alA, ssel);
            if (lane < 16) devacc += adA * Yp[(size_t)ei * 16 + lane];
        }
        if (lane < 16) outbuf[n * 16 + lane] = devacc;
    }
}

// ---------------------------------------------------------------------------
// MFMA exchange block: 64 nodes/block, 4 waves.
// ---------------------------------------------------------------------------
__global__ __launch_bounds__(256) void exchange_mfma_kernel(
    float* __restrict__ f, float* __restrict__ ev, const float* __restrict__ dEv,
    const unsigned int* __restrict__ B1, const float* __restrict__ Wex1,
    const float* __restrict__ bex1,
    const unsigned int* __restrict__ B2, const float* __restrict__ Wex2,
    const float* __restrict__ bex2, int N)
{
    __shared__ unsigned int sA[64 * APITCH];  // f bf16, later hid bf16
    __shared__ float sev[64][17];
    __shared__ float sEvInv[64][4];
    __shared__ float sW1x[4][F];              // Wex1 rows 128..131
    __shared__ float sW2x[F][4];              // Wex2 cols 128..131
    __shared__ float sB1[F];
    __shared__ float sB2[F];
    __shared__ float sb2x[4];
    __shared__ float syb[64][4];

    int tid = threadIdx.x;
    int n0 = blockIdx.x * 64;
    #pragma unroll
    for (int rep = 0; rep < 16; rep++) {
        int idx = rep * 256 + tid;
        int node = idx >> 6, jj = idx & 63;
        int n = n0 + node;
        float2 v = (n < N) ? ((const float2*)f)[(size_t)n * 64 + jj] : make_float2(0.f, 0.f);
        sA[node * APITCH + jj] = pk_bf2(v.x, v.y);
    }
    for (int idx = tid; idx < 64 * 16; idx += 256) {
        int node = idx >> 4, c = idx & 15;
        int n = n0 + node;
        sev[node][c] = (n < N) ? (ev[(size_t)n * 16 + c] + dEv[(size_t)n * 16 + c]) : 0.0f;
    }
    for (int idx = tid; idx < 4 * F; idx += 256)
        sW1x[idx >> 7][idx & 127] = Wex1[(size_t)(128 + (idx >> 7)) * F + (idx & 127)];
    for (int idx = tid; idx < F * 4; idx += 256)
        sW2x[idx >> 2][idx & 3] = Wex2[(size_t)(idx >> 2) * (F + 4) + 128 + (idx & 3)];
    if (tid < F) sB1[tid] = bex1[tid];
    else sB2[tid - F] = bex2[tid - F];
    if (tid < 4) sb2x[tid] = bex2[F + tid];
    __syncthreads();
    {
        int node = tid >> 2, d = tid & 3;
        int c0 = (d == 0) ? 0 : (d == 1) ? 1 : (d == 2) ? 4 : 9;
        int c1 = (d == 0) ? 1 : (d == 1) ? 4 : (d == 2) ? 9 : 16;
        float a = 0.0f;
        for (int c = c0; c < c1; c++) { float v = sev[node][c]; a += v * v; }
        sEvInv[node][d] = a;
    }
    int wave = tid >> 6, lane = tid & 63;
    int quad = lane >> 4, col = lane & 15;
    int mrow = wave * 16 + col;
    s16x8 af[4];
    #pragma unroll
    for (int kb = 0; kb < 4; kb++) {
        FragU fu;
        fu.u = *(const uint4*)&sA[mrow * APITCH + kb * 16 + quad * 4];
        af[kb] = fu.s;
    }
    __syncthreads();
    float evq[4][4];
    #pragma unroll
    for (int r = 0; r < 4; r++) {
        int node = wave * 16 + quad * 4 + r;
        #pragma unroll
        for (int d = 0; d < 4; d++) evq[r][d] = sEvInv[node][d];
    }
    // GEMM1: hid = silu(f@Wex1[:128] + ev_inv@Wex1[128:] + b1) -> sA (bf16)
    for (int ct = 0; ct < 8; ct++) {
        f32x4 acc = {0.f, 0.f, 0.f, 0.f};
        #pragma unroll
        for (int kb = 0; kb < 4; kb++) {
            FragU bu;
            bu.u = *(const uint4*)&B1[(size_t)((ct * 16 + kb * 4 + quad) * 16 + col) * 4];
            acc = __builtin_amdgcn_mfma_f32_16x16x32_bf16(af[kb], bu.s, acc, 0, 0, 0);
        }
        int j = ct * 16 + col;
        float w0 = sW1x[0][j], w1 = sW1x[1][j], w2 = sW1x[2][j], w3 = sW1x[3][j];
        float bj = sB1[j];
        #pragma unroll
        for (int r = 0; r < 4; r++) {
            float x = acc[r] + bj + evq[r][0] * w0 + evq[r][1] * w1
                    + evq[r][2] * w2 + evq[r][3] * w3;
            float h = silu_f(x);
            float other = __shfl_xor(h, 1, 64);
            if (!(lane & 1)) {
                int node = wave * 16 + quad * 4 + r;
                sA[node * APITCH + ct * 8 + (col >> 1)] = pk_bf2(h, other);
            }
        }
    }
    __syncthreads();
    s16x8 a2[4];
    #pragma unroll
    for (int kb = 0; kb < 4; kb++) {
        FragU fu;
        fu.u = *(const uint4*)&sA[mrow * APITCH + kb * 16 + quad * 4];
        a2[kb] = fu.s;
    }
    // yb2 (cols 128..131) per (node, d) thread
    {
        int node = tid >> 2, d = tid & 3;
        float a = sb2x[d];
        for (int dw = 0; dw < 64; dw++) {
            unsigned int u = sA[node * APITCH + dw];
            a += up_lo(u) * sW2x[2 * dw][d] + up_hi(u) * sW2x[2 * dw + 1][d];
        }
        syb[node][d] = a;
    }
    // GEMM2 cols 0..127: f += hid@Wex2[:, :128] + b2
    for (int ct = 0; ct < 8; ct++) {
        f32x4 acc = {0.f, 0.f, 0.f, 0.f};
        #pragma unroll
        for (int kb = 0; kb < 4; kb++) {
            FragU bu;
            bu.u = *(const uint4*)&B2[(size_t)((ct * 16 + kb * 4 + quad) * 16 + col) * 4];
            acc = __builtin_amdgcn_mfma_f32_16x16x32_bf16(a2[kb], bu.s, acc, 0, 0, 0);
        }
        int j = ct * 16 + col;
        float bj = sB2[j];
        #pragma unroll
        for (int r = 0; r < 4; r++) {
            int n = n0 + wave * 16 + quad * 4 + r;
            if (n < N) {
                size_t ix = (size_t)n * F + j;
                f[ix] = f[ix] + acc[r] + bj;
            }
        }
    }
    __syncthreads();
    for (int idx = tid; idx < 64 * 16; idx += 256) {
        int node = idx >> 4, c = idx & 15;
        int n = n0 + node;
        if (n < N) ev[(size_t)n * 16 + c] = sev[node][c] * (1.0f + syb[node][deg_of(c)]);
    }
}

// ---------------------------------------------------------------------------
// MFMA readout: node_e[n] = silu(f@Wo1+bo1) . Wo2 + bo2  (64 nodes/block)
// ---------------------------------------------------------------------------
__global__ __launch_bounds__(256) void readout_mfma_kernel(
    const float* __restrict__ f, const unsigned int* __restrict__ B,
    const float* __restrict__ bo1, const float* __restrict__ Wo2,
    const float* __restrict__ bo2, float* __restrict__ node_e, int N)
{
    __shared__ unsigned int sA[64 * APITCH];
    __shared__ float sB1[F];
    __shared__ float sW2[F];
    int tid = threadIdx.x;
    int n0 = blockIdx.x * 64;
    #pragma unroll
    for (int rep = 0; rep < 16; rep++) {
        int idx = rep * 256 + tid;
        int node = idx >> 6, jj = idx & 63;
        int n = n0 + node;
        float2 v = (n < N) ? ((const float2*)f)[(size_t)n * 64 + jj] : make_float2(0.f, 0.f);
        sA[node * APITCH + jj] = pk_bf2(v.x, v.y);
    }
    if (tid < F) sB1[tid] = bo1[tid];
    else sW2[tid - F] = Wo2[tid - F];
    __syncthreads();
    int wave = tid >> 6, lane = tid & 63;
    int quad = lane >> 4, col = lane & 15;
    int mrow = wave * 16 + col;
    s16x8 af[4];
    #pragma unroll
    for (int kb = 0; kb < 4; kb++) {
        FragU fu;
        fu.u = *(const uint4*)&sA[mrow * APITCH + kb * 16 + quad * 4];
        af[kb] = fu.s;
    }
    float part[4] = {0.f, 0.f, 0.f, 0.f};
    for (int ct = 0; ct < 8; ct++) {
        f32x4 acc = {0.f, 0.f, 0.f, 0.f};
        #pragma unroll
        for (int kb = 0; kb < 4; kb++) {
            FragU bu;
            bu.u = *(const uint4*)&B[(size_t)((ct * 16 + kb * 4 + quad) * 16 + col) * 4];
            acc = __builtin_amdgcn_mfma_f32_16x16x32_bf16(af[kb], bu.s, acc, 0, 0, 0);
        }
        int j = ct * 16 + col;
        float bj = sB1[j], wj = sW2[j];
        #pragma unroll
        for (int r = 0; r < 4; r++) part[r] += silu_f(acc[r] + bj) * wj;
    }
    #pragma unroll
    for (int r = 0; r < 4; r++) {
        #pragma unroll
        for (int o = 1; o < 16; o <<= 1) part[r] += __shfl_xor(part[r], o, 64);
    }
    if (col == 0) {
        #pragma unroll
        for (int r = 0; r < 4; r++) {
            int n = n0 + wave * 16 + quad * 4 + r;
            if (n < N) node_e[n] = part[r] + bo2[0];
        }
    }
}

// ---------------------------------------------------------------------------
// energy[g] = sum_{batch[n]==g} node_e[n]
// ---------------------------------------------------------------------------
__global__ __launch_bounds__(256) void energy_reduce_kernel(
    const float* __restrict__ node_e, const int* __restrict__ batch,
    float* __restrict__ energy, int N)
{
    __shared__ float eacc[64];
    if (threadIdx.x < 64) eacc[threadIdx.x] = 0.0f;
    __syncthreads();
    for (int n = blockIdx.x * blockDim.x + threadIdx.x; n < N; n += gridDim.x * blockDim.x)
        atomicAdd(&eacc[batch[n]], node_e[n]);
    __syncthreads();
    if (threadIdx.x < 64) atomicAdd(&energy[threadIdx.x], eacc[threadIdx.x]);
}

// ---------------------------------------------------------------------------
extern "C" void kernel_launch(void* const* d_in, const int* in_sizes, int n_in,
                              void* d_out, int out_size, void* d_ws, size_t ws_size,
                              hipStream_t stream)
{
    const float* positions = (const float*)d_in[0];
    const int*   species   = (const int*)d_in[1];
    const int*   senders   = (const int*)d_in[2];
    const int*   receivers = (const int*)d_in[3];
    const int*   batch     = (const int*)d_in[4];
    const float* embed     = (const float*)d_in[5];
    const float* Wq    = (const float*)d_in[6];
    const float* Wk    = (const float*)d_in[7];
    const float* Wv    = (const float*)d_in[8];
    const float* Wo    = (const float*)d_in[9];
    const float* Wrbf1 = (const float*)d_in[10];
    const float* brbf1 = (const float*)d_in[11];
    const float* Wrbf2 = (const float*)d_in[12];
    const float* Wdeg  = (const float*)d_in[13];
    const float* Wq2   = (const float*)d_in[14];
    const float* Wk2   = (const float*)d_in[15];
    const float* Wex1  = (const float*)d_in[16];
    const float* bex1  = (const float*)d_in[17];
    const float* Wex2  = (const float*)d_in[18];
    const float* bex2  = (const float*)d_in[19];
    const float* Wo1   = (const float*)d_in[20];
    const float* bo1   = (const float*)d_in[21];
    const float* Wo2   = (const float*)d_in[22];
    const float* bo2   = (const float*)d_in[23];

    int N = in_sizes[0] / 3;
    int E = in_sizes[2];

    // ---- workspace layout (~127 MB) ----
    float* ws     = (float*)d_ws;
    float* Yp     = ws;  ws += (size_t)E * 16;        // CSR-ordered Y
    float2* rcC   = (float2*)ws; ws += (size_t)E * 2; // CSR-ordered (r, C)
    float* f      = ws;  ws += (size_t)N * F;
    float* evb    = ws;  ws += (size_t)N * 16;
    float* dEv    = ws;  ws += (size_t)N * 16;
    float* q      = ws;  ws += (size_t)N * F;
    float* agg    = ws;  ws += (size_t)N * F;
    float* node_e = ws;  ws += (size_t)N;
    // union region (E*18 floats): tab2 / kv16 / k16p / ddl
    float* un     = ws;  ws += (size_t)E * 18;
    uint2* tab2 = (uint2*)un;                                      // 3*TAB_N*64 uint2 (3 MB)
    uint2* kv16 = tab2 + (size_t)TINTER * TAB_N * 64;              // N*64 uint2 (k,v)
    unsigned int* k16p = (unsigned int*)(kv16 + (size_t)N * 64);   // N*64 (k2)
    float4* ddl   = (float4*)(k16p + (size_t)N * 64);              // E
    int* sp    = (int*)ws;  ws += E;
    int* rcvp  = (int*)ws;  ws += E;
    int* cnt   = (int*)ws;  ws += N;
    int* off   = (int*)ws;  ws += N + 1;
    int* cur   = (int*)ws;  ws += N;
    int* elist = (int*)ws;  ws += E;
    unsigned int* Wpk  = (unsigned int*)ws;  ws += 18 * 8192;      // qkv/o/q2/k2 packed
    unsigned int* Wpk2 = (unsigned int*)ws;  ws += 7 * 8192;       // ex1[3], ex2[3], wo1
    unsigned int* tabp = (unsigned int*)agg;                       // plain table scratch (agg dead here)

    // ---- CSR build ----
    hipMemsetAsync(cnt, 0, (size_t)N * sizeof(int), stream);
    count_kernel<<<(E + 255) / 256, 256, 0, stream>>>(receivers, cnt, E);
    scan_kernel<<<1, 1024, 0, stream>>>(cnt, off, cur, N);
    scatter_kernel<<<(E + 255) / 256, 256, 0, stream>>>(receivers, cur, elist, E);

    // ---- fused CSR-order geometry ----
    edge_geom_csr_kernel<<<(E + 255) / 256, 256, 0, stream>>>(elist, positions, senders,
                                                              receivers, sp, rcvp, rcC, Yp, E);
    pack_w_kernel<<<(18 * 8192 + 255) / 256, 256, 0, stream>>>(Wq, Wk, Wv, Wo, Wq2, Wk2, Wpk);
    for (int t = 0; t < TINTER; t++) {
        pack_one_kernel<<<32, 256, 0, stream>>>(Wex1 + (size_t)t * (F + 4) * F, F,
                                                Wpk2 + (size_t)t * 8192);
        pack_one_kernel<<<32, 256, 0, stream>>>(Wex2 + (size_t)t * F * (F + 4), F + 4,
                                                Wpk2 + (size_t)(3 + t) * 8192);
    }
    pack_one_kernel<<<32, 256, 0, stream>>>(Wo1, F, Wpk2 + (size_t)6 * 8192);
    build_table_kernel<<<dim3(TAB_N / 4, TINTER), 256, 0, stream>>>(Wrbf1, brbf1, Wrbf2, tabp);
    pair_table_kernel<<<(TINTER * TAB_N * 64 + 255) / 256, 256, 0, stream>>>(tabp, tab2);
    ev0_kernel<<<(N + 15) / 16, 256, 0, stream>>>(off, Yp, rcC, evb, N);
    embed_kernel<<<N, F, 0, stream>>>(species, embed, f, N);

    int nmb = (N + 63) / 64;
    int npb = (N + 3) / 4;
    int edb = (E + 255) / 256;
    for (int t = 0; t < TINTER; t++) {
        const unsigned int* Wpk_q  = Wpk + (size_t)(0 * 3 + t) * 8192;
        const unsigned int* Wpk_k  = Wpk + (size_t)(1 * 3 + t) * 8192;
        const unsigned int* Wpk_v  = Wpk + (size_t)(2 * 3 + t) * 8192;
        const unsigned int* Wpk_o  = Wpk + (size_t)(3 * 3 + t) * 8192;
        const unsigned int* Wpk_q2 = Wpk + (size_t)(4 * 3 + t) * 8192;
        const unsigned int* Wpk_k2 = Wpk + (size_t)(5 * 3 + t) * 8192;
        const uint2* tab_t = tab2 + (size_t)t * TAB_N * 64;
        const float* Wdeg_t = Wdeg + (size_t)t * 4 * F;
        node_gemm_mfma_kernel<<<nmb, 256, 0, stream>>>(f, Wpk_q, Wpk_k, Wpk_v,
                                                       q, (unsigned int*)kv16, nullptr,
                                                       N, 3, 0, 1);
        dd_kernel<<<edb, 256, 0, stream>>>(sp, rcvp, evb, ddl, E);
        edge_pass_node_kernel<<<npb, 256, 0, stream>>>(off, sp, rcC, ddl, Yp,
            q, kv16, nullptr, tab_t, Wdeg_t, agg, N, 0);
        node_gemm_mfma_kernel<<<nmb, 256, 0, stream>>>(agg, Wpk_o, nullptr, nullptr,
                                                       f, nullptr, nullptr, N, 1, 1, 0);
        node_gemm_mfma_kernel<<<nmb, 256, 0, stream>>>(f, Wpk_q2, Wpk_k2, nullptr,
                                                       q, k16p, nullptr, N, 2, 0, 0);
        edge_pass_node_kernel<<<npb, 256, 0, stream>>>(off, sp, rcC, ddl, Yp,
            q, nullptr, k16p, tab_t, Wdeg_t, dEv, N, 1);
        exchange_mfma_kernel<<<nmb, 256, 0, stream>>>(f, evb, dEv,
            Wpk2 + (size_t)t * 8192, Wex1 + (size_t)t * (F + 4) * F, bex1 + (size_t)t * F,
            Wpk2 + (size_t)(3 + t) * 8192, Wex2 + (size_t)t * F * (F + 4),
            bex2 + (size_t)t * (F + 4), N);
    }
    readout_mfma_kernel<<<nmb, 256, 0, stream>>>(f, Wpk2 + (size_t)6 * 8192,
                                                 bo1, Wo2, bo2, node_e, N);
    hipMemsetAsync(d_out, 0, (size_t)out_size * sizeof(float), stream);
    energy_reduce_kernel<<<16, 256, 0, stream>>>(node_e, batch, (float*)d_out, N);
}

// Round 11
// 867.199 us; speedup vs baseline: 9.8094x; 1.0785x over previous
//
#include <hip/hip_runtime.h>
#include <math.h>

// ---- static config (matches reference) ----
#define F 128
#define KRBF 32
#define TINTER 3
#define RMAX 5.0f
#define INV_AVG (1.0f/16.0f)
#define GAMMA 40.96f               // (KRBF/RMAX)^2
#define RSQRT_DH 0.17677669529663689f  // 1/sqrt(32)
#define PI_F 3.14159265358979323846f
#define TAB_N 2048                 // w(r) interpolation table entries over [0, RMAX]
#define APITCH 68                  // LDS A-tile pitch in dwords (16B-aligned rows)

__device__ __forceinline__ float silu_f(float x) { return x / (1.0f + expf(-x)); }
__device__ __forceinline__ int deg_of(int c) { return (c == 0) ? 0 : (c < 4) ? 1 : (c < 9) ? 2 : 3; }

// bf16x2 pack/unpack: packed word = (elem0) | (elem1 << 16), RNE rounding
__device__ __forceinline__ unsigned int pk_bf2(float lo, float hi) {
    unsigned int a = __float_as_uint(lo), b = __float_as_uint(hi);
    unsigned int ar = (a + 0x7fffu + ((a >> 16) & 1u)) >> 16;
    unsigned int br = (b + 0x7fffu + ((b >> 16) & 1u)) >> 16;
    return ar | (br << 16);
}
__device__ __forceinline__ float up_lo(unsigned int u) { return __uint_as_float(u << 16); }
__device__ __forceinline__ float up_hi(unsigned int u) { return __uint_as_float(u & 0xffff0000u); }

typedef short s16x8 __attribute__((ext_vector_type(8)));
typedef float f32x4 __attribute__((ext_vector_type(4)));
typedef float f32x2 __attribute__((ext_vector_type(2)));
union FragU { uint4 u; s16x8 s; };

__device__ __forceinline__ f32x2 up2(unsigned int u) {
    f32x2 r; r.x = up_lo(u); r.y = up_hi(u); return r;
}

// 16-lane (head-group) sum via DPP: xor1, xor2 (quad_perm), then row_ror 4/8.
// Pure VALU — no LDS-pipe bpermute.
__device__ __forceinline__ float red16_dpp(float p) {
    p += __uint_as_float((unsigned)__builtin_amdgcn_update_dpp(
        0, (int)__float_as_uint(p), 0xB1, 0xF, 0xF, true));   // quad_perm [1,0,3,2]
    p += __uint_as_float((unsigned)__builtin_amdgcn_update_dpp(
        0, (int)__float_as_uint(p), 0x4E, 0xF, 0xF, true));   // quad_perm [2,3,0,1]
    p += __uint_as_float((unsigned)__builtin_amdgcn_update_dpp(
        0, (int)__float_as_uint(p), 0x124, 0xF, 0xF, true));  // row_ror:4
    p += __uint_as_float((unsigned)__builtin_amdgcn_update_dpp(
        0, (int)__float_as_uint(p), 0x128, 0xF, 0xF, true));  // row_ror:8
    return p;
}

// ---------------------------------------------------------------------------
// CSR build: count -> scan -> scatter
// ---------------------------------------------------------------------------
__global__ void count_kernel(const int* __restrict__ rcv, int* __restrict__ cnt, int E)
{
    int e = blockIdx.x * blockDim.x + threadIdx.x;
    if (e < E) atomicAdd(&cnt[rcv[e]], 1);
}

__global__ __launch_bounds__(1024) void scan_kernel(const int* __restrict__ cnt,
                                                    int* __restrict__ off,
                                                    int* __restrict__ cur, int N)
{
    __shared__ int part[1024];
    int t = threadIdx.x;
    int chunk = (N + 1023) / 1024;
    int lo = t * chunk, hi = min(lo + chunk, N);
    int sum = 0;
    for (int i = lo; i < hi; i++) sum += cnt[i];
    part[t] = sum;
    __syncthreads();
    for (int st = 1; st < 1024; st <<= 1) {
        int v = (t >= st) ? part[t - st] : 0;
        __syncthreads();
        part[t] += v;
        __syncthreads();
    }
    int run = (t == 0) ? 0 : part[t - 1];
    for (int i = lo; i < hi; i++) {
        off[i] = run; cur[i] = run;
        run += cnt[i];
    }
    if (t == 1023) off[N] = part[1023];
}

__global__ void scatter_kernel(const int* __restrict__ rcv, int* __restrict__ cur,
                               int* __restrict__ elist, int E)
{
    int e = blockIdx.x * blockDim.x + threadIdx.x;
    if (e < E) {
        int p = atomicAdd(&cur[rcv[e]], 1);
        elist[p] = e;
    }
}

// ---------------------------------------------------------------------------
// Fused edge geometry in CSR order: sp, rcvp, (r,C), Y written directly
// ---------------------------------------------------------------------------
__global__ void edge_geom_csr_kernel(const int* __restrict__ elist,
                                     const float* __restrict__ pos,
                                     const int* __restrict__ snd,
                                     const int* __restrict__ rcv,
                                     int* __restrict__ sp, int* __restrict__ rcvp,
                                     float2* __restrict__ rcC,
                                     float* __restrict__ Yp, int E)
{
    int ei = blockIdx.x * blockDim.x + threadIdx.x;
    if (ei >= E) return;
    int e = elist[ei];
    int s = snd[e], rc = rcv[e];
    sp[ei] = s; rcvp[ei] = rc;
    float vx = pos[rc * 3 + 0] - pos[s * 3 + 0];
    float vy = pos[rc * 3 + 1] - pos[s * 3 + 1];
    float vz = pos[rc * 3 + 2] - pos[s * 3 + 2];
    float r = sqrtf(vx * vx + vy * vy + vz * vz);
    float rinv = 1.0f / fmaxf(r, 1e-9f);
    float x = vx * rinv, y = vy * rinv, z = vz * rinv;
    float x2 = x * x, y2 = y * y, z2 = z * z;
    const float s3 = 1.7320508075688772f, s5 = 2.23606797749979f, s15 = 3.872983346207417f;
    const float s70 = 8.366600265340756f, s105 = 10.246950765959598f;
    const float s42 = 6.48074069840786f, s7 = 2.6457513110645907f;
    float Y[16];
    Y[0] = 1.0f;
    Y[1] = s3 * x; Y[2] = s3 * y; Y[3] = s3 * z;
    Y[4] = s15 * x * y; Y[5] = s15 * y * z; Y[6] = 0.5f * s5 * (3.0f * z2 - 1.0f);
    Y[7] = s15 * x * z; Y[8] = 0.5f * s15 * (x2 - y2);
    Y[9]  = 0.25f * s70 * y * (3.0f * x2 - y2);
    Y[10] = s105 * x * y * z;
    Y[11] = 0.25f * s42 * y * (5.0f * z2 - 1.0f);
    Y[12] = 0.5f * s7 * z * (5.0f * z2 - 3.0f);
    Y[13] = 0.25f * s42 * x * (5.0f * z2 - 1.0f);
    Y[14] = 0.5f * s105 * z * (x2 - y2);
    Y[15] = 0.25f * s70 * x * (x2 - 3.0f * y2);
    float C = (r < RMAX) ? 0.5f * (cosf(PI_F * r / RMAX) + 1.0f) : 0.0f;
    rcC[ei] = make_float2(r, C);
    #pragma unroll
    for (int c = 0; c < 16; c++) Yp[(size_t)ei * 16 + c] = Y[c];
}

// ---------------------------------------------------------------------------
// ev0[n] = sum_{ei in CSR(n)} Yp[ei]*C[ei] * INV_AVG
// ---------------------------------------------------------------------------
__global__ void ev0_kernel(const int* __restrict__ off,
                           const float* __restrict__ Yp, const float2* __restrict__ rcC,
                           float* __restrict__ ev, int N)
{
    int n = blockIdx.x * 16 + (threadIdx.x >> 4);
    int c = threadIdx.x & 15;
    if (n >= N) return;
    float acc = 0.0f;
    int e0 = off[n], e1 = off[n + 1];
    for (int ei = e0; ei < e1; ei++)
        acc += Yp[(size_t)ei * 16 + c] * rcC[ei].y;
    ev[n * 16 + c] = acc * INV_AVG;
}

// ---------------------------------------------------------------------------
// f = embed[species]
// ---------------------------------------------------------------------------
__global__ void embed_kernel(const int* __restrict__ species,
                             const float* __restrict__ embed,
                             float* __restrict__ f, int N)
{
    int n = blockIdx.x;
    if (n >= N) return;
    int j = threadIdx.x;
    f[n * F + j] = embed[species[n] * F + j];
}

// ---------------------------------------------------------------------------
// Pack 18 128x128 fp32 weight matrices into MFMA B-operand bf16 layout.
// ---------------------------------------------------------------------------
__global__ void pack_w_kernel(const float* __restrict__ Wq, const float* __restrict__ Wk,
                              const float* __restrict__ Wv, const float* __restrict__ Wo,
                              const float* __restrict__ Wq2, const float* __restrict__ Wk2,
                              unsigned int* __restrict__ Wpk)
{
    int tid = blockIdx.x * blockDim.x + threadIdx.x;
    if (tid >= 18 * 8192) return;
    int mat = tid >> 13;
    int rem = tid & 8191;
    int iw = rem & 3;
    int n = (rem >> 2) & 15;
    int quad = (rem >> 6) & 3;
    int kb = (rem >> 8) & 3;
    int ct = rem >> 10;
    const float* fam = (mat < 3) ? Wq : (mat < 6) ? Wk : (mat < 9) ? Wv
                     : (mat < 12) ? Wo : (mat < 15) ? Wq2 : Wk2;
    const float* src = fam + (size_t)(mat % 3) * F * F;
    int k = kb * 32 + quad * 8 + iw * 2;
    int col = ct * 16 + n;
    Wpk[tid] = pk_bf2(src[k * F + col], src[(k + 1) * F + col]);
}

// Pack the 7 exchange/readout 128x128 submatrices in one dispatch:
// mats 0-2: Wex1[t] (stride F); 3-5: Wex2[t] (stride F+4); 6: Wo1 (stride F)
__global__ void pack_ex_kernel(const float* __restrict__ Wex1, const float* __restrict__ Wex2,
                               const float* __restrict__ Wo1, unsigned int* __restrict__ Wpk2)
{
    int tid = blockIdx.x * blockDim.x + threadIdx.x;
    if (tid >= 7 * 8192) return;
    int mat = tid >> 13;
    int rem = tid & 8191;
    int iw = rem & 3;
    int n = (rem >> 2) & 15;
    int quad = (rem >> 6) & 3;
    int kb = (rem >> 8) & 3;
    int ct = rem >> 10;
    const float* src; int stride;
    if (mat < 3)      { src = Wex1 + (size_t)mat * (F + 4) * F; stride = F; }
    else if (mat < 6) { src = Wex2 + (size_t)(mat - 3) * F * (F + 4); stride = F + 4; }
    else              { src = Wo1; stride = F; }
    int k = kb * 32 + quad * 8 + iw * 2;
    int col = ct * 16 + n;
    Wpk2[tid] = pk_bf2(src[(size_t)k * stride + col], src[(size_t)(k + 1) * stride + col]);
}

// ---------------------------------------------------------------------------
// Build paired bf16 w(r) table directly:
// tab2[t][i][l] = ( bf16x2(w_i[2l],w_i[2l+1]), bf16x2(w_{i+1}[2l],w_{i+1}[2l+1]) )
// Each (t,i) wave writes its value into entry i's .x and entry i-1's .y.
// ---------------------------------------------------------------------------
__global__ __launch_bounds__(256) void build_table_kernel(
    const float* __restrict__ Wrbf1_all, const float* __restrict__ brbf1_all,
    const float* __restrict__ Wrbf2_all, unsigned int* __restrict__ tab2w)
{
    int wave = threadIdx.x >> 6;
    int lane = threadIdx.x & 63;
    int idx = blockIdx.x * 4 + wave;
    int t = blockIdx.y;
    const float* W1 = Wrbf1_all + (size_t)t * KRBF * F;
    const float* b1 = brbf1_all + (size_t)t * F;
    const float* W2 = Wrbf2_all + (size_t)t * F * F;
    float r = idx * (RMAX / (TAB_N - 1));
    __shared__ float sR[4][KRBF];
    __shared__ float sH[4][F];
    if (lane < KRBF) {
        float mu = lane * (RMAX / (KRBF - 1));
        float d = r - mu;
        sR[wave][lane] = expf(-GAMMA * d * d);
    }
    __syncthreads();
    float h0 = b1[lane], h1 = b1[lane + 64];
    #pragma unroll
    for (int kk = 0; kk < KRBF; kk++) {
        float rv = sR[wave][kk];
        h0 += rv * W1[kk * F + lane];
        h1 += rv * W1[kk * F + lane + 64];
    }
    sH[wave][lane] = silu_f(h0);
    sH[wave][lane + 64] = silu_f(h1);
    __syncthreads();
    float w0 = 0.0f, w1 = 0.0f;
    for (int i = 0; i < F; i++) {
        float hv = sH[wave][i];
        w0 += hv * W2[i * F + 2 * lane];
        w1 += hv * W2[i * F + 2 * lane + 1];
    }
    unsigned int w = pk_bf2(w0, w1);
    size_t base = ((size_t)t * TAB_N + idx) * 64 + lane;   // uint2 index
    tab2w[base * 2] = w;                                    // entry idx, .x
    if (idx > 0) tab2w[(base - 64) * 2 + 1] = w;            // entry idx-1, .y
    if (idx == TAB_N - 1) tab2w[base * 2 + 1] = w;          // last .y (unused, init)
}

// ---------------------------------------------------------------------------
// dd_list[ei] = deg_reduce(ev[sp[ei]] * ev[rcvp[ei]])  (CSR order, float4)
// ---------------------------------------------------------------------------
__global__ void dd_kernel(const int* __restrict__ sp, const int* __restrict__ rcvp,
                          const float* __restrict__ ev, float4* __restrict__ ddl, int E)
{
    int ei = blockIdx.x * blockDim.x + threadIdx.x;
    if (ei >= E) return;
    int s = sp[ei], rc = rcvp[ei];
    const float4* a = (const float4*)(ev + (size_t)s * 16);
    const float4* b = (const float4*)(ev + (size_t)rc * 16);
    float4 a0 = a[0], a1 = a[1], a2 = a[2], a3 = a[3];
    float4 b0 = b[0], b1 = b[1], b2 = b[2], b3 = b[3];
    float d0 = a0.x * b0.x;
    float d1 = a0.y * b0.y + a0.z * b0.z + a0.w * b0.w;
    float d2 = a1.x * b1.x + a1.y * b1.y + a1.z * b1.z + a1.w * b1.w + a2.x * b2.x;
    float d3 = a2.y * b2.y + a2.z * b2.z + a2.w * b2.w
             + a3.x * b3.x + a3.y * b3.y + a3.z * b3.z + a3.w * b3.w;
    ddl[ei] = make_float4(d0, d1, d2, d3);
}

// ---------------------------------------------------------------------------
// MFMA node GEMM: out[m] = A @ W[m]. 64 nodes/block, 4 waves, 16x16x32 bf16.
// ---------------------------------------------------------------------------
__global__ __launch_bounds__(256) void node_gemm_mfma_kernel(
    const float* __restrict__ A,
    const unsigned int* __restrict__ B0, const unsigned int* __restrict__ B1,
    const unsigned int* __restrict__ B2,
    float* __restrict__ out0, unsigned int* __restrict__ out1, unsigned int* __restrict__ out2,
    int N, int nw, int accumulate, int ileave)
{
    __shared__ unsigned int sA[64 * APITCH];
    int tid = threadIdx.x;
    int n0 = blockIdx.x * 64;
    #pragma unroll
    for (int rep = 0; rep < 16; rep++) {
        int idx = rep * 256 + tid;
        int node = idx >> 6, jj = idx & 63;
        int n = n0 + node;
        float2 v = (n < N) ? ((const float2*)A)[(size_t)n * 64 + jj] : make_float2(0.f, 0.f);
        sA[node * APITCH + jj] = pk_bf2(v.x, v.y);
    }
    __syncthreads();
    int wave = tid >> 6, lane = tid & 63;
    int quad = lane >> 4, col = lane & 15;
    int mrow = wave * 16 + col;
    s16x8 af[4];
    #pragma unroll
    for (int kb = 0; kb < 4; kb++) {
        FragU fu;
        fu.u = *(const uint4*)&sA[mrow * APITCH + kb * 16 + quad * 4];
        af[kb] = fu.s;
    }
    for (int m = 0; m < nw; m++) {
        const unsigned int* B = (m == 0) ? B0 : (m == 1) ? B1 : B2;
        for (int ct = 0; ct < 8; ct++) {
            f32x4 acc = {0.f, 0.f, 0.f, 0.f};
            #pragma unroll
            for (int kb = 0; kb < 4; kb++) {
                FragU bu;
                bu.u = *(const uint4*)&B[(size_t)((ct * 16 + kb * 4 + quad) * 16 + col) * 4];
                acc = __builtin_amdgcn_mfma_f32_16x16x32_bf16(af[kb], bu.s, acc, 0, 0, 0);
            }
            if (m == 0) {
                #pragma unroll
                for (int r = 0; r < 4; r++) {
                    int n = n0 + wave * 16 + quad * 4 + r;
                    if (n < N) {
                        size_t ix = (size_t)n * F + ct * 16 + col;
                        out0[ix] = accumulate ? out0[ix] + acc[r] : acc[r];
                    }
                }
            } else {
                unsigned int* o16 = (m == 1) ? out1 : out2;
                #pragma unroll
                for (int r = 0; r < 4; r++) {
                    float other = __shfl_xor(acc[r], 1, 64);
                    if (!(lane & 1)) {
                        int n = n0 + wave * 16 + quad * 4 + r;
                        if (n < N) {
                            size_t base = (size_t)n * 64 + ct * 8 + (col >> 1);
                            if (ileave)
                                out1[base * 2 + (m - 1)] = pk_bf2(acc[r], other);
                            else
                                o16[base] = pk_bf2(acc[r], other);
                        }
                    }
                }
            }
        }
    }
}

// ---------------------------------------------------------------------------
// Per-edge alpha (without C scale; q pre-scaled by RSQRT_DH*INV_AVG).
// Table row base scalarized via readfirstlane; 16-lane reduce via DPP.
// ---------------------------------------------------------------------------
__device__ __forceinline__ float edge_alpha(
    int lane, f32x2 qq, f32x2 wd0, f32x2 wd1, f32x2 wd2, f32x2 wd3,
    const uint2* __restrict__ tab2, float rr, float4 dd, unsigned int ku)
{
    float u = rr * ((float)(TAB_N - 1) / RMAX);
    int i0 = (int)u;
    i0 = (i0 > TAB_N - 2) ? (TAB_N - 2) : i0;
    float fr = u - (float)i0;
    int i0s = __builtin_amdgcn_readfirstlane(i0);
    uint2 tp = (tab2 + (size_t)i0s * 64)[lane];
    f32x2 a = up2(tp.x), b = up2(tp.y);
    f32x2 fr2 = {fr, fr};
    f32x2 w = a + fr2 * (b - a);
    f32x2 d0 = {dd.x, dd.x}, d1 = {dd.y, dd.y}, d2 = {dd.z, dd.z}, d3 = {dd.w, dd.w};
    w = w + d0 * wd0 + d1 * wd1 + d2 * wd2 + d3 * wd3;
    f32x2 p2 = qq * w * up2(ku);
    return red16_dpp(p2.x + p2.y);
}

// ---------------------------------------------------------------------------
// Node-centric fused edge pass. One wave per node; uniform edge stream
// scalarized; Wdeg in registers; DPP reductions; no LDS.
// mode 0: 4-way unrolled -> agg[n,128]
// mode 1: 4 edges/iter, lane group g handles edge ei+g's Y row -> dEv[n,16]
// ---------------------------------------------------------------------------
__global__ __launch_bounds__(256) void edge_pass_node_kernel(
    const int* __restrict__ off, const int* __restrict__ sp,
    const float2* __restrict__ rcC, const float4* __restrict__ ddl,
    const float* __restrict__ Yp,
    const float* __restrict__ qbuf,
    const uint2* __restrict__ kv16, const unsigned int* __restrict__ k16p,
    const uint2* __restrict__ tab2, const float* __restrict__ Wdeg_t,
    float* __restrict__ outbuf, int N, int mode)
{
    int wave = threadIdx.x >> 6;
    int lane = threadIdx.x & 63;
    int n = blockIdx.x * 4 + wave;
    if (n >= N) return;

    const float2* wdp = (const float2*)Wdeg_t;
    float2 w0f = wdp[lane], w1f = wdp[64 + lane], w2f = wdp[128 + lane], w3f = wdp[192 + lane];
    f32x2 wd0 = {w0f.x, w0f.y}, wd1 = {w1f.x, w1f.y};
    f32x2 wd2 = {w2f.x, w2f.y}, wd3 = {w3f.x, w3f.y};

    int e0 = __builtin_amdgcn_readfirstlane(off[n]);
    int e1 = __builtin_amdgcn_readfirstlane(off[n + 1]);
    float2 qf = ((const float2*)qbuf)[(size_t)n * 64 + lane];
    const float QS = RSQRT_DH * INV_AVG;
    f32x2 qq = {qf.x * QS, qf.y * QS};
    f32x2 acc2 = {0.f, 0.f};
    float devacc = 0.0f;

    int ei = e0;
    if (mode == 0) {
        for (; ei + 3 < e1; ei += 4) {
            int sA = sp[ei], sB = sp[ei + 1], sC = sp[ei + 2], sD = sp[ei + 3];
            float2 rcA = rcC[ei], rcB = rcC[ei + 1], rcCc = rcC[ei + 2], rcD = rcC[ei + 3];
            float4 ddA = ddl[ei], ddB = ddl[ei + 1], ddC = ddl[ei + 2], ddD = ddl[ei + 3];
            uint2 kvA = kv16[(size_t)sA * 64 + lane];
            uint2 kvB = kv16[(size_t)sB * 64 + lane];
            uint2 kvC = kv16[(size_t)sC * 64 + lane];
            uint2 kvD = kv16[(size_t)sD * 64 + lane];
            float alA = rcA.y * edge_alpha(lane, qq, wd0, wd1, wd2, wd3, tab2, rcA.x, ddA, kvA.x);
            float alB = rcB.y * edge_alpha(lane, qq, wd0, wd1, wd2, wd3, tab2, rcB.x, ddB, kvB.x);
            float alC = rcCc.y * edge_alpha(lane, qq, wd0, wd1, wd2, wd3, tab2, rcCc.x, ddC, kvC.x);
            float alD = rcD.y * edge_alpha(lane, qq, wd0, wd1, wd2, wd3, tab2, rcD.x, ddD, kvD.x);
            f32x2 vA = {alA, alA}, vB = {alB, alB}, vC = {alC, alC}, vD = {alD, alD};
            acc2 = acc2 + vA * up2(kvA.y) + vB * up2(kvB.y)
                        + vC * up2(kvC.y) + vD * up2(kvD.y);
        }
        for (; ei < e1; ei++) {
            int sA = sp[ei];
            float2 rcA = rcC[ei];
            uint2 kvA = kv16[(size_t)sA * 64 + lane];
            float alA = rcA.y * edge_alpha(lane, qq, wd0, wd1, wd2, wd3, tab2, rcA.x, ddl[ei], kvA.x);
            f32x2 vA = {alA, alA};
            acc2 = acc2 + vA * up2(kvA.y);
        }
        ((float2*)outbuf)[(size_t)n * 64 + lane] = make_float2(acc2.x, acc2.y);
    } else {
        int c = lane & 15;
        int g = lane >> 4;
        int ssel = ((c == 0) ? 0 : (c < 4) ? 16 : (c < 9) ? 32 : 48) + c;
        for (; ei + 3 < e1; ei += 4) {
            int sA = sp[ei], sB = sp[ei + 1], sC = sp[ei + 2], sD = sp[ei + 3];
            float2 rcA = rcC[ei], rcB = rcC[ei + 1], rcCc = rcC[ei + 2], rcD = rcC[ei + 3];
            float4 ddA = ddl[ei], ddB = ddl[ei + 1], ddC = ddl[ei + 2], ddD = ddl[ei + 3];
            unsigned int kA = k16p[(size_t)sA * 64 + lane];
            unsigned int kB = k16p[(size_t)sB * 64 + lane];
            unsigned int kC = k16p[(size_t)sC * 64 + lane];
            unsigned int kD = k16p[(size_t)sD * 64 + lane];
            float alA = rcA.y * edge_alpha(lane, qq, wd0, wd1, wd2, wd3, tab2, rcA.x, ddA, kA);
            float alB = rcB.y * edge_alpha(lane, qq, wd0, wd1, wd2, wd3, tab2, rcB.x, ddB, kB);
            float alC = rcCc.y * edge_alpha(lane, qq, wd0, wd1, wd2, wd3, tab2, rcCc.x, ddC, kC);
            float alD = rcD.y * edge_alpha(lane, qq, wd0, wd1, wd2, wd3, tab2, rcD.x, ddD, kD);
            float adA = __shfl(alA, ssel);
            float adB = __shfl(alB, ssel);
            float adC = __shfl(alC, ssel);
            float adD = __shfl(alD, ssel);
            float ad = (g == 0) ? adA : (g == 1) ? adB : (g == 2) ? adC : adD;
            devacc += ad * Yp[(size_t)(ei + g) * 16 + c];
        }
        for (; ei < e1; ei++) {
            int sA = sp[ei];
            float2 rcA = rcC[ei];
            unsigned int kA = k16p[(size_t)sA * 64 + lane];
            float alA = rcA.y * edge_alpha(lane, qq, wd0, wd1, wd2, wd3, tab2, rcA.x, ddl[ei], kA);
            float adA = __shfl(alA, ssel);
            if (g == 0) devacc += adA * Yp[(size_t)ei * 16 + c];
        }
        devacc += __shfl_xor(devacc, 16, 64);
        devacc += __shfl_xor(devacc, 32, 64);
        if (lane < 16) outbuf[n * 16 + lane] = devacc;
    }
}

// ---------------------------------------------------------------------------
// MFMA exchange block: 64 nodes/block, 4 waves.
// ---------------------------------------------------------------------------
__global__ __launch_bounds__(256) void exchange_mfma_kernel(
    float* __restrict__ f, float* __restrict__ ev, const float* __restrict__ dEv,
    const unsigned int* __restrict__ B1, const float* __restrict__ Wex1,
    const float* __restrict__ bex1,
    const unsigned int* __restrict__ B2, const float* __restrict__ Wex2,
    const float* __restrict__ bex2, int N)
{
    __shared__ unsigned int sA[64 * APITCH];  // f bf16, later hid bf16
    __shared__ float sev[64][17];
    __shared__ float sEvInv[64][4];
    __shared__ float sW1x[4][F];              // Wex1 rows 128..131
    __shared__ float sW2x[F][4];              // Wex2 cols 128..131
    __shared__ float sB1[F];
    __shared__ float sB2[F];
    __shared__ float sb2x[4];
    __shared__ float syb[64][4];

    int tid = threadIdx.x;
    int n0 = blockIdx.x * 64;
    #pragma unroll
    for (int rep = 0; rep < 16; rep++) {
        int idx = rep * 256 + tid;
        int node = idx >> 6, jj = idx & 63;
        int n = n0 + node;
        float2 v = (n < N) ? ((const float2*)f)[(size_t)n * 64 + jj] : make_float2(0.f, 0.f);
        sA[node * APITCH + jj] = pk_bf2(v.x, v.y);
    }
    for (int idx = tid; idx < 64 * 16; idx += 256) {
        int node = idx >> 4, c = idx & 15;
        int n = n0 + node;
        sev[node][c] = (n < N) ? (ev[(size_t)n * 16 + c] + dEv[(size_t)n * 16 + c]) : 0.0f;
    }
    for (int idx = tid; idx < 4 * F; idx += 256)
        sW1x[idx >> 7][idx & 127] = Wex1[(size_t)(128 + (idx >> 7)) * F + (idx & 127)];
    for (int idx = tid; idx < F * 4; idx += 256)
        sW2x[idx >> 2][idx & 3] = Wex2[(size_t)(idx >> 2) * (F + 4) + 128 + (idx & 3)];
    if (tid < F) sB1[tid] = bex1[tid];
    else sB2[tid - F] = bex2[tid - F];
    if (tid < 4) sb2x[tid] = bex2[F + tid];
    __syncthreads();
    {
        int node = tid >> 2, d = tid & 3;
        int c0 = (d == 0) ? 0 : (d == 1) ? 1 : (d == 2) ? 4 : 9;
        int c1 = (d == 0) ? 1 : (d == 1) ? 4 : (d == 2) ? 9 : 16;
        float a = 0.0f;
        for (int c = c0; c < c1; c++) { float v = sev[node][c]; a += v * v; }
        sEvInv[node][d] = a;
    }
    int wave = tid >> 6, lane = tid & 63;
    int quad = lane >> 4, col = lane & 15;
    int mrow = wave * 16 + col;
    s16x8 af[4];
    #pragma unroll
    for (int kb = 0; kb < 4; kb++) {
        FragU fu;
        fu.u = *(const uint4*)&sA[mrow * APITCH + kb * 16 + quad * 4];
        af[kb] = fu.s;
    }
    __syncthreads();
    float evq[4][4];
    #pragma unroll
    for (int r = 0; r < 4; r++) {
        int node = wave * 16 + quad * 4 + r;
        #pragma unroll
        for (int d = 0; d < 4; d++) evq[r][d] = sEvInv[node][d];
    }
    // GEMM1: hid = silu(f@Wex1[:128] + ev_inv@Wex1[128:] + b1) -> sA (bf16)
    for (int ct = 0; ct < 8; ct++) {
        f32x4 acc = {0.f, 0.f, 0.f, 0.f};
        #pragma unroll
        for (int kb = 0; kb < 4; kb++) {
            FragU bu;
            bu.u = *(const uint4*)&B1[(size_t)((ct * 16 + kb * 4 + quad) * 16 + col) * 4];
            acc = __builtin_amdgcn_mfma_f32_16x16x32_bf16(af[kb], bu.s, acc, 0, 0, 0);
        }
        int j = ct * 16 + col;
        float w0 = sW1x[0][j], w1 = sW1x[1][j], w2 = sW1x[2][j], w3 = sW1x[3][j];
        float bj = sB1[j];
        #pragma unroll
        for (int r = 0; r < 4; r++) {
            float x = acc[r] + bj + evq[r][0] * w0 + evq[r][1] * w1
                    + evq[r][2] * w2 + evq[r][3] * w3;
            float h = silu_f(x);
            float other = __shfl_xor(h, 1, 64);
            if (!(lane & 1)) {
                int node = wave * 16 + quad * 4 + r;
                sA[node * APITCH + ct * 8 + (col >> 1)] = pk_bf2(h, other);
            }
        }
    }
    __syncthreads();
    s16x8 a2[4];
    #pragma unroll
    for (int kb = 0; kb < 4; kb++) {
        FragU fu;
        fu.u = *(const uint4*)&sA[mrow * APITCH + kb * 16 + quad * 4];
        a2[kb] = fu.s;
    }
    // yb2 (cols 128..131) per (node, d) thread
    {
        int node = tid >> 2, d = tid & 3;
        float a = sb2x[d];
        for (int dw = 0; dw < 64; dw++) {
            unsigned int u = sA[node * APITCH + dw];
            a += up_lo(u) * sW2x[2 * dw][d] + up_hi(u) * sW2x[2 * dw + 1][d];
        }
        syb[node][d] = a;
    }
    // GEMM2 cols 0..127: f += hid@Wex2[:, :128] + b2
    for (int ct = 0; ct < 8; ct++) {
        f32x4 acc = {0.f, 0.f, 0.f, 0.f};
        #pragma unroll
        for (int kb = 0; kb < 4; kb++) {
            FragU bu;
            bu.u = *(const uint4*)&B2[(size_t)((ct * 16 + kb * 4 + quad) * 16 + col) * 4];
            acc = __builtin_amdgcn_mfma_f32_16x16x32_bf16(a2[kb], bu.s, acc, 0, 0, 0);
        }
        int j = ct * 16 + col;
        float bj = sB2[j];
        #pragma unroll
        for (int r = 0; r < 4; r++) {
            int n = n0 + wave * 16 + quad * 4 + r;
            if (n < N) {
                size_t ix = (size_t)n * F + j;
                f[ix] = f[ix] + acc[r] + bj;
            }
        }
    }
    __syncthreads();
    for (int idx = tid; idx < 64 * 16; idx += 256) {
        int node = idx >> 4, c = idx & 15;
        int n = n0 + node;
        if (n < N) ev[(size_t)n * 16 + c] = sev[node][c] * (1.0f + syb[node][deg_of(c)]);
    }
}

// ---------------------------------------------------------------------------
// MFMA readout: node_e[n] = silu(f@Wo1+bo1) . Wo2 + bo2  (64 nodes/block)
// ---------------------------------------------------------------------------
__global__ __launch_bounds__(256) void readout_mfma_kernel(
    const float* __restrict__ f, const unsigned int* __restrict__ B,
    const float* __restrict__ bo1, const float* __restrict__ Wo2,
    const float* __restrict__ bo2, float* __restrict__ node_e, int N)
{
    __shared__ unsigned int sA[64 * APITCH];
    __shared__ float sB1[F];
    __shared__ float sW2[F];
    int tid = threadIdx.x;
    int n0 = blockIdx.x * 64;
    #pragma unroll
    for (int rep = 0; rep < 16; rep++) {
        int idx = rep * 256 + tid;
        int node = idx >> 6, jj = idx & 63;
        int n = n0 + node;
        float2 v = (n < N) ? ((const float2*)f)[(size_t)n * 64 + jj] : make_float2(0.f, 0.f);
        sA[node * APITCH + jj] = pk_bf2(v.x, v.y);
    }
    if (tid < F) sB1[tid] = bo1[tid];
    else sW2[tid - F] = Wo2[tid - F];
    __syncthreads();
    int wave = tid >> 6, lane = tid & 63;
    int quad = lane >> 4, col = lane & 15;
    int mrow = wave * 16 + col;
    s16x8 af[4];
    #pragma unroll
    for (int kb = 0; kb < 4; kb++) {
        FragU fu;
        fu.u = *(const uint4*)&sA[mrow * APITCH + kb * 16 + quad * 4];
        af[kb] = fu.s;
    }
    float part[4] = {0.f, 0.f, 0.f, 0.f};
    for (int ct = 0; ct < 8; ct++) {
        f32x4 acc = {0.f, 0.f, 0.f, 0.f};
        #pragma unroll
        for (int kb = 0; kb < 4; kb++) {
            FragU bu;
            bu.u = *(const uint4*)&B[(size_t)((ct * 16 + kb * 4 + quad) * 16 + col) * 4];
            acc = __builtin_amdgcn_mfma_f32_16x16x32_bf16(af[kb], bu.s, acc, 0, 0, 0);
        }
        int j = ct * 16 + col;
        float bj = sB1[j], wj = sW2[j];
        #pragma unroll
        for (int r = 0; r < 4; r++) part[r] += silu_f(acc[r] + bj) * wj;
    }
    #pragma unroll
    for (int r = 0; r < 4; r++) part[r] = red16_dpp(part[r]);
    if (col == 0) {
        #pragma unroll
        for (int r = 0; r < 4; r++) {
            int n = n0 + wave * 16 + quad * 4 + r;
            if (n < N) node_e[n] = part[r] + bo2[0];
        }
    }
}

// ---------------------------------------------------------------------------
// energy[g] = sum_{batch[n]==g} node_e[n]
// ---------------------------------------------------------------------------
__global__ __launch_bounds__(256) void energy_reduce_kernel(
    const float* __restrict__ node_e, const int* __restrict__ batch,
    float* __restrict__ energy, int N)
{
    __shared__ float eacc[64];
    if (threadIdx.x < 64) eacc[threadIdx.x] = 0.0f;
    __syncthreads();
    for (int n = blockIdx.x * blockDim.x + threadIdx.x; n < N; n += gridDim.x * blockDim.x)
        atomicAdd(&eacc[batch[n]], node_e[n]);
    __syncthreads();
    if (threadIdx.x < 64) atomicAdd(&energy[threadIdx.x], eacc[threadIdx.x]);
}

// ---------------------------------------------------------------------------
extern "C" void kernel_launch(void* const* d_in, const int* in_sizes, int n_in,
                              void* d_out, int out_size, void* d_ws, size_t ws_size,
                              hipStream_t stream)
{
    const float* positions = (const float*)d_in[0];
    const int*   species   = (const int*)d_in[1];
    const int*   senders   = (const int*)d_in[2];
    const int*   receivers = (const int*)d_in[3];
    const int*   batch     = (const int*)d_in[4];
    const float* embed     = (const float*)d_in[5];
    const float* Wq    = (const float*)d_in[6];
    const float* Wk    = (const float*)d_in[7];
    const float* Wv    = (const float*)d_in[8];
    const float* Wo    = (const float*)d_in[9];
    const float* Wrbf1 = (const float*)d_in[10];
    const float* brbf1 = (const float*)d_in[11];
    const float* Wrbf2 = (const float*)d_in[12];
    const float* Wdeg  = (const float*)d_in[13];
    const float* Wq2   = (const float*)d_in[14];
    const float* Wk2   = (const float*)d_in[15];
    const float* Wex1  = (const float*)d_in[16];
    const float* bex1  = (const float*)d_in[17];
    const float* Wex2  = (const float*)d_in[18];
    const float* bex2  = (const float*)d_in[19];
    const float* Wo1   = (const float*)d_in[20];
    const float* bo1   = (const float*)d_in[21];
    const float* Wo2   = (const float*)d_in[22];
    const float* bo2   = (const float*)d_in[23];

    int N = in_sizes[0] / 3;
    int E = in_sizes[2];

    // ---- workspace layout (~127 MB) ----
    float* ws     = (float*)d_ws;
    float* Yp     = ws;  ws += (size_t)E * 16;        // CSR-ordered Y
    float2* rcC   = (float2*)ws; ws += (size_t)E * 2; // CSR-ordered (r, C)
    float* f      = ws;  ws += (size_t)N * F;
    float* evb    = ws;  ws += (size_t)N * 16;
    float* dEv    = ws;  ws += (size_t)N * 16;
    float* q      = ws;  ws += (size_t)N * F;
    float* agg    = ws;  ws += (size_t)N * F;
    float* node_e = ws;  ws += (size_t)N;
    // union region (E*18 floats): tab2 / kv16 / k16p / ddl
    float* un     = ws;  ws += (size_t)E * 18;
    uint2* tab2 = (uint2*)un;                                      // 3*TAB_N*64 uint2 (3 MB)
    uint2* kv16 = tab2 + (size_t)TINTER * TAB_N * 64;              // N*64 uint2 (k,v)
    unsigned int* k16p = (unsigned int*)(kv16 + (size_t)N * 64);   // N*64 (k2)
    float4* ddl   = (float4*)(k16p + (size_t)N * 64);              // E
    int* sp    = (int*)ws;  ws += E;
    int* rcvp  = (int*)ws;  ws += E;
    int* cnt   = (int*)ws;  ws += N;
    int* off   = (int*)ws;  ws += N + 1;
    int* cur   = (int*)ws;  ws += N;
    int* elist = (int*)ws;  ws += E;
    unsigned int* Wpk  = (unsigned int*)ws;  ws += 18 * 8192;      // qkv/o/q2/k2 packed
    unsigned int* Wpk2 = (unsigned int*)ws;  ws += 7 * 8192;       // ex1[3], ex2[3], wo1

    // ---- CSR build ----
    hipMemsetAsync(cnt, 0, (size_t)N * sizeof(int), stream);
    count_kernel<<<(E + 255) / 256, 256, 0, stream>>>(receivers, cnt, E);
    scan_kernel<<<1, 1024, 0, stream>>>(cnt, off, cur, N);
    scatter_kernel<<<(E + 255) / 256, 256, 0, stream>>>(receivers, cur, elist, E);

    // ---- fused CSR-order geometry + weight packing + table ----
    edge_geom_csr_kernel<<<(E + 255) / 256, 256, 0, stream>>>(elist, positions, senders,
                                                              receivers, sp, rcvp, rcC, Yp, E);
    pack_w_kernel<<<(18 * 8192 + 255) / 256, 256, 0, stream>>>(Wq, Wk, Wv, Wo, Wq2, Wk2, Wpk);
    pack_ex_kernel<<<(7 * 8192 + 255) / 256, 256, 0, stream>>>(Wex1, Wex2, Wo1, Wpk2);
    build_table_kernel<<<dim3(TAB_N / 4, TINTER), 256, 0, stream>>>(Wrbf1, brbf1, Wrbf2,
                                                                    (unsigned int*)tab2);
    ev0_kernel<<<(N + 15) / 16, 256, 0, stream>>>(off, Yp, rcC, evb, N);
    embed_kernel<<<N, F, 0, stream>>>(species, embed, f, N);

    int nmb = (N + 63) / 64;
    int npb = (N + 3) / 4;
    int edb = (E + 255) / 256;
    for (int t = 0; t < TINTER; t++) {
        const unsigned int* Wpk_q  = Wpk + (size_t)(0 * 3 + t) * 8192;
        const unsigned int* Wpk_k  = Wpk + (size_t)(1 * 3 + t) * 8192;
        const unsigned int* Wpk_v  = Wpk + (size_t)(2 * 3 + t) * 8192;
        const unsigned int* Wpk_o  = Wpk + (size_t)(3 * 3 + t) * 8192;
        const unsigned int* Wpk_q2 = Wpk + (size_t)(4 * 3 + t) * 8192;
        const unsigned int* Wpk_k2 = Wpk + (size_t)(5 * 3 + t) * 8192;
        const uint2* tab_t = tab2 + (size_t)t * TAB_N * 64;
        const float* Wdeg_t = Wdeg + (size_t)t * 4 * F;
        node_gemm_mfma_kernel<<<nmb, 256, 0, stream>>>(f, Wpk_q, Wpk_k, Wpk_v,
                                                       q, (unsigned int*)kv16, nullptr,
                                                       N, 3, 0, 1);
        dd_kernel<<<edb, 256, 0, stream>>>(sp, rcvp, evb, ddl, E);
        edge_pass_node_kernel<<<npb, 256, 0, stream>>>(off, sp, rcC, ddl, Yp,
            q, kv16, nullptr, tab_t, Wdeg_t, agg, N, 0);
        node_gemm_mfma_kernel<<<nmb, 256, 0, stream>>>(agg, Wpk_o, nullptr, nullptr,
                                                       f, nullptr, nullptr, N, 1, 1, 0);
        node_gemm_mfma_kernel<<<nmb, 256, 0, stream>>>(f, Wpk_q2, Wpk_k2, nullptr,
                                                       q, k16p, nullptr, N, 2, 0, 0);
        edge_pass_node_kernel<<<npb, 256, 0, stream>>>(off, sp, rcC, ddl, Yp,
            q, nullptr, k16p, tab_t, Wdeg_t, dEv, N, 1);
        exchange_mfma_kernel<<<nmb, 256, 0, stream>>>(f, evb, dEv,
            Wpk2 + (size_t)t * 8192, Wex1 + (size_t)t * (F + 4) * F, bex1 + (size_t)t * F,
            Wpk2 + (size_t)(3 + t) * 8192, Wex2 + (size_t)t * F * (F + 4),
            bex2 + (size_t)t * (F + 4), N);
    }
    readout_mfma_kernel<<<nmb, 256, 0, stream>>>(f, Wpk2 + (size_t)6 * 8192,
                                                 bo1, Wo2, bo2, node_e, N);
    hipMemsetAsync(d_out, 0, (size_t)out_size * sizeof(float), stream);
    energy_reduce_kernel<<<16, 256, 0, stream>>>(node_e, batch, (float*)d_out, N);
}

// Round 12
// 796.853 us; speedup vs baseline: 10.6753x; 1.0883x over previous
//
#include <hip/hip_runtime.h>
#include <math.h>

// ---- static config (matches reference) ----
#define F 128
#define KRBF 32
#define TINTER 3
#define RMAX 5.0f
#define INV_AVG (1.0f/16.0f)
#define GAMMA 40.96f               // (KRBF/RMAX)^2
#define RSQRT_DH 0.17677669529663689f  // 1/sqrt(32)
#define PI_F 3.14159265358979323846f
#define TAB_N 2048                 // w(r) interpolation table entries over [0, RMAX]
#define APITCH 68                  // LDS A-tile pitch in dwords (16B-aligned rows)
#define SCB 256                    // scan block size

__device__ __forceinline__ float silu_f(float x) { return x / (1.0f + expf(-x)); }
__device__ __forceinline__ int deg_of(int c) { return (c == 0) ? 0 : (c < 4) ? 1 : (c < 9) ? 2 : 3; }

// bf16x2 pack/unpack: packed word = (elem0) | (elem1 << 16), RNE rounding
__device__ __forceinline__ unsigned int pk_bf2(float lo, float hi) {
    unsigned int a = __float_as_uint(lo), b = __float_as_uint(hi);
    unsigned int ar = (a + 0x7fffu + ((a >> 16) & 1u)) >> 16;
    unsigned int br = (b + 0x7fffu + ((b >> 16) & 1u)) >> 16;
    return ar | (br << 16);
}
__device__ __forceinline__ float up_lo(unsigned int u) { return __uint_as_float(u << 16); }
__device__ __forceinline__ float up_hi(unsigned int u) { return __uint_as_float(u & 0xffff0000u); }

typedef short s16x8 __attribute__((ext_vector_type(8)));
typedef float f32x4 __attribute__((ext_vector_type(4)));
typedef float f32x2 __attribute__((ext_vector_type(2)));
union FragU { uint4 u; s16x8 s; };

__device__ __forceinline__ f32x2 up2(unsigned int u) {
    f32x2 r; r.x = up_lo(u); r.y = up_hi(u); return r;
}

// 16-lane (head-group) sum via DPP — pure VALU, no LDS-pipe bpermute.
__device__ __forceinline__ float red16_dpp(float p) {
    p += __uint_as_float((unsigned)__builtin_amdgcn_update_dpp(
        0, (int)__float_as_uint(p), 0xB1, 0xF, 0xF, true));   // quad_perm [1,0,3,2]
    p += __uint_as_float((unsigned)__builtin_amdgcn_update_dpp(
        0, (int)__float_as_uint(p), 0x4E, 0xF, 0xF, true));   // quad_perm [2,3,0,1]
    p += __uint_as_float((unsigned)__builtin_amdgcn_update_dpp(
        0, (int)__float_as_uint(p), 0x124, 0xF, 0xF, true));  // row_ror:4
    p += __uint_as_float((unsigned)__builtin_amdgcn_update_dpp(
        0, (int)__float_as_uint(p), 0x128, 0xF, 0xF, true));  // row_ror:8
    return p;
}

// ---------------------------------------------------------------------------
// CSR build: count -> parallel 3-phase scan -> scatter
// ---------------------------------------------------------------------------
__global__ void count_kernel(const int* __restrict__ rcv, int* __restrict__ cnt, int E)
{
    int e = blockIdx.x * blockDim.x + threadIdx.x;
    if (e < E) atomicAdd(&cnt[rcv[e]], 1);
}

// Phase 1: per-block inclusive scan; write in-block exclusive prefix + block sum
__global__ __launch_bounds__(SCB) void scan_part_kernel(const int* __restrict__ cnt,
                                                        int* __restrict__ off,
                                                        int* __restrict__ bsum, int N)
{
    __shared__ int s[SCB];
    int tid = threadIdx.x;
    int i = blockIdx.x * SCB + tid;
    int v = (i < N) ? cnt[i] : 0;
    s[tid] = v;
    __syncthreads();
    for (int st = 1; st < SCB; st <<= 1) {
        int t = (tid >= st) ? s[tid - st] : 0;
        __syncthreads();
        s[tid] += t;
        __syncthreads();
    }
    if (i < N) off[i] = s[tid] - v;            // exclusive within block
    if (tid == SCB - 1) bsum[blockIdx.x] = s[tid];
}

// Phase 2: single-block exclusive scan of block sums (nb <= 1024); off[N] = total
__global__ __launch_bounds__(1024) void scan_mid_kernel(const int* __restrict__ bsum,
                                                        int* __restrict__ boff,
                                                        int* __restrict__ off, int N, int nb)
{
    __shared__ int s[1024];
    int tid = threadIdx.x;
    int v = (tid < nb) ? bsum[tid] : 0;
    s[tid] = v;
    __syncthreads();
    for (int st = 1; st < 1024; st <<= 1) {
        int t = (tid >= st) ? s[tid - st] : 0;
        __syncthreads();
        s[tid] += t;
        __syncthreads();
    }
    if (tid < nb) boff[tid] = s[tid] - v;
    if (tid == 1023) off[N] = s[1023];
}

// Phase 3: add block offsets; init cur
__global__ void scan_add_kernel(int* __restrict__ off, int* __restrict__ cur,
                                const int* __restrict__ boff, int N)
{
    int i = blockIdx.x * blockDim.x + threadIdx.x;
    if (i < N) {
        int v = off[i] + boff[i / SCB];
        off[i] = v; cur[i] = v;
    }
}

__global__ void scatter_kernel(const int* __restrict__ rcv, int* __restrict__ cur,
                               int* __restrict__ elist, int E)
{
    int e = blockIdx.x * blockDim.x + threadIdx.x;
    if (e < E) {
        int p = atomicAdd(&cur[rcv[e]], 1);
        elist[p] = e;
    }
}

// ---------------------------------------------------------------------------
// Fused edge geometry in CSR order: sp, rcvp, (r,C), Y written directly
// ---------------------------------------------------------------------------
__global__ void edge_geom_csr_kernel(const int* __restrict__ elist,
                                     const float* __restrict__ pos,
                                     const int* __restrict__ snd,
                                     const int* __restrict__ rcv,
                                     int* __restrict__ sp, int* __restrict__ rcvp,
                                     float2* __restrict__ rcC,
                                     float* __restrict__ Yp, int E)
{
    int ei = blockIdx.x * blockDim.x + threadIdx.x;
    if (ei >= E) return;
    int e = elist[ei];
    int s = snd[e], rc = rcv[e];
    sp[ei] = s; rcvp[ei] = rc;
    float vx = pos[rc * 3 + 0] - pos[s * 3 + 0];
    float vy = pos[rc * 3 + 1] - pos[s * 3 + 1];
    float vz = pos[rc * 3 + 2] - pos[s * 3 + 2];
    float r = sqrtf(vx * vx + vy * vy + vz * vz);
    float rinv = 1.0f / fmaxf(r, 1e-9f);
    float x = vx * rinv, y = vy * rinv, z = vz * rinv;
    float x2 = x * x, y2 = y * y, z2 = z * z;
    const float s3 = 1.7320508075688772f, s5 = 2.23606797749979f, s15 = 3.872983346207417f;
    const float s70 = 8.366600265340756f, s105 = 10.246950765959598f;
    const float s42 = 6.48074069840786f, s7 = 2.6457513110645907f;
    float Y[16];
    Y[0] = 1.0f;
    Y[1] = s3 * x; Y[2] = s3 * y; Y[3] = s3 * z;
    Y[4] = s15 * x * y; Y[5] = s15 * y * z; Y[6] = 0.5f * s5 * (3.0f * z2 - 1.0f);
    Y[7] = s15 * x * z; Y[8] = 0.5f * s15 * (x2 - y2);
    Y[9]  = 0.25f * s70 * y * (3.0f * x2 - y2);
    Y[10] = s105 * x * y * z;
    Y[11] = 0.25f * s42 * y * (5.0f * z2 - 1.0f);
    Y[12] = 0.5f * s7 * z * (5.0f * z2 - 3.0f);
    Y[13] = 0.25f * s42 * x * (5.0f * z2 - 1.0f);
    Y[14] = 0.5f * s105 * z * (x2 - y2);
    Y[15] = 0.25f * s70 * x * (x2 - 3.0f * y2);
    float C = (r < RMAX) ? 0.5f * (cosf(PI_F * r / RMAX) + 1.0f) : 0.0f;
    rcC[ei] = make_float2(r, C);
    #pragma unroll
    for (int c = 0; c < 16; c++) Yp[(size_t)ei * 16 + c] = Y[c];
}

// ---------------------------------------------------------------------------
// ev0[n] = sum_{ei in CSR(n)} Yp[ei]*C[ei] * INV_AVG
// ---------------------------------------------------------------------------
__global__ void ev0_kernel(const int* __restrict__ off,
                           const float* __restrict__ Yp, const float2* __restrict__ rcC,
                           float* __restrict__ ev, int N)
{
    int n = blockIdx.x * 16 + (threadIdx.x >> 4);
    int c = threadIdx.x & 15;
    if (n >= N) return;
    float acc = 0.0f;
    int e0 = off[n], e1 = off[n + 1];
    for (int ei = e0; ei < e1; ei++)
        acc += Yp[(size_t)ei * 16 + c] * rcC[ei].y;
    ev[n * 16 + c] = acc * INV_AVG;
}

// ---------------------------------------------------------------------------
// f = embed[species]
// ---------------------------------------------------------------------------
__global__ void embed_kernel(const int* __restrict__ species,
                             const float* __restrict__ embed,
                             float* __restrict__ f, int N)
{
    int n = blockIdx.x;
    if (n >= N) return;
    int j = threadIdx.x;
    f[n * F + j] = embed[species[n] * F + j];
}

// ---------------------------------------------------------------------------
// Pack 18 128x128 fp32 weight matrices into MFMA B-operand bf16 layout.
// ---------------------------------------------------------------------------
__global__ void pack_w_kernel(const float* __restrict__ Wq, const float* __restrict__ Wk,
                              const float* __restrict__ Wv, const float* __restrict__ Wo,
                              const float* __restrict__ Wq2, const float* __restrict__ Wk2,
                              unsigned int* __restrict__ Wpk)
{
    int tid = blockIdx.x * blockDim.x + threadIdx.x;
    if (tid >= 18 * 8192) return;
    int mat = tid >> 13;
    int rem = tid & 8191;
    int iw = rem & 3;
    int n = (rem >> 2) & 15;
    int quad = (rem >> 6) & 3;
    int kb = (rem >> 8) & 3;
    int ct = rem >> 10;
    const float* fam = (mat < 3) ? Wq : (mat < 6) ? Wk : (mat < 9) ? Wv
                     : (mat < 12) ? Wo : (mat < 15) ? Wq2 : Wk2;
    const float* src = fam + (size_t)(mat % 3) * F * F;
    int k = kb * 32 + quad * 8 + iw * 2;
    int col = ct * 16 + n;
    Wpk[tid] = pk_bf2(src[k * F + col], src[(k + 1) * F + col]);
}

// Pack the 7 exchange/readout 128x128 submatrices in one dispatch
__global__ void pack_ex_kernel(const float* __restrict__ Wex1, const float* __restrict__ Wex2,
                               const float* __restrict__ Wo1, unsigned int* __restrict__ Wpk2)
{
    int tid = blockIdx.x * blockDim.x + threadIdx.x;
    if (tid >= 7 * 8192) return;
    int mat = tid >> 13;
    int rem = tid & 8191;
    int iw = rem & 3;
    int n = (rem >> 2) & 15;
    int quad = (rem >> 6) & 3;
    int kb = (rem >> 8) & 3;
    int ct = rem >> 10;
    const float* src; int stride;
    if (mat < 3)      { src = Wex1 + (size_t)mat * (F + 4) * F; stride = F; }
    else if (mat < 6) { src = Wex2 + (size_t)(mat - 3) * F * (F + 4); stride = F + 4; }
    else              { src = Wo1; stride = F; }
    int k = kb * 32 + quad * 8 + iw * 2;
    int col = ct * 16 + n;
    Wpk2[tid] = pk_bf2(src[(size_t)k * stride + col], src[(size_t)(k + 1) * stride + col]);
}

// ---------------------------------------------------------------------------
// Build paired bf16 w(r) table directly (entry i holds w_i and w_{i+1})
// ---------------------------------------------------------------------------
__global__ __launch_bounds__(256) void build_table_kernel(
    const float* __restrict__ Wrbf1_all, const float* __restrict__ brbf1_all,
    const float* __restrict__ Wrbf2_all, unsigned int* __restrict__ tab2w)
{
    int wave = threadIdx.x >> 6;
    int lane = threadIdx.x & 63;
    int idx = blockIdx.x * 4 + wave;
    int t = blockIdx.y;
    const float* W1 = Wrbf1_all + (size_t)t * KRBF * F;
    const float* b1 = brbf1_all + (size_t)t * F;
    const float* W2 = Wrbf2_all + (size_t)t * F * F;
    float r = idx * (RMAX / (TAB_N - 1));
    __shared__ float sR[4][KRBF];
    __shared__ float sH[4][F];
    if (lane < KRBF) {
        float mu = lane * (RMAX / (KRBF - 1));
        float d = r - mu;
        sR[wave][lane] = expf(-GAMMA * d * d);
    }
    __syncthreads();
    float h0 = b1[lane], h1 = b1[lane + 64];
    #pragma unroll
    for (int kk = 0; kk < KRBF; kk++) {
        float rv = sR[wave][kk];
        h0 += rv * W1[kk * F + lane];
        h1 += rv * W1[kk * F + lane + 64];
    }
    sH[wave][lane] = silu_f(h0);
    sH[wave][lane + 64] = silu_f(h1);
    __syncthreads();
    float w0 = 0.0f, w1 = 0.0f;
    for (int i = 0; i < F; i++) {
        float hv = sH[wave][i];
        w0 += hv * W2[i * F + 2 * lane];
        w1 += hv * W2[i * F + 2 * lane + 1];
    }
    unsigned int w = pk_bf2(w0, w1);
    size_t base = ((size_t)t * TAB_N + idx) * 64 + lane;   // uint2 index
    tab2w[base * 2] = w;                                    // entry idx, .x
    if (idx > 0) tab2w[(base - 64) * 2 + 1] = w;            // entry idx-1, .y
    if (idx == TAB_N - 1) tab2w[base * 2 + 1] = w;          // last .y (unused, init)
}

// ---------------------------------------------------------------------------
// dd_list[ei] = deg_reduce(ev[sp[ei]] * ev[rcvp[ei]])  (CSR order, float4)
// ---------------------------------------------------------------------------
__global__ void dd_kernel(const int* __restrict__ sp, const int* __restrict__ rcvp,
                          const float* __restrict__ ev, float4* __restrict__ ddl, int E)
{
    int ei = blockIdx.x * blockDim.x + threadIdx.x;
    if (ei >= E) return;
    int s = sp[ei], rc = rcvp[ei];
    const float4* a = (const float4*)(ev + (size_t)s * 16);
    const float4* b = (const float4*)(ev + (size_t)rc * 16);
    float4 a0 = a[0], a1 = a[1], a2 = a[2], a3 = a[3];
    float4 b0 = b[0], b1 = b[1], b2 = b[2], b3 = b[3];
    float d0 = a0.x * b0.x;
    float d1 = a0.y * b0.y + a0.z * b0.z + a0.w * b0.w;
    float d2 = a1.x * b1.x + a1.y * b1.y + a1.z * b1.z + a1.w * b1.w + a2.x * b2.x;
    float d3 = a2.y * b2.y + a2.z * b2.z + a2.w * b2.w
             + a3.x * b3.x + a3.y * b3.y + a3.z * b3.z + a3.w * b3.w;
    ddl[ei] = make_float4(d0, d1, d2, d3);
}

// ---------------------------------------------------------------------------
// MFMA node GEMM: out[m] = A @ W[m]. 64 nodes/block, 4 waves, 16x16x32 bf16.
// (used for the qkv pass; ileave=1 writes k/v interleaved into out1)
// ---------------------------------------------------------------------------
__global__ __launch_bounds__(256) void node_gemm_mfma_kernel(
    const float* __restrict__ A,
    const unsigned int* __restrict__ B0, const unsigned int* __restrict__ B1,
    const unsigned int* __restrict__ B2,
    float* __restrict__ out0, unsigned int* __restrict__ out1, unsigned int* __restrict__ out2,
    int N, int nw, int accumulate, int ileave)
{
    __shared__ unsigned int sA[64 * APITCH];
    int tid = threadIdx.x;
    int n0 = blockIdx.x * 64;
    #pragma unroll
    for (int rep = 0; rep < 16; rep++) {
        int idx = rep * 256 + tid;
        int node = idx >> 6, jj = idx & 63;
        int n = n0 + node;
        float2 v = (n < N) ? ((const float2*)A)[(size_t)n * 64 + jj] : make_float2(0.f, 0.f);
        sA[node * APITCH + jj] = pk_bf2(v.x, v.y);
    }
    __syncthreads();
    int wave = tid >> 6, lane = tid & 63;
    int quad = lane >> 4, col = lane & 15;
    int mrow = wave * 16 + col;
    s16x8 af[4];
    #pragma unroll
    for (int kb = 0; kb < 4; kb++) {
        FragU fu;
        fu.u = *(const uint4*)&sA[mrow * APITCH + kb * 16 + quad * 4];
        af[kb] = fu.s;
    }
    for (int m = 0; m < nw; m++) {
        const unsigned int* B = (m == 0) ? B0 : (m == 1) ? B1 : B2;
        for (int ct = 0; ct < 8; ct++) {
            f32x4 acc = {0.f, 0.f, 0.f, 0.f};
            #pragma unroll
            for (int kb = 0; kb < 4; kb++) {
                FragU bu;
                bu.u = *(const uint4*)&B[(size_t)((ct * 16 + kb * 4 + quad) * 16 + col) * 4];
                acc = __builtin_amdgcn_mfma_f32_16x16x32_bf16(af[kb], bu.s, acc, 0, 0, 0);
            }
            if (m == 0) {
                #pragma unroll
                for (int r = 0; r < 4; r++) {
                    int n = n0 + wave * 16 + quad * 4 + r;
                    if (n < N) {
                        size_t ix = (size_t)n * F + ct * 16 + col;
                        out0[ix] = accumulate ? out0[ix] + acc[r] : acc[r];
                    }
                }
            } else {
                unsigned int* o16 = (m == 1) ? out1 : out2;
                #pragma unroll
                for (int r = 0; r < 4; r++) {
                    float other = __shfl_xor(acc[r], 1, 64);
                    if (!(lane & 1)) {
                        int n = n0 + wave * 16 + quad * 4 + r;
                        if (n < N) {
                            size_t base = (size_t)n * 64 + ct * 8 + (col >> 1);
                            if (ileave)
                                out1[base * 2 + (m - 1)] = pk_bf2(acc[r], other);
                            else
                                o16[base] = pk_bf2(acc[r], other);
                        }
                    }
                }
            }
        }
    }
}

// ---------------------------------------------------------------------------
// Fused: f += agg@Wo ; then q = f@Wq2 (fp32), k2 = f@Wk2 (bf16 packed).
// f_new never round-trips through global between the GEMMs (LDS repack).
// ---------------------------------------------------------------------------
__global__ __launch_bounds__(256) void fused_o_qk_kernel(
    const float* __restrict__ agg,
    const unsigned int* __restrict__ Bo, const unsigned int* __restrict__ Bq2,
    const unsigned int* __restrict__ Bk2,
    float* __restrict__ f, float* __restrict__ qout, unsigned int* __restrict__ k16p,
    int N)
{
    __shared__ unsigned int sA[64 * APITCH];
    int tid = threadIdx.x;
    int n0 = blockIdx.x * 64;
    #pragma unroll
    for (int rep = 0; rep < 16; rep++) {
        int idx = rep * 256 + tid;
        int node = idx >> 6, jj = idx & 63;
        int n = n0 + node;
        float2 v = (n < N) ? ((const float2*)agg)[(size_t)n * 64 + jj] : make_float2(0.f, 0.f);
        sA[node * APITCH + jj] = pk_bf2(v.x, v.y);
    }
    __syncthreads();
    int wave = tid >> 6, lane = tid & 63;
    int quad = lane >> 4, col = lane & 15;
    int mrow = wave * 16 + col;
    s16x8 af[4];
    #pragma unroll
    for (int kb = 0; kb < 4; kb++) {
        FragU fu;
        fu.u = *(const uint4*)&sA[mrow * APITCH + kb * 16 + quad * 4];
        af[kb] = fu.s;
    }
    __syncthreads();   // all frags read before sA is overwritten below
    // GEMM1: f_new = f + agg@Wo -> write f (fp32) + pack f_new into sA (bf16)
    for (int ct = 0; ct < 8; ct++) {
        f32x4 acc = {0.f, 0.f, 0.f, 0.f};
        #pragma unroll
        for (int kb = 0; kb < 4; kb++) {
            FragU bu;
            bu.u = *(const uint4*)&Bo[(size_t)((ct * 16 + kb * 4 + quad) * 16 + col) * 4];
            acc = __builtin_amdgcn_mfma_f32_16x16x32_bf16(af[kb], bu.s, acc, 0, 0, 0);
        }
        #pragma unroll
        for (int r = 0; r < 4; r++) {
            int node = wave * 16 + quad * 4 + r;
            int n = n0 + node;
            float fx = 0.0f;
            if (n < N) {
                size_t ix = (size_t)n * F + ct * 16 + col;
                fx = f[ix] + acc[r];
                f[ix] = fx;
            }
            float other = __shfl_xor(fx, 1, 64);
            if (!(lane & 1)) sA[node * APITCH + ct * 8 + (col >> 1)] = pk_bf2(fx, other);
        }
    }
    __syncthreads();
    s16x8 a2[4];
    #pragma unroll
    for (int kb = 0; kb < 4; kb++) {
        FragU fu;
        fu.u = *(const uint4*)&sA[mrow * APITCH + kb * 16 + quad * 4];
        a2[kb] = fu.s;
    }
    // GEMM2a: q = f_new @ Wq2 (fp32)
    for (int ct = 0; ct < 8; ct++) {
        f32x4 acc = {0.f, 0.f, 0.f, 0.f};
        #pragma unroll
        for (int kb = 0; kb < 4; kb++) {
            FragU bu;
            bu.u = *(const uint4*)&Bq2[(size_t)((ct * 16 + kb * 4 + quad) * 16 + col) * 4];
            acc = __builtin_amdgcn_mfma_f32_16x16x32_bf16(a2[kb], bu.s, acc, 0, 0, 0);
        }
        #pragma unroll
        for (int r = 0; r < 4; r++) {
            int n = n0 + wave * 16 + quad * 4 + r;
            if (n < N) qout[(size_t)n * F + ct * 16 + col] = acc[r];
        }
    }
    // GEMM2b: k2 = f_new @ Wk2 (bf16 packed)
    for (int ct = 0; ct < 8; ct++) {
        f32x4 acc = {0.f, 0.f, 0.f, 0.f};
        #pragma unroll
        for (int kb = 0; kb < 4; kb++) {
            FragU bu;
            bu.u = *(const uint4*)&Bk2[(size_t)((ct * 16 + kb * 4 + quad) * 16 + col) * 4];
            acc = __builtin_amdgcn_mfma_f32_16x16x32_bf16(a2[kb], bu.s, acc, 0, 0, 0);
        }
        #pragma unroll
        for (int r = 0; r < 4; r++) {
            float other = __shfl_xor(acc[r], 1, 64);
            if (!(lane & 1)) {
                int n = n0 + wave * 16 + quad * 4 + r;
                if (n < N) k16p[(size_t)n * 64 + ct * 8 + (col >> 1)] = pk_bf2(acc[r], other);
            }
        }
    }
}

// ---------------------------------------------------------------------------
// Per-edge alpha (q pre-scaled). Table row base scalarized; DPP reduce.
// ---------------------------------------------------------------------------
__device__ __forceinline__ float edge_alpha(
    int lane, f32x2 qq, f32x2 wd0, f32x2 wd1, f32x2 wd2, f32x2 wd3,
    const uint2* __restrict__ tab2, float rr, float4 dd, unsigned int ku)
{
    float u = rr * ((float)(TAB_N - 1) / RMAX);
    int i0 = (int)u;
    i0 = (i0 > TAB_N - 2) ? (TAB_N - 2) : i0;
    float fr = u - (float)i0;
    int i0s = __builtin_amdgcn_readfirstlane(i0);
    uint2 tp = (tab2 + (size_t)i0s * 64)[lane];
    f32x2 a = up2(tp.x), b = up2(tp.y);
    f32x2 fr2 = {fr, fr};
    f32x2 w = a + fr2 * (b - a);
    f32x2 d0 = {dd.x, dd.x}, d1 = {dd.y, dd.y}, d2 = {dd.z, dd.z}, d3 = {dd.w, dd.w};
    w = w + d0 * wd0 + d1 * wd1 + d2 * wd2 + d3 * wd3;
    f32x2 p2 = qq * w * up2(ku);
    return red16_dpp(p2.x + p2.y);
}

// ---------------------------------------------------------------------------
// Node-centric fused edge pass (one wave/node; scalarized edge stream).
// ---------------------------------------------------------------------------
__global__ __launch_bounds__(256) void edge_pass_node_kernel(
    const int* __restrict__ off, const int* __restrict__ sp,
    const float2* __restrict__ rcC, const float4* __restrict__ ddl,
    const float* __restrict__ Yp,
    const float* __restrict__ qbuf,
    const uint2* __restrict__ kv16, const unsigned int* __restrict__ k16p,
    const uint2* __restrict__ tab2, const float* __restrict__ Wdeg_t,
    float* __restrict__ outbuf, int N, int mode)
{
    int wave = threadIdx.x >> 6;
    int lane = threadIdx.x & 63;
    int n = blockIdx.x * 4 + wave;
    if (n >= N) return;

    const float2* wdp = (const float2*)Wdeg_t;
    float2 w0f = wdp[lane], w1f = wdp[64 + lane], w2f = wdp[128 + lane], w3f = wdp[192 + lane];
    f32x2 wd0 = {w0f.x, w0f.y}, wd1 = {w1f.x, w1f.y};
    f32x2 wd2 = {w2f.x, w2f.y}, wd3 = {w3f.x, w3f.y};

    int e0 = __builtin_amdgcn_readfirstlane(off[n]);
    int e1 = __builtin_amdgcn_readfirstlane(off[n + 1]);
    float2 qf = ((const float2*)qbuf)[(size_t)n * 64 + lane];
    const float QS = RSQRT_DH * INV_AVG;
    f32x2 qq = {qf.x * QS, qf.y * QS};
    f32x2 acc2 = {0.f, 0.f};
    float devacc = 0.0f;

    int ei = e0;
    if (mode == 0) {
        for (; ei + 3 < e1; ei += 4) {
            int sA = sp[ei], sB = sp[ei + 1], sC = sp[ei + 2], sD = sp[ei + 3];
            float2 rcA = rcC[ei], rcB = rcC[ei + 1], rcCc = rcC[ei + 2], rcD = rcC[ei + 3];
            float4 ddA = ddl[ei], ddB = ddl[ei + 1], ddC = ddl[ei + 2], ddD = ddl[ei + 3];
            uint2 kvA = kv16[(size_t)sA * 64 + lane];
            uint2 kvB = kv16[(size_t)sB * 64 + lane];
            uint2 kvC = kv16[(size_t)sC * 64 + lane];
            uint2 kvD = kv16[(size_t)sD * 64 + lane];
            float alA = rcA.y * edge_alpha(lane, qq, wd0, wd1, wd2, wd3, tab2, rcA.x, ddA, kvA.x);
            float alB = rcB.y * edge_alpha(lane, qq, wd0, wd1, wd2, wd3, tab2, rcB.x, ddB, kvB.x);
            float alC = rcCc.y * edge_alpha(lane, qq, wd0, wd1, wd2, wd3, tab2, rcCc.x, ddC, kvC.x);
            float alD = rcD.y * edge_alpha(lane, qq, wd0, wd1, wd2, wd3, tab2, rcD.x, ddD, kvD.x);
            f32x2 vA = {alA, alA}, vB = {alB, alB}, vC = {alC, alC}, vD = {alD, alD};
            acc2 = acc2 + vA * up2(kvA.y) + vB * up2(kvB.y)
                        + vC * up2(kvC.y) + vD * up2(kvD.y);
        }
        for (; ei < e1; ei++) {
            int sA = sp[ei];
            float2 rcA = rcC[ei];
            uint2 kvA = kv16[(size_t)sA * 64 + lane];
            float alA = rcA.y * edge_alpha(lane, qq, wd0, wd1, wd2, wd3, tab2, rcA.x, ddl[ei], kvA.x);
            f32x2 vA = {alA, alA};
            acc2 = acc2 + vA * up2(kvA.y);
        }
        ((float2*)outbuf)[(size_t)n * 64 + lane] = make_float2(acc2.x, acc2.y);
    } else {
        int c = lane & 15;
        int g = lane >> 4;
        int ssel = ((c == 0) ? 0 : (c < 4) ? 16 : (c < 9) ? 32 : 48) + c;
        for (; ei + 3 < e1; ei += 4) {
            int sA = sp[ei], sB = sp[ei + 1], sC = sp[ei + 2], sD = sp[ei + 3];
            float2 rcA = rcC[ei], rcB = rcC[ei + 1], rcCc = rcC[ei + 2], rcD = rcC[ei + 3];
            float4 ddA = ddl[ei], ddB = ddl[ei + 1], ddC = ddl[ei + 2], ddD = ddl[ei + 3];
            unsigned int kA = k16p[(size_t)sA * 64 + lane];
            unsigned int kB = k16p[(size_t)sB * 64 + lane];
            unsigned int kC = k16p[(size_t)sC * 64 + lane];
            unsigned int kD = k16p[(size_t)sD * 64 + lane];
            float alA = rcA.y * edge_alpha(lane, qq, wd0, wd1, wd2, wd3, tab2, rcA.x, ddA, kA);
            float alB = rcB.y * edge_alpha(lane, qq, wd0, wd1, wd2, wd3, tab2, rcB.x, ddB, kB);
            float alC = rcCc.y * edge_alpha(lane, qq, wd0, wd1, wd2, wd3, tab2, rcCc.x, ddC, kC);
            float alD = rcD.y * edge_alpha(lane, qq, wd0, wd1, wd2, wd3, tab2, rcD.x, ddD, kD);
            float adA = __shfl(alA, ssel);
            float adB = __shfl(alB, ssel);
            float adC = __shfl(alC, ssel);
            float adD = __shfl(alD, ssel);
            float ad = (g == 0) ? adA : (g == 1) ? adB : (g == 2) ? adC : adD;
            devacc += ad * Yp[(size_t)(ei + g) * 16 + c];
        }
        for (; ei < e1; ei++) {
            int sA = sp[ei];
            float2 rcA = rcC[ei];
            unsigned int kA = k16p[(size_t)sA * 64 + lane];
            float alA = rcA.y * edge_alpha(lane, qq, wd0, wd1, wd2, wd3, tab2, rcA.x, ddl[ei], kA);
            float adA = __shfl(alA, ssel);
            if (g == 0) devacc += adA * Yp[(size_t)ei * 16 + c];
        }
        devacc += __shfl_xor(devacc, 16, 64);
        devacc += __shfl_xor(devacc, 32, 64);
        if (lane < 16) outbuf[n * 16 + lane] = devacc;
    }
}

// ---------------------------------------------------------------------------
// MFMA exchange block: 64 nodes/block, 4 waves.
// ---------------------------------------------------------------------------
__global__ __launch_bounds__(256) void exchange_mfma_kernel(
    float* __restrict__ f, float* __restrict__ ev, const float* __restrict__ dEv,
    const unsigned int* __restrict__ B1, const float* __restrict__ Wex1,
    const float* __restrict__ bex1,
    const unsigned int* __restrict__ B2, const float* __restrict__ Wex2,
    const float* __restrict__ bex2, int N)
{
    __shared__ unsigned int sA[64 * APITCH];  // f bf16, later hid bf16
    __shared__ float sev[64][17];
    __shared__ float sEvInv[64][4];
    __shared__ float sW1x[4][F];              // Wex1 rows 128..131
    __shared__ float sW2x[F][4];              // Wex2 cols 128..131
    __shared__ float sB1[F];
    __shared__ float sB2[F];
    __shared__ float sb2x[4];
    __shared__ float syb[64][4];

    int tid = threadIdx.x;
    int n0 = blockIdx.x * 64;
    #pragma unroll
    for (int rep = 0; rep < 16; rep++) {
        int idx = rep * 256 + tid;
        int node = idx >> 6, jj = idx & 63;
        int n = n0 + node;
        float2 v = (n < N) ? ((const float2*)f)[(size_t)n * 64 + jj] : make_float2(0.f, 0.f);
        sA[node * APITCH + jj] = pk_bf2(v.x, v.y);
    }
    for (int idx = tid; idx < 64 * 16; idx += 256) {
        int node = idx >> 4, c = idx & 15;
        int n = n0 + node;
        sev[node][c] = (n < N) ? (ev[(size_t)n * 16 + c] + dEv[(size_t)n * 16 + c]) : 0.0f;
    }
    for (int idx = tid; idx < 4 * F; idx += 256)
        sW1x[idx >> 7][idx & 127] = Wex1[(size_t)(128 + (idx >> 7)) * F + (idx & 127)];
    for (int idx = tid; idx < F * 4; idx += 256)
        sW2x[idx >> 2][idx & 3] = Wex2[(size_t)(idx >> 2) * (F + 4) + 128 + (idx & 3)];
    if (tid < F) sB1[tid] = bex1[tid];
    else sB2[tid - F] = bex2[tid - F];
    if (tid < 4) sb2x[tid] = bex2[F + tid];
    __syncthreads();
    {
        int node = tid >> 2, d = tid & 3;
        int c0 = (d == 0) ? 0 : (d == 1) ? 1 : (d == 2) ? 4 : 9;
        int c1 = (d == 0) ? 1 : (d == 1) ? 4 : (d == 2) ? 9 : 16;
        float a = 0.0f;
        for (int c = c0; c < c1; c++) { float v = sev[node][c]; a += v * v; }
        sEvInv[node][d] = a;
    }
    int wave = tid >> 6, lane = tid & 63;
    int quad = lane >> 4, col = lane & 15;
    int mrow = wave * 16 + col;
    s16x8 af[4];
    #pragma unroll
    for (int kb = 0; kb < 4; kb++) {
        FragU fu;
        fu.u = *(const uint4*)&sA[mrow * APITCH + kb * 16 + quad * 4];
        af[kb] = fu.s;
    }
    __syncthreads();
    float evq[4][4];
    #pragma unroll
    for (int r = 0; r < 4; r++) {
        int node = wave * 16 + quad * 4 + r;
        #pragma unroll
        for (int d = 0; d < 4; d++) evq[r][d] = sEvInv[node][d];
    }
    // GEMM1: hid = silu(f@Wex1[:128] + ev_inv@Wex1[128:] + b1) -> sA (bf16)
    for (int ct = 0; ct < 8; ct++) {
        f32x4 acc = {0.f, 0.f, 0.f, 0.f};
        #pragma unroll
        for (int kb = 0; kb < 4; kb++) {
            FragU bu;
            bu.u = *(const uint4*)&B1[(size_t)((ct * 16 + kb * 4 + quad) * 16 + col) * 4];
            acc = __builtin_amdgcn_mfma_f32_16x16x32_bf16(af[kb], bu.s, acc, 0, 0, 0);
        }
        int j = ct * 16 + col;
        float w0 = sW1x[0][j], w1 = sW1x[1][j], w2 = sW1x[2][j], w3 = sW1x[3][j];
        float bj = sB1[j];
        #pragma unroll
        for (int r = 0; r < 4; r++) {
            float x = acc[r] + bj + evq[r][0] * w0 + evq[r][1] * w1
                    + evq[r][2] * w2 + evq[r][3] * w3;
            float h = silu_f(x);
            float other = __shfl_xor(h, 1, 64);
            if (!(lane & 1)) {
                int node = wave * 16 + quad * 4 + r;
                sA[node * APITCH + ct * 8 + (col >> 1)] = pk_bf2(h, other);
            }
        }
    }
    __syncthreads();
    s16x8 a2[4];
    #pragma unroll
    for (int kb = 0; kb < 4; kb++) {
        FragU fu;
        fu.u = *(const uint4*)&sA[mrow * APITCH + kb * 16 + quad * 4];
        a2[kb] = fu.s;
    }
    // yb2 (cols 128..131) per (node, d) thread
    {
        int node = tid >> 2, d = tid & 3;
        float a = sb2x[d];
        for (int dw = 0; dw < 64; dw++) {
            unsigned int u = sA[node * APITCH + dw];
            a += up_lo(u) * sW2x[2 * dw][d] + up_hi(u) * sW2x[2 * dw + 1][d];
        }
        syb[node][d] = a;
    }
    // GEMM2 cols 0..127: f += hid@Wex2[:, :128] + b2
    for (int ct = 0; ct < 8; ct++) {
        f32x4 acc = {0.f, 0.f, 0.f, 0.f};
        #pragma unroll
        for (int kb = 0; kb < 4; kb++) {
            FragU bu;
            bu.u = *(const uint4*)&B2[(size_t)((ct * 16 + kb * 4 + quad) * 16 + col) * 4];
            acc = __builtin_amdgcn_mfma_f32_16x16x32_bf16(a2[kb], bu.s, acc, 0, 0, 0);
        }
        int j = ct * 16 + col;
        float bj = sB2[j];
        #pragma unroll
        for (int r = 0; r < 4; r++) {
            int n = n0 + wave * 16 + quad * 4 + r;
            if (n < N) {
                size_t ix = (size_t)n * F + j;
                f[ix] = f[ix] + acc[r] + bj;
            }
        }
    }
    __syncthreads();
    for (int idx = tid; idx < 64 * 16; idx += 256) {
        int node = idx >> 4, c = idx & 15;
        int n = n0 + node;
        if (n < N) ev[(size_t)n * 16 + c] = sev[node][c] * (1.0f + syb[node][deg_of(c)]);
    }
}

// ---------------------------------------------------------------------------
// MFMA readout: node_e[n] = silu(f@Wo1+bo1) . Wo2 + bo2  (64 nodes/block)
// ---------------------------------------------------------------------------
__global__ __launch_bounds__(256) void readout_mfma_kernel(
    const float* __restrict__ f, const unsigned int* __restrict__ B,
    const float* __restrict__ bo1, const float* __restrict__ Wo2,
    const float* __restrict__ bo2, float* __restrict__ node_e, int N)
{
    __shared__ unsigned int sA[64 * APITCH];
    __shared__ float sB1[F];
    __shared__ float sW2[F];
    int tid = threadIdx.x;
    int n0 = blockIdx.x * 64;
    #pragma unroll
    for (int rep = 0; rep < 16; rep++) {
        int idx = rep * 256 + tid;
        int node = idx >> 6, jj = idx & 63;
        int n = n0 + node;
        float2 v = (n < N) ? ((const float2*)f)[(size_t)n * 64 + jj] : make_float2(0.f, 0.f);
        sA[node * APITCH + jj] = pk_bf2(v.x, v.y);
    }
    if (tid < F) sB1[tid] = bo1[tid];
    else sW2[tid - F] = Wo2[tid - F];
    __syncthreads();
    int wave = tid >> 6, lane = tid & 63;
    int quad = lane >> 4, col = lane & 15;
    int mrow = wave * 16 + col;
    s16x8 af[4];
    #pragma unroll
    for (int kb = 0; kb < 4; kb++) {
        FragU fu;
        fu.u = *(const uint4*)&sA[mrow * APITCH + kb * 16 + quad * 4];
        af[kb] = fu.s;
    }
    float part[4] = {0.f, 0.f, 0.f, 0.f};
    for (int ct = 0; ct < 8; ct++) {
        f32x4 acc = {0.f, 0.f, 0.f, 0.f};
        #pragma unroll
        for (int kb = 0; kb < 4; kb++) {
            FragU bu;
            bu.u = *(const uint4*)&B[(size_t)((ct * 16 + kb * 4 + quad) * 16 + col) * 4];
            acc = __builtin_amdgcn_mfma_f32_16x16x32_bf16(af[kb], bu.s, acc, 0, 0, 0);
        }
        int j = ct * 16 + col;
        float bj = sB1[j], wj = sW2[j];
        #pragma unroll
        for (int r = 0; r < 4; r++) part[r] += silu_f(acc[r] + bj) * wj;
    }
    #pragma unroll
    for (int r = 0; r < 4; r++) part[r] = red16_dpp(part[r]);
    if (col == 0) {
        #pragma unroll
        for (int r = 0; r < 4; r++) {
            int n = n0 + wave * 16 + quad * 4 + r;
            if (n < N) node_e[n] = part[r] + bo2[0];
        }
    }
}

// ---------------------------------------------------------------------------
// energy[g] = sum_{batch[n]==g} node_e[n]
// ---------------------------------------------------------------------------
__global__ __launch_bounds__(256) void energy_reduce_kernel(
    const float* __restrict__ node_e, const int* __restrict__ batch,
    float* __restrict__ energy, int N)
{
    __shared__ float eacc[64];
    if (threadIdx.x < 64) eacc[threadIdx.x] = 0.0f;
    __syncthreads();
    for (int n = blockIdx.x * blockDim.x + threadIdx.x; n < N; n += gridDim.x * blockDim.x)
        atomicAdd(&eacc[batch[n]], node_e[n]);
    __syncthreads();
    if (threadIdx.x < 64) atomicAdd(&energy[threadIdx.x], eacc[threadIdx.x]);
}

// ---------------------------------------------------------------------------
extern "C" void kernel_launch(void* const* d_in, const int* in_sizes, int n_in,
                              void* d_out, int out_size, void* d_ws, size_t ws_size,
                              hipStream_t stream)
{
    const float* positions = (const float*)d_in[0];
    const int*   species   = (const int*)d_in[1];
    const int*   senders   = (const int*)d_in[2];
    const int*   receivers = (const int*)d_in[3];
    const int*   batch     = (const int*)d_in[4];
    const float* embed     = (const float*)d_in[5];
    const float* Wq    = (const float*)d_in[6];
    const float* Wk    = (const float*)d_in[7];
    const float* Wv    = (const float*)d_in[8];
    const float* Wo    = (const float*)d_in[9];
    const float* Wrbf1 = (const float*)d_in[10];
    const float* brbf1 = (const float*)d_in[11];
    const float* Wrbf2 = (const float*)d_in[12];
    const float* Wdeg  = (const float*)d_in[13];
    const float* Wq2   = (const float*)d_in[14];
    const float* Wk2   = (const float*)d_in[15];
    const float* Wex1  = (const float*)d_in[16];
    const float* bex1  = (const float*)d_in[17];
    const float* Wex2  = (const float*)d_in[18];
    const float* bex2  = (const float*)d_in[19];
    const float* Wo1   = (const float*)d_in[20];
    const float* bo1   = (const float*)d_in[21];
    const float* Wo2   = (const float*)d_in[22];
    const float* bo2   = (const float*)d_in[23];

    int N = in_sizes[0] / 3;
    int E = in_sizes[2];

    // ---- workspace layout (~127 MB) ----
    float* ws     = (float*)d_ws;
    float* Yp     = ws;  ws += (size_t)E * 16;        // CSR-ordered Y
    float2* rcC   = (float2*)ws; ws += (size_t)E * 2; // CSR-ordered (r, C)
    float* f      = ws;  ws += (size_t)N * F;
    float* evb    = ws;  ws += (size_t)N * 16;
    float* dEv    = ws;  ws += (size_t)N * 16;
    float* q      = ws;  ws += (size_t)N * F;
    float* agg    = ws;  ws += (size_t)N * F;
    float* node_e = ws;  ws += (size_t)N;
    // union region (E*18 floats): tab2 / kv16 / k16p / ddl
    float* un     = ws;  ws += (size_t)E * 18;
    uint2* tab2 = (uint2*)un;                                      // 3*TAB_N*64 uint2 (3 MB)
    uint2* kv16 = tab2 + (size_t)TINTER * TAB_N * 64;              // N*64 uint2 (k,v)
    unsigned int* k16p = (unsigned int*)(kv16 + (size_t)N * 64);   // N*64 (k2)
    float4* ddl   = (float4*)(k16p + (size_t)N * 64);              // E
    int* sp    = (int*)ws;  ws += E;
    int* rcvp  = (int*)ws;  ws += E;
    int* cnt   = (int*)ws;  ws += N;
    int* off   = (int*)ws;  ws += N + 1;
    int* cur   = (int*)ws;  ws += N;
    int* elist = (int*)ws;  ws += E;
    int* bsum  = (int*)ws;  ws += 1024;
    int* boff  = (int*)ws;  ws += 1024;
    unsigned int* Wpk  = (unsigned int*)ws;  ws += 18 * 8192;      // qkv/o/q2/k2 packed
    unsigned int* Wpk2 = (unsigned int*)ws;  ws += 7 * 8192;       // ex1[3], ex2[3], wo1

    // ---- CSR build (parallel scan) ----
    int nb = (N + SCB - 1) / SCB;   // <= 1024 for N <= 262144
    hipMemsetAsync(cnt, 0, (size_t)N * sizeof(int), stream);
    count_kernel<<<(E + 255) / 256, 256, 0, stream>>>(receivers, cnt, E);
    scan_part_kernel<<<nb, SCB, 0, stream>>>(cnt, off, bsum, N);
    scan_mid_kernel<<<1, 1024, 0, stream>>>(bsum, boff, off, N, nb);
    scan_add_kernel<<<(N + 255) / 256, 256, 0, stream>>>(off, cur, boff, N);
    scatter_kernel<<<(E + 255) / 256, 256, 0, stream>>>(receivers, cur, elist, E);

    // ---- fused CSR-order geometry + weight packing + table ----
    edge_geom_csr_kernel<<<(E + 255) / 256, 256, 0, stream>>>(elist, positions, senders,
                                                              receivers, sp, rcvp, rcC, Yp, E);
    pack_w_kernel<<<(18 * 8192 + 255) / 256, 256, 0, stream>>>(Wq, Wk, Wv, Wo, Wq2, Wk2, Wpk);
    pack_ex_kernel<<<(7 * 8192 + 255) / 256, 256, 0, stream>>>(Wex1, Wex2, Wo1, Wpk2);
    build_table_kernel<<<dim3(TAB_N / 4, TINTER), 256, 0, stream>>>(Wrbf1, brbf1, Wrbf2,
                                                                    (unsigned int*)tab2);
    ev0_kernel<<<(N + 15) / 16, 256, 0, stream>>>(off, Yp, rcC, evb, N);
    embed_kernel<<<N, F, 0, stream>>>(species, embed, f, N);

    int nmb = (N + 63) / 64;
    int npb = (N + 3) / 4;
    int edb = (E + 255) / 256;
    for (int t = 0; t < TINTER; t++) {
        const unsigned int* Wpk_q  = Wpk + (size_t)(0 * 3 + t) * 8192;
        const unsigned int* Wpk_k  = Wpk + (size_t)(1 * 3 + t) * 8192;
        const unsigned int* Wpk_v  = Wpk + (size_t)(2 * 3 + t) * 8192;
        const unsigned int* Wpk_o  = Wpk + (size_t)(3 * 3 + t) * 8192;
        const unsigned int* Wpk_q2 = Wpk + (size_t)(4 * 3 + t) * 8192;
        const unsigned int* Wpk_k2 = Wpk + (size_t)(5 * 3 + t) * 8192;
        const uint2* tab_t = tab2 + (size_t)t * TAB_N * 64;
        const float* Wdeg_t = Wdeg + (size_t)t * 4 * F;
        node_gemm_mfma_kernel<<<nmb, 256, 0, stream>>>(f, Wpk_q, Wpk_k, Wpk_v,
                                                       q, (unsigned int*)kv16, nullptr,
                                                       N, 3, 0, 1);
        dd_kernel<<<edb, 256, 0, stream>>>(sp, rcvp, evb, ddl, E);
        edge_pass_node_kernel<<<npb, 256, 0, stream>>>(off, sp, rcC, ddl, Yp,
            q, kv16, nullptr, tab_t, Wdeg_t, agg, N, 0);
        fused_o_qk_kernel<<<nmb, 256, 0, stream>>>(agg, Wpk_o, Wpk_q2, Wpk_k2,
                                                   f, q, k16p, N);
        edge_pass_node_kernel<<<npb, 256, 0, stream>>>(off, sp, rcC, ddl, Yp,
            q, nullptr, k16p, tab_t, Wdeg_t, dEv, N, 1);
        exchange_mfma_kernel<<<nmb, 256, 0, stream>>>(f, evb, dEv,
            Wpk2 + (size_t)t * 8192, Wex1 + (size_t)t * (F + 4) * F, bex1 + (size_t)t * F,
            Wpk2 + (size_t)(3 + t) * 8192, Wex2 + (size_t)t * F * (F + 4),
            bex2 + (size_t)t * (F + 4), N);
    }
    readout_mfma_kernel<<<nmb, 256, 0, stream>>>(f, Wpk2 + (size_t)6 * 8192,
                                                 bo1, Wo2, bo2, node_e, N);
    hipMemsetAsync(d_out, 0, (size_t)out_size * sizeof(float), stream);
    energy_reduce_kernel<<<16, 256, 0, stream>>>(node_e, batch, (float*)d_out, N);
}

// Round 13
// 775.145 us; speedup vs baseline: 10.9743x; 1.0280x over previous
//
#include <hip/hip_runtime.h>
#include <math.h>

// ---- static config (matches reference) ----
#define F 128
#define KRBF 32
#define TINTER 3
#define RMAX 5.0f
#define INV_AVG (1.0f/16.0f)
#define GAMMA 40.96f               // (KRBF/RMAX)^2
#define RSQRT_DH 0.17677669529663689f  // 1/sqrt(32)
#define PI_F 3.14159265358979323846f
#define TAB_N 2048                 // w(r) interpolation table entries over [0, RMAX]
#define APITCH 68                  // LDS A-tile pitch in dwords (16B-aligned rows)
#define SCB 256                    // scan block size

__device__ __forceinline__ float silu_f(float x) { return x / (1.0f + expf(-x)); }
__device__ __forceinline__ int deg_of(int c) { return (c == 0) ? 0 : (c < 4) ? 1 : (c < 9) ? 2 : 3; }

// bf16x2 pack/unpack: packed word = (elem0) | (elem1 << 16), RNE rounding
__device__ __forceinline__ unsigned int pk_bf2(float lo, float hi) {
    unsigned int a = __float_as_uint(lo), b = __float_as_uint(hi);
    unsigned int ar = (a + 0x7fffu + ((a >> 16) & 1u)) >> 16;
    unsigned int br = (b + 0x7fffu + ((b >> 16) & 1u)) >> 16;
    return ar | (br << 16);
}
__device__ __forceinline__ float up_lo(unsigned int u) { return __uint_as_float(u << 16); }
__device__ __forceinline__ float up_hi(unsigned int u) { return __uint_as_float(u & 0xffff0000u); }

typedef short s16x8 __attribute__((ext_vector_type(8)));
typedef float f32x4 __attribute__((ext_vector_type(4)));
typedef float f32x2 __attribute__((ext_vector_type(2)));
union FragU { uint4 u; s16x8 s; };

__device__ __forceinline__ f32x2 up2(unsigned int u) {
    f32x2 r; r.x = up_lo(u); r.y = up_hi(u); return r;
}

// 16-lane (head-group) sum via DPP — pure VALU, no LDS-pipe bpermute.
__device__ __forceinline__ float red16_dpp(float p) {
    p += __uint_as_float((unsigned)__builtin_amdgcn_update_dpp(
        0, (int)__float_as_uint(p), 0xB1, 0xF, 0xF, true));   // quad_perm [1,0,3,2]
    p += __uint_as_float((unsigned)__builtin_amdgcn_update_dpp(
        0, (int)__float_as_uint(p), 0x4E, 0xF, 0xF, true));   // quad_perm [2,3,0,1]
    p += __uint_as_float((unsigned)__builtin_amdgcn_update_dpp(
        0, (int)__float_as_uint(p), 0x124, 0xF, 0xF, true));  // row_ror:4
    p += __uint_as_float((unsigned)__builtin_amdgcn_update_dpp(
        0, (int)__float_as_uint(p), 0x128, 0xF, 0xF, true));  // row_ror:8
    return p;
}

// ---------------------------------------------------------------------------
// CSR build: count -> parallel 3-phase scan -> scatter
// ---------------------------------------------------------------------------
__global__ void count_kernel(const int* __restrict__ rcv, int* __restrict__ cnt, int E)
{
    int e = blockIdx.x * blockDim.x + threadIdx.x;
    if (e < E) atomicAdd(&cnt[rcv[e]], 1);
}

__global__ __launch_bounds__(SCB) void scan_part_kernel(const int* __restrict__ cnt,
                                                        int* __restrict__ off,
                                                        int* __restrict__ bsum, int N)
{
    __shared__ int s[SCB];
    int tid = threadIdx.x;
    int i = blockIdx.x * SCB + tid;
    int v = (i < N) ? cnt[i] : 0;
    s[tid] = v;
    __syncthreads();
    for (int st = 1; st < SCB; st <<= 1) {
        int t = (tid >= st) ? s[tid - st] : 0;
        __syncthreads();
        s[tid] += t;
        __syncthreads();
    }
    if (i < N) off[i] = s[tid] - v;
    if (tid == SCB - 1) bsum[blockIdx.x] = s[tid];
}

__global__ __launch_bounds__(1024) void scan_mid_kernel(const int* __restrict__ bsum,
                                                        int* __restrict__ boff,
                                                        int* __restrict__ off, int N, int nb)
{
    __shared__ int s[1024];
    int tid = threadIdx.x;
    int v = (tid < nb) ? bsum[tid] : 0;
    s[tid] = v;
    __syncthreads();
    for (int st = 1; st < 1024; st <<= 1) {
        int t = (tid >= st) ? s[tid - st] : 0;
        __syncthreads();
        s[tid] += t;
        __syncthreads();
    }
    if (tid < nb) boff[tid] = s[tid] - v;
    if (tid == 1023) off[N] = s[1023];
}

__global__ void scan_add_kernel(int* __restrict__ off, int* __restrict__ cur,
                                const int* __restrict__ boff, int N)
{
    int i = blockIdx.x * blockDim.x + threadIdx.x;
    if (i < N) {
        int v = off[i] + boff[i / SCB];
        off[i] = v; cur[i] = v;
    }
}

__global__ void scatter_kernel(const int* __restrict__ rcv, int* __restrict__ cur,
                               int* __restrict__ elist, int E)
{
    int e = blockIdx.x * blockDim.x + threadIdx.x;
    if (e < E) {
        int p = atomicAdd(&cur[rcv[e]], 1);
        elist[p] = e;
    }
}

// ---------------------------------------------------------------------------
// Fused edge geometry in CSR order. edata[ei] = {s, r, C, pad | dd0..3}
// (first 16B written here; dd half written per-t by dd_kernel)
// ---------------------------------------------------------------------------
__global__ void edge_geom_csr_kernel(const int* __restrict__ elist,
                                     const float* __restrict__ pos,
                                     const int* __restrict__ snd,
                                     const int* __restrict__ rcv,
                                     int* __restrict__ sp, int* __restrict__ rcvp,
                                     float* __restrict__ Cb,
                                     float4* __restrict__ edata,
                                     float* __restrict__ Yp, int E)
{
    int ei = blockIdx.x * blockDim.x + threadIdx.x;
    if (ei >= E) return;
    int e = elist[ei];
    int s = snd[e], rc = rcv[e];
    sp[ei] = s; rcvp[ei] = rc;
    float vx = pos[rc * 3 + 0] - pos[s * 3 + 0];
    float vy = pos[rc * 3 + 1] - pos[s * 3 + 1];
    float vz = pos[rc * 3 + 2] - pos[s * 3 + 2];
    float r = sqrtf(vx * vx + vy * vy + vz * vz);
    float rinv = 1.0f / fmaxf(r, 1e-9f);
    float x = vx * rinv, y = vy * rinv, z = vz * rinv;
    float x2 = x * x, y2 = y * y, z2 = z * z;
    const float s3 = 1.7320508075688772f, s5 = 2.23606797749979f, s15 = 3.872983346207417f;
    const float s70 = 8.366600265340756f, s105 = 10.246950765959598f;
    const float s42 = 6.48074069840786f, s7 = 2.6457513110645907f;
    float Y[16];
    Y[0] = 1.0f;
    Y[1] = s3 * x; Y[2] = s3 * y; Y[3] = s3 * z;
    Y[4] = s15 * x * y; Y[5] = s15 * y * z; Y[6] = 0.5f * s5 * (3.0f * z2 - 1.0f);
    Y[7] = s15 * x * z; Y[8] = 0.5f * s15 * (x2 - y2);
    Y[9]  = 0.25f * s70 * y * (3.0f * x2 - y2);
    Y[10] = s105 * x * y * z;
    Y[11] = 0.25f * s42 * y * (5.0f * z2 - 1.0f);
    Y[12] = 0.5f * s7 * z * (5.0f * z2 - 3.0f);
    Y[13] = 0.25f * s42 * x * (5.0f * z2 - 1.0f);
    Y[14] = 0.5f * s105 * z * (x2 - y2);
    Y[15] = 0.25f * s70 * x * (x2 - 3.0f * y2);
    float C = (r < RMAX) ? 0.5f * (cosf(PI_F * r / RMAX) + 1.0f) : 0.0f;
    Cb[ei] = C;
    edata[2 * ei] = make_float4(__int_as_float(s), r, C, 0.0f);
    #pragma unroll
    for (int c = 0; c < 16; c++) Yp[(size_t)ei * 16 + c] = Y[c];
}

// ---------------------------------------------------------------------------
// ev0[n] = sum_{ei in CSR(n)} Yp[ei]*C[ei] * INV_AVG
// ---------------------------------------------------------------------------
__global__ void ev0_kernel(const int* __restrict__ off,
                           const float* __restrict__ Yp, const float* __restrict__ Cb,
                           float* __restrict__ ev, int N)
{
    int n = blockIdx.x * 16 + (threadIdx.x >> 4);
    int c = threadIdx.x & 15;
    if (n >= N) return;
    float acc = 0.0f;
    int e0 = off[n], e1 = off[n + 1];
    for (int ei = e0; ei < e1; ei++)
        acc += Yp[(size_t)ei * 16 + c] * Cb[ei];
    ev[n * 16 + c] = acc * INV_AVG;
}

// ---------------------------------------------------------------------------
// f = embed[species]
// ---------------------------------------------------------------------------
__global__ void embed_kernel(const int* __restrict__ species,
                             const float* __restrict__ embed,
                             float* __restrict__ f, int N)
{
    int n = blockIdx.x;
    if (n >= N) return;
    int j = threadIdx.x;
    f[n * F + j] = embed[species[n] * F + j];
}

// ---------------------------------------------------------------------------
// Pack 18 128x128 fp32 weight matrices into MFMA B-operand bf16 layout.
// ---------------------------------------------------------------------------
__global__ void pack_w_kernel(const float* __restrict__ Wq, const float* __restrict__ Wk,
                              const float* __restrict__ Wv, const float* __restrict__ Wo,
                              const float* __restrict__ Wq2, const float* __restrict__ Wk2,
                              unsigned int* __restrict__ Wpk)
{
    int tid = blockIdx.x * blockDim.x + threadIdx.x;
    if (tid >= 18 * 8192) return;
    int mat = tid >> 13;
    int rem = tid & 8191;
    int iw = rem & 3;
    int n = (rem >> 2) & 15;
    int quad = (rem >> 6) & 3;
    int kb = (rem >> 8) & 3;
    int ct = rem >> 10;
    const float* fam = (mat < 3) ? Wq : (mat < 6) ? Wk : (mat < 9) ? Wv
                     : (mat < 12) ? Wo : (mat < 15) ? Wq2 : Wk2;
    const float* src = fam + (size_t)(mat % 3) * F * F;
    int k = kb * 32 + quad * 8 + iw * 2;
    int col = ct * 16 + n;
    Wpk[tid] = pk_bf2(src[k * F + col], src[(k + 1) * F + col]);
}

// Pack the 7 exchange/readout 128x128 submatrices in one dispatch
__global__ void pack_ex_kernel(const float* __restrict__ Wex1, const float* __restrict__ Wex2,
                               const float* __restrict__ Wo1, unsigned int* __restrict__ Wpk2)
{
    int tid = blockIdx.x * blockDim.x + threadIdx.x;
    if (tid >= 7 * 8192) return;
    int mat = tid >> 13;
    int rem = tid & 8191;
    int iw = rem & 3;
    int n = (rem >> 2) & 15;
    int quad = (rem >> 6) & 3;
    int kb = (rem >> 8) & 3;
    int ct = rem >> 10;
    const float* src; int stride;
    if (mat < 3)      { src = Wex1 + (size_t)mat * (F + 4) * F; stride = F; }
    else if (mat < 6) { src = Wex2 + (size_t)(mat - 3) * F * (F + 4); stride = F + 4; }
    else              { src = Wo1; stride = F; }
    int k = kb * 32 + quad * 8 + iw * 2;
    int col = ct * 16 + n;
    Wpk2[tid] = pk_bf2(src[(size_t)k * stride + col], src[(size_t)(k + 1) * stride + col]);
}

// ---------------------------------------------------------------------------
// Build paired bf16 w(r) table directly (entry i holds w_i and w_{i+1})
// ---------------------------------------------------------------------------
__global__ __launch_bounds__(256) void build_table_kernel(
    const float* __restrict__ Wrbf1_all, const float* __restrict__ brbf1_all,
    const float* __restrict__ Wrbf2_all, unsigned int* __restrict__ tab2w)
{
    int wave = threadIdx.x >> 6;
    int lane = threadIdx.x & 63;
    int idx = blockIdx.x * 4 + wave;
    int t = blockIdx.y;
    const float* W1 = Wrbf1_all + (size_t)t * KRBF * F;
    const float* b1 = brbf1_all + (size_t)t * F;
    const float* W2 = Wrbf2_all + (size_t)t * F * F;
    float r = idx * (RMAX / (TAB_N - 1));
    __shared__ float sR[4][KRBF];
    __shared__ float sH[4][F];
    if (lane < KRBF) {
        float mu = lane * (RMAX / (KRBF - 1));
        float d = r - mu;
        sR[wave][lane] = expf(-GAMMA * d * d);
    }
    __syncthreads();
    float h0 = b1[lane], h1 = b1[lane + 64];
    #pragma unroll
    for (int kk = 0; kk < KRBF; kk++) {
        float rv = sR[wave][kk];
        h0 += rv * W1[kk * F + lane];
        h1 += rv * W1[kk * F + lane + 64];
    }
    sH[wave][lane] = silu_f(h0);
    sH[wave][lane + 64] = silu_f(h1);
    __syncthreads();
    float w0 = 0.0f, w1 = 0.0f;
    for (int i = 0; i < F; i++) {
        float hv = sH[wave][i];
        w0 += hv * W2[i * F + 2 * lane];
        w1 += hv * W2[i * F + 2 * lane + 1];
    }
    unsigned int w = pk_bf2(w0, w1);
    size_t base = ((size_t)t * TAB_N + idx) * 64 + lane;   // uint2 index
    tab2w[base * 2] = w;
    if (idx > 0) tab2w[(base - 64) * 2 + 1] = w;
    if (idx == TAB_N - 1) tab2w[base * 2 + 1] = w;
}

// ---------------------------------------------------------------------------
// edata[ei].dd = deg_reduce(ev[sp[ei]] * ev[rcvp[ei]])  (second 16B half)
// ---------------------------------------------------------------------------
__global__ void dd_kernel(const int* __restrict__ sp, const int* __restrict__ rcvp,
                          const float* __restrict__ ev, float4* __restrict__ edata, int E)
{
    int ei = blockIdx.x * blockDim.x + threadIdx.x;
    if (ei >= E) return;
    int s = sp[ei], rc = rcvp[ei];
    const float4* a = (const float4*)(ev + (size_t)s * 16);
    const float4* b = (const float4*)(ev + (size_t)rc * 16);
    float4 a0 = a[0], a1 = a[1], a2 = a[2], a3 = a[3];
    float4 b0 = b[0], b1 = b[1], b2 = b[2], b3 = b[3];
    float d0 = a0.x * b0.x;
    float d1 = a0.y * b0.y + a0.z * b0.z + a0.w * b0.w;
    float d2 = a1.x * b1.x + a1.y * b1.y + a1.z * b1.z + a1.w * b1.w + a2.x * b2.x;
    float d3 = a2.y * b2.y + a2.z * b2.z + a2.w * b2.w
             + a3.x * b3.x + a3.y * b3.y + a3.z * b3.z + a3.w * b3.w;
    edata[2 * ei + 1] = make_float4(d0, d1, d2, d3);
}

// ---------------------------------------------------------------------------
// MFMA node GEMM (t=0 qkv only): out0 = A@W0 fp32; W1/W2 -> kv interleaved.
// ---------------------------------------------------------------------------
__global__ __launch_bounds__(256) void node_gemm_mfma_kernel(
    const float* __restrict__ A,
    const unsigned int* __restrict__ B0, const unsigned int* __restrict__ B1,
    const unsigned int* __restrict__ B2,
    float* __restrict__ out0, unsigned int* __restrict__ out1,
    int N)
{
    __shared__ unsigned int sA[64 * APITCH];
    int tid = threadIdx.x;
    int n0 = blockIdx.x * 64;
    #pragma unroll
    for (int rep = 0; rep < 16; rep++) {
        int idx = rep * 256 + tid;
        int node = idx >> 6, jj = idx & 63;
        int n = n0 + node;
        float2 v = (n < N) ? ((const float2*)A)[(size_t)n * 64 + jj] : make_float2(0.f, 0.f);
        sA[node * APITCH + jj] = pk_bf2(v.x, v.y);
    }
    __syncthreads();
    int wave = tid >> 6, lane = tid & 63;
    int quad = lane >> 4, col = lane & 15;
    int mrow = wave * 16 + col;
    s16x8 af[4];
    #pragma unroll
    for (int kb = 0; kb < 4; kb++) {
        FragU fu;
        fu.u = *(const uint4*)&sA[mrow * APITCH + kb * 16 + quad * 4];
        af[kb] = fu.s;
    }
    for (int m = 0; m < 3; m++) {
        const unsigned int* B = (m == 0) ? B0 : (m == 1) ? B1 : B2;
        for (int ct = 0; ct < 8; ct++) {
            f32x4 acc = {0.f, 0.f, 0.f, 0.f};
            #pragma unroll
            for (int kb = 0; kb < 4; kb++) {
                FragU bu;
                bu.u = *(const uint4*)&B[(size_t)((ct * 16 + kb * 4 + quad) * 16 + col) * 4];
                acc = __builtin_amdgcn_mfma_f32_16x16x32_bf16(af[kb], bu.s, acc, 0, 0, 0);
            }
            if (m == 0) {
                #pragma unroll
                for (int r = 0; r < 4; r++) {
                    int n = n0 + wave * 16 + quad * 4 + r;
                    if (n < N) out0[(size_t)n * F + ct * 16 + col] = acc[r];
                }
            } else {
                #pragma unroll
                for (int r = 0; r < 4; r++) {
                    float other = __shfl_xor(acc[r], 1, 64);
                    if (!(lane & 1)) {
                        int n = n0 + wave * 16 + quad * 4 + r;
                        if (n < N) {
                            size_t base = (size_t)n * 64 + ct * 8 + (col >> 1);
                            out1[base * 2 + (m - 1)] = pk_bf2(acc[r], other);
                        }
                    }
                }
            }
        }
    }
}

// ---------------------------------------------------------------------------
// Fused: f += agg@Wo ; then q = f@Wq2 (fp32), k2 = f@Wk2 (bf16 packed).
// agg may alias qout (input tile fully staged to LDS before any write).
// ---------------------------------------------------------------------------
__global__ __launch_bounds__(256) void fused_o_qk_kernel(
    const float* __restrict__ agg,
    const unsigned int* __restrict__ Bo, const unsigned int* __restrict__ Bq2,
    const unsigned int* __restrict__ Bk2,
    float* __restrict__ f, float* __restrict__ qout, unsigned int* __restrict__ k16p,
    int N)
{
    __shared__ unsigned int sA[64 * APITCH];
    int tid = threadIdx.x;
    int n0 = blockIdx.x * 64;
    #pragma unroll
    for (int rep = 0; rep < 16; rep++) {
        int idx = rep * 256 + tid;
        int node = idx >> 6, jj = idx & 63;
        int n = n0 + node;
        float2 v = (n < N) ? ((const float2*)agg)[(size_t)n * 64 + jj] : make_float2(0.f, 0.f);
        sA[node * APITCH + jj] = pk_bf2(v.x, v.y);
    }
    __syncthreads();
    int wave = tid >> 6, lane = tid & 63;
    int quad = lane >> 4, col = lane & 15;
    int mrow = wave * 16 + col;
    s16x8 af[4];
    #pragma unroll
    for (int kb = 0; kb < 4; kb++) {
        FragU fu;
        fu.u = *(const uint4*)&sA[mrow * APITCH + kb * 16 + quad * 4];
        af[kb] = fu.s;
    }
    __syncthreads();
    // GEMM1: f_new = f + agg@Wo -> write f (fp32) + pack f_new into sA (bf16)
    for (int ct = 0; ct < 8; ct++) {
        f32x4 acc = {0.f, 0.f, 0.f, 0.f};
        #pragma unroll
        for (int kb = 0; kb < 4; kb++) {
            FragU bu;
            bu.u = *(const uint4*)&Bo[(size_t)((ct * 16 + kb * 4 + quad) * 16 + col) * 4];
            acc = __builtin_amdgcn_mfma_f32_16x16x32_bf16(af[kb], bu.s, acc, 0, 0, 0);
        }
        #pragma unroll
        for (int r = 0; r < 4; r++) {
            int node = wave * 16 + quad * 4 + r;
            int n = n0 + node;
            float fx = 0.0f;
            if (n < N) {
                size_t ix = (size_t)n * F + ct * 16 + col;
                fx = f[ix] + acc[r];
                f[ix] = fx;
            }
            float other = __shfl_xor(fx, 1, 64);
            if (!(lane & 1)) sA[node * APITCH + ct * 8 + (col >> 1)] = pk_bf2(fx, other);
        }
    }
    __syncthreads();
    s16x8 a2[4];
    #pragma unroll
    for (int kb = 0; kb < 4; kb++) {
        FragU fu;
        fu.u = *(const uint4*)&sA[mrow * APITCH + kb * 16 + quad * 4];
        a2[kb] = fu.s;
    }
    // GEMM2a: q = f_new @ Wq2 (fp32)
    for (int ct = 0; ct < 8; ct++) {
        f32x4 acc = {0.f, 0.f, 0.f, 0.f};
        #pragma unroll
        for (int kb = 0; kb < 4; kb++) {
            FragU bu;
            bu.u = *(const uint4*)&Bq2[(size_t)((ct * 16 + kb * 4 + quad) * 16 + col) * 4];
            acc = __builtin_amdgcn_mfma_f32_16x16x32_bf16(a2[kb], bu.s, acc, 0, 0, 0);
        }
        #pragma unroll
        for (int r = 0; r < 4; r++) {
            int n = n0 + wave * 16 + quad * 4 + r;
            if (n < N) qout[(size_t)n * F + ct * 16 + col] = acc[r];
        }
    }
    // GEMM2b: k2 = f_new @ Wk2 (bf16 packed)
    for (int ct = 0; ct < 8; ct++) {
        f32x4 acc = {0.f, 0.f, 0.f, 0.f};
        #pragma unroll
        for (int kb = 0; kb < 4; kb++) {
            FragU bu;
            bu.u = *(const uint4*)&Bk2[(size_t)((ct * 16 + kb * 4 + quad) * 16 + col) * 4];
            acc = __builtin_amdgcn_mfma_f32_16x16x32_bf16(a2[kb], bu.s, acc, 0, 0, 0);
        }
        #pragma unroll
        for (int r = 0; r < 4; r++) {
            float other = __shfl_xor(acc[r], 1, 64);
            if (!(lane & 1)) {
                int n = n0 + wave * 16 + quad * 4 + r;
                if (n < N) k16p[(size_t)n * 64 + ct * 8 + (col >> 1)] = pk_bf2(acc[r], other);
            }
        }
    }
}

// ---------------------------------------------------------------------------
// Per-edge alpha (q pre-scaled). Table row base scalarized; DPP reduce.
// ---------------------------------------------------------------------------
__device__ __forceinline__ float edge_alpha(
    int lane, f32x2 qq, f32x2 wd0, f32x2 wd1, f32x2 wd2, f32x2 wd3,
    const uint2* __restrict__ tab2, float rr, float4 dd, unsigned int ku)
{
    float u = rr * ((float)(TAB_N - 1) / RMAX);
    int i0 = (int)u;
    i0 = (i0 > TAB_N - 2) ? (TAB_N - 2) : i0;
    float fr = u - (float)i0;
    int i0s = __builtin_amdgcn_readfirstlane(i0);
    uint2 tp = (tab2 + (size_t)i0s * 64)[lane];
    f32x2 a = up2(tp.x), b = up2(tp.y);
    f32x2 fr2 = {fr, fr};
    f32x2 w = a + fr2 * (b - a);
    f32x2 d0 = {dd.x, dd.x}, d1 = {dd.y, dd.y}, d2 = {dd.z, dd.z}, d3 = {dd.w, dd.w};
    w = w + d0 * wd0 + d1 * wd1 + d2 * wd2 + d3 * wd3;
    f32x2 p2 = qq * w * up2(ku);
    return red16_dpp(p2.x + p2.y);
}

// ---------------------------------------------------------------------------
// Node-centric fused edge pass; packed scalar edge stream (edata).
// mode 0: 4-way unroll -> outbuf[n,128] (may alias qbuf: own row only)
// mode 1: 4 edges/iter lane-group Y -> dEv[n,16]
// ---------------------------------------------------------------------------
__global__ __launch_bounds__(256) void edge_pass_node_kernel(
    const int* __restrict__ off, const float4* __restrict__ edata,
    const float* __restrict__ Yp,
    const float* __restrict__ qbuf,
    const uint2* __restrict__ kv16, const unsigned int* __restrict__ k16p,
    const uint2* __restrict__ tab2, const float* __restrict__ Wdeg_t,
    float* __restrict__ outbuf, int N, int mode)
{
    int wave = threadIdx.x >> 6;
    int lane = threadIdx.x & 63;
    int n = blockIdx.x * 4 + wave;
    if (n >= N) return;

    const float2* wdp = (const float2*)Wdeg_t;
    float2 w0f = wdp[lane], w1f = wdp[64 + lane], w2f = wdp[128 + lane], w3f = wdp[192 + lane];
    f32x2 wd0 = {w0f.x, w0f.y}, wd1 = {w1f.x, w1f.y};
    f32x2 wd2 = {w2f.x, w2f.y}, wd3 = {w3f.x, w3f.y};

    int e0 = __builtin_amdgcn_readfirstlane(off[n]);
    int e1 = __builtin_amdgcn_readfirstlane(off[n + 1]);
    float2 qf = ((const float2*)qbuf)[(size_t)n * 64 + lane];
    const float QS = RSQRT_DH * INV_AVG;
    f32x2 qq = {qf.x * QS, qf.y * QS};
    f32x2 acc2 = {0.f, 0.f};
    float devacc = 0.0f;

    int ei = e0;
    if (mode == 0) {
        for (; ei + 3 < e1; ei += 4) {
            float4 hA = edata[2 * ei],     dA = edata[2 * ei + 1];
            float4 hB = edata[2 * ei + 2], dB = edata[2 * ei + 3];
            float4 hC = edata[2 * ei + 4], dC = edata[2 * ei + 5];
            float4 hD = edata[2 * ei + 6], dD = edata[2 * ei + 7];
            int sA = __float_as_int(hA.x), sB = __float_as_int(hB.x);
            int sC = __float_as_int(hC.x), sD = __float_as_int(hD.x);
            uint2 kvA = kv16[(size_t)sA * 64 + lane];
            uint2 kvB = kv16[(size_t)sB * 64 + lane];
            uint2 kvC = kv16[(size_t)sC * 64 + lane];
            uint2 kvD = kv16[(size_t)sD * 64 + lane];
            float alA = hA.z * edge_alpha(lane, qq, wd0, wd1, wd2, wd3, tab2, hA.y, dA, kvA.x);
            float alB = hB.z * edge_alpha(lane, qq, wd0, wd1, wd2, wd3, tab2, hB.y, dB, kvB.x);
            float alC = hC.z * edge_alpha(lane, qq, wd0, wd1, wd2, wd3, tab2, hC.y, dC, kvC.x);
            float alD = hD.z * edge_alpha(lane, qq, wd0, wd1, wd2, wd3, tab2, hD.y, dD, kvD.x);
            f32x2 vA = {alA, alA}, vB = {alB, alB}, vC = {alC, alC}, vD = {alD, alD};
            acc2 = acc2 + vA * up2(kvA.y) + vB * up2(kvB.y)
                        + vC * up2(kvC.y) + vD * up2(kvD.y);
        }
        for (; ei < e1; ei++) {
            float4 hA = edata[2 * ei], dA = edata[2 * ei + 1];
            int sA = __float_as_int(hA.x);
            uint2 kvA = kv16[(size_t)sA * 64 + lane];
            float alA = hA.z * edge_alpha(lane, qq, wd0, wd1, wd2, wd3, tab2, hA.y, dA, kvA.x);
            f32x2 vA = {alA, alA};
            acc2 = acc2 + vA * up2(kvA.y);
        }
        ((float2*)outbuf)[(size_t)n * 64 + lane] = make_float2(acc2.x, acc2.y);
    } else {
        int c = lane & 15;
        int g = lane >> 4;
        int ssel = ((c == 0) ? 0 : (c < 4) ? 16 : (c < 9) ? 32 : 48) + c;
        for (; ei + 3 < e1; ei += 4) {
            float4 hA = edata[2 * ei],     dA = edata[2 * ei + 1];
            float4 hB = edata[2 * ei + 2], dB = edata[2 * ei + 3];
            float4 hC = edata[2 * ei + 4], dC = edata[2 * ei + 5];
            float4 hD = edata[2 * ei + 6], dD = edata[2 * ei + 7];
            int sA = __float_as_int(hA.x), sB = __float_as_int(hB.x);
            int sC = __float_as_int(hC.x), sD = __float_as_int(hD.x);
            unsigned int kA = k16p[(size_t)sA * 64 + lane];
            unsigned int kB = k16p[(size_t)sB * 64 + lane];
            unsigned int kC = k16p[(size_t)sC * 64 + lane];
            unsigned int kD = k16p[(size_t)sD * 64 + lane];
            float alA = hA.z * edge_alpha(lane, qq, wd0, wd1, wd2, wd3, tab2, hA.y, dA, kA);
            float alB = hB.z * edge_alpha(lane, qq, wd0, wd1, wd2, wd3, tab2, hB.y, dB, kB);
            float alC = hC.z * edge_alpha(lane, qq, wd0, wd1, wd2, wd3, tab2, hC.y, dC, kC);
            float alD = hD.z * edge_alpha(lane, qq, wd0, wd1, wd2, wd3, tab2, hD.y, dD, kD);
            float adA = __shfl(alA, ssel);
            float adB = __shfl(alB, ssel);
            float adC = __shfl(alC, ssel);
            float adD = __shfl(alD, ssel);
            float ad = (g == 0) ? adA : (g == 1) ? adB : (g == 2) ? adC : adD;
            devacc += ad * Yp[(size_t)(ei + g) * 16 + c];
        }
        for (; ei < e1; ei++) {
            float4 hA = edata[2 * ei], dA = edata[2 * ei + 1];
            int sA = __float_as_int(hA.x);
            unsigned int kA = k16p[(size_t)sA * 64 + lane];
            float alA = hA.z * edge_alpha(lane, qq, wd0, wd1, wd2, wd3, tab2, hA.y, dA, kA);
            float adA = __shfl(alA, ssel);
            if (g == 0) devacc += adA * Yp[(size_t)ei * 16 + c];
        }
        devacc += __shfl_xor(devacc, 16, 64);
        devacc += __shfl_xor(devacc, 32, 64);
        if (lane < 16) outbuf[n * 16 + lane] = devacc;
    }
}

// ---------------------------------------------------------------------------
// Mega-fused exchange: exchange block + next-t qkv GEMMs (or readout if last).
// ---------------------------------------------------------------------------
__global__ __launch_bounds__(256) void exchange_fused_kernel(
    float* __restrict__ f, float* __restrict__ ev, const float* __restrict__ dEv,
    const unsigned int* __restrict__ B1, const float* __restrict__ Wex1,
    const float* __restrict__ bex1,
    const unsigned int* __restrict__ B2, const float* __restrict__ Wex2,
    const float* __restrict__ bex2,
    const unsigned int* __restrict__ Bq, const unsigned int* __restrict__ Bk,
    const unsigned int* __restrict__ Bv,
    float* __restrict__ qout, unsigned int* __restrict__ kvout,
    const float* __restrict__ bo1, const float* __restrict__ Wo2,
    const float* __restrict__ bo2, float* __restrict__ node_e,
    int last, int N)
{
    __shared__ unsigned int sA[64 * APITCH];  // f bf16 -> hid bf16 -> fnew bf16
    __shared__ float sev[64][17];
    __shared__ float sEvInv[64][4];
    __shared__ float sW1x[4][F];
    __shared__ float sW2x[F][4];
    __shared__ float sB1[F];
    __shared__ float sB2[F];
    __shared__ float sb2x[4];
    __shared__ float syb[64][4];
    __shared__ float sRB[F];
    __shared__ float sRW[F];

    int tid = threadIdx.x;
    int n0 = blockIdx.x * 64;
    #pragma unroll
    for (int rep = 0; rep < 16; rep++) {
        int idx = rep * 256 + tid;
        int node = idx >> 6, jj = idx & 63;
        int n = n0 + node;
        float2 v = (n < N) ? ((const float2*)f)[(size_t)n * 64 + jj] : make_float2(0.f, 0.f);
        sA[node * APITCH + jj] = pk_bf2(v.x, v.y);
    }
    for (int idx = tid; idx < 64 * 16; idx += 256) {
        int node = idx >> 4, c = idx & 15;
        int n = n0 + node;
        sev[node][c] = (n < N) ? (ev[(size_t)n * 16 + c] + dEv[(size_t)n * 16 + c]) : 0.0f;
    }
    for (int idx = tid; idx < 4 * F; idx += 256)
        sW1x[idx >> 7][idx & 127] = Wex1[(size_t)(128 + (idx >> 7)) * F + (idx & 127)];
    for (int idx = tid; idx < F * 4; idx += 256)
        sW2x[idx >> 2][idx & 3] = Wex2[(size_t)(idx >> 2) * (F + 4) + 128 + (idx & 3)];
    if (tid < F) sB1[tid] = bex1[tid];
    else sB2[tid - F] = bex2[tid - F];
    if (tid < 4) sb2x[tid] = bex2[F + tid];
    if (last) {
        if (tid < F) sRB[tid] = bo1[tid];
        else sRW[tid - F] = Wo2[tid - F];
    }
    __syncthreads();
    {
        int node = tid >> 2, d = tid & 3;
        int c0 = (d == 0) ? 0 : (d == 1) ? 1 : (d == 2) ? 4 : 9;
        int c1 = (d == 0) ? 1 : (d == 1) ? 4 : (d == 2) ? 9 : 16;
        float a = 0.0f;
        for (int c = c0; c < c1; c++) { float v = sev[node][c]; a += v * v; }
        sEvInv[node][d] = a;
    }
    int wave = tid >> 6, lane = tid & 63;
    int quad = lane >> 4, col = lane & 15;
    int mrow = wave * 16 + col;
    s16x8 af[4];
    #pragma unroll
    for (int kb = 0; kb < 4; kb++) {
        FragU fu;
        fu.u = *(const uint4*)&sA[mrow * APITCH + kb * 16 + quad * 4];
        af[kb] = fu.s;
    }
    __syncthreads();
    float evq[4][4];
    #pragma unroll
    for (int r = 0; r < 4; r++) {
        int node = wave * 16 + quad * 4 + r;
        #pragma unroll
        for (int d = 0; d < 4; d++) evq[r][d] = sEvInv[node][d];
    }
    // GEMM1: hid = silu(f@Wex1[:128] + ev_inv@Wex1[128:] + b1) -> sA
    for (int ct = 0; ct < 8; ct++) {
        f32x4 acc = {0.f, 0.f, 0.f, 0.f};
        #pragma unroll
        for (int kb = 0; kb < 4; kb++) {
            FragU bu;
            bu.u = *(const uint4*)&B1[(size_t)((ct * 16 + kb * 4 + quad) * 16 + col) * 4];
            acc = __builtin_amdgcn_mfma_f32_16x16x32_bf16(af[kb], bu.s, acc, 0, 0, 0);
        }
        int j = ct * 16 + col;
        float w0 = sW1x[0][j], w1 = sW1x[1][j], w2 = sW1x[2][j], w3 = sW1x[3][j];
        float bj = sB1[j];
        #pragma unroll
        for (int r = 0; r < 4; r++) {
            float x = acc[r] + bj + evq[r][0] * w0 + evq[r][1] * w1
                    + evq[r][2] * w2 + evq[r][3] * w3;
            float h = silu_f(x);
            float other = __shfl_xor(h, 1, 64);
            if (!(lane & 1)) {
                int node = wave * 16 + quad * 4 + r;
                sA[node * APITCH + ct * 8 + (col >> 1)] = pk_bf2(h, other);
            }
        }
    }
    __syncthreads();
    s16x8 a2[4];
    #pragma unroll
    for (int kb = 0; kb < 4; kb++) {
        FragU fu;
        fu.u = *(const uint4*)&sA[mrow * APITCH + kb * 16 + quad * 4];
        a2[kb] = fu.s;
    }
    // yb2 (cols 128..131) per (node, d) thread — reads sA(hid)
    {
        int node = tid >> 2, d = tid & 3;
        float a = sb2x[d];
        for (int dw = 0; dw < 64; dw++) {
            unsigned int u = sA[node * APITCH + dw];
            a += up_lo(u) * sW2x[2 * dw][d] + up_hi(u) * sW2x[2 * dw + 1][d];
        }
        syb[node][d] = a;
    }
    __syncthreads();   // all sA(hid) reads done before overwrite with fnew
    // GEMM2: fnew = f + hid@Wex2[:, :128] + b2 -> write f + pack fnew -> sA
    for (int ct = 0; ct < 8; ct++) {
        f32x4 acc = {0.f, 0.f, 0.f, 0.f};
        #pragma unroll
        for (int kb = 0; kb < 4; kb++) {
            FragU bu;
            bu.u = *(const uint4*)&B2[(size_t)((ct * 16 + kb * 4 + quad) * 16 + col) * 4];
            acc = __builtin_amdgcn_mfma_f32_16x16x32_bf16(a2[kb], bu.s, acc, 0, 0, 0);
        }
        int j = ct * 16 + col;
        float bj = sB2[j];
        #pragma unroll
        for (int r = 0; r < 4; r++) {
            int node = wave * 16 + quad * 4 + r;
            int n = n0 + node;
            float fx = 0.0f;
            if (n < N) {
                size_t ix = (size_t)n * F + j;
                fx = f[ix] + acc[r] + bj;
                f[ix] = fx;
            }
            float other = __shfl_xor(fx, 1, 64);
            if (!(lane & 1)) sA[node * APITCH + ct * 8 + (col >> 1)] = pk_bf2(fx, other);
        }
    }
    __syncthreads();
    // ev update
    for (int idx = tid; idx < 64 * 16; idx += 256) {
        int node = idx >> 4, c = idx & 15;
        int n = n0 + node;
        if (n < N) ev[(size_t)n * 16 + c] = sev[node][c] * (1.0f + syb[node][deg_of(c)]);
    }
    s16x8 a3[4];
    #pragma unroll
    for (int kb = 0; kb < 4; kb++) {
        FragU fu;
        fu.u = *(const uint4*)&sA[mrow * APITCH + kb * 16 + quad * 4];
        a3[kb] = fu.s;
    }
    if (!last) {
        // q = fnew @ Wq[t+1] (fp32)
        for (int ct = 0; ct < 8; ct++) {
            f32x4 acc = {0.f, 0.f, 0.f, 0.f};
            #pragma unroll
            for (int kb = 0; kb < 4; kb++) {
                FragU bu;
                bu.u = *(const uint4*)&Bq[(size_t)((ct * 16 + kb * 4 + quad) * 16 + col) * 4];
                acc = __builtin_amdgcn_mfma_f32_16x16x32_bf16(a3[kb], bu.s, acc, 0, 0, 0);
            }
            #pragma unroll
            for (int r = 0; r < 4; r++) {
                int n = n0 + wave * 16 + quad * 4 + r;
                if (n < N) qout[(size_t)n * F + ct * 16 + col] = acc[r];
            }
        }
        // k and v = fnew @ Wk/Wv (bf16 packed, interleaved kv)
        for (int m = 0; m < 2; m++) {
            const unsigned int* B = (m == 0) ? Bk : Bv;
            for (int ct = 0; ct < 8; ct++) {
                f32x4 acc = {0.f, 0.f, 0.f, 0.f};
                #pragma unroll
                for (int kb = 0; kb < 4; kb++) {
                    FragU bu;
                    bu.u = *(const uint4*)&B[(size_t)((ct * 16 + kb * 4 + quad) * 16 + col) * 4];
                    acc = __builtin_amdgcn_mfma_f32_16x16x32_bf16(a3[kb], bu.s, acc, 0, 0, 0);
                }
                #pragma unroll
                for (int r = 0; r < 4; r++) {
                    float other = __shfl_xor(acc[r], 1, 64);
                    if (!(lane & 1)) {
                        int n = n0 + wave * 16 + quad * 4 + r;
                        if (n < N) {
                            size_t base = (size_t)n * 64 + ct * 8 + (col >> 1);
                            kvout[base * 2 + m] = pk_bf2(acc[r], other);
                        }
                    }
                }
            }
        }
    } else {
        // readout: node_e = silu(fnew@Wo1 + bo1) . Wo2 + bo2
        float part[4] = {0.f, 0.f, 0.f, 0.f};
        for (int ct = 0; ct < 8; ct++) {
            f32x4 acc = {0.f, 0.f, 0.f, 0.f};
            #pragma unroll
            for (int kb = 0; kb < 4; kb++) {
                FragU bu;
                bu.u = *(const uint4*)&Bq[(size_t)((ct * 16 + kb * 4 + quad) * 16 + col) * 4];
                acc = __builtin_amdgcn_mfma_f32_16x16x32_bf16(a3[kb], bu.s, acc, 0, 0, 0);
            }
            int j = ct * 16 + col;
            float bj = sRB[j], wj = sRW[j];
            #pragma unroll
            for (int r = 0; r < 4; r++) part[r] += silu_f(acc[r] + bj) * wj;
        }
        #pragma unroll
        for (int r = 0; r < 4; r++) part[r] = red16_dpp(part[r]);
        if (col == 0) {
            #pragma unroll
            for (int r = 0; r < 4; r++) {
                int n = n0 + wave * 16 + quad * 4 + r;
                if (n < N) node_e[n] = part[r] + bo2[0];
            }
        }
    }
}

// ---------------------------------------------------------------------------
// energy[g] = sum_{batch[n]==g} node_e[n]
// ---------------------------------------------------------------------------
__global__ __launch_bounds__(256) void energy_reduce_kernel(
    const float* __restrict__ node_e, const int* __restrict__ batch,
    float* __restrict__ energy, int N)
{
    __shared__ float eacc[64];
    if (threadIdx.x < 64) eacc[threadIdx.x] = 0.0f;
    __syncthreads();
    for (int n = blockIdx.x * blockDim.x + threadIdx.x; n < N; n += gridDim.x * blockDim.x)
        atomicAdd(&eacc[batch[n]], node_e[n]);
    __syncthreads();
    if (threadIdx.x < 64) atomicAdd(&energy[threadIdx.x], eacc[threadIdx.x]);
}

// ---------------------------------------------------------------------------
extern "C" void kernel_launch(void* const* d_in, const int* in_sizes, int n_in,
                              void* d_out, int out_size, void* d_ws, size_t ws_size,
                              hipStream_t stream)
{
    const float* positions = (const float*)d_in[0];
    const int*   species   = (const int*)d_in[1];
    const int*   senders   = (const int*)d_in[2];
    const int*   receivers = (const int*)d_in[3];
    const int*   batch     = (const int*)d_in[4];
    const float* embed     = (const float*)d_in[5];
    const float* Wq    = (const float*)d_in[6];
    const float* Wk    = (const float*)d_in[7];
    const float* Wv    = (const float*)d_in[8];
    const float* Wo    = (const float*)d_in[9];
    const float* Wrbf1 = (const float*)d_in[10];
    const float* brbf1 = (const float*)d_in[11];
    const float* Wrbf2 = (const float*)d_in[12];
    const float* Wdeg  = (const float*)d_in[13];
    const float* Wq2   = (const float*)d_in[14];
    const float* Wk2   = (const float*)d_in[15];
    const float* Wex1  = (const float*)d_in[16];
    const float* bex1  = (const float*)d_in[17];
    const float* Wex2  = (const float*)d_in[18];
    const float* bex2  = (const float*)d_in[19];
    const float* Wo1   = (const float*)d_in[20];
    const float* bo1   = (const float*)d_in[21];
    const float* Wo2   = (const float*)d_in[22];
    const float* bo2   = (const float*)d_in[23];

    int N = in_sizes[0] / 3;
    int E = in_sizes[2];

    // ---- workspace layout (~115 MB) ----
    float* ws     = (float*)d_ws;
    float* Yp     = ws;  ws += (size_t)E * 16;        // CSR-ordered Y (30.7 MB)
    float4* edata = (float4*)ws; ws += (size_t)E * 8; // packed edge stream (15.4 MB)
    float* f      = ws;  ws += (size_t)N * F;
    float* evb    = ws;  ws += (size_t)N * 16;
    float* dEv    = ws;  ws += (size_t)N * 16;
    float* q      = ws;  ws += (size_t)N * F;         // doubles as agg
    float* node_e = ws;  ws += (size_t)N;
    float* Cb     = ws;  ws += (size_t)E;             // C only (for ev0)
    uint2* tab2 = (uint2*)ws;  ws += (size_t)TINTER * TAB_N * 64 * 2;
    uint2* kv16 = (uint2*)ws;  ws += (size_t)N * 64 * 2;
    unsigned int* k16p = (unsigned int*)ws;  ws += (size_t)N * 64;
    int* sp    = (int*)ws;  ws += E;
    int* rcvp  = (int*)ws;  ws += E;
    int* cnt   = (int*)ws;  ws += N;
    int* off   = (int*)ws;  ws += N + 1;
    int* cur   = (int*)ws;  ws += N;
    int* elist = (int*)ws;  ws += E;
    int* bsum  = (int*)ws;  ws += 1024;
    int* boff  = (int*)ws;  ws += 1024;
    unsigned int* Wpk  = (unsigned int*)ws;  ws += 18 * 8192;
    unsigned int* Wpk2 = (unsigned int*)ws;  ws += 7 * 8192;

    // ---- CSR build (parallel scan) ----
    int nb = (N + SCB - 1) / SCB;
    hipMemsetAsync(cnt, 0, (size_t)N * sizeof(int), stream);
    count_kernel<<<(E + 255) / 256, 256, 0, stream>>>(receivers, cnt, E);
    scan_part_kernel<<<nb, SCB, 0, stream>>>(cnt, off, bsum, N);
    scan_mid_kernel<<<1, 1024, 0, stream>>>(bsum, boff, off, N, nb);
    scan_add_kernel<<<(N + 255) / 256, 256, 0, stream>>>(off, cur, boff, N);
    scatter_kernel<<<(E + 255) / 256, 256, 0, stream>>>(receivers, cur, elist, E);

    // ---- geometry + packing + table ----
    edge_geom_csr_kernel<<<(E + 255) / 256, 256, 0, stream>>>(elist, positions, senders,
                                                              receivers, sp, rcvp, Cb,
                                                              edata, Yp, E);
    pack_w_kernel<<<(18 * 8192 + 255) / 256, 256, 0, stream>>>(Wq, Wk, Wv, Wo, Wq2, Wk2, Wpk);
    pack_ex_kernel<<<(7 * 8192 + 255) / 256, 256, 0, stream>>>(Wex1, Wex2, Wo1, Wpk2);
    build_table_kernel<<<dim3(TAB_N / 4, TINTER), 256, 0, stream>>>(Wrbf1, brbf1, Wrbf2,
                                                                    (unsigned int*)tab2);
    ev0_kernel<<<(N + 15) / 16, 256, 0, stream>>>(off, Yp, Cb, evb, N);
    embed_kernel<<<N, F, 0, stream>>>(species, embed, f, N);

    int nmb = (N + 63) / 64;
    int npb = (N + 3) / 4;
    int edb = (E + 255) / 256;
    // t=0 qkv
    node_gemm_mfma_kernel<<<nmb, 256, 0, stream>>>(f, Wpk + 0 * 8192, Wpk + 3 * 8192,
                                                   Wpk + 6 * 8192, q, (unsigned int*)kv16, N);
    for (int t = 0; t < TINTER; t++) {
        const unsigned int* Wpk_o  = Wpk + (size_t)(3 * 3 + t) * 8192;
        const unsigned int* Wpk_q2 = Wpk + (size_t)(4 * 3 + t) * 8192;
        const unsigned int* Wpk_k2 = Wpk + (size_t)(5 * 3 + t) * 8192;
        const uint2* tab_t = tab2 + (size_t)t * TAB_N * 64;
        const float* Wdeg_t = Wdeg + (size_t)t * 4 * F;
        int last = (t == TINTER - 1);
        const unsigned int* Bq_n = last ? (Wpk2 + (size_t)6 * 8192)
                                        : (Wpk + (size_t)(0 * 3 + t + 1) * 8192);
        const unsigned int* Bk_n = Wpk + (size_t)(1 * 3 + (last ? t : t + 1)) * 8192;
        const unsigned int* Bv_n = Wpk + (size_t)(2 * 3 + (last ? t : t + 1)) * 8192;

        dd_kernel<<<edb, 256, 0, stream>>>(sp, rcvp, evb, edata, E);
        edge_pass_node_kernel<<<npb, 256, 0, stream>>>(off, edata, Yp,
            q, kv16, nullptr, tab_t, Wdeg_t, q /*agg: aliases qbuf, own-row only*/, N, 0);
        fused_o_qk_kernel<<<nmb, 256, 0, stream>>>(q, Wpk_o, Wpk_q2, Wpk_k2,
                                                   f, q, k16p, N);
        edge_pass_node_kernel<<<npb, 256, 0, stream>>>(off, edata, Yp,
            q, nullptr, k16p, tab_t, Wdeg_t, dEv, N, 1);
        exchange_fused_kernel<<<nmb, 256, 0, stream>>>(f, evb, dEv,
            Wpk2 + (size_t)t * 8192, Wex1 + (size_t)t * (F + 4) * F, bex1 + (size_t)t * F,
            Wpk2 + (size_t)(3 + t) * 8192, Wex2 + (size_t)t * F * (F + 4),
            bex2 + (size_t)t * (F + 4),
            Bq_n, Bk_n, Bv_n, q, (unsigned int*)kv16,
            bo1, Wo2, bo2, node_e, last, N);
    }
    hipMemsetAsync(d_out, 0, (size_t)out_size * sizeof(float), stream);
    energy_reduce_kernel<<<16, 256, 0, stream>>>(node_e, batch, (float*)d_out, N);
}